// Round 9
// baseline (585.426 us; speedup 1.0000x reference)
//
#include <hip/hip_runtime.h>
#include <cmath>
#include <complex>
#include <cstdio>
#include <cstring>
#include <algorithm>

#define E_EDGES 32768
#define NNODES  2048
#define VN_E    32      // edges per vn_k block

// ============================ host-side CG tables ============================
namespace cgt {

static double fct(int n){
  static const double f[13] = {1.,1.,2.,6.,24.,120.,720.,5040.,40320.,362880.,
                               3628800.,39916800.,479001600.};
  return f[n];
}

static double cg(int j1,int m1,int j2,int m2,int j3,int m3){
  if (m1+m2 != m3) return 0.0;
  double pre = std::sqrt((2*j3+1)*fct(j1+j2-j3)*fct(j1-j2+j3)*fct(-j1+j2+j3)/fct(j1+j2+j3+1));
  pre *= std::sqrt(fct(j3+m3)*fct(j3-m3)*fct(j1-m1)*fct(j1+m1)*fct(j2-m2)*fct(j2+m2));
  int kmin = 0;
  if (j2-j3-m1 > kmin) kmin = j2-j3-m1;
  if (j1-j3+m2 > kmin) kmin = j1-j3+m2;
  int kmax = j1+j2-j3;
  if (j1-m1 < kmax) kmax = j1-m1;
  if (j2+m2 < kmax) kmax = j2+m2;
  double s = 0.0;
  for (int k=kmin;k<=kmax;k++){
    double d = fct(k)*fct(j1+j2-j3-k)*fct(j1-m1-k)*fct(j2+m2-k)*fct(j3-j2+m1+k)*fct(j3-j1-m2+k);
    s += ((k&1)? -1.0:1.0)/d;
  }
  return pre*s;
}

typedef std::complex<double> cd;

static void umat(int l, cd U[7][7]){
  for (int a=0;a<7;a++) for (int b=0;b<7;b++) U[a][b]=cd(0,0);
  U[l][l] = cd(1,0);
  double s2 = 1.0/std::sqrt(2.0);
  for (int m=1;m<=l;m++){
    double sg = (m&1)? -1.0 : 1.0;
    U[l+m][l-m] = cd(s2,0);
    U[l+m][l+m] = cd(sg*s2,0);
    U[l-m][l-m] = cd(0, s2);
    U[l-m][l+m] = cd(0, -sg*s2);
  }
}

static bool realCoupling(int l1,int l2,int l3, double T[7][7][7]){
  cd U1[7][7],U2[7][7],U3[7][7];
  umat(l1,U1); umat(l2,U2); umat(l3,U3);
  int n1=2*l1+1, n2=2*l2+1, n3=2*l3+1;
  double Cg[7][7][7];
  for (int m=0;m<n1;m++) for(int n=0;n<n2;n++) for(int k=0;k<n3;k++)
    Cg[m][n][k] = cg(l1,m-l1,l2,n-l2,l3,k-l3);
  double Tr[7][7][7], Ti[7][7][7];
  double nr=0, ni=0;
  for (int a=0;a<n1;a++) for(int b=0;b<n2;b++) for(int c=0;c<n3;c++){
    cd s(0,0);
    for (int m=0;m<n1;m++){
      if (U1[a][m]==cd(0,0)) continue;
      for (int n=0;n<n2;n++){
        if (U2[b][n]==cd(0,0)) continue;
        for (int k=0;k<n3;k++){
          double cgv = Cg[m][n][k];
          if (cgv==0.0) continue;
          s += U1[a][m]*U2[b][n]*std::conj(U3[c][k])*cgv;
        }
      }
    }
    Tr[a][b][c]=s.real(); Ti[a][b][c]=s.imag();
    nr += s.real()*s.real(); ni += s.imag()*s.imag();
  }
  bool useR = (nr >= ni);
  double nn = std::sqrt(useR? nr : ni);
  if (nn < 1e-8) return false;
  for (int a=0;a<n1;a++)for(int b=0;b<n2;b++)for(int c=0;c<n3;c++)
    T[a][b][c] = (useR? Tr[a][b][c] : Ti[a][b][c])/nn;
  return true;
}

struct Tables {
  float val[4096];
  int   ij[4096];        // (a_abs) | (b_abs<<8), entries grouped by (path, c)
  int   pmeta[40*4];     // per SLOT: tpOff(orig layout), entStart, entCount, kdim
  int   ccnt[40*8];      // per SLOT: entry count for each c (kd <= 7)
  int   l3base[4];
  int   l3np[4];
  int   npaths;
  int   nent;
  int   tptot;
  // --- pair/TD tables for the fused Vn GEMM (l>=1 slots only) ---
  int   pairs[256];      // raw (a_abs) | (b_abs<<8)
  float TD[256*30*8];    // TD[pair][slot-4][kloc] = T*sqrt(2l3+1)
  int   sl_origc[40];    // per slot: original c-base (origIdxInL*16) for Wv rows
  int   npairs;          // padded even
};

struct PathTmp {
  int l1,l2,l3, tpoff, kd;
  int ec;                 // total nonzero entries
  double T[7][7][7];
};

static void build(Tables& tb){
  static PathTmp paths[40];
  int np = 0, tpoff = 0;
  int l3start[5];
  for (int l3=0;l3<=3;l3++){
    tb.l3base[l3] = tpoff;
    l3start[l3] = np;
    int kd = 2*l3+1;
    for (int l1=0;l1<=3;l1++) for (int l2=0;l2<=3;l2++){
      int lo = (l1>l2)? l1-l2 : l2-l1;
      int hi = std::min(l1+l2,3);
      if (l3 < lo || l3 > hi) continue;
      PathTmp& pt = paths[np];
      if (!realCoupling(l1,l2,l3,pt.T)) continue;
      pt.l1=l1; pt.l2=l2; pt.l3=l3; pt.kd=kd; pt.tpoff=tpoff;
      double scale = std::sqrt((double)kd);
      int cnt = 0;
      for (int a=0;a<2*l1+1;a++)for(int b=0;b<2*l2+1;b++)for(int c=0;c<kd;c++)
        if (std::fabs(pt.T[a][b][c]*scale) > 1e-7) cnt++;
      pt.ec = cnt;
      tpoff += 16*kd;
      np++;
    }
  }
  l3start[4] = np;
  for (int l3=0;l3<=3;l3++) tb.l3np[l3] = l3start[l3+1]-l3start[l3];
  static int order[40];
  for (int i=0;i<np;i++) order[i]=i;
  for (int l3=0;l3<=3;l3++)
    std::sort(order+l3start[l3], order+l3start[l3+1],
              [&](int a,int b){ return paths[a].ec > paths[b].ec; });
  // emit entries grouped by (slot, c); build pair map + TD for l>=1 slots
  std::memset(tb.TD, 0, sizeof(tb.TD));
  std::memset(tb.pairs, 0, sizeof(tb.pairs));
  static int pmap[16][16];
  for (int i=0;i<16;i++) for (int j=0;j<16;j++) pmap[i][j] = -1;
  int npr = 0;
  int ep = 0;
  for (int slot=0; slot<np; slot++){
    const PathTmp& pt = paths[order[slot]];
    double scale = std::sqrt((double)pt.kd);
    int s1 = pt.l1*pt.l1, s2 = pt.l2*pt.l2;
    tb.pmeta[slot*4+0] = pt.tpoff;
    tb.pmeta[slot*4+1] = ep;
    tb.sl_origc[slot] = ((pt.tpoff - tb.l3base[pt.l3]) / (16*pt.kd)) * 16;
    int tot = 0;
    for (int c=0;c<pt.kd;c++){
      int cnt = 0;
      for (int a=0;a<2*pt.l1+1;a++)for(int b=0;b<2*pt.l2+1;b++){
        double v = pt.T[a][b][c]*scale;
        if (std::fabs(v) > 1e-7){
          tb.val[ep] = (float)v;
          tb.ij[ep]  = (s1+a) | ((s2+b)<<8);
          ep++; cnt++;
          if (pt.l3 >= 1){
            int aa = s1+a, bb = s2+b;
            int pi = pmap[aa][bb];
            if (pi < 0){ pi = npr; pmap[aa][bb] = pi;
                         tb.pairs[npr] = aa | (bb<<8); npr++; }
            tb.TD[(pi*30 + (slot-4))*8 + c] = (float)v;
          }
        }
      }
      tb.ccnt[slot*8+c] = cnt;
      tot += cnt;
    }
    for (int c=pt.kd;c<8;c++) tb.ccnt[slot*8+c]=0;
    tb.pmeta[slot*4+2] = tot;
    tb.pmeta[slot*4+3] = pt.kd;
  }
  if (npr & 1){ tb.pairs[npr] = 0; npr++; }   // pad to even -> Kdim % 32 == 0
  tb.npairs = npr;
  tb.npaths = np; tb.nent = ep; tb.tptot = tpoff;
}

} // namespace cgt

// ============================ device kernels ============================
// LAYOUT CONVENTION: node/V/Vn rows are [a][m] (spherical-major,
// element (m,a) at a*16+m).

enum GFlags { F_NONE=0, F_SILU=1, F_ENV=2, F_RESID=4 };

typedef _Float16 half8 __attribute__((ext_vector_type(8)));
typedef _Float16 half4 __attribute__((ext_vector_type(4)));
typedef __attribute__((ext_vector_type(4))) float f32x4;

__device__ inline unsigned short f2h(float f){
  union { _Float16 h; unsigned short u; } x;
  x.h = (_Float16)f;           // v_cvt_f16_f32, RNE
  return x.u;
}
__device__ inline float h2f(unsigned short u){
  union { _Float16 h; unsigned short u; } x; x.u = u;
  return (float)x.h;
}

// XOR swizzle for 64B-row LDS tiles of 16-bit data: permutes 16B units so
// ds_read_b128 fragment loads are ~conflict-free. kh in ushort units (mult of 4).
__device__ inline int swz(int row, int kh){
  int b = row*64 + kh*2;
  return b ^ (((row >> 1) & 3) << 4);
}

// ---- fp16 MFMA GEMM: C[M,N] = post( A[M,K] @ W[K,N] / sqrt(K) ), A fp32 ----
template<int FLAGS>
__global__ __launch_bounds__(256) void mgemm_k(
    const float* __restrict__ A1, const float* __restrict__ A2,
    int K1, int K, const unsigned short* __restrict__ Wt, int N,
    float* Cout, const float* __restrict__ env,
    const float* __restrict__ alphap, const float* Xres)
{
  __shared__ unsigned short AsB[128*32];
  __shared__ unsigned short BsB[128*32];
  const int tid  = threadIdx.x;
  const int wave = tid >> 6, lane = tid & 63;
  const int bm = blockIdx.x*128, bn = blockIdx.y*128;
  const int wr = (wave >> 1)*64, wc = (wave & 1)*64;
  const int K2 = K - K1;
  f32x4 acc[4][4] = {};

  const int sr  = tid >> 3;          // staging row 0..31 (A)
  const int skq = (tid & 7) * 4;     // staging k 0..28 step 4 (A)
  const int bn_ = tid >> 1;          // staging n 0..127 (B)
  const int bkh = (tid & 1) * 16;    // staging k half (B)

  for (int k0 = 0; k0 < K; k0 += 32) {
#pragma unroll
    for (int q = 0; q < 4; q++) {
      int row = q*32 + sr;
      int grow = bm + row;
      int kk = k0 + skq;
      float4 f4 = (kk < K1) ? *(const float4*)(A1 + (size_t)grow*K1 + kk)
                            : *(const float4*)(A2 + (size_t)grow*K2 + (kk - K1));
      ushort4 u;
      u.x = f2h(f4.x); u.y = f2h(f4.y); u.z = f2h(f4.z); u.w = f2h(f4.w);
      *(ushort4*)((char*)AsB + swz(row, skq)) = u;
    }
    {
      const unsigned short* s = Wt + (size_t)(bn + bn_)*K + k0 + bkh;
#pragma unroll
      for (int q = 0; q < 4; q++) {
        ushort4 u = *(const ushort4*)(s + q*4);
        *(ushort4*)((char*)BsB + swz(bn_, bkh + q*4)) = u;
      }
    }
    __syncthreads();
    const int fr = lane & 15, fk = (lane >> 4) * 8;
    half8 af[4], bf[4];
#pragma unroll
    for (int i = 0; i < 4; i++)
      af[i] = *(half8*)((char*)AsB + swz(wr + i*16 + fr, fk));
#pragma unroll
    for (int j = 0; j < 4; j++)
      bf[j] = *(half8*)((char*)BsB + swz(wc + j*16 + fr, fk));
#pragma unroll
    for (int i = 0; i < 4; i++)
#pragma unroll
      for (int j = 0; j < 4; j++)
        acc[i][j] = __builtin_amdgcn_mfma_f32_16x16x32_f16(af[i], bf[j], acc[i][j], 0, 0, 0);
    __syncthreads();
  }

  const float rscale = 1.f/sqrtf((float)K);
  float a2 = 0.f, inv1a2 = 1.f;
  if (FLAGS & F_RESID) { float al = alphap[0]; a2 = al*al; inv1a2 = 1.f/(1.f+a2); }
#pragma unroll
  for (int i = 0; i < 4; i++) {
#pragma unroll
    for (int r = 0; r < 4; r++) {
      int row = bm + wr + i*16 + ((lane >> 4) << 2) + r;
      float ev = (FLAGS & F_ENV) ? env[row] : 1.f;
#pragma unroll
      for (int j = 0; j < 4; j++) {
        int col = bn + wc + j*16 + (lane & 15);
        float v = acc[i][j][r]*rscale;
        if (FLAGS & F_SILU) v = v/(1.f+__expf(-v));
        if (FLAGS & F_ENV)  v *= ev;
        if (FLAGS & F_RESID) v = (Xres[(size_t)row*N+col] + a2*v)*inv1a2;
        Cout[(size_t)row*N+col] = v;
      }
    }
  }
}

// ---- fused Vn kernel v4: barrier-free + A-side software pipeline ----
// Vn[e, kabs*16+d] = sum_k X[e,k]*G[k,col]; X[(pair,m)] = (eps*node[s])(m,a)*V[e](m,b).
// R8 fix (still latency-bound at 143us, 9x above throughput floors): the
// per-iteration chain {Ps read -> addr -> ds_read a -> mul -> MFMA} was
// serial. Now BOTH A-side (ds_read) and G-side (global) are prefetched one
// slab ahead; iteration sl's MFMAs depend only on loads issued in sl-1.
__global__ __launch_bounds__(256) void vn_k(
    const float* __restrict__ node, const float* __restrict__ V,
    const int* __restrict__ senders, const float* __restrict__ varepsp,
    const int* __restrict__ pairsG, const unsigned short* __restrict__ Gtt,
    float* __restrict__ Vn, int Kdim)
{
  __shared__ unsigned short Ab[VN_E*264];   // fp16 eps*node rows, pad 264
  __shared__ unsigned short Bb[VN_E*264];   // fp16 V rows
  __shared__ int Ps[256];
  const int tid = threadIdx.x;
  const int e0 = blockIdx.x * VN_E;
  float ve = varepsp[0];
  float eps = rsqrtf(1.f + ve*ve);
  Ps[tid] = pairsG[tid];
  {
    int row = tid >> 3;            // 0..31
    int seg = (tid & 7) * 32;      // 0..224
    int s = senders[e0 + row];
    const float* ap = node + ((size_t)s << 8) + seg;
    const float* bp = V + (((size_t)(e0 + row)) << 8) + seg;
    unsigned short* ad = Ab + row*264 + seg;
    unsigned short* bd = Bb + row*264 + seg;
#pragma unroll
    for (int q = 0; q < 8; q++) {
      float4 fa = *(const float4*)(ap + q*4);
      float4 fb = *(const float4*)(bp + q*4);
      *(unsigned*)(ad + q*4)     = (unsigned)f2h(fa.x*eps) | ((unsigned)f2h(fa.y*eps) << 16);
      *(unsigned*)(ad + q*4 + 2) = (unsigned)f2h(fa.z*eps) | ((unsigned)f2h(fa.w*eps) << 16);
      *(unsigned*)(bd + q*4)     = (unsigned)f2h(fb.x) | ((unsigned)f2h(fb.y) << 16);
      *(unsigned*)(bd + q*4 + 2) = (unsigned)f2h(fb.z) | ((unsigned)f2h(fb.w) << 16);
    }
  }
  __syncthreads();
  const int wave = tid >> 6, lane = tid & 63;
  const int wc = wave * 64;              // 64 output cols per wave
  const int fr = lane & 15, fk = (lane >> 4) * 8;
  const int pairSel = fk >> 4;           // 0 or 1 (which pair of the slab)
  const int moff = fk & 15;              // 0 or 8 (m offset within pair)
  const int nslab = Kdim >> 5;
  f32x4 acc[2][4] = {};                  // [row group 0/16][j]

  const unsigned short* Ar0 = Ab + fr*264;
  const unsigned short* Br0 = Bb + fr*264;
  const unsigned short* Ar1 = Ab + (16 + fr)*264;
  const unsigned short* Br1 = Bb + (16 + fr)*264;

  // G fragment base for this lane
  const unsigned short* gp = Gtt + ((size_t)(wc + fr)) * 32 + fk;
  // ---- prologue: loads for slab 0 ----
  half8 b0 = *(const half8*)(gp);
  half8 b1 = *(const half8*)(gp + 512);
  half8 b2 = *(const half8*)(gp + 1024);
  half8 b3 = *(const half8*)(gp + 1536);
  int p0 = Ps[pairSel];
  int aoff = ((p0 & 255) << 4) + moff;
  int boff = (((p0 >> 8) & 255) << 4) + moff;
  half8 rA0 = *(const half8*)(Ar0 + aoff);
  half8 rB0 = *(const half8*)(Br0 + boff);
  half8 rA1 = *(const half8*)(Ar1 + aoff);
  half8 rB1 = *(const half8*)(Br1 + boff);

  for (int sl = 0; sl < nslab; sl++) {
    // current A-fragments from last iteration's loads
    half8 a0 = rA0 * rB0;
    half8 a1 = rA1 * rB1;
    // ---- prefetch slab+1 (A: ds_read, G: global) before any MFMA ----
    half8 n0, n1, n2, n3;
    if (sl + 1 < nslab) {
      int pn = Ps[2*(sl + 1) + pairSel];
      int aoffn = ((pn & 255) << 4) + moff;
      int boffn = (((pn >> 8) & 255) << 4) + moff;
      rA0 = *(const half8*)(Ar0 + aoffn);
      rB0 = *(const half8*)(Br0 + boffn);
      rA1 = *(const half8*)(Ar1 + aoffn);
      rB1 = *(const half8*)(Br1 + boffn);
      const unsigned short* gn = gp + (size_t)(sl + 1) * 8192;
      n0 = *(const half8*)(gn);
      n1 = *(const half8*)(gn + 512);
      n2 = *(const half8*)(gn + 1024);
      n3 = *(const half8*)(gn + 1536);
    } else { n0 = b0; n1 = b1; n2 = b2; n3 = b3; }
    acc[0][0] = __builtin_amdgcn_mfma_f32_16x16x32_f16(a0, b0, acc[0][0], 0, 0, 0);
    acc[1][0] = __builtin_amdgcn_mfma_f32_16x16x32_f16(a1, b0, acc[1][0], 0, 0, 0);
    acc[0][1] = __builtin_amdgcn_mfma_f32_16x16x32_f16(a0, b1, acc[0][1], 0, 0, 0);
    acc[1][1] = __builtin_amdgcn_mfma_f32_16x16x32_f16(a1, b1, acc[1][1], 0, 0, 0);
    acc[0][2] = __builtin_amdgcn_mfma_f32_16x16x32_f16(a0, b2, acc[0][2], 0, 0, 0);
    acc[1][2] = __builtin_amdgcn_mfma_f32_16x16x32_f16(a1, b2, acc[1][2], 0, 0, 0);
    acc[0][3] = __builtin_amdgcn_mfma_f32_16x16x32_f16(a0, b3, acc[0][3], 0, 0, 0);
    acc[1][3] = __builtin_amdgcn_mfma_f32_16x16x32_f16(a1, b3, acc[1][3], 0, 0, 0);
    b0 = n0; b1 = n1; b2 = n2; b3 = n3;
  }
  const int r4 = (lane >> 4) << 2;
#pragma unroll
  for (int rg = 0; rg < 2; rg++) {
#pragma unroll
    for (int j = 0; j < 4; j++) {
#pragma unroll
      for (int r = 0; r < 4; r++) {
        int row = e0 + rg*16 + r4 + r;
        int col = wc + j*16 + fr;
        Vn[(size_t)row*256 + col] = acc[rg][j][r];
      }
    }
  }
}

// ---- Gtt[slab][col][32] = coupling x Wv (fp16, tiled). col = kabs*16+d ----
__global__ void gbuild_k(const float* __restrict__ TD,
    const float* __restrict__ Wv1, const float* __restrict__ Wv2,
    const float* __restrict__ Wv3, const int* __restrict__ sl_origc,
    unsigned short* __restrict__ Gt, int Kdim, int npairs,
    int s1b, int s1e, int s2e, int s3e)
{
  int k = blockIdx.x*256 + threadIdx.x;
  if (k >= Kdim) return;
  int col = blockIdx.y;
  int pair = k >> 4, m = k & 15;
  int d = col & 15, kabs = col >> 4;     // transposed output convention
  float acc = 0.f;
  if (kabs > 0 && pair < npairs) {
    const float* Wv; int ss, se, kloc;
    if (kabs < 4)      { Wv = Wv1; ss = s1b; se = s1e; kloc = kabs - 1; }
    else if (kabs < 9) { Wv = Wv2; ss = s1e; se = s2e; kloc = kabs - 4; }
    else               { Wv = Wv3; ss = s2e; se = s3e; kloc = kabs - 9; }
    for (int slot = ss; slot < se; slot++)
      acc += TD[((pair*30) + (slot - 4))*8 + kloc] * Wv[(sl_origc[slot] + m)*16 + d];
    acc *= rsqrtf((float)(16*(se - ss)));
  }
  Gt[((size_t)((k >> 5)*256 + col))*32 + (k & 31)] = f2h(acc);
}

// ---- weight convert + transpose: Wt[n][k] = fp16(W[k][n]) ----
struct WDesc { const float* src; unsigned short* dst; int K; int lgN; };
struct WPack { WDesc d[9]; };
__global__ void wcvt_k(WPack p){
  WDesc d = p.d[blockIdx.y];
  int total = d.K << d.lgN;
  int gid = blockIdx.x*256 + threadIdx.x;
  if (gid >= total) return;
  int k = gid >> d.lgN, n = gid & ((1 << d.lgN) - 1);
  d.dst[(size_t)n*d.K + k] = f2h(d.src[gid]);
}

// Generic fp32 tiled GEMM (small two-body layers).
template<int FLAGS>
__global__ __launch_bounds__(256) void gemm_k(
    const float* __restrict__ A1, const float* __restrict__ A2,
    int K1, int K, const float* __restrict__ W, int N,
    float* Cout,
    const float* __restrict__ env, const float* __restrict__ alphap,
    const float* Xres)
{
  __shared__ float As[16][68];
  __shared__ float Ws[16][68];
  const int tid = threadIdx.x;
  const int bm = blockIdx.x * 64;
  const int bn = blockIdx.y * 64;
  const int tx = tid & 15, ty = tid >> 4;
  const int K2 = K - K1;
  float acc[4][4] = {};
  for (int k0 = 0; k0 < K; k0 += 16) {
#pragma unroll
    for (int i = 0; i < 4; i++) {
      int idx = tid + i*256;
      int m = idx >> 4, kk = idx & 15;
      int k = k0 + kk;
      float v = 0.f;
      if (k < K) {
        int row = bm + m;
        v = (k < K1) ? A1[(size_t)row*K1 + k] : A2[(size_t)row*K2 + (k-K1)];
      }
      As[kk][m] = v;
    }
#pragma unroll
    for (int i = 0; i < 4; i++) {
      int idx = tid + i*256;
      int n = idx & 63, kk = idx >> 6;
      int k = k0 + kk, col = bn + n;
      Ws[kk][n] = (k < K && col < N) ? W[(size_t)k*N + col] : 0.f;
    }
    __syncthreads();
#pragma unroll
    for (int kk = 0; kk < 16; kk++) {
      float a[4], b[4];
#pragma unroll
      for (int i=0;i<4;i++) a[i] = As[kk][ty*4+i];
#pragma unroll
      for (int j=0;j<4;j++) b[j] = Ws[kk][tx*4+j];
#pragma unroll
      for (int i=0;i<4;i++)
#pragma unroll
        for (int j=0;j<4;j++)
          acc[i][j] += a[i]*b[j];
    }
    __syncthreads();
  }
  const float rscale = 1.f/sqrtf((float)K);
  float a2 = 0.f, inv1a2 = 1.f;
  if (FLAGS & F_RESID) { float al = alphap[0]; a2 = al*al; inv1a2 = 1.f/(1.f+a2); }
#pragma unroll
  for (int i=0;i<4;i++) {
    int row = bm + ty*4 + i;
    float ev = (FLAGS & F_ENV) ? env[row] : 1.f;
#pragma unroll
    for (int j=0;j<4;j++) {
      int col = bn + tx*4 + j;
      if (col >= N) continue;
      float v = acc[i][j]*rscale;
      if (FLAGS & F_SILU) v = v/(1.f+__expf(-v));
      if (FLAGS & F_ENV)  v *= ev;
      if (FLAGS & F_RESID) v = (Xres[(size_t)row*N+col] + a2*v)*inv1a2;
      Cout[(size_t)row*N+col] = v;
    }
  }
}

// dense to 16 outputs, K=256 fixed, scale 1/16
__global__ __launch_bounds__(256) void dense16_k(const float* __restrict__ A,
    const float* __restrict__ W, float* __restrict__ C)
{
  __shared__ float As[16*256];
  const int r0 = blockIdx.x << 4;
  const int tid = threadIdx.x;
  for (int i = tid; i < 16*256; i += 256)
    As[i] = A[((size_t)r0<<8) + i];
  __syncthreads();
  const int r = tid >> 4, n = tid & 15;
  float acc = 0.f;
#pragma unroll 8
  for (int k = 0; k < 256; k++)
    acc += As[(r<<8)+k] * W[(k<<4)+n];
  C[((size_t)(r0+r)<<4)+n] = acc * 0.0625f;
}

__global__ void edge_init_k(const float* __restrict__ vectors, const int* __restrict__ senders,
    const int* __restrict__ receivers, const int* __restrict__ species,
    const float* __restrict__ emb, float* __restrict__ envb, float* __restrict__ Yb,
    float* __restrict__ x72)
{
  const int e = blockIdx.x*256 + threadIdx.x;
  float vx = vectors[e*3+0], vy = vectors[e*3+1], vz = vectors[e*3+2];
  float d = sqrtf(vx*vx+vy*vy+vz*vz);
  float dd = (d==0.f) ? 1.f : d;
  float invd = 1.f/dd;
  float x = vx*invd, y = vy*invd, z = vz*invd;
  float d2=d*d, d3=d2*d, d6=d3*d3, d7=d6*d, d8=d7*d;
  float envv = (d<1.f) ? (1.f - 28.f*d6 + 48.f*d7 - 21.f*d8) : 0.f;
  envb[e] = envv;
  float mask = (d==0.f)?0.f:1.f;
  const float SQ2 = 1.41421356237309515f;
  const float PIf = 3.14159265358979323846f;
  float* xr = x72 + (size_t)e*72;
#pragma unroll
  for (int n=1;n<=8;n++)
    xr[n-1] = SQ2 * sinf((float)n*PIf*dd)*invd*envv*mask;
  int sp_s = species[senders[e]], sp_r = species[receivers[e]];
  const float* es_ = emb + (size_t)sp_s*32;
  const float* er_ = emb + (size_t)sp_r*32;
#pragma unroll 8
  for (int k=0;k<32;k++){ xr[8+k] = es_[k]*mask; xr[40+k] = er_[k]*mask; }
  float x2=x*x, y2=y*y, z2=z*z;
  const float s3=1.7320508075688772f, s15=3.872983346207417f, s5=2.23606797749979f;
  const float s358=2.0916500663351889f, s105=10.246950765959598f;
  const float s218=1.6201851746019651f, s7=2.6457513110645907f;
  float* Yr = Yb + ((size_t)e<<4);
  Yr[0]=1.f;           Yr[1]=s3*y;          Yr[2]=s3*z;           Yr[3]=s3*x;
  Yr[4]=s15*x*y;       Yr[5]=s15*y*z;       Yr[6]=0.5f*s5*(3.f*z2-1.f);
  Yr[7]=s15*x*z;       Yr[8]=0.5f*s15*(x2-y2);
  Yr[9]=s358*y*(3.f*x2-y2);  Yr[10]=s105*x*y*z;  Yr[11]=s218*y*(5.f*z2-1.f);
  Yr[12]=0.5f*s7*(5.f*z2-3.f)*z;  Yr[13]=s218*x*(5.f*z2-1.f);
  Yr[14]=0.5f*s105*(x2-y2)*z;     Yr[15]=s358*x*(x2-y2);
}

// V[e][a*16+m] = w0[e,m]*Y[e,a]  (transposed layout, coalesced writes)
__global__ void vinit_k(const float* __restrict__ w0, const float* __restrict__ Y,
                        float* __restrict__ V)
{
  const int gid = blockIdx.x*256 + threadIdx.x;
  const int e = gid >> 8, idx = gid & 255;
  V[gid] = w0[(e<<4)+(idx&15)] * Y[(e<<4)+(idx>>4)];
}

// node[senders[e]][a*16+m] += w[e,m]*Y[e,a]  (transposed layout)
__global__ void scatter_k(const float* __restrict__ w, const float* __restrict__ Y,
                          const int* __restrict__ senders, float* node)
{
  const int gid = blockIdx.x*256 + threadIdx.x;
  const int e = gid >> 8, idx = gid & 255;
  float v = w[(e<<4) + (idx&15)] * Y[(e<<4) + (idx>>4)];
  atomicAdd(&node[((size_t)senders[e]<<8) + idx], v);
}

// l3=0 TP (slots 0..3), one thread per (e, p*16+m). [a][m] layout:
// element (m,a) at a*16+m -> consecutive-m lanes read coalesced.
__global__ void tp2_k(const float* __restrict__ node, const float* __restrict__ Vn,
    const int* __restrict__ senders, const float* __restrict__ varepsp,
    const int* __restrict__ pmeta, const int* __restrict__ entIJ,
    const float* __restrict__ entVal, float* __restrict__ tp0)
{
  const int gid = blockIdx.x*256 + threadIdx.x;
  const int e = gid >> 6, c = gid & 63;
  const int p = c >> 4, m = c & 15;
  float ve = varepsp[0];
  float eps = rsqrtf(1.f + ve*ve);
  int s = senders[e];
  const float* Am = &node[((size_t)s<<8)];
  const float* Bm = &Vn[((size_t)e<<8)];
  int es = pmeta[p*4+1], ec = pmeta[p*4+2];
  float acc = 0.f;
  for (int t=0;t<ec;t++){
    int ij = entIJ[es+t];
    acc += entVal[es+t] * Am[((ij&255)<<4) + m] * Bm[(((ij>>8)&255)<<4) + m];
  }
  tp0[((size_t)e<<6) + pmeta[p*4+0] + m] = acc * eps;
}

// out[e] = env[e] * dot(X[e,:128], Wout) / sqrt(128)
__global__ void final_k(const float* __restrict__ X, const float* __restrict__ Wout,
                        const float* __restrict__ env, float* __restrict__ out)
{
  const int e = blockIdx.x*256 + threadIdx.x;
  float acc = 0.f;
#pragma unroll 16
  for (int k=0;k<128;k++) acc += X[((size_t)e<<7)+k]*Wout[k];
  out[e] = env[e]*acc*0.088388347648318447f;
}

// ============================ host launcher ============================

static void launch_gemm(int flags, const float* A1, const float* A2, int K1, int K,
    const float* W, int N, float* C, const float* env, const float* alphap,
    const float* Xres, hipStream_t stream)
{
  dim3 grid(E_EDGES/64, (N+63)/64);
  switch(flags){
    case F_NONE:        gemm_k<F_NONE>       <<<grid,256,0,stream>>>(A1,A2,K1,K,W,N,C,env,alphap,Xres); break;
    case F_SILU:        gemm_k<F_SILU>       <<<grid,256,0,stream>>>(A1,A2,K1,K,W,N,C,env,alphap,Xres); break;
    case F_ENV:         gemm_k<F_ENV>        <<<grid,256,0,stream>>>(A1,A2,K1,K,W,N,C,env,alphap,Xres); break;
    case F_ENV|F_RESID: gemm_k<F_ENV|F_RESID><<<grid,256,0,stream>>>(A1,A2,K1,K,W,N,C,env,alphap,Xres); break;
  }
}

static void launch_mgemm(int flags, const float* A1, const float* A2, int K1, int K,
    const unsigned short* Wt, int N, float* C, const float* env, const float* alphap,
    const float* Xres, hipStream_t stream)
{
  dim3 grid(E_EDGES/128, N/128);
  switch(flags){
    case F_NONE:        mgemm_k<F_NONE>       <<<grid,256,0,stream>>>(A1,A2,K1,K,Wt,N,C,env,alphap,Xres); break;
    case F_SILU:        mgemm_k<F_SILU>       <<<grid,256,0,stream>>>(A1,A2,K1,K,Wt,N,C,env,alphap,Xres); break;
    case F_ENV:         mgemm_k<F_ENV>        <<<grid,256,0,stream>>>(A1,A2,K1,K,Wt,N,C,env,alphap,Xres); break;
    case F_ENV|F_RESID: mgemm_k<F_ENV|F_RESID><<<grid,256,0,stream>>>(A1,A2,K1,K,Wt,N,C,env,alphap,Xres); break;
  }
}

extern "C" void kernel_launch(void* const* d_in, const int* in_sizes, int n_in,
                              void* d_out, int out_size, void* d_ws, size_t ws_size,
                              hipStream_t stream)
{
  const float* vectors = (const float*)d_in[0];
  const float* vareps  = (const float*)d_in[1];
  const float* alpha   = (const float*)d_in[2];
  const float* emb     = (const float*)d_in[3];
  const float* W_tb1   = (const float*)d_in[4];
  const float* W_tb2   = (const float*)d_in[5];
  const float* W_tb3   = (const float*)d_in[6];
  const float* W_tb4   = (const float*)d_in[7];
  const float* W_w0    = (const float*)d_in[8];
  const float* W_w1    = (const float*)d_in[9];
  const float* W_l11   = (const float*)d_in[10];
  const float* W_l12   = (const float*)d_in[11];
  const float* W_l13   = (const float*)d_in[12];
  const float* W_v1    = (const float*)d_in[13];
  const float* W_v2    = (const float*)d_in[14];
  const float* W_v3    = (const float*)d_in[15];
  const float* W_w2    = (const float*)d_in[16];
  const float* W_l21   = (const float*)d_in[17];
  const float* W_l22   = (const float*)d_in[18];
  const float* W_l23   = (const float*)d_in[19];
  const float* W_h     = (const float*)d_in[20];
  const float* W_out   = (const float*)d_in[21];
  const int* senders   = (const int*)d_in[22];
  const int* receivers = (const int*)d_in[23];
  const int* species   = (const int*)d_in[24];

  static cgt::Tables tb;
  cgt::build(tb);
  const int Kdim = tb.npairs * 16;

  char* ws = (char*)d_ws;
  size_t off = 0;
  auto alloc = [&](size_t bytes)->void*{
    void* p = ws + off; off += (bytes + 255) & ~(size_t)255; return p;
  };
  float* t_val = (float*)alloc(sizeof(tb.val));
  int*   t_ij  = (int*)  alloc(sizeof(tb.ij));
  int*   t_pm  = (int*)  alloc(sizeof(tb.pmeta));
  float* t_td  = (float*)alloc(sizeof(tb.TD));
  int*   t_pr  = (int*)  alloc(sizeof(tb.pairs));
  int*   t_oc  = (int*)  alloc(sizeof(tb.sl_origc));
  float* envb  = (float*)alloc((size_t)E_EDGES*4);
  float* Yb    = (float*)alloc((size_t)E_EDGES*16*4);
  float* xb    = (float*)alloc((size_t)E_EDGES*256*4);
  float* Vb    = (float*)alloc((size_t)E_EDGES*256*4);   // V, then Vn (in-place)
  float* bufA  = (float*)alloc((size_t)E_EDGES*256*4);
  float* bufB  = (float*)alloc((size_t)E_EDGES*256*4);
  float* wb    = (float*)alloc((size_t)E_EDGES*16*4);
  float* tp0b  = (float*)alloc((size_t)E_EDGES*64*4);
  float* nodeb = (float*)alloc((size_t)NNODES*256*4);
  unsigned short* Gt = (unsigned short*)alloc((size_t)256*Kdim*2);
  unsigned short* Wt_tb3 = (unsigned short*)alloc(64*128*2);
  unsigned short* Wt_tb4 = (unsigned short*)alloc(128*256*2);
  unsigned short* Wt_l11 = (unsigned short*)alloc(320*256*2);
  unsigned short* Wt_l12 = (unsigned short*)alloc(256*256*2);
  unsigned short* Wt_l13 = (unsigned short*)alloc(256*256*2);
  unsigned short* Wt_l21 = (unsigned short*)alloc(320*256*2);
  unsigned short* Wt_l22 = (unsigned short*)alloc(256*256*2);
  unsigned short* Wt_l23 = (unsigned short*)alloc(256*256*2);
  unsigned short* Wt_h   = (unsigned short*)alloc(256*128*2);
  if (off > ws_size) {
    fprintf(stderr, "[allegro] workspace too small: need %zu, have %zu\n", off, ws_size);
    return;
  }

  hipMemcpyAsync(t_val, tb.val,     sizeof(tb.val),     hipMemcpyHostToDevice, stream);
  hipMemcpyAsync(t_ij,  tb.ij,      sizeof(tb.ij),      hipMemcpyHostToDevice, stream);
  hipMemcpyAsync(t_pm,  tb.pmeta,   sizeof(tb.pmeta),   hipMemcpyHostToDevice, stream);
  hipMemcpyAsync(t_td,  tb.TD,      sizeof(tb.TD),      hipMemcpyHostToDevice, stream);
  hipMemcpyAsync(t_pr,  tb.pairs,   sizeof(tb.pairs),   hipMemcpyHostToDevice, stream);
  hipMemcpyAsync(t_oc,  tb.sl_origc,sizeof(tb.sl_origc),hipMemcpyHostToDevice, stream);

  // slot ranges (l3 blocks contiguous in slot order): l1: [s1b,s1e) etc.
  const int s1b = tb.l3np[0];
  const int s1e = s1b + tb.l3np[1];
  const int s2e = s1e + tb.l3np[2];
  const int s3e = s2e + tb.l3np[3];

  // combined coupling x Wv matrix (fp16, tiled [slab][col][32])
  {
    dim3 g((Kdim + 255)/256, 256);
    gbuild_k<<<g, 256, 0, stream>>>(t_td, W_v1, W_v2, W_v3, t_oc, Gt, Kdim,
                                    tb.npairs, s1b, s1e, s2e, s3e);
  }
  // weight convert+transpose (fp16)
  {
    WPack p;
    p.d[0] = { W_tb3, Wt_tb3,  64, 7 };
    p.d[1] = { W_tb4, Wt_tb4, 128, 8 };
    p.d[2] = { W_l11, Wt_l11, 320, 8 };
    p.d[3] = { W_l12, Wt_l12, 256, 8 };
    p.d[4] = { W_l13, Wt_l13, 256, 8 };
    p.d[5] = { W_l21, Wt_l21, 320, 8 };
    p.d[6] = { W_l22, Wt_l22, 256, 8 };
    p.d[7] = { W_h,   Wt_h,   256, 7 };
    p.d[8] = { W_l23, Wt_l23, 256, 8 };
    dim3 g(320, 9);
    wcvt_k<<<g, 256, 0, stream>>>(p);
  }

  // 1. edge features + Y + env
  edge_init_k<<<E_EDGES/256, 256, 0, stream>>>(vectors, senders, receivers, species,
                                               emb, envb, Yb, bufA);
  // 2. two-body MLP: 72 -> 32 -> 64 (fp32) -> 128 -> 256 (fp16 MFMA)
  launch_gemm (F_SILU, bufA, nullptr, 72, 72,  W_tb1, 32,   bufB, envb, alpha, nullptr, stream);
  launch_gemm (F_SILU, bufB, nullptr, 32, 32,  W_tb2, 64,   bufA, envb, alpha, nullptr, stream);
  launch_mgemm(F_SILU, bufA, nullptr, 64, 64,  Wt_tb3, 128, bufB, envb, alpha, nullptr, stream);
  launch_mgemm(F_ENV,  bufB, nullptr, 128,128, Wt_tb4, 256, xb,   envb, alpha, nullptr, stream);
  // 3. V = dense(x,W_w0) outer Y  ([a][m] layout)
  dense16_k<<<E_EDGES/16, 256, 0, stream>>>(xb, W_w0, wb);
  vinit_k<<<E_EDGES, 256, 0, stream>>>(wb, Yb, Vb);

  // ---- layer 1 ----
  dense16_k<<<E_EDGES/16, 256, 0, stream>>>(xb, W_w1, wb);
  hipMemsetAsync(nodeb, 0, (size_t)NNODES*256*4, stream);
  scatter_k<<<E_EDGES, 256, 0, stream>>>(wb, Yb, senders, nodeb);
  // tp0 (l3=0) exact fp32; B = V
  tp2_k<<<E_EDGES*64/256, 256, 0, stream>>>(nodeb, Vb, senders, vareps, t_pm, t_ij,
                                            t_val, tp0b);
  // Vn: fused on-the-fly X + fp16 MFMA (in-place V -> Vn), pipelined loop
  vn_k<<<E_EDGES/VN_E, 256, 0, stream>>>(nodeb, Vb, senders, vareps, t_pr, Gt, Vb, Kdim);
  launch_mgemm(F_SILU,        xb,   tp0b,   256, 320, Wt_l11, 256, bufB, envb, alpha, nullptr, stream);
  launch_mgemm(F_SILU,        bufB, nullptr,256, 256, Wt_l12, 256, bufA, envb, alpha, nullptr, stream);
  launch_mgemm(F_ENV|F_RESID, bufA, nullptr,256, 256, Wt_l13, 256, xb,   envb, alpha, xb,      stream);

  // ---- layer 2 (lmax_out = 0) ----
  dense16_k<<<E_EDGES/16, 256, 0, stream>>>(xb, W_w2, wb);
  hipMemsetAsync(nodeb, 0, (size_t)NNODES*256*4, stream);
  scatter_k<<<E_EDGES, 256, 0, stream>>>(wb, Yb, senders, nodeb);
  tp2_k<<<E_EDGES*64/256, 256, 0, stream>>>(nodeb, Vb, senders, vareps, t_pm, t_ij,
                                            t_val, tp0b);
  launch_mgemm(F_SILU,        xb,   tp0b,   256, 320, Wt_l21, 256, bufB, envb, alpha, nullptr, stream);
  launch_mgemm(F_SILU,        bufB, nullptr,256, 256, Wt_l22, 256, bufA, envb, alpha, nullptr, stream);
  launch_mgemm(F_ENV|F_RESID, bufA, nullptr,256, 256, Wt_l23, 256, xb,   envb, alpha, xb,      stream);

  // ---- head ----
  launch_mgemm(F_NONE, xb, nullptr, 256, 256, Wt_h, 128, bufB, envb, alpha, nullptr, stream);
  final_k<<<E_EDGES/256, 256, 0, stream>>>(bufB, W_out, envb, (float*)d_out);
}

// Round 10
// 583.013 us; speedup vs baseline: 1.0041x; 1.0041x over previous
//
#include <hip/hip_runtime.h>
#include <cmath>
#include <complex>
#include <cstdio>
#include <cstring>
#include <algorithm>

#define E_EDGES 32768
#define NNODES  2048
#define VN_E    64      // edges per vn_k block (R10: 32 -> 64, halves G L2 traffic)

// ============================ host-side CG tables ============================
namespace cgt {

static double fct(int n){
  static const double f[13] = {1.,1.,2.,6.,24.,120.,720.,5040.,40320.,362880.,
                               3628800.,39916800.,479001600.};
  return f[n];
}

static double cg(int j1,int m1,int j2,int m2,int j3,int m3){
  if (m1+m2 != m3) return 0.0;
  double pre = std::sqrt((2*j3+1)*fct(j1+j2-j3)*fct(j1-j2+j3)*fct(-j1+j2+j3)/fct(j1+j2+j3+1));
  pre *= std::sqrt(fct(j3+m3)*fct(j3-m3)*fct(j1-m1)*fct(j1+m1)*fct(j2-m2)*fct(j2+m2));
  int kmin = 0;
  if (j2-j3-m1 > kmin) kmin = j2-j3-m1;
  if (j1-j3+m2 > kmin) kmin = j1-j3+m2;
  int kmax = j1+j2-j3;
  if (j1-m1 < kmax) kmax = j1-m1;
  if (j2+m2 < kmax) kmax = j2+m2;
  double s = 0.0;
  for (int k=kmin;k<=kmax;k++){
    double d = fct(k)*fct(j1+j2-j3-k)*fct(j1-m1-k)*fct(j2+m2-k)*fct(j3-j2+m1+k)*fct(j3-j1-m2+k);
    s += ((k&1)? -1.0:1.0)/d;
  }
  return pre*s;
}

typedef std::complex<double> cd;

static void umat(int l, cd U[7][7]){
  for (int a=0;a<7;a++) for (int b=0;b<7;b++) U[a][b]=cd(0,0);
  U[l][l] = cd(1,0);
  double s2 = 1.0/std::sqrt(2.0);
  for (int m=1;m<=l;m++){
    double sg = (m&1)? -1.0 : 1.0;
    U[l+m][l-m] = cd(s2,0);
    U[l+m][l+m] = cd(sg*s2,0);
    U[l-m][l-m] = cd(0, s2);
    U[l-m][l+m] = cd(0, -sg*s2);
  }
}

static bool realCoupling(int l1,int l2,int l3, double T[7][7][7]){
  cd U1[7][7],U2[7][7],U3[7][7];
  umat(l1,U1); umat(l2,U2); umat(l3,U3);
  int n1=2*l1+1, n2=2*l2+1, n3=2*l3+1;
  double Cg[7][7][7];
  for (int m=0;m<n1;m++) for(int n=0;n<n2;n++) for(int k=0;k<n3;k++)
    Cg[m][n][k] = cg(l1,m-l1,l2,n-l2,l3,k-l3);
  double Tr[7][7][7], Ti[7][7][7];
  double nr=0, ni=0;
  for (int a=0;a<n1;a++) for(int b=0;b<n2;b++) for(int c=0;c<n3;c++){
    cd s(0,0);
    for (int m=0;m<n1;m++){
      if (U1[a][m]==cd(0,0)) continue;
      for (int n=0;n<n2;n++){
        if (U2[b][n]==cd(0,0)) continue;
        for (int k=0;k<n3;k++){
          double cgv = Cg[m][n][k];
          if (cgv==0.0) continue;
          s += U1[a][m]*U2[b][n]*std::conj(U3[c][k])*cgv;
        }
      }
    }
    Tr[a][b][c]=s.real(); Ti[a][b][c]=s.imag();
    nr += s.real()*s.real(); ni += s.imag()*s.imag();
  }
  bool useR = (nr >= ni);
  double nn = std::sqrt(useR? nr : ni);
  if (nn < 1e-8) return false;
  for (int a=0;a<n1;a++)for(int b=0;b<n2;b++)for(int c=0;c<n3;c++)
    T[a][b][c] = (useR? Tr[a][b][c] : Ti[a][b][c])/nn;
  return true;
}

struct Tables {
  float val[4096];
  int   ij[4096];        // (a_abs) | (b_abs<<8), entries grouped by (path, c)
  int   pmeta[40*4];     // per SLOT: tpOff(orig layout), entStart, entCount, kdim
  int   ccnt[40*8];      // per SLOT: entry count for each c (kd <= 7)
  int   l3base[4];
  int   l3np[4];
  int   npaths;
  int   nent;
  int   tptot;
  // --- pair/TD tables for the fused Vn GEMM (l>=1 slots only) ---
  int   pairs[256];      // raw (a_abs) | (b_abs<<8)
  float TD[256*30*8];    // TD[pair][slot-4][kloc] = T*sqrt(2l3+1)
  int   sl_origc[40];    // per slot: original c-base (origIdxInL*16) for Wv rows
  int   npairs;          // padded even
};

struct PathTmp {
  int l1,l2,l3, tpoff, kd;
  int ec;                 // total nonzero entries
  double T[7][7][7];
};

static void build(Tables& tb){
  static PathTmp paths[40];
  int np = 0, tpoff = 0;
  int l3start[5];
  for (int l3=0;l3<=3;l3++){
    tb.l3base[l3] = tpoff;
    l3start[l3] = np;
    int kd = 2*l3+1;
    for (int l1=0;l1<=3;l1++) for (int l2=0;l2<=3;l2++){
      int lo = (l1>l2)? l1-l2 : l2-l1;
      int hi = std::min(l1+l2,3);
      if (l3 < lo || l3 > hi) continue;
      PathTmp& pt = paths[np];
      if (!realCoupling(l1,l2,l3,pt.T)) continue;
      pt.l1=l1; pt.l2=l2; pt.l3=l3; pt.kd=kd; pt.tpoff=tpoff;
      double scale = std::sqrt((double)kd);
      int cnt = 0;
      for (int a=0;a<2*l1+1;a++)for(int b=0;b<2*l2+1;b++)for(int c=0;c<kd;c++)
        if (std::fabs(pt.T[a][b][c]*scale) > 1e-7) cnt++;
      pt.ec = cnt;
      tpoff += 16*kd;
      np++;
    }
  }
  l3start[4] = np;
  for (int l3=0;l3<=3;l3++) tb.l3np[l3] = l3start[l3+1]-l3start[l3];
  static int order[40];
  for (int i=0;i<np;i++) order[i]=i;
  for (int l3=0;l3<=3;l3++)
    std::sort(order+l3start[l3], order+l3start[l3+1],
              [&](int a,int b){ return paths[a].ec > paths[b].ec; });
  // emit entries grouped by (slot, c); build pair map + TD for l>=1 slots
  std::memset(tb.TD, 0, sizeof(tb.TD));
  std::memset(tb.pairs, 0, sizeof(tb.pairs));
  static int pmap[16][16];
  for (int i=0;i<16;i++) for (int j=0;j<16;j++) pmap[i][j] = -1;
  int npr = 0;
  int ep = 0;
  for (int slot=0; slot<np; slot++){
    const PathTmp& pt = paths[order[slot]];
    double scale = std::sqrt((double)pt.kd);
    int s1 = pt.l1*pt.l1, s2 = pt.l2*pt.l2;
    tb.pmeta[slot*4+0] = pt.tpoff;
    tb.pmeta[slot*4+1] = ep;
    tb.sl_origc[slot] = ((pt.tpoff - tb.l3base[pt.l3]) / (16*pt.kd)) * 16;
    int tot = 0;
    for (int c=0;c<pt.kd;c++){
      int cnt = 0;
      for (int a=0;a<2*pt.l1+1;a++)for(int b=0;b<2*pt.l2+1;b++){
        double v = pt.T[a][b][c]*scale;
        if (std::fabs(v) > 1e-7){
          tb.val[ep] = (float)v;
          tb.ij[ep]  = (s1+a) | ((s2+b)<<8);
          ep++; cnt++;
          if (pt.l3 >= 1){
            int aa = s1+a, bb = s2+b;
            int pi = pmap[aa][bb];
            if (pi < 0){ pi = npr; pmap[aa][bb] = pi;
                         tb.pairs[npr] = aa | (bb<<8); npr++; }
            tb.TD[(pi*30 + (slot-4))*8 + c] = (float)v;
          }
        }
      }
      tb.ccnt[slot*8+c] = cnt;
      tot += cnt;
    }
    for (int c=pt.kd;c<8;c++) tb.ccnt[slot*8+c]=0;
    tb.pmeta[slot*4+2] = tot;
    tb.pmeta[slot*4+3] = pt.kd;
  }
  if (npr & 1){ tb.pairs[npr] = 0; npr++; }   // pad to even -> Kdim % 32 == 0
  tb.npairs = npr;
  tb.npaths = np; tb.nent = ep; tb.tptot = tpoff;
}

} // namespace cgt

// ============================ device kernels ============================
// LAYOUT CONVENTION: node/V/Vn rows are [a][m] (spherical-major,
// element (m,a) at a*16+m).

enum GFlags { F_NONE=0, F_SILU=1, F_ENV=2, F_RESID=4 };

typedef _Float16 half8 __attribute__((ext_vector_type(8)));
typedef _Float16 half4 __attribute__((ext_vector_type(4)));
typedef __attribute__((ext_vector_type(4))) float f32x4;

__device__ inline unsigned short f2h(float f){
  union { _Float16 h; unsigned short u; } x;
  x.h = (_Float16)f;           // v_cvt_f16_f32, RNE
  return x.u;
}
__device__ inline float h2f(unsigned short u){
  union { _Float16 h; unsigned short u; } x; x.u = u;
  return (float)x.h;
}

// XOR swizzle for 64B-row LDS tiles of 16-bit data: permutes 16B units so
// ds_read_b128 fragment loads are ~conflict-free. kh in ushort units (mult of 4).
__device__ inline int swz(int row, int kh){
  int b = row*64 + kh*2;
  return b ^ (((row >> 1) & 3) << 4);
}

// ---- fp16 MFMA GEMM: C[M,N] = post( A[M,K] @ W[K,N] / sqrt(K) ), A fp32 ----
template<int FLAGS>
__global__ __launch_bounds__(256) void mgemm_k(
    const float* __restrict__ A1, const float* __restrict__ A2,
    int K1, int K, const unsigned short* __restrict__ Wt, int N,
    float* Cout, const float* __restrict__ env,
    const float* __restrict__ alphap, const float* Xres)
{
  __shared__ unsigned short AsB[128*32];
  __shared__ unsigned short BsB[128*32];
  const int tid  = threadIdx.x;
  const int wave = tid >> 6, lane = tid & 63;
  const int bm = blockIdx.x*128, bn = blockIdx.y*128;
  const int wr = (wave >> 1)*64, wc = (wave & 1)*64;
  const int K2 = K - K1;
  f32x4 acc[4][4] = {};

  const int sr  = tid >> 3;          // staging row 0..31 (A)
  const int skq = (tid & 7) * 4;     // staging k 0..28 step 4 (A)
  const int bn_ = tid >> 1;          // staging n 0..127 (B)
  const int bkh = (tid & 1) * 16;    // staging k half (B)

  for (int k0 = 0; k0 < K; k0 += 32) {
#pragma unroll
    for (int q = 0; q < 4; q++) {
      int row = q*32 + sr;
      int grow = bm + row;
      int kk = k0 + skq;
      float4 f4 = (kk < K1) ? *(const float4*)(A1 + (size_t)grow*K1 + kk)
                            : *(const float4*)(A2 + (size_t)grow*K2 + (kk - K1));
      ushort4 u;
      u.x = f2h(f4.x); u.y = f2h(f4.y); u.z = f2h(f4.z); u.w = f2h(f4.w);
      *(ushort4*)((char*)AsB + swz(row, skq)) = u;
    }
    {
      const unsigned short* s = Wt + (size_t)(bn + bn_)*K + k0 + bkh;
#pragma unroll
      for (int q = 0; q < 4; q++) {
        ushort4 u = *(const ushort4*)(s + q*4);
        *(ushort4*)((char*)BsB + swz(bn_, bkh + q*4)) = u;
      }
    }
    __syncthreads();
    const int fr = lane & 15, fk = (lane >> 4) * 8;
    half8 af[4], bf[4];
#pragma unroll
    for (int i = 0; i < 4; i++)
      af[i] = *(half8*)((char*)AsB + swz(wr + i*16 + fr, fk));
#pragma unroll
    for (int j = 0; j < 4; j++)
      bf[j] = *(half8*)((char*)BsB + swz(wc + j*16 + fr, fk));
#pragma unroll
    for (int i = 0; i < 4; i++)
#pragma unroll
      for (int j = 0; j < 4; j++)
        acc[i][j] = __builtin_amdgcn_mfma_f32_16x16x32_f16(af[i], bf[j], acc[i][j], 0, 0, 0);
    __syncthreads();
  }

  const float rscale = 1.f/sqrtf((float)K);
  float a2 = 0.f, inv1a2 = 1.f;
  if (FLAGS & F_RESID) { float al = alphap[0]; a2 = al*al; inv1a2 = 1.f/(1.f+a2); }
#pragma unroll
  for (int i = 0; i < 4; i++) {
#pragma unroll
    for (int r = 0; r < 4; r++) {
      int row = bm + wr + i*16 + ((lane >> 4) << 2) + r;
      float ev = (FLAGS & F_ENV) ? env[row] : 1.f;
#pragma unroll
      for (int j = 0; j < 4; j++) {
        int col = bn + wc + j*16 + (lane & 15);
        float v = acc[i][j][r]*rscale;
        if (FLAGS & F_SILU) v = v/(1.f+__expf(-v));
        if (FLAGS & F_ENV)  v *= ev;
        if (FLAGS & F_RESID) v = (Xres[(size_t)row*N+col] + a2*v)*inv1a2;
        Cout[(size_t)row*N+col] = v;
      }
    }
  }
}

// ---- fused Vn kernel v5: 64 edges/block, conflict-free staging, 2-deep G ----
// Vn[e, kabs*16+d] = sum_k X[e,k]*G[k,col]; X[(pair,m)] = (eps*node[s])(m,a)*V[e](m,b).
// R9 post-mortem: kernel was bounded by (1) G L2 traffic: every block streams
// the full 1.2MB G -> 1024 blocks = 1.26GB/L2 ~ 36us floor; (2) staging-write
// 8-way bank conflicts (9.1e6 cyc). Fix: VN_E=64 + 512 threads (8 waves =
// rowhalf x 4 colgroups) halves G traffic; staging rewritten lane-contiguous
// (wave stages its 8 rows, lane l -> float4 @ 4l -> 8B LDS store, 2-way max);
// G prefetched 2 slabs deep. LDS 69KB -> 2 blocks/CU (4 waves/SIMD, as before).
__global__ __launch_bounds__(512) void vn_k(
    const float* __restrict__ node, const float* __restrict__ V,
    const int* __restrict__ senders, const float* __restrict__ varepsp,
    const int* __restrict__ pairsG, const unsigned short* __restrict__ Gtt,
    float* __restrict__ Vn, int Kdim)
{
  __shared__ unsigned short Ab[VN_E*264];   // fp16 eps*node rows
  __shared__ unsigned short Bb[VN_E*264];   // fp16 V rows
  __shared__ int Ps[256];
  const int tid = threadIdx.x;
  const int e0 = blockIdx.x * VN_E;
  const int wave = tid >> 6, lane = tid & 63;
  float ve = varepsp[0];
  float eps = rsqrtf(1.f + ve*ve);
  if (tid < 256) Ps[tid] = pairsG[tid];
  // ---- staging: wave stages rows wave*8..wave*8+7, lane-contiguous ----
#pragma unroll
  for (int rr = 0; rr < 8; rr++) {
    int row = wave*8 + rr;                     // wave-uniform
    int s = senders[e0 + row];                 // scalar load
    float4 fa = *(const float4*)(node + ((size_t)s << 8) + 4*lane);
    float4 fb = *(const float4*)(V + (((size_t)(e0 + row)) << 8) + 4*lane);
    unsigned short* ad = Ab + row*264 + 4*lane;
    unsigned short* bd = Bb + row*264 + 4*lane;
    uint2 ua, ub;
    ua.x = (unsigned)f2h(fa.x*eps) | ((unsigned)f2h(fa.y*eps) << 16);
    ua.y = (unsigned)f2h(fa.z*eps) | ((unsigned)f2h(fa.w*eps) << 16);
    ub.x = (unsigned)f2h(fb.x) | ((unsigned)f2h(fb.y) << 16);
    ub.y = (unsigned)f2h(fb.z) | ((unsigned)f2h(fb.w) << 16);
    *(uint2*)ad = ua;                          // 8B store, 8B-aligned (528|8l)
    *(uint2*)bd = ub;
  }
  __syncthreads();
  const int rowb = (wave & 1) * 32;      // which 32-edge half
  const int wc   = (wave >> 1) * 64;     // 64 output cols per wave pair
  const int fr = lane & 15, fk = (lane >> 4) * 8;
  const int pairSel = fk >> 4;           // 0 or 1 (which pair of the slab)
  const int moff = fk & 15;              // 0 or 8 (m offset within pair)
  const int nslab = Kdim >> 5;
  f32x4 acc[2][4] = {};                  // [row subgroup 0/16][j]

  const unsigned short* Ar0 = Ab + (rowb + fr)*264;
  const unsigned short* Br0 = Bb + (rowb + fr)*264;
  const unsigned short* Ar1 = Ab + (rowb + 16 + fr)*264;
  const unsigned short* Br1 = Bb + (rowb + 16 + fr)*264;

  // G fragment base for this lane
  const unsigned short* gp = Gtt + ((size_t)(wc + fr)) * 32 + fk;
  // ---- prologue: G slabs 0 and 1, A slab 0 ----
  half8 b0 = *(const half8*)(gp);
  half8 b1 = *(const half8*)(gp + 512);
  half8 b2 = *(const half8*)(gp + 1024);
  half8 b3 = *(const half8*)(gp + 1536);
  half8 c0 = b0, c1 = b1, c2 = b2, c3 = b3;
  if (nslab > 1) {
    const unsigned short* g1 = gp + 8192;
    c0 = *(const half8*)(g1);
    c1 = *(const half8*)(g1 + 512);
    c2 = *(const half8*)(g1 + 1024);
    c3 = *(const half8*)(g1 + 1536);
  }
  int p0 = Ps[pairSel];
  int aoff = ((p0 & 255) << 4) + moff;
  int boff = (((p0 >> 8) & 255) << 4) + moff;
  half8 rA0 = *(const half8*)(Ar0 + aoff);
  half8 rB0 = *(const half8*)(Br0 + boff);
  half8 rA1 = *(const half8*)(Ar1 + aoff);
  half8 rB1 = *(const half8*)(Br1 + boff);

  for (int sl = 0; sl < nslab; sl++) {
    half8 a0 = rA0 * rB0;
    half8 a1 = rA1 * rB1;
    // prefetch A for slab+1 (LDS)
    if (sl + 1 < nslab) {
      int pn = Ps[2*(sl + 1) + pairSel];
      int aoffn = ((pn & 255) << 4) + moff;
      int boffn = (((pn >> 8) & 255) << 4) + moff;
      rA0 = *(const half8*)(Ar0 + aoffn);
      rB0 = *(const half8*)(Br0 + boffn);
      rA1 = *(const half8*)(Ar1 + aoffn);
      rB1 = *(const half8*)(Br1 + boffn);
    }
    // prefetch G for slab+2 (global, 2-deep)
    half8 d0, d1, d2, d3;
    if (sl + 2 < nslab) {
      const unsigned short* gn = gp + (size_t)(sl + 2) * 8192;
      d0 = *(const half8*)(gn);
      d1 = *(const half8*)(gn + 512);
      d2 = *(const half8*)(gn + 1024);
      d3 = *(const half8*)(gn + 1536);
    } else { d0 = c0; d1 = c1; d2 = c2; d3 = c3; }
    acc[0][0] = __builtin_amdgcn_mfma_f32_16x16x32_f16(a0, b0, acc[0][0], 0, 0, 0);
    acc[1][0] = __builtin_amdgcn_mfma_f32_16x16x32_f16(a1, b0, acc[1][0], 0, 0, 0);
    acc[0][1] = __builtin_amdgcn_mfma_f32_16x16x32_f16(a0, b1, acc[0][1], 0, 0, 0);
    acc[1][1] = __builtin_amdgcn_mfma_f32_16x16x32_f16(a1, b1, acc[1][1], 0, 0, 0);
    acc[0][2] = __builtin_amdgcn_mfma_f32_16x16x32_f16(a0, b2, acc[0][2], 0, 0, 0);
    acc[1][2] = __builtin_amdgcn_mfma_f32_16x16x32_f16(a1, b2, acc[1][2], 0, 0, 0);
    acc[0][3] = __builtin_amdgcn_mfma_f32_16x16x32_f16(a0, b3, acc[0][3], 0, 0, 0);
    acc[1][3] = __builtin_amdgcn_mfma_f32_16x16x32_f16(a1, b3, acc[1][3], 0, 0, 0);
    b0 = c0; b1 = c1; b2 = c2; b3 = c3;
    c0 = d0; c1 = d1; c2 = d2; c3 = d3;
  }
  const int r4 = (lane >> 4) << 2;
#pragma unroll
  for (int rg = 0; rg < 2; rg++) {
#pragma unroll
    for (int j = 0; j < 4; j++) {
#pragma unroll
      for (int r = 0; r < 4; r++) {
        int row = e0 + rowb + rg*16 + r4 + r;
        int col = wc + j*16 + fr;
        Vn[(size_t)row*256 + col] = acc[rg][j][r];
      }
    }
  }
}

// ---- Gtt[slab][col][32] = coupling x Wv (fp16, tiled). col = kabs*16+d ----
__global__ void gbuild_k(const float* __restrict__ TD,
    const float* __restrict__ Wv1, const float* __restrict__ Wv2,
    const float* __restrict__ Wv3, const int* __restrict__ sl_origc,
    unsigned short* __restrict__ Gt, int Kdim, int npairs,
    int s1b, int s1e, int s2e, int s3e)
{
  int k = blockIdx.x*256 + threadIdx.x;
  if (k >= Kdim) return;
  int col = blockIdx.y;
  int pair = k >> 4, m = k & 15;
  int d = col & 15, kabs = col >> 4;     // transposed output convention
  float acc = 0.f;
  if (kabs > 0 && pair < npairs) {
    const float* Wv; int ss, se, kloc;
    if (kabs < 4)      { Wv = Wv1; ss = s1b; se = s1e; kloc = kabs - 1; }
    else if (kabs < 9) { Wv = Wv2; ss = s1e; se = s2e; kloc = kabs - 4; }
    else               { Wv = Wv3; ss = s2e; se = s3e; kloc = kabs - 9; }
    for (int slot = ss; slot < se; slot++)
      acc += TD[((pair*30) + (slot - 4))*8 + kloc] * Wv[(sl_origc[slot] + m)*16 + d];
    acc *= rsqrtf((float)(16*(se - ss)));
  }
  Gt[((size_t)((k >> 5)*256 + col))*32 + (k & 31)] = f2h(acc);
}

// ---- weight convert + transpose: Wt[n][k] = fp16(W[k][n]) ----
struct WDesc { const float* src; unsigned short* dst; int K; int lgN; };
struct WPack { WDesc d[9]; };
__global__ void wcvt_k(WPack p){
  WDesc d = p.d[blockIdx.y];
  int total = d.K << d.lgN;
  int gid = blockIdx.x*256 + threadIdx.x;
  if (gid >= total) return;
  int k = gid >> d.lgN, n = gid & ((1 << d.lgN) - 1);
  d.dst[(size_t)n*d.K + k] = f2h(d.src[gid]);
}

// Generic fp32 tiled GEMM (small two-body layers).
template<int FLAGS>
__global__ __launch_bounds__(256) void gemm_k(
    const float* __restrict__ A1, const float* __restrict__ A2,
    int K1, int K, const float* __restrict__ W, int N,
    float* Cout,
    const float* __restrict__ env, const float* __restrict__ alphap,
    const float* Xres)
{
  __shared__ float As[16][68];
  __shared__ float Ws[16][68];
  const int tid = threadIdx.x;
  const int bm = blockIdx.x * 64;
  const int bn = blockIdx.y * 64;
  const int tx = tid & 15, ty = tid >> 4;
  const int K2 = K - K1;
  float acc[4][4] = {};
  for (int k0 = 0; k0 < K; k0 += 16) {
#pragma unroll
    for (int i = 0; i < 4; i++) {
      int idx = tid + i*256;
      int m = idx >> 4, kk = idx & 15;
      int k = k0 + kk;
      float v = 0.f;
      if (k < K) {
        int row = bm + m;
        v = (k < K1) ? A1[(size_t)row*K1 + k] : A2[(size_t)row*K2 + (k-K1)];
      }
      As[kk][m] = v;
    }
#pragma unroll
    for (int i = 0; i < 4; i++) {
      int idx = tid + i*256;
      int n = idx & 63, kk = idx >> 6;
      int k = k0 + kk, col = bn + n;
      Ws[kk][n] = (k < K && col < N) ? W[(size_t)k*N + col] : 0.f;
    }
    __syncthreads();
#pragma unroll
    for (int kk = 0; kk < 16; kk++) {
      float a[4], b[4];
#pragma unroll
      for (int i=0;i<4;i++) a[i] = As[kk][ty*4+i];
#pragma unroll
      for (int j=0;j<4;j++) b[j] = Ws[kk][tx*4+j];
#pragma unroll
      for (int i=0;i<4;i++)
#pragma unroll
        for (int j=0;j<4;j++)
          acc[i][j] += a[i]*b[j];
    }
    __syncthreads();
  }
  const float rscale = 1.f/sqrtf((float)K);
  float a2 = 0.f, inv1a2 = 1.f;
  if (FLAGS & F_RESID) { float al = alphap[0]; a2 = al*al; inv1a2 = 1.f/(1.f+a2); }
#pragma unroll
  for (int i=0;i<4;i++) {
    int row = bm + ty*4 + i;
    float ev = (FLAGS & F_ENV) ? env[row] : 1.f;
#pragma unroll
    for (int j=0;j<4;j++) {
      int col = bn + tx*4 + j;
      if (col >= N) continue;
      float v = acc[i][j]*rscale;
      if (FLAGS & F_SILU) v = v/(1.f+__expf(-v));
      if (FLAGS & F_ENV)  v *= ev;
      if (FLAGS & F_RESID) v = (Xres[(size_t)row*N+col] + a2*v)*inv1a2;
      Cout[(size_t)row*N+col] = v;
    }
  }
}

// dense to 16 outputs, K=256 fixed, scale 1/16
__global__ __launch_bounds__(256) void dense16_k(const float* __restrict__ A,
    const float* __restrict__ W, float* __restrict__ C)
{
  __shared__ float As[16*256];
  const int r0 = blockIdx.x << 4;
  const int tid = threadIdx.x;
  for (int i = tid; i < 16*256; i += 256)
    As[i] = A[((size_t)r0<<8) + i];
  __syncthreads();
  const int r = tid >> 4, n = tid & 15;
  float acc = 0.f;
#pragma unroll 8
  for (int k = 0; k < 256; k++)
    acc += As[(r<<8)+k] * W[(k<<4)+n];
  C[((size_t)(r0+r)<<4)+n] = acc * 0.0625f;
}

__global__ void edge_init_k(const float* __restrict__ vectors, const int* __restrict__ senders,
    const int* __restrict__ receivers, const int* __restrict__ species,
    const float* __restrict__ emb, float* __restrict__ envb, float* __restrict__ Yb,
    float* __restrict__ x72)
{
  const int e = blockIdx.x*256 + threadIdx.x;
  float vx = vectors[e*3+0], vy = vectors[e*3+1], vz = vectors[e*3+2];
  float d = sqrtf(vx*vx+vy*vy+vz*vz);
  float dd = (d==0.f) ? 1.f : d;
  float invd = 1.f/dd;
  float x = vx*invd, y = vy*invd, z = vz*invd;
  float d2=d*d, d3=d2*d, d6=d3*d3, d7=d6*d, d8=d7*d;
  float envv = (d<1.f) ? (1.f - 28.f*d6 + 48.f*d7 - 21.f*d8) : 0.f;
  envb[e] = envv;
  float mask = (d==0.f)?0.f:1.f;
  const float SQ2 = 1.41421356237309515f;
  const float PIf = 3.14159265358979323846f;
  float* xr = x72 + (size_t)e*72;
#pragma unroll
  for (int n=1;n<=8;n++)
    xr[n-1] = SQ2 * sinf((float)n*PIf*dd)*invd*envv*mask;
  int sp_s = species[senders[e]], sp_r = species[receivers[e]];
  const float* es_ = emb + (size_t)sp_s*32;
  const float* er_ = emb + (size_t)sp_r*32;
#pragma unroll 8
  for (int k=0;k<32;k++){ xr[8+k] = es_[k]*mask; xr[40+k] = er_[k]*mask; }
  float x2=x*x, y2=y*y, z2=z*z;
  const float s3=1.7320508075688772f, s15=3.872983346207417f, s5=2.23606797749979f;
  const float s358=2.0916500663351889f, s105=10.246950765959598f;
  const float s218=1.6201851746019651f, s7=2.6457513110645907f;
  float* Yr = Yb + ((size_t)e<<4);
  Yr[0]=1.f;           Yr[1]=s3*y;          Yr[2]=s3*z;           Yr[3]=s3*x;
  Yr[4]=s15*x*y;       Yr[5]=s15*y*z;       Yr[6]=0.5f*s5*(3.f*z2-1.f);
  Yr[7]=s15*x*z;       Yr[8]=0.5f*s15*(x2-y2);
  Yr[9]=s358*y*(3.f*x2-y2);  Yr[10]=s105*x*y*z;  Yr[11]=s218*y*(5.f*z2-1.f);
  Yr[12]=0.5f*s7*(5.f*z2-3.f)*z;  Yr[13]=s218*x*(5.f*z2-1.f);
  Yr[14]=0.5f*s105*(x2-y2)*z;     Yr[15]=s358*x*(x2-y2);
}

// V[e][a*16+m] = w0[e,m]*Y[e,a]  (transposed layout, coalesced writes)
__global__ void vinit_k(const float* __restrict__ w0, const float* __restrict__ Y,
                        float* __restrict__ V)
{
  const int gid = blockIdx.x*256 + threadIdx.x;
  const int e = gid >> 8, idx = gid & 255;
  V[gid] = w0[(e<<4)+(idx&15)] * Y[(e<<4)+(idx>>4)];
}

// node[senders[e]][a*16+m] += w[e,m]*Y[e,a]  (transposed layout)
__global__ void scatter_k(const float* __restrict__ w, const float* __restrict__ Y,
                          const int* __restrict__ senders, float* node)
{
  const int gid = blockIdx.x*256 + threadIdx.x;
  const int e = gid >> 8, idx = gid & 255;
  float v = w[(e<<4) + (idx&15)] * Y[(e<<4) + (idx>>4)];
  atomicAdd(&node[((size_t)senders[e]<<8) + idx], v);
}

// l3=0 TP (slots 0..3), one thread per (e, p*16+m). [a][m] layout:
// element (m,a) at a*16+m -> consecutive-m lanes read coalesced.
__global__ void tp2_k(const float* __restrict__ node, const float* __restrict__ Vn,
    const int* __restrict__ senders, const float* __restrict__ varepsp,
    const int* __restrict__ pmeta, const int* __restrict__ entIJ,
    const float* __restrict__ entVal, float* __restrict__ tp0)
{
  const int gid = blockIdx.x*256 + threadIdx.x;
  const int e = gid >> 6, c = gid & 63;
  const int p = c >> 4, m = c & 15;
  float ve = varepsp[0];
  float eps = rsqrtf(1.f + ve*ve);
  int s = senders[e];
  const float* Am = &node[((size_t)s<<8)];
  const float* Bm = &Vn[((size_t)e<<8)];
  int es = pmeta[p*4+1], ec = pmeta[p*4+2];
  float acc = 0.f;
  for (int t=0;t<ec;t++){
    int ij = entIJ[es+t];
    acc += entVal[es+t] * Am[((ij&255)<<4) + m] * Bm[(((ij>>8)&255)<<4) + m];
  }
  tp0[((size_t)e<<6) + pmeta[p*4+0] + m] = acc * eps;
}

// out[e] = env[e] * dot(X[e,:128], Wout) / sqrt(128)
__global__ void final_k(const float* __restrict__ X, const float* __restrict__ Wout,
                        const float* __restrict__ env, float* __restrict__ out)
{
  const int e = blockIdx.x*256 + threadIdx.x;
  float acc = 0.f;
#pragma unroll 16
  for (int k=0;k<128;k++) acc += X[((size_t)e<<7)+k]*Wout[k];
  out[e] = env[e]*acc*0.088388347648318447f;
}

// ============================ host launcher ============================

static void launch_gemm(int flags, const float* A1, const float* A2, int K1, int K,
    const float* W, int N, float* C, const float* env, const float* alphap,
    const float* Xres, hipStream_t stream)
{
  dim3 grid(E_EDGES/64, (N+63)/64);
  switch(flags){
    case F_NONE:        gemm_k<F_NONE>       <<<grid,256,0,stream>>>(A1,A2,K1,K,W,N,C,env,alphap,Xres); break;
    case F_SILU:        gemm_k<F_SILU>       <<<grid,256,0,stream>>>(A1,A2,K1,K,W,N,C,env,alphap,Xres); break;
    case F_ENV:         gemm_k<F_ENV>        <<<grid,256,0,stream>>>(A1,A2,K1,K,W,N,C,env,alphap,Xres); break;
    case F_ENV|F_RESID: gemm_k<F_ENV|F_RESID><<<grid,256,0,stream>>>(A1,A2,K1,K,W,N,C,env,alphap,Xres); break;
  }
}

static void launch_mgemm(int flags, const float* A1, const float* A2, int K1, int K,
    const unsigned short* Wt, int N, float* C, const float* env, const float* alphap,
    const float* Xres, hipStream_t stream)
{
  dim3 grid(E_EDGES/128, N/128);
  switch(flags){
    case F_NONE:        mgemm_k<F_NONE>       <<<grid,256,0,stream>>>(A1,A2,K1,K,Wt,N,C,env,alphap,Xres); break;
    case F_SILU:        mgemm_k<F_SILU>       <<<grid,256,0,stream>>>(A1,A2,K1,K,Wt,N,C,env,alphap,Xres); break;
    case F_ENV:         mgemm_k<F_ENV>        <<<grid,256,0,stream>>>(A1,A2,K1,K,Wt,N,C,env,alphap,Xres); break;
    case F_ENV|F_RESID: mgemm_k<F_ENV|F_RESID><<<grid,256,0,stream>>>(A1,A2,K1,K,Wt,N,C,env,alphap,Xres); break;
  }
}

extern "C" void kernel_launch(void* const* d_in, const int* in_sizes, int n_in,
                              void* d_out, int out_size, void* d_ws, size_t ws_size,
                              hipStream_t stream)
{
  const float* vectors = (const float*)d_in[0];
  const float* vareps  = (const float*)d_in[1];
  const float* alpha   = (const float*)d_in[2];
  const float* emb     = (const float*)d_in[3];
  const float* W_tb1   = (const float*)d_in[4];
  const float* W_tb2   = (const float*)d_in[5];
  const float* W_tb3   = (const float*)d_in[6];
  const float* W_tb4   = (const float*)d_in[7];
  const float* W_w0    = (const float*)d_in[8];
  const float* W_w1    = (const float*)d_in[9];
  const float* W_l11   = (const float*)d_in[10];
  const float* W_l12   = (const float*)d_in[11];
  const float* W_l13   = (const float*)d_in[12];
  const float* W_v1    = (const float*)d_in[13];
  const float* W_v2    = (const float*)d_in[14];
  const float* W_v3    = (const float*)d_in[15];
  const float* W_w2    = (const float*)d_in[16];
  const float* W_l21   = (const float*)d_in[17];
  const float* W_l22   = (const float*)d_in[18];
  const float* W_l23   = (const float*)d_in[19];
  const float* W_h     = (const float*)d_in[20];
  const float* W_out   = (const float*)d_in[21];
  const int* senders   = (const int*)d_in[22];
  const int* receivers = (const int*)d_in[23];
  const int* species   = (const int*)d_in[24];

  static cgt::Tables tb;
  cgt::build(tb);
  const int Kdim = tb.npairs * 16;

  char* ws = (char*)d_ws;
  size_t off = 0;
  auto alloc = [&](size_t bytes)->void*{
    void* p = ws + off; off += (bytes + 255) & ~(size_t)255; return p;
  };
  float* t_val = (float*)alloc(sizeof(tb.val));
  int*   t_ij  = (int*)  alloc(sizeof(tb.ij));
  int*   t_pm  = (int*)  alloc(sizeof(tb.pmeta));
  float* t_td  = (float*)alloc(sizeof(tb.TD));
  int*   t_pr  = (int*)  alloc(sizeof(tb.pairs));
  int*   t_oc  = (int*)  alloc(sizeof(tb.sl_origc));
  float* envb  = (float*)alloc((size_t)E_EDGES*4);
  float* Yb    = (float*)alloc((size_t)E_EDGES*16*4);
  float* xb    = (float*)alloc((size_t)E_EDGES*256*4);
  float* Vb    = (float*)alloc((size_t)E_EDGES*256*4);   // V, then Vn (in-place)
  float* bufA  = (float*)alloc((size_t)E_EDGES*256*4);
  float* bufB  = (float*)alloc((size_t)E_EDGES*256*4);
  float* wb    = (float*)alloc((size_t)E_EDGES*16*4);
  float* tp0b  = (float*)alloc((size_t)E_EDGES*64*4);
  float* nodeb = (float*)alloc((size_t)NNODES*256*4);
  unsigned short* Gt = (unsigned short*)alloc((size_t)256*Kdim*2);
  unsigned short* Wt_tb3 = (unsigned short*)alloc(64*128*2);
  unsigned short* Wt_tb4 = (unsigned short*)alloc(128*256*2);
  unsigned short* Wt_l11 = (unsigned short*)alloc(320*256*2);
  unsigned short* Wt_l12 = (unsigned short*)alloc(256*256*2);
  unsigned short* Wt_l13 = (unsigned short*)alloc(256*256*2);
  unsigned short* Wt_l21 = (unsigned short*)alloc(320*256*2);
  unsigned short* Wt_l22 = (unsigned short*)alloc(256*256*2);
  unsigned short* Wt_l23 = (unsigned short*)alloc(256*256*2);
  unsigned short* Wt_h   = (unsigned short*)alloc(256*128*2);
  if (off > ws_size) {
    fprintf(stderr, "[allegro] workspace too small: need %zu, have %zu\n", off, ws_size);
    return;
  }

  hipMemcpyAsync(t_val, tb.val,     sizeof(tb.val),     hipMemcpyHostToDevice, stream);
  hipMemcpyAsync(t_ij,  tb.ij,      sizeof(tb.ij),      hipMemcpyHostToDevice, stream);
  hipMemcpyAsync(t_pm,  tb.pmeta,   sizeof(tb.pmeta),   hipMemcpyHostToDevice, stream);
  hipMemcpyAsync(t_td,  tb.TD,      sizeof(tb.TD),      hipMemcpyHostToDevice, stream);
  hipMemcpyAsync(t_pr,  tb.pairs,   sizeof(tb.pairs),   hipMemcpyHostToDevice, stream);
  hipMemcpyAsync(t_oc,  tb.sl_origc,sizeof(tb.sl_origc),hipMemcpyHostToDevice, stream);

  // slot ranges (l3 blocks contiguous in slot order): l1: [s1b,s1e) etc.
  const int s1b = tb.l3np[0];
  const int s1e = s1b + tb.l3np[1];
  const int s2e = s1e + tb.l3np[2];
  const int s3e = s2e + tb.l3np[3];

  // combined coupling x Wv matrix (fp16, tiled [slab][col][32])
  {
    dim3 g((Kdim + 255)/256, 256);
    gbuild_k<<<g, 256, 0, stream>>>(t_td, W_v1, W_v2, W_v3, t_oc, Gt, Kdim,
                                    tb.npairs, s1b, s1e, s2e, s3e);
  }
  // weight convert+transpose (fp16)
  {
    WPack p;
    p.d[0] = { W_tb3, Wt_tb3,  64, 7 };
    p.d[1] = { W_tb4, Wt_tb4, 128, 8 };
    p.d[2] = { W_l11, Wt_l11, 320, 8 };
    p.d[3] = { W_l12, Wt_l12, 256, 8 };
    p.d[4] = { W_l13, Wt_l13, 256, 8 };
    p.d[5] = { W_l21, Wt_l21, 320, 8 };
    p.d[6] = { W_l22, Wt_l22, 256, 8 };
    p.d[7] = { W_h,   Wt_h,   256, 7 };
    p.d[8] = { W_l23, Wt_l23, 256, 8 };
    dim3 g(320, 9);
    wcvt_k<<<g, 256, 0, stream>>>(p);
  }

  // 1. edge features + Y + env
  edge_init_k<<<E_EDGES/256, 256, 0, stream>>>(vectors, senders, receivers, species,
                                               emb, envb, Yb, bufA);
  // 2. two-body MLP: 72 -> 32 -> 64 (fp32) -> 128 -> 256 (fp16 MFMA)
  launch_gemm (F_SILU, bufA, nullptr, 72, 72,  W_tb1, 32,   bufB, envb, alpha, nullptr, stream);
  launch_gemm (F_SILU, bufB, nullptr, 32, 32,  W_tb2, 64,   bufA, envb, alpha, nullptr, stream);
  launch_mgemm(F_SILU, bufA, nullptr, 64, 64,  Wt_tb3, 128, bufB, envb, alpha, nullptr, stream);
  launch_mgemm(F_ENV,  bufB, nullptr, 128,128, Wt_tb4, 256, xb,   envb, alpha, nullptr, stream);
  // 3. V = dense(x,W_w0) outer Y  ([a][m] layout)
  dense16_k<<<E_EDGES/16, 256, 0, stream>>>(xb, W_w0, wb);
  vinit_k<<<E_EDGES, 256, 0, stream>>>(wb, Yb, Vb);

  // ---- layer 1 ----
  dense16_k<<<E_EDGES/16, 256, 0, stream>>>(xb, W_w1, wb);
  hipMemsetAsync(nodeb, 0, (size_t)NNODES*256*4, stream);
  scatter_k<<<E_EDGES, 256, 0, stream>>>(wb, Yb, senders, nodeb);
  // tp0 (l3=0) exact fp32; B = V
  tp2_k<<<E_EDGES*64/256, 256, 0, stream>>>(nodeb, Vb, senders, vareps, t_pm, t_ij,
                                            t_val, tp0b);
  // Vn: fused on-the-fly X + fp16 MFMA (in-place V -> Vn), 64 edges/block
  vn_k<<<E_EDGES/VN_E, 512, 0, stream>>>(nodeb, Vb, senders, vareps, t_pr, Gt, Vb, Kdim);
  launch_mgemm(F_SILU,        xb,   tp0b,   256, 320, Wt_l11, 256, bufB, envb, alpha, nullptr, stream);
  launch_mgemm(F_SILU,        bufB, nullptr,256, 256, Wt_l12, 256, bufA, envb, alpha, nullptr, stream);
  launch_mgemm(F_ENV|F_RESID, bufA, nullptr,256, 256, Wt_l13, 256, xb,   envb, alpha, xb,      stream);

  // ---- layer 2 (lmax_out = 0) ----
  dense16_k<<<E_EDGES/16, 256, 0, stream>>>(xb, W_w2, wb);
  hipMemsetAsync(nodeb, 0, (size_t)NNODES*256*4, stream);
  scatter_k<<<E_EDGES, 256, 0, stream>>>(wb, Yb, senders, nodeb);
  tp2_k<<<E_EDGES*64/256, 256, 0, stream>>>(nodeb, Vb, senders, vareps, t_pm, t_ij,
                                            t_val, tp0b);
  launch_mgemm(F_SILU,        xb,   tp0b,   256, 320, Wt_l21, 256, bufB, envb, alpha, nullptr, stream);
  launch_mgemm(F_SILU,        bufB, nullptr,256, 256, Wt_l22, 256, bufA, envb, alpha, nullptr, stream);
  launch_mgemm(F_ENV|F_RESID, bufA, nullptr,256, 256, Wt_l23, 256, xb,   envb, alpha, xb,      stream);

  // ---- head ----
  launch_mgemm(F_NONE, xb, nullptr, 256, 256, Wt_h, 128, bufB, envb, alpha, nullptr, stream);
  final_k<<<E_EDGES/256, 256, 0, stream>>>(bufB, W_out, envb, (float*)d_out);
}

// Round 11
// 554.619 us; speedup vs baseline: 1.0555x; 1.0512x over previous
//
#include <hip/hip_runtime.h>
#include <cmath>
#include <complex>
#include <cstdio>
#include <cstring>
#include <algorithm>

#define E_EDGES 32768
#define NNODES  2048
#define VN_E    64      // edges per vn_k block

// ============================ host-side CG tables ============================
namespace cgt {

static double fct(int n){
  static const double f[13] = {1.,1.,2.,6.,24.,120.,720.,5040.,40320.,362880.,
                               3628800.,39916800.,479001600.};
  return f[n];
}

static double cg(int j1,int m1,int j2,int m2,int j3,int m3){
  if (m1+m2 != m3) return 0.0;
  double pre = std::sqrt((2*j3+1)*fct(j1+j2-j3)*fct(j1-j2+j3)*fct(-j1+j2+j3)/fct(j1+j2+j3+1));
  pre *= std::sqrt(fct(j3+m3)*fct(j3-m3)*fct(j1-m1)*fct(j1+m1)*fct(j2-m2)*fct(j2+m2));
  int kmin = 0;
  if (j2-j3-m1 > kmin) kmin = j2-j3-m1;
  if (j1-j3+m2 > kmin) kmin = j1-j3+m2;
  int kmax = j1+j2-j3;
  if (j1-m1 < kmax) kmax = j1-m1;
  if (j2+m2 < kmax) kmax = j2+m2;
  double s = 0.0;
  for (int k=kmin;k<=kmax;k++){
    double d = fct(k)*fct(j1+j2-j3-k)*fct(j1-m1-k)*fct(j2+m2-k)*fct(j3-j2+m1+k)*fct(j3-j1-m2+k);
    s += ((k&1)? -1.0:1.0)/d;
  }
  return pre*s;
}

typedef std::complex<double> cd;

static void umat(int l, cd U[7][7]){
  for (int a=0;a<7;a++) for (int b=0;b<7;b++) U[a][b]=cd(0,0);
  U[l][l] = cd(1,0);
  double s2 = 1.0/std::sqrt(2.0);
  for (int m=1;m<=l;m++){
    double sg = (m&1)? -1.0 : 1.0;
    U[l+m][l-m] = cd(s2,0);
    U[l+m][l+m] = cd(sg*s2,0);
    U[l-m][l-m] = cd(0, s2);
    U[l-m][l+m] = cd(0, -sg*s2);
  }
}

static bool realCoupling(int l1,int l2,int l3, double T[7][7][7]){
  cd U1[7][7],U2[7][7],U3[7][7];
  umat(l1,U1); umat(l2,U2); umat(l3,U3);
  int n1=2*l1+1, n2=2*l2+1, n3=2*l3+1;
  double Cg[7][7][7];
  for (int m=0;m<n1;m++) for(int n=0;n<n2;n++) for(int k=0;k<n3;k++)
    Cg[m][n][k] = cg(l1,m-l1,l2,n-l2,l3,k-l3);
  double Tr[7][7][7], Ti[7][7][7];
  double nr=0, ni=0;
  for (int a=0;a<n1;a++) for(int b=0;b<n2;b++) for(int c=0;c<n3;c++){
    cd s(0,0);
    for (int m=0;m<n1;m++){
      if (U1[a][m]==cd(0,0)) continue;
      for (int n=0;n<n2;n++){
        if (U2[b][n]==cd(0,0)) continue;
        for (int k=0;k<n3;k++){
          double cgv = Cg[m][n][k];
          if (cgv==0.0) continue;
          s += U1[a][m]*U2[b][n]*std::conj(U3[c][k])*cgv;
        }
      }
    }
    Tr[a][b][c]=s.real(); Ti[a][b][c]=s.imag();
    nr += s.real()*s.real(); ni += s.imag()*s.imag();
  }
  bool useR = (nr >= ni);
  double nn = std::sqrt(useR? nr : ni);
  if (nn < 1e-8) return false;
  for (int a=0;a<n1;a++)for(int b=0;b<n2;b++)for(int c=0;c<n3;c++)
    T[a][b][c] = (useR? Tr[a][b][c] : Ti[a][b][c])/nn;
  return true;
}

struct Tables {
  float val[4096];
  int   ij[4096];
  int   pmeta[40*4];
  int   ccnt[40*8];
  int   l3base[4];
  int   l3np[4];
  int   npaths;
  int   nent;
  int   tptot;
  int   pairs[256];
  float TD[256*30*8];
  int   sl_origc[40];
  int   npairs;
};

struct PathTmp {
  int l1,l2,l3, tpoff, kd;
  int ec;
  double T[7][7][7];
};

static void build(Tables& tb){
  static PathTmp paths[40];
  int np = 0, tpoff = 0;
  int l3start[5];
  for (int l3=0;l3<=3;l3++){
    tb.l3base[l3] = tpoff;
    l3start[l3] = np;
    int kd = 2*l3+1;
    for (int l1=0;l1<=3;l1++) for (int l2=0;l2<=3;l2++){
      int lo = (l1>l2)? l1-l2 : l2-l1;
      int hi = std::min(l1+l2,3);
      if (l3 < lo || l3 > hi) continue;
      PathTmp& pt = paths[np];
      if (!realCoupling(l1,l2,l3,pt.T)) continue;
      pt.l1=l1; pt.l2=l2; pt.l3=l3; pt.kd=kd; pt.tpoff=tpoff;
      double scale = std::sqrt((double)kd);
      int cnt = 0;
      for (int a=0;a<2*l1+1;a++)for(int b=0;b<2*l2+1;b++)for(int c=0;c<kd;c++)
        if (std::fabs(pt.T[a][b][c]*scale) > 1e-7) cnt++;
      pt.ec = cnt;
      tpoff += 16*kd;
      np++;
    }
  }
  l3start[4] = np;
  for (int l3=0;l3<=3;l3++) tb.l3np[l3] = l3start[l3+1]-l3start[l3];
  static int order[40];
  for (int i=0;i<np;i++) order[i]=i;
  for (int l3=0;l3<=3;l3++)
    std::sort(order+l3start[l3], order+l3start[l3+1],
              [&](int a,int b){ return paths[a].ec > paths[b].ec; });
  std::memset(tb.TD, 0, sizeof(tb.TD));
  std::memset(tb.pairs, 0, sizeof(tb.pairs));
  static int pmap[16][16];
  for (int i=0;i<16;i++) for (int j=0;j<16;j++) pmap[i][j] = -1;
  int npr = 0;
  int ep = 0;
  for (int slot=0; slot<np; slot++){
    const PathTmp& pt = paths[order[slot]];
    double scale = std::sqrt((double)pt.kd);
    int s1 = pt.l1*pt.l1, s2 = pt.l2*pt.l2;
    tb.pmeta[slot*4+0] = pt.tpoff;
    tb.pmeta[slot*4+1] = ep;
    tb.sl_origc[slot] = ((pt.tpoff - tb.l3base[pt.l3]) / (16*pt.kd)) * 16;
    int tot = 0;
    for (int c=0;c<pt.kd;c++){
      int cnt = 0;
      for (int a=0;a<2*pt.l1+1;a++)for(int b=0;b<2*pt.l2+1;b++){
        double v = pt.T[a][b][c]*scale;
        if (std::fabs(v) > 1e-7){
          tb.val[ep] = (float)v;
          tb.ij[ep]  = (s1+a) | ((s2+b)<<8);
          ep++; cnt++;
          if (pt.l3 >= 1){
            int aa = s1+a, bb = s2+b;
            int pi = pmap[aa][bb];
            if (pi < 0){ pi = npr; pmap[aa][bb] = pi;
                         tb.pairs[npr] = aa | (bb<<8); npr++; }
            tb.TD[(pi*30 + (slot-4))*8 + c] = (float)v;
          }
        }
      }
      tb.ccnt[slot*8+c] = cnt;
      tot += cnt;
    }
    for (int c=pt.kd;c<8;c++) tb.ccnt[slot*8+c]=0;
    tb.pmeta[slot*4+2] = tot;
    tb.pmeta[slot*4+3] = pt.kd;
  }
  if (npr & 1){ tb.pairs[npr] = 0; npr++; }
  tb.npairs = npr;
  tb.npaths = np; tb.nent = ep; tb.tptot = tpoff;
}

} // namespace cgt

// ============================ device kernels ============================
// LAYOUT: node/V/Vn rows are [a][m] (element (m,a) at a*16+m).
// R11: all MFMA-path activations stored fp16 in HBM (xb, post-tb3 bufs,
// tp0, V/Vn, head out) -> halves activation traffic, kills f2h in staging.

enum GFlags { F_NONE=0, F_SILU=1, F_ENV=2, F_RESID=4 };

typedef _Float16 half8 __attribute__((ext_vector_type(8)));
typedef _Float16 half4 __attribute__((ext_vector_type(4)));
typedef __attribute__((ext_vector_type(4))) float f32x4;

__device__ inline unsigned short f2h(float f){
  union { _Float16 h; unsigned short u; } x;
  x.h = (_Float16)f;
  return x.u;
}
__device__ inline float h2f(unsigned short u){
  union { _Float16 h; unsigned short u; } x; x.u = u;
  return (float)x.h;
}

__device__ inline int swz(int row, int kh){
  int b = row*64 + kh*2;
  return b ^ (((row >> 1) & 3) << 4);
}

// ---- fp16 MFMA GEMM: C16[M,N] = post( A[M,K] @ W[K,N] / sqrt(K) ) ----
// A16=1: A1/A2 are fp16; A16=0: fp32 (converted in staging).
template<int FLAGS, int A16>
__global__ __launch_bounds__(256) void mgemm_k(
    const void* __restrict__ A1v, const void* __restrict__ A2v,
    int K1, int K, const unsigned short* __restrict__ Wt, int N,
    unsigned short* Cout, const float* __restrict__ env,
    const float* __restrict__ alphap, const unsigned short* Xres)
{
  __shared__ unsigned short AsB[128*32];
  __shared__ unsigned short BsB[128*32];
  const int tid  = threadIdx.x;
  const int wave = tid >> 6, lane = tid & 63;
  const int bm = blockIdx.x*128, bn = blockIdx.y*128;
  const int wr = (wave >> 1)*64, wc = (wave & 1)*64;
  const int K2 = K - K1;
  f32x4 acc[4][4] = {};

  const int sr  = tid >> 3;          // fp32 staging row 0..31
  const int skq = (tid & 7) * 4;
  const int sr2 = tid >> 1;          // fp16 staging row 0..127
  const int skh = (tid & 1) * 16;
  const int bn_ = tid >> 1;          // B staging n 0..127
  const int bkh = (tid & 1) * 16;

  for (int k0 = 0; k0 < K; k0 += 32) {
    if (A16) {
      int kk = k0 + skh;
      const unsigned short* ap = (kk < K1)
        ? (const unsigned short*)A1v + (size_t)(bm + sr2)*K1 + kk
        : (const unsigned short*)A2v + (size_t)(bm + sr2)*K2 + (kk - K1);
      uint4 u0 = *(const uint4*)ap;
      uint4 u1 = *(const uint4*)(ap + 8);
      *(uint4*)((char*)AsB + swz(sr2, skh))     = u0;
      *(uint4*)((char*)AsB + swz(sr2, skh + 8)) = u1;
    } else {
#pragma unroll
      for (int q = 0; q < 4; q++) {
        int row = q*32 + sr;
        int grow = bm + row;
        int kk = k0 + skq;
        float4 f4 = (kk < K1)
          ? *(const float4*)((const float*)A1v + (size_t)grow*K1 + kk)
          : *(const float4*)((const float*)A2v + (size_t)grow*K2 + (kk - K1));
        ushort4 u;
        u.x = f2h(f4.x); u.y = f2h(f4.y); u.z = f2h(f4.z); u.w = f2h(f4.w);
        *(ushort4*)((char*)AsB + swz(row, skq)) = u;
      }
    }
    {
      const unsigned short* s = Wt + (size_t)(bn + bn_)*K + k0 + bkh;
#pragma unroll
      for (int q = 0; q < 4; q++) {
        ushort4 u = *(const ushort4*)(s + q*4);
        *(ushort4*)((char*)BsB + swz(bn_, bkh + q*4)) = u;
      }
    }
    __syncthreads();
    const int fr = lane & 15, fk = (lane >> 4) * 8;
    half8 af[4], bf[4];
#pragma unroll
    for (int i = 0; i < 4; i++)
      af[i] = *(half8*)((char*)AsB + swz(wr + i*16 + fr, fk));
#pragma unroll
    for (int j = 0; j < 4; j++)
      bf[j] = *(half8*)((char*)BsB + swz(wc + j*16 + fr, fk));
#pragma unroll
    for (int i = 0; i < 4; i++)
#pragma unroll
      for (int j = 0; j < 4; j++)
        acc[i][j] = __builtin_amdgcn_mfma_f32_16x16x32_f16(af[i], bf[j], acc[i][j], 0, 0, 0);
    __syncthreads();
  }

  const float rscale = 1.f/sqrtf((float)K);
  float a2 = 0.f, inv1a2 = 1.f;
  if (FLAGS & F_RESID) { float al = alphap[0]; a2 = al*al; inv1a2 = 1.f/(1.f+a2); }
#pragma unroll
  for (int i = 0; i < 4; i++) {
#pragma unroll
    for (int r = 0; r < 4; r++) {
      int row = bm + wr + i*16 + ((lane >> 4) << 2) + r;
      float ev = (FLAGS & F_ENV) ? env[row] : 1.f;
#pragma unroll
      for (int j = 0; j < 4; j++) {
        int col = bn + wc + j*16 + (lane & 15);
        float v = acc[i][j][r]*rscale;
        if (FLAGS & F_SILU) v = v/(1.f+__expf(-v));
        if (FLAGS & F_ENV)  v *= ev;
        if (FLAGS & F_RESID) v = (h2f(Xres[(size_t)row*N+col]) + a2*v)*inv1a2;
        Cout[(size_t)row*N+col] = f2h(v);
      }
    }
  }
}

// ---- fused Vn kernel (structure from R10; V/Vn now fp16) ----
__global__ __launch_bounds__(512) void vn_k(
    const float* __restrict__ node, const unsigned short* __restrict__ V,
    const int* __restrict__ senders, const float* __restrict__ varepsp,
    const int* __restrict__ pairsG, const unsigned short* __restrict__ Gtt,
    unsigned short* __restrict__ Vn, int Kdim)
{
  __shared__ unsigned short Ab[VN_E*264];
  __shared__ unsigned short Bb[VN_E*264];
  __shared__ int Ps[256];
  const int tid = threadIdx.x;
  const int e0 = blockIdx.x * VN_E;
  const int wave = tid >> 6, lane = tid & 63;
  float ve = varepsp[0];
  float eps = rsqrtf(1.f + ve*ve);
  if (tid < 256) Ps[tid] = pairsG[tid];
#pragma unroll
  for (int rr = 0; rr < 8; rr++) {
    int row = wave*8 + rr;
    int s = senders[e0 + row];
    float4 fa = *(const float4*)(node + ((size_t)s << 8) + 4*lane);
    uint2 ub = *(const uint2*)(V + (((size_t)(e0 + row)) << 8) + 4*lane);
    unsigned short* ad = Ab + row*264 + 4*lane;
    unsigned short* bd = Bb + row*264 + 4*lane;
    uint2 ua;
    ua.x = (unsigned)f2h(fa.x*eps) | ((unsigned)f2h(fa.y*eps) << 16);
    ua.y = (unsigned)f2h(fa.z*eps) | ((unsigned)f2h(fa.w*eps) << 16);
    *(uint2*)ad = ua;
    *(uint2*)bd = ub;
  }
  __syncthreads();
  const int rowb = (wave & 1) * 32;
  const int wc   = (wave >> 1) * 64;
  const int fr = lane & 15, fk = (lane >> 4) * 8;
  const int pairSel = fk >> 4;
  const int moff = fk & 15;
  const int nslab = Kdim >> 5;
  f32x4 acc[2][4] = {};

  const unsigned short* Ar0 = Ab + (rowb + fr)*264;
  const unsigned short* Br0 = Bb + (rowb + fr)*264;
  const unsigned short* Ar1 = Ab + (rowb + 16 + fr)*264;
  const unsigned short* Br1 = Bb + (rowb + 16 + fr)*264;

  const unsigned short* gp = Gtt + ((size_t)(wc + fr)) * 32 + fk;
  half8 b0 = *(const half8*)(gp);
  half8 b1 = *(const half8*)(gp + 512);
  half8 b2 = *(const half8*)(gp + 1024);
  half8 b3 = *(const half8*)(gp + 1536);
  half8 c0 = b0, c1 = b1, c2 = b2, c3 = b3;
  if (nslab > 1) {
    const unsigned short* g1 = gp + 8192;
    c0 = *(const half8*)(g1);
    c1 = *(const half8*)(g1 + 512);
    c2 = *(const half8*)(g1 + 1024);
    c3 = *(const half8*)(g1 + 1536);
  }
  int p0 = Ps[pairSel];
  int aoff = ((p0 & 255) << 4) + moff;
  int boff = (((p0 >> 8) & 255) << 4) + moff;
  half8 rA0 = *(const half8*)(Ar0 + aoff);
  half8 rB0 = *(const half8*)(Br0 + boff);
  half8 rA1 = *(const half8*)(Ar1 + aoff);
  half8 rB1 = *(const half8*)(Br1 + boff);

  for (int sl = 0; sl < nslab; sl++) {
    half8 a0 = rA0 * rB0;
    half8 a1 = rA1 * rB1;
    if (sl + 1 < nslab) {
      int pn = Ps[2*(sl + 1) + pairSel];
      int aoffn = ((pn & 255) << 4) + moff;
      int boffn = (((pn >> 8) & 255) << 4) + moff;
      rA0 = *(const half8*)(Ar0 + aoffn);
      rB0 = *(const half8*)(Br0 + boffn);
      rA1 = *(const half8*)(Ar1 + aoffn);
      rB1 = *(const half8*)(Br1 + boffn);
    }
    half8 d0, d1, d2, d3;
    if (sl + 2 < nslab) {
      const unsigned short* gn = gp + (size_t)(sl + 2) * 8192;
      d0 = *(const half8*)(gn);
      d1 = *(const half8*)(gn + 512);
      d2 = *(const half8*)(gn + 1024);
      d3 = *(const half8*)(gn + 1536);
    } else { d0 = c0; d1 = c1; d2 = c2; d3 = c3; }
    acc[0][0] = __builtin_amdgcn_mfma_f32_16x16x32_f16(a0, b0, acc[0][0], 0, 0, 0);
    acc[1][0] = __builtin_amdgcn_mfma_f32_16x16x32_f16(a1, b0, acc[1][0], 0, 0, 0);
    acc[0][1] = __builtin_amdgcn_mfma_f32_16x16x32_f16(a0, b1, acc[0][1], 0, 0, 0);
    acc[1][1] = __builtin_amdgcn_mfma_f32_16x16x32_f16(a1, b1, acc[1][1], 0, 0, 0);
    acc[0][2] = __builtin_amdgcn_mfma_f32_16x16x32_f16(a0, b2, acc[0][2], 0, 0, 0);
    acc[1][2] = __builtin_amdgcn_mfma_f32_16x16x32_f16(a1, b2, acc[1][2], 0, 0, 0);
    acc[0][3] = __builtin_amdgcn_mfma_f32_16x16x32_f16(a0, b3, acc[0][3], 0, 0, 0);
    acc[1][3] = __builtin_amdgcn_mfma_f32_16x16x32_f16(a1, b3, acc[1][3], 0, 0, 0);
    b0 = c0; b1 = c1; b2 = c2; b3 = c3;
    c0 = d0; c1 = d1; c2 = d2; c3 = d3;
  }
  const int r4 = (lane >> 4) << 2;
#pragma unroll
  for (int rg = 0; rg < 2; rg++) {
#pragma unroll
    for (int j = 0; j < 4; j++) {
#pragma unroll
      for (int r = 0; r < 4; r++) {
        int row = e0 + rowb + rg*16 + r4 + r;
        int col = wc + j*16 + fr;
        Vn[(size_t)row*256 + col] = f2h(acc[rg][j][r]);
      }
    }
  }
}

// ---- Gtt[slab][col][32] = coupling x Wv (fp16, tiled). col = kabs*16+d ----
__global__ void gbuild_k(const float* __restrict__ TD,
    const float* __restrict__ Wv1, const float* __restrict__ Wv2,
    const float* __restrict__ Wv3, const int* __restrict__ sl_origc,
    unsigned short* __restrict__ Gt, int Kdim, int npairs,
    int s1b, int s1e, int s2e, int s3e)
{
  int k = blockIdx.x*256 + threadIdx.x;
  if (k >= Kdim) return;
  int col = blockIdx.y;
  int pair = k >> 4, m = k & 15;
  int d = col & 15, kabs = col >> 4;
  float acc = 0.f;
  if (kabs > 0 && pair < npairs) {
    const float* Wv; int ss, se, kloc;
    if (kabs < 4)      { Wv = Wv1; ss = s1b; se = s1e; kloc = kabs - 1; }
    else if (kabs < 9) { Wv = Wv2; ss = s1e; se = s2e; kloc = kabs - 4; }
    else               { Wv = Wv3; ss = s2e; se = s3e; kloc = kabs - 9; }
    for (int slot = ss; slot < se; slot++)
      acc += TD[((pair*30) + (slot - 4))*8 + kloc] * Wv[(sl_origc[slot] + m)*16 + d];
    acc *= rsqrtf((float)(16*(se - ss)));
  }
  Gt[((size_t)((k >> 5)*256 + col))*32 + (k & 31)] = f2h(acc);
}

// ---- weight convert + transpose: Wt[n][k] = fp16(W[k][n]) ----
struct WDesc { const float* src; unsigned short* dst; int K; int lgN; };
struct WPack { WDesc d[9]; };
__global__ void wcvt_k(WPack p){
  WDesc d = p.d[blockIdx.y];
  int total = d.K << d.lgN;
  int gid = blockIdx.x*256 + threadIdx.x;
  if (gid >= total) return;
  int k = gid >> d.lgN, n = gid & ((1 << d.lgN) - 1);
  d.dst[(size_t)n*d.K + k] = f2h(d.src[gid]);
}

// Generic fp32 tiled GEMM (small two-body layers, fp32 in/out).
template<int FLAGS>
__global__ __launch_bounds__(256) void gemm_k(
    const float* __restrict__ A1, const float* __restrict__ A2,
    int K1, int K, const float* __restrict__ W, int N,
    float* Cout,
    const float* __restrict__ env, const float* __restrict__ alphap,
    const float* Xres)
{
  __shared__ float As[16][68];
  __shared__ float Ws[16][68];
  const int tid = threadIdx.x;
  const int bm = blockIdx.x * 64;
  const int bn = blockIdx.y * 64;
  const int tx = tid & 15, ty = tid >> 4;
  const int K2 = K - K1;
  float acc[4][4] = {};
  for (int k0 = 0; k0 < K; k0 += 16) {
#pragma unroll
    for (int i = 0; i < 4; i++) {
      int idx = tid + i*256;
      int m = idx >> 4, kk = idx & 15;
      int k = k0 + kk;
      float v = 0.f;
      if (k < K) {
        int row = bm + m;
        v = (k < K1) ? A1[(size_t)row*K1 + k] : A2[(size_t)row*K2 + (k-K1)];
      }
      As[kk][m] = v;
    }
#pragma unroll
    for (int i = 0; i < 4; i++) {
      int idx = tid + i*256;
      int n = idx & 63, kk = idx >> 6;
      int k = k0 + kk, col = bn + n;
      Ws[kk][n] = (k < K && col < N) ? W[(size_t)k*N + col] : 0.f;
    }
    __syncthreads();
#pragma unroll
    for (int kk = 0; kk < 16; kk++) {
      float a[4], b[4];
#pragma unroll
      for (int i=0;i<4;i++) a[i] = As[kk][ty*4+i];
#pragma unroll
      for (int j=0;j<4;j++) b[j] = Ws[kk][tx*4+j];
#pragma unroll
      for (int i=0;i<4;i++)
#pragma unroll
        for (int j=0;j<4;j++)
          acc[i][j] += a[i]*b[j];
    }
    __syncthreads();
  }
  const float rscale = 1.f/sqrtf((float)K);
  float a2 = 0.f, inv1a2 = 1.f;
  if (FLAGS & F_RESID) { float al = alphap[0]; a2 = al*al; inv1a2 = 1.f/(1.f+a2); }
#pragma unroll
  for (int i=0;i<4;i++) {
    int row = bm + ty*4 + i;
    float ev = (FLAGS & F_ENV) ? env[row] : 1.f;
#pragma unroll
    for (int j=0;j<4;j++) {
      int col = bn + tx*4 + j;
      if (col >= N) continue;
      float v = acc[i][j]*rscale;
      if (FLAGS & F_SILU) v = v/(1.f+__expf(-v));
      if (FLAGS & F_ENV)  v *= ev;
      if (FLAGS & F_RESID) v = (Xres[(size_t)row*N+col] + a2*v)*inv1a2;
      Cout[(size_t)row*N+col] = v;
    }
  }
}

// dense to 16 outputs, K=256 fixed, scale 1/16; A fp16
__global__ __launch_bounds__(256) void dense16_k(const unsigned short* __restrict__ A,
    const float* __restrict__ W, float* __restrict__ C)
{
  __shared__ float As[16*256];
  const int r0 = blockIdx.x << 4;
  const int tid = threadIdx.x;
  for (int i = tid; i < 16*256; i += 256)
    As[i] = h2f(A[((size_t)r0<<8) + i]);
  __syncthreads();
  const int r = tid >> 4, n = tid & 15;
  float acc = 0.f;
#pragma unroll 8
  for (int k = 0; k < 256; k++)
    acc += As[(r<<8)+k] * W[(k<<4)+n];
  C[((size_t)(r0+r)<<4)+n] = acc * 0.0625f;
}

__global__ void edge_init_k(const float* __restrict__ vectors, const int* __restrict__ senders,
    const int* __restrict__ receivers, const int* __restrict__ species,
    const float* __restrict__ emb, float* __restrict__ envb, float* __restrict__ Yb,
    float* __restrict__ x72)
{
  const int e = blockIdx.x*256 + threadIdx.x;
  float vx = vectors[e*3+0], vy = vectors[e*3+1], vz = vectors[e*3+2];
  float d = sqrtf(vx*vx+vy*vy+vz*vz);
  float dd = (d==0.f) ? 1.f : d;
  float invd = 1.f/dd;
  float x = vx*invd, y = vy*invd, z = vz*invd;
  float d2=d*d, d3=d2*d, d6=d3*d3, d7=d6*d, d8=d7*d;
  float envv = (d<1.f) ? (1.f - 28.f*d6 + 48.f*d7 - 21.f*d8) : 0.f;
  envb[e] = envv;
  float mask = (d==0.f)?0.f:1.f;
  const float SQ2 = 1.41421356237309515f;
  const float PIf = 3.14159265358979323846f;
  float* xr = x72 + (size_t)e*72;
#pragma unroll
  for (int n=1;n<=8;n++)
    xr[n-1] = SQ2 * sinf((float)n*PIf*dd)*invd*envv*mask;
  int sp_s = species[senders[e]], sp_r = species[receivers[e]];
  const float* es_ = emb + (size_t)sp_s*32;
  const float* er_ = emb + (size_t)sp_r*32;
#pragma unroll 8
  for (int k=0;k<32;k++){ xr[8+k] = es_[k]*mask; xr[40+k] = er_[k]*mask; }
  float x2=x*x, y2=y*y, z2=z*z;
  const float s3=1.7320508075688772f, s15=3.872983346207417f, s5=2.23606797749979f;
  const float s358=2.0916500663351889f, s105=10.246950765959598f;
  const float s218=1.6201851746019651f, s7=2.6457513110645907f;
  float* Yr = Yb + ((size_t)e<<4);
  Yr[0]=1.f;           Yr[1]=s3*y;          Yr[2]=s3*z;           Yr[3]=s3*x;
  Yr[4]=s15*x*y;       Yr[5]=s15*y*z;       Yr[6]=0.5f*s5*(3.f*z2-1.f);
  Yr[7]=s15*x*z;       Yr[8]=0.5f*s15*(x2-y2);
  Yr[9]=s358*y*(3.f*x2-y2);  Yr[10]=s105*x*y*z;  Yr[11]=s218*y*(5.f*z2-1.f);
  Yr[12]=0.5f*s7*(5.f*z2-3.f)*z;  Yr[13]=s218*x*(5.f*z2-1.f);
  Yr[14]=0.5f*s105*(x2-y2)*z;     Yr[15]=s358*x*(x2-y2);
}

// V16[e][a*16+m] = fp16(w0[e,m]*Y[e,a])
__global__ void vinit_k(const float* __restrict__ w0, const float* __restrict__ Y,
                        unsigned short* __restrict__ V)
{
  const int gid = blockIdx.x*256 + threadIdx.x;
  const int e = gid >> 8, idx = gid & 255;
  V[gid] = f2h(w0[(e<<4)+(idx&15)] * Y[(e<<4)+(idx>>4)]);
}

// node[senders[e]][a*16+m] += w[e,m]*Y[e,a]  (fp32 atomics)
__global__ void scatter_k(const float* __restrict__ w, const float* __restrict__ Y,
                          const int* __restrict__ senders, float* node)
{
  const int gid = blockIdx.x*256 + threadIdx.x;
  const int e = gid >> 8, idx = gid & 255;
  float v = w[(e<<4) + (idx&15)] * Y[(e<<4) + (idx>>4)];
  atomicAdd(&node[((size_t)senders[e]<<8) + idx], v);
}

// l3=0 TP (slots 0..3); B (V/Vn) fp16; tp0 out fp16
__global__ void tp2_k(const float* __restrict__ node, const unsigned short* __restrict__ Vn,
    const int* __restrict__ senders, const float* __restrict__ varepsp,
    const int* __restrict__ pmeta, const int* __restrict__ entIJ,
    const float* __restrict__ entVal, unsigned short* __restrict__ tp0)
{
  const int gid = blockIdx.x*256 + threadIdx.x;
  const int e = gid >> 6, c = gid & 63;
  const int p = c >> 4, m = c & 15;
  float ve = varepsp[0];
  float eps = rsqrtf(1.f + ve*ve);
  int s = senders[e];
  const float* Am = &node[((size_t)s<<8)];
  const unsigned short* Bm = &Vn[((size_t)e<<8)];
  int es = pmeta[p*4+1], ec = pmeta[p*4+2];
  float acc = 0.f;
  for (int t=0;t<ec;t++){
    int ij = entIJ[es+t];
    acc += entVal[es+t] * Am[((ij&255)<<4) + m] * h2f(Bm[(((ij>>8)&255)<<4) + m]);
  }
  tp0[((size_t)e<<6) + pmeta[p*4+0] + m] = f2h(acc * eps);
}

// out[e] = env[e] * dot(X16[e,:128], Wout) / sqrt(128)
__global__ void final_k(const unsigned short* __restrict__ X, const float* __restrict__ Wout,
                        const float* __restrict__ env, float* __restrict__ out)
{
  const int e = blockIdx.x*256 + threadIdx.x;
  float acc = 0.f;
#pragma unroll 16
  for (int k=0;k<128;k++) acc += h2f(X[((size_t)e<<7)+k])*Wout[k];
  out[e] = env[e]*acc*0.088388347648318447f;
}

// ============================ host launcher ============================

static void launch_gemm(int flags, const float* A1, const float* A2, int K1, int K,
    const float* W, int N, float* C, const float* env, const float* alphap,
    const float* Xres, hipStream_t stream)
{
  dim3 grid(E_EDGES/64, (N+63)/64);
  switch(flags){
    case F_NONE:        gemm_k<F_NONE>       <<<grid,256,0,stream>>>(A1,A2,K1,K,W,N,C,env,alphap,Xres); break;
    case F_SILU:        gemm_k<F_SILU>       <<<grid,256,0,stream>>>(A1,A2,K1,K,W,N,C,env,alphap,Xres); break;
    case F_ENV:         gemm_k<F_ENV>        <<<grid,256,0,stream>>>(A1,A2,K1,K,W,N,C,env,alphap,Xres); break;
    case F_ENV|F_RESID: gemm_k<F_ENV|F_RESID><<<grid,256,0,stream>>>(A1,A2,K1,K,W,N,C,env,alphap,Xres); break;
  }
}

static void launch_mgemm(int flags, int a16, const void* A1, const void* A2, int K1, int K,
    const unsigned short* Wt, int N, unsigned short* C, const float* env,
    const float* alphap, const unsigned short* Xres, hipStream_t stream)
{
  dim3 grid(E_EDGES/128, N/128);
  if (a16) {
    switch(flags){
      case F_NONE:        mgemm_k<F_NONE,1>       <<<grid,256,0,stream>>>(A1,A2,K1,K,Wt,N,C,env,alphap,Xres); break;
      case F_SILU:        mgemm_k<F_SILU,1>       <<<grid,256,0,stream>>>(A1,A2,K1,K,Wt,N,C,env,alphap,Xres); break;
      case F_ENV:         mgemm_k<F_ENV,1>        <<<grid,256,0,stream>>>(A1,A2,K1,K,Wt,N,C,env,alphap,Xres); break;
      case F_ENV|F_RESID: mgemm_k<F_ENV|F_RESID,1><<<grid,256,0,stream>>>(A1,A2,K1,K,Wt,N,C,env,alphap,Xres); break;
    }
  } else {
    switch(flags){
      case F_SILU:        mgemm_k<F_SILU,0>       <<<grid,256,0,stream>>>(A1,A2,K1,K,Wt,N,C,env,alphap,Xres); break;
      case F_ENV:         mgemm_k<F_ENV,0>        <<<grid,256,0,stream>>>(A1,A2,K1,K,Wt,N,C,env,alphap,Xres); break;
      default: break;
    }
  }
}

extern "C" void kernel_launch(void* const* d_in, const int* in_sizes, int n_in,
                              void* d_out, int out_size, void* d_ws, size_t ws_size,
                              hipStream_t stream)
{
  const float* vectors = (const float*)d_in[0];
  const float* vareps  = (const float*)d_in[1];
  const float* alpha   = (const float*)d_in[2];
  const float* emb     = (const float*)d_in[3];
  const float* W_tb1   = (const float*)d_in[4];
  const float* W_tb2   = (const float*)d_in[5];
  const float* W_tb3   = (const float*)d_in[6];
  const float* W_tb4   = (const float*)d_in[7];
  const float* W_w0    = (const float*)d_in[8];
  const float* W_w1    = (const float*)d_in[9];
  const float* W_l11   = (const float*)d_in[10];
  const float* W_l12   = (const float*)d_in[11];
  const float* W_l13   = (const float*)d_in[12];
  const float* W_v1    = (const float*)d_in[13];
  const float* W_v2    = (const float*)d_in[14];
  const float* W_v3    = (const float*)d_in[15];
  const float* W_w2    = (const float*)d_in[16];
  const float* W_l21   = (const float*)d_in[17];
  const float* W_l22   = (const float*)d_in[18];
  const float* W_l23   = (const float*)d_in[19];
  const float* W_h     = (const float*)d_in[20];
  const float* W_out   = (const float*)d_in[21];
  const int* senders   = (const int*)d_in[22];
  const int* receivers = (const int*)d_in[23];
  const int* species   = (const int*)d_in[24];

  static cgt::Tables tb;
  cgt::build(tb);
  const int Kdim = tb.npairs * 16;

  char* ws = (char*)d_ws;
  size_t off = 0;
  auto alloc = [&](size_t bytes)->void*{
    void* p = ws + off; off += (bytes + 255) & ~(size_t)255; return p;
  };
  float* t_val = (float*)alloc(sizeof(tb.val));
  int*   t_ij  = (int*)  alloc(sizeof(tb.ij));
  int*   t_pm  = (int*)  alloc(sizeof(tb.pmeta));
  float* t_td  = (float*)alloc(sizeof(tb.TD));
  int*   t_pr  = (int*)  alloc(sizeof(tb.pairs));
  int*   t_oc  = (int*)  alloc(sizeof(tb.sl_origc));
  float* envb  = (float*)alloc((size_t)E_EDGES*4);
  float* Yb    = (float*)alloc((size_t)E_EDGES*16*4);
  float* xb    = (float*)alloc((size_t)E_EDGES*256*4);
  float* Vb    = (float*)alloc((size_t)E_EDGES*256*4);
  float* bufA  = (float*)alloc((size_t)E_EDGES*256*4);
  float* bufB  = (float*)alloc((size_t)E_EDGES*256*4);
  float* wb    = (float*)alloc((size_t)E_EDGES*16*4);
  float* tp0b  = (float*)alloc((size_t)E_EDGES*64*4);
  float* nodeb = (float*)alloc((size_t)NNODES*256*4);
  unsigned short* Gt = (unsigned short*)alloc((size_t)256*Kdim*2);
  unsigned short* Wt_tb3 = (unsigned short*)alloc(64*128*2);
  unsigned short* Wt_tb4 = (unsigned short*)alloc(128*256*2);
  unsigned short* Wt_l11 = (unsigned short*)alloc(320*256*2);
  unsigned short* Wt_l12 = (unsigned short*)alloc(256*256*2);
  unsigned short* Wt_l13 = (unsigned short*)alloc(256*256*2);
  unsigned short* Wt_l21 = (unsigned short*)alloc(320*256*2);
  unsigned short* Wt_l22 = (unsigned short*)alloc(256*256*2);
  unsigned short* Wt_l23 = (unsigned short*)alloc(256*256*2);
  unsigned short* Wt_h   = (unsigned short*)alloc(256*128*2);
  if (off > ws_size) {
    fprintf(stderr, "[allegro] workspace too small: need %zu, have %zu\n", off, ws_size);
    return;
  }
  // fp16 views of activation buffers
  unsigned short* xb16 = (unsigned short*)xb;
  unsigned short* bA16 = (unsigned short*)bufA;
  unsigned short* bB16 = (unsigned short*)bufB;
  unsigned short* tp016 = (unsigned short*)tp0b;
  unsigned short* V16 = (unsigned short*)Vb;

  hipMemcpyAsync(t_val, tb.val,     sizeof(tb.val),     hipMemcpyHostToDevice, stream);
  hipMemcpyAsync(t_ij,  tb.ij,      sizeof(tb.ij),      hipMemcpyHostToDevice, stream);
  hipMemcpyAsync(t_pm,  tb.pmeta,   sizeof(tb.pmeta),   hipMemcpyHostToDevice, stream);
  hipMemcpyAsync(t_td,  tb.TD,      sizeof(tb.TD),      hipMemcpyHostToDevice, stream);
  hipMemcpyAsync(t_pr,  tb.pairs,   sizeof(tb.pairs),   hipMemcpyHostToDevice, stream);
  hipMemcpyAsync(t_oc,  tb.sl_origc,sizeof(tb.sl_origc),hipMemcpyHostToDevice, stream);

  const int s1b = tb.l3np[0];
  const int s1e = s1b + tb.l3np[1];
  const int s2e = s1e + tb.l3np[2];
  const int s3e = s2e + tb.l3np[3];

  {
    dim3 g((Kdim + 255)/256, 256);
    gbuild_k<<<g, 256, 0, stream>>>(t_td, W_v1, W_v2, W_v3, t_oc, Gt, Kdim,
                                    tb.npairs, s1b, s1e, s2e, s3e);
  }
  {
    WPack p;
    p.d[0] = { W_tb3, Wt_tb3,  64, 7 };
    p.d[1] = { W_tb4, Wt_tb4, 128, 8 };
    p.d[2] = { W_l11, Wt_l11, 320, 8 };
    p.d[3] = { W_l12, Wt_l12, 256, 8 };
    p.d[4] = { W_l13, Wt_l13, 256, 8 };
    p.d[5] = { W_l21, Wt_l21, 320, 8 };
    p.d[6] = { W_l22, Wt_l22, 256, 8 };
    p.d[7] = { W_h,   Wt_h,   256, 7 };
    p.d[8] = { W_l23, Wt_l23, 256, 8 };
    dim3 g(320, 9);
    wcvt_k<<<g, 256, 0, stream>>>(p);
  }

  // 1. edge features + Y + env  (x72 -> bufA fp32)
  edge_init_k<<<E_EDGES/256, 256, 0, stream>>>(vectors, senders, receivers, species,
                                               emb, envb, Yb, bufA);
  // 2. two-body MLP: 72->32->64 (fp32 gemm), 64->128->256 (fp16 mgemm)
  launch_gemm (F_SILU, bufA, nullptr, 72, 72,  W_tb1, 32,  bufB, envb, alpha, nullptr, stream);
  launch_gemm (F_SILU, bufB, nullptr, 32, 32,  W_tb2, 64,  bufA, envb, alpha, nullptr, stream);
  launch_mgemm(F_SILU, 0, bufA, nullptr, 64, 64,  Wt_tb3, 128, bB16, envb, alpha, nullptr, stream);
  launch_mgemm(F_ENV,  1, bB16, nullptr, 128,128, Wt_tb4, 256, xb16, envb, alpha, nullptr, stream);
  // 3. V = dense(x,W_w0) outer Y  ([a][m] layout, fp16)
  dense16_k<<<E_EDGES/16, 256, 0, stream>>>(xb16, W_w0, wb);
  vinit_k<<<E_EDGES, 256, 0, stream>>>(wb, Yb, V16);

  // ---- layer 1 ----
  dense16_k<<<E_EDGES/16, 256, 0, stream>>>(xb16, W_w1, wb);
  hipMemsetAsync(nodeb, 0, (size_t)NNODES*256*4, stream);
  scatter_k<<<E_EDGES, 256, 0, stream>>>(wb, Yb, senders, nodeb);
  tp2_k<<<E_EDGES*64/256, 256, 0, stream>>>(nodeb, V16, senders, vareps, t_pm, t_ij,
                                            t_val, tp016);
  vn_k<<<E_EDGES/VN_E, 512, 0, stream>>>(nodeb, V16, senders, vareps, t_pr, Gt, V16, Kdim);
  launch_mgemm(F_SILU,        1, xb16, tp016,  256, 320, Wt_l11, 256, bB16, envb, alpha, nullptr, stream);
  launch_mgemm(F_SILU,        1, bB16, nullptr,256, 256, Wt_l12, 256, bA16, envb, alpha, nullptr, stream);
  launch_mgemm(F_ENV|F_RESID, 1, bA16, nullptr,256, 256, Wt_l13, 256, xb16, envb, alpha, xb16,    stream);

  // ---- layer 2 (lmax_out = 0) ----
  dense16_k<<<E_EDGES/16, 256, 0, stream>>>(xb16, W_w2, wb);
  hipMemsetAsync(nodeb, 0, (size_t)NNODES*256*4, stream);
  scatter_k<<<E_EDGES, 256, 0, stream>>>(wb, Yb, senders, nodeb);
  tp2_k<<<E_EDGES*64/256, 256, 0, stream>>>(nodeb, V16, senders, vareps, t_pm, t_ij,
                                            t_val, tp016);
  launch_mgemm(F_SILU,        1, xb16, tp016,  256, 320, Wt_l21, 256, bB16, envb, alpha, nullptr, stream);
  launch_mgemm(F_SILU,        1, bB16, nullptr,256, 256, Wt_l22, 256, bA16, envb, alpha, nullptr, stream);
  launch_mgemm(F_ENV|F_RESID, 1, bA16, nullptr,256, 256, Wt_l23, 256, xb16, envb, alpha, xb16,    stream);

  // ---- head ----
  launch_mgemm(F_NONE, 1, xb16, nullptr, 256, 256, Wt_h, 128, bB16, envb, alpha, nullptr, stream);
  final_k<<<E_EDGES/256, 256, 0, stream>>>(bB16, W_out, envb, (float*)d_out);
}

// Round 12
// 507.583 us; speedup vs baseline: 1.1534x; 1.0927x over previous
//
#include <hip/hip_runtime.h>
#include <cmath>
#include <complex>
#include <cstdio>
#include <cstring>
#include <algorithm>

#define E_EDGES 32768
#define NNODES  2048
#define VN_E    128     // edges per vn_k block (R12: 64 -> 128, 2x MFMA per G byte)

// ============================ host-side CG tables ============================
namespace cgt {

static double fct(int n){
  static const double f[13] = {1.,1.,2.,6.,24.,120.,720.,5040.,40320.,362880.,
                               3628800.,39916800.,479001600.};
  return f[n];
}

static double cg(int j1,int m1,int j2,int m2,int j3,int m3){
  if (m1+m2 != m3) return 0.0;
  double pre = std::sqrt((2*j3+1)*fct(j1+j2-j3)*fct(j1-j2+j3)*fct(-j1+j2+j3)/fct(j1+j2+j3+1));
  pre *= std::sqrt(fct(j3+m3)*fct(j3-m3)*fct(j1-m1)*fct(j1+m1)*fct(j2-m2)*fct(j2+m2));
  int kmin = 0;
  if (j2-j3-m1 > kmin) kmin = j2-j3-m1;
  if (j1-j3+m2 > kmin) kmin = j1-j3+m2;
  int kmax = j1+j2-j3;
  if (j1-m1 < kmax) kmax = j1-m1;
  if (j2+m2 < kmax) kmax = j2+m2;
  double s = 0.0;
  for (int k=kmin;k<=kmax;k++){
    double d = fct(k)*fct(j1+j2-j3-k)*fct(j1-m1-k)*fct(j2+m2-k)*fct(j3-j2+m1+k)*fct(j3-j1-m2+k);
    s += ((k&1)? -1.0:1.0)/d;
  }
  return pre*s;
}

typedef std::complex<double> cd;

static void umat(int l, cd U[7][7]){
  for (int a=0;a<7;a++) for (int b=0;b<7;b++) U[a][b]=cd(0,0);
  U[l][l] = cd(1,0);
  double s2 = 1.0/std::sqrt(2.0);
  for (int m=1;m<=l;m++){
    double sg = (m&1)? -1.0 : 1.0;
    U[l+m][l-m] = cd(s2,0);
    U[l+m][l+m] = cd(sg*s2,0);
    U[l-m][l-m] = cd(0, s2);
    U[l-m][l+m] = cd(0, -sg*s2);
  }
}

static bool realCoupling(int l1,int l2,int l3, double T[7][7][7]){
  cd U1[7][7],U2[7][7],U3[7][7];
  umat(l1,U1); umat(l2,U2); umat(l3,U3);
  int n1=2*l1+1, n2=2*l2+1, n3=2*l3+1;
  double Cg[7][7][7];
  for (int m=0;m<n1;m++) for(int n=0;n<n2;n++) for(int k=0;k<n3;k++)
    Cg[m][n][k] = cg(l1,m-l1,l2,n-l2,l3,k-l3);
  double Tr[7][7][7], Ti[7][7][7];
  double nr=0, ni=0;
  for (int a=0;a<n1;a++) for(int b=0;b<n2;b++) for(int c=0;c<n3;c++){
    cd s(0,0);
    for (int m=0;m<n1;m++){
      if (U1[a][m]==cd(0,0)) continue;
      for (int n=0;n<n2;n++){
        if (U2[b][n]==cd(0,0)) continue;
        for (int k=0;k<n3;k++){
          double cgv = Cg[m][n][k];
          if (cgv==0.0) continue;
          s += U1[a][m]*U2[b][n]*std::conj(U3[c][k])*cgv;
        }
      }
    }
    Tr[a][b][c]=s.real(); Ti[a][b][c]=s.imag();
    nr += s.real()*s.real(); ni += s.imag()*s.imag();
  }
  bool useR = (nr >= ni);
  double nn = std::sqrt(useR? nr : ni);
  if (nn < 1e-8) return false;
  for (int a=0;a<n1;a++)for(int b=0;b<n2;b++)for(int c=0;c<n3;c++)
    T[a][b][c] = (useR? Tr[a][b][c] : Ti[a][b][c])/nn;
  return true;
}

struct Tables {
  float val[4096];
  int   ij[4096];
  int   pmeta[40*4];
  int   ccnt[40*8];
  int   l3base[4];
  int   l3np[4];
  int   npaths;
  int   nent;
  int   tptot;
  int   pairs[256];
  float TD[256*30*8];
  int   sl_origc[40];
  int   npairs;
};

struct PathTmp {
  int l1,l2,l3, tpoff, kd;
  int ec;
  double T[7][7][7];
};

static void build(Tables& tb){
  static PathTmp paths[40];
  int np = 0, tpoff = 0;
  int l3start[5];
  for (int l3=0;l3<=3;l3++){
    tb.l3base[l3] = tpoff;
    l3start[l3] = np;
    int kd = 2*l3+1;
    for (int l1=0;l1<=3;l1++) for (int l2=0;l2<=3;l2++){
      int lo = (l1>l2)? l1-l2 : l2-l1;
      int hi = std::min(l1+l2,3);
      if (l3 < lo || l3 > hi) continue;
      PathTmp& pt = paths[np];
      if (!realCoupling(l1,l2,l3,pt.T)) continue;
      pt.l1=l1; pt.l2=l2; pt.l3=l3; pt.kd=kd; pt.tpoff=tpoff;
      double scale = std::sqrt((double)kd);
      int cnt = 0;
      for (int a=0;a<2*l1+1;a++)for(int b=0;b<2*l2+1;b++)for(int c=0;c<kd;c++)
        if (std::fabs(pt.T[a][b][c]*scale) > 1e-7) cnt++;
      pt.ec = cnt;
      tpoff += 16*kd;
      np++;
    }
  }
  l3start[4] = np;
  for (int l3=0;l3<=3;l3++) tb.l3np[l3] = l3start[l3+1]-l3start[l3];
  static int order[40];
  for (int i=0;i<np;i++) order[i]=i;
  for (int l3=0;l3<=3;l3++)
    std::sort(order+l3start[l3], order+l3start[l3+1],
              [&](int a,int b){ return paths[a].ec > paths[b].ec; });
  std::memset(tb.TD, 0, sizeof(tb.TD));
  std::memset(tb.pairs, 0, sizeof(tb.pairs));
  static int pmap[16][16];
  for (int i=0;i<16;i++) for (int j=0;j<16;j++) pmap[i][j] = -1;
  int npr = 0;
  int ep = 0;
  for (int slot=0; slot<np; slot++){
    const PathTmp& pt = paths[order[slot]];
    double scale = std::sqrt((double)pt.kd);
    int s1 = pt.l1*pt.l1, s2 = pt.l2*pt.l2;
    tb.pmeta[slot*4+0] = pt.tpoff;
    tb.pmeta[slot*4+1] = ep;
    tb.sl_origc[slot] = ((pt.tpoff - tb.l3base[pt.l3]) / (16*pt.kd)) * 16;
    int tot = 0;
    for (int c=0;c<pt.kd;c++){
      int cnt = 0;
      for (int a=0;a<2*pt.l1+1;a++)for(int b=0;b<2*pt.l2+1;b++){
        double v = pt.T[a][b][c]*scale;
        if (std::fabs(v) > 1e-7){
          tb.val[ep] = (float)v;
          tb.ij[ep]  = (s1+a) | ((s2+b)<<8);
          ep++; cnt++;
          if (pt.l3 >= 1){
            int aa = s1+a, bb = s2+b;
            int pi = pmap[aa][bb];
            if (pi < 0){ pi = npr; pmap[aa][bb] = pi;
                         tb.pairs[npr] = aa | (bb<<8); npr++; }
            tb.TD[(pi*30 + (slot-4))*8 + c] = (float)v;
          }
        }
      }
      tb.ccnt[slot*8+c] = cnt;
      tot += cnt;
    }
    for (int c=pt.kd;c<8;c++) tb.ccnt[slot*8+c]=0;
    tb.pmeta[slot*4+2] = tot;
    tb.pmeta[slot*4+3] = pt.kd;
  }
  if (npr & 1){ tb.pairs[npr] = 0; npr++; }
  tb.npairs = npr;
  tb.npaths = np; tb.nent = ep; tb.tptot = tpoff;
}

} // namespace cgt

// ============================ device kernels ============================
// LAYOUT: node/V/Vn rows are [a][m] (element (m,a) at a*16+m).
// Activations in HBM are fp16 on the MFMA path.

enum GFlags { F_NONE=0, F_SILU=1, F_ENV=2, F_RESID=4 };

typedef _Float16 half8 __attribute__((ext_vector_type(8)));
typedef _Float16 half4 __attribute__((ext_vector_type(4)));
typedef __attribute__((ext_vector_type(4))) float f32x4;

__device__ inline unsigned short f2h(float f){
  union { _Float16 h; unsigned short u; } x;
  x.h = (_Float16)f;
  return x.u;
}
__device__ inline float h2f(unsigned short u){
  union { _Float16 h; unsigned short u; } x; x.u = u;
  return (float)x.h;
}

__device__ inline int swz(int row, int kh){
  int b = row*64 + kh*2;
  return b ^ (((row >> 1) & 3) << 4);
}

// ---- fp16 MFMA GEMM: C16[M,N] = post( A[M,K] @ W[K,N] / sqrt(K) ) ----
template<int FLAGS, int A16>
__global__ __launch_bounds__(256) void mgemm_k(
    const void* __restrict__ A1v, const void* __restrict__ A2v,
    int K1, int K, const unsigned short* __restrict__ Wt, int N,
    unsigned short* Cout, const float* __restrict__ env,
    const float* __restrict__ alphap, const unsigned short* Xres)
{
  __shared__ unsigned short AsB[128*32];
  __shared__ unsigned short BsB[128*32];
  const int tid  = threadIdx.x;
  const int wave = tid >> 6, lane = tid & 63;
  const int bm = blockIdx.x*128, bn = blockIdx.y*128;
  const int wr = (wave >> 1)*64, wc = (wave & 1)*64;
  const int K2 = K - K1;
  f32x4 acc[4][4] = {};

  const int sr  = tid >> 3;
  const int skq = (tid & 7) * 4;
  const int sr2 = tid >> 1;
  const int skh = (tid & 1) * 16;
  const int bn_ = tid >> 1;
  const int bkh = (tid & 1) * 16;

  for (int k0 = 0; k0 < K; k0 += 32) {
    if (A16) {
      int kk = k0 + skh;
      const unsigned short* ap = (kk < K1)
        ? (const unsigned short*)A1v + (size_t)(bm + sr2)*K1 + kk
        : (const unsigned short*)A2v + (size_t)(bm + sr2)*K2 + (kk - K1);
      uint4 u0 = *(const uint4*)ap;
      uint4 u1 = *(const uint4*)(ap + 8);
      *(uint4*)((char*)AsB + swz(sr2, skh))     = u0;
      *(uint4*)((char*)AsB + swz(sr2, skh + 8)) = u1;
    } else {
#pragma unroll
      for (int q = 0; q < 4; q++) {
        int row = q*32 + sr;
        int grow = bm + row;
        int kk = k0 + skq;
        float4 f4 = (kk < K1)
          ? *(const float4*)((const float*)A1v + (size_t)grow*K1 + kk)
          : *(const float4*)((const float*)A2v + (size_t)grow*K2 + (kk - K1));
        ushort4 u;
        u.x = f2h(f4.x); u.y = f2h(f4.y); u.z = f2h(f4.z); u.w = f2h(f4.w);
        *(ushort4*)((char*)AsB + swz(row, skq)) = u;
      }
    }
    {
      const unsigned short* s = Wt + (size_t)(bn + bn_)*K + k0 + bkh;
#pragma unroll
      for (int q = 0; q < 4; q++) {
        ushort4 u = *(const ushort4*)(s + q*4);
        *(ushort4*)((char*)BsB + swz(bn_, bkh + q*4)) = u;
      }
    }
    __syncthreads();
    const int fr = lane & 15, fk = (lane >> 4) * 8;
    half8 af[4], bf[4];
#pragma unroll
    for (int i = 0; i < 4; i++)
      af[i] = *(half8*)((char*)AsB + swz(wr + i*16 + fr, fk));
#pragma unroll
    for (int j = 0; j < 4; j++)
      bf[j] = *(half8*)((char*)BsB + swz(wc + j*16 + fr, fk));
#pragma unroll
    for (int i = 0; i < 4; i++)
#pragma unroll
      for (int j = 0; j < 4; j++)
        acc[i][j] = __builtin_amdgcn_mfma_f32_16x16x32_f16(af[i], bf[j], acc[i][j], 0, 0, 0);
    __syncthreads();
  }

  const float rscale = 1.f/sqrtf((float)K);
  float a2 = 0.f, inv1a2 = 1.f;
  if (FLAGS & F_RESID) { float al = alphap[0]; a2 = al*al; inv1a2 = 1.f/(1.f+a2); }
#pragma unroll
  for (int i = 0; i < 4; i++) {
#pragma unroll
    for (int r = 0; r < 4; r++) {
      int row = bm + wr + i*16 + ((lane >> 4) << 2) + r;
      float ev = (FLAGS & F_ENV) ? env[row] : 1.f;
#pragma unroll
      for (int j = 0; j < 4; j++) {
        int col = bn + wc + j*16 + (lane & 15);
        float v = acc[i][j][r]*rscale;
        if (FLAGS & F_SILU) v = v/(1.f+__expf(-v));
        if (FLAGS & F_ENV)  v *= ev;
        if (FLAGS & F_RESID) v = (h2f(Xres[(size_t)row*N+col]) + a2*v)*inv1a2;
        Cout[(size_t)row*N+col] = f2h(v);
      }
    }
  }
}

// ---- fused Vn kernel v6: 128 edges/block, wave = 64 rows x 64 cols ----
// R11 post-mortem: waves can't share G registers, so per-block G traffic was
// 2x G regardless of VN_E; each G fragment fed only 2 MFMAs. Fix: 4 row-frags
// per wave -> 16 MFMAs per slab per wave (2x MFMA per G byte, 2x work per
// loop-iteration overhead). LDS 135KB -> 1 block/CU, 8 waves; 2-deep G
// register prefetch unchanged.
__global__ __launch_bounds__(512) void vn_k(
    const float* __restrict__ node, const unsigned short* __restrict__ V,
    const int* __restrict__ senders, const float* __restrict__ varepsp,
    const int* __restrict__ pairsG, const unsigned short* __restrict__ Gtt,
    unsigned short* __restrict__ Vn, int Kdim)
{
  __shared__ unsigned short Ab[VN_E*264];
  __shared__ unsigned short Bb[VN_E*264];
  __shared__ int Ps[256];
  const int tid = threadIdx.x;
  const int e0 = blockIdx.x * VN_E;
  const int wave = tid >> 6, lane = tid & 63;
  float ve = varepsp[0];
  float eps = rsqrtf(1.f + ve*ve);
  if (tid < 256) Ps[tid] = pairsG[tid];
#pragma unroll
  for (int rr = 0; rr < 16; rr++) {
    int row = wave*16 + rr;
    int s = senders[e0 + row];
    float4 fa = *(const float4*)(node + ((size_t)s << 8) + 4*lane);
    uint2 ub = *(const uint2*)(V + (((size_t)(e0 + row)) << 8) + 4*lane);
    unsigned short* ad = Ab + row*264 + 4*lane;
    unsigned short* bd = Bb + row*264 + 4*lane;
    uint2 ua;
    ua.x = (unsigned)f2h(fa.x*eps) | ((unsigned)f2h(fa.y*eps) << 16);
    ua.y = (unsigned)f2h(fa.z*eps) | ((unsigned)f2h(fa.w*eps) << 16);
    *(uint2*)ad = ua;
    *(uint2*)bd = ub;
  }
  __syncthreads();
  const int rowb = (wave & 1) * 64;      // 64-edge half
  const int wc   = (wave >> 1) * 64;     // 64 output cols
  const int fr = lane & 15, fk = (lane >> 4) * 8;
  const int pairSel = fk >> 4;
  const int moff = fk & 15;
  const int nslab = Kdim >> 5;
  f32x4 acc[4][4] = {};                  // [row frag][col frag]

  const unsigned short* Ar0 = Ab + (rowb + fr)*264;
  const unsigned short* Br0 = Bb + (rowb + fr)*264;
  const unsigned short* Ar1 = Ab + (rowb + 16 + fr)*264;
  const unsigned short* Br1 = Bb + (rowb + 16 + fr)*264;
  const unsigned short* Ar2 = Ab + (rowb + 32 + fr)*264;
  const unsigned short* Br2 = Bb + (rowb + 32 + fr)*264;
  const unsigned short* Ar3 = Ab + (rowb + 48 + fr)*264;
  const unsigned short* Br3 = Bb + (rowb + 48 + fr)*264;

  const unsigned short* gp = Gtt + ((size_t)(wc + fr)) * 32 + fk;
  half8 b0 = *(const half8*)(gp);
  half8 b1 = *(const half8*)(gp + 512);
  half8 b2 = *(const half8*)(gp + 1024);
  half8 b3 = *(const half8*)(gp + 1536);
  half8 c0 = b0, c1 = b1, c2 = b2, c3 = b3;
  if (nslab > 1) {
    const unsigned short* g1 = gp + 8192;
    c0 = *(const half8*)(g1);
    c1 = *(const half8*)(g1 + 512);
    c2 = *(const half8*)(g1 + 1024);
    c3 = *(const half8*)(g1 + 1536);
  }
  int p0 = Ps[pairSel];
  int aoff = ((p0 & 255) << 4) + moff;
  int boff = (((p0 >> 8) & 255) << 4) + moff;
  half8 rA0 = *(const half8*)(Ar0 + aoff);
  half8 rB0 = *(const half8*)(Br0 + boff);
  half8 rA1 = *(const half8*)(Ar1 + aoff);
  half8 rB1 = *(const half8*)(Br1 + boff);
  half8 rA2 = *(const half8*)(Ar2 + aoff);
  half8 rB2 = *(const half8*)(Br2 + boff);
  half8 rA3 = *(const half8*)(Ar3 + aoff);
  half8 rB3 = *(const half8*)(Br3 + boff);

  for (int sl = 0; sl < nslab; sl++) {
    half8 a0 = rA0 * rB0;
    half8 a1 = rA1 * rB1;
    half8 a2 = rA2 * rB2;
    half8 a3 = rA3 * rB3;
    // prefetch A for slab+1 (LDS)
    if (sl + 1 < nslab) {
      int pn = Ps[2*(sl + 1) + pairSel];
      int aoffn = ((pn & 255) << 4) + moff;
      int boffn = (((pn >> 8) & 255) << 4) + moff;
      rA0 = *(const half8*)(Ar0 + aoffn);
      rB0 = *(const half8*)(Br0 + boffn);
      rA1 = *(const half8*)(Ar1 + aoffn);
      rB1 = *(const half8*)(Br1 + boffn);
      rA2 = *(const half8*)(Ar2 + aoffn);
      rB2 = *(const half8*)(Br2 + boffn);
      rA3 = *(const half8*)(Ar3 + aoffn);
      rB3 = *(const half8*)(Br3 + boffn);
    }
    // prefetch G for slab+2 (global, 2-deep)
    half8 d0, d1, d2, d3;
    if (sl + 2 < nslab) {
      const unsigned short* gn = gp + (size_t)(sl + 2) * 8192;
      d0 = *(const half8*)(gn);
      d1 = *(const half8*)(gn + 512);
      d2 = *(const half8*)(gn + 1024);
      d3 = *(const half8*)(gn + 1536);
    } else { d0 = c0; d1 = c1; d2 = c2; d3 = c3; }
    acc[0][0] = __builtin_amdgcn_mfma_f32_16x16x32_f16(a0, b0, acc[0][0], 0, 0, 0);
    acc[1][0] = __builtin_amdgcn_mfma_f32_16x16x32_f16(a1, b0, acc[1][0], 0, 0, 0);
    acc[2][0] = __builtin_amdgcn_mfma_f32_16x16x32_f16(a2, b0, acc[2][0], 0, 0, 0);
    acc[3][0] = __builtin_amdgcn_mfma_f32_16x16x32_f16(a3, b0, acc[3][0], 0, 0, 0);
    acc[0][1] = __builtin_amdgcn_mfma_f32_16x16x32_f16(a0, b1, acc[0][1], 0, 0, 0);
    acc[1][1] = __builtin_amdgcn_mfma_f32_16x16x32_f16(a1, b1, acc[1][1], 0, 0, 0);
    acc[2][1] = __builtin_amdgcn_mfma_f32_16x16x32_f16(a2, b1, acc[2][1], 0, 0, 0);
    acc[3][1] = __builtin_amdgcn_mfma_f32_16x16x32_f16(a3, b1, acc[3][1], 0, 0, 0);
    acc[0][2] = __builtin_amdgcn_mfma_f32_16x16x32_f16(a0, b2, acc[0][2], 0, 0, 0);
    acc[1][2] = __builtin_amdgcn_mfma_f32_16x16x32_f16(a1, b2, acc[1][2], 0, 0, 0);
    acc[2][2] = __builtin_amdgcn_mfma_f32_16x16x32_f16(a2, b2, acc[2][2], 0, 0, 0);
    acc[3][2] = __builtin_amdgcn_mfma_f32_16x16x32_f16(a3, b2, acc[3][2], 0, 0, 0);
    acc[0][3] = __builtin_amdgcn_mfma_f32_16x16x32_f16(a0, b3, acc[0][3], 0, 0, 0);
    acc[1][3] = __builtin_amdgcn_mfma_f32_16x16x32_f16(a1, b3, acc[1][3], 0, 0, 0);
    acc[2][3] = __builtin_amdgcn_mfma_f32_16x16x32_f16(a2, b3, acc[2][3], 0, 0, 0);
    acc[3][3] = __builtin_amdgcn_mfma_f32_16x16x32_f16(a3, b3, acc[3][3], 0, 0, 0);
    b0 = c0; b1 = c1; b2 = c2; b3 = c3;
    c0 = d0; c1 = d1; c2 = d2; c3 = d3;
  }
  const int r4 = (lane >> 4) << 2;
#pragma unroll
  for (int rg = 0; rg < 4; rg++) {
#pragma unroll
    for (int j = 0; j < 4; j++) {
#pragma unroll
      for (int r = 0; r < 4; r++) {
        int row = e0 + rowb + rg*16 + r4 + r;
        int col = wc + j*16 + fr;
        Vn[(size_t)row*256 + col] = f2h(acc[rg][j][r]);
      }
    }
  }
}

// ---- Gtt[slab][col][32] = coupling x Wv (fp16, tiled). col = kabs*16+d ----
__global__ void gbuild_k(const float* __restrict__ TD,
    const float* __restrict__ Wv1, const float* __restrict__ Wv2,
    const float* __restrict__ Wv3, const int* __restrict__ sl_origc,
    unsigned short* __restrict__ Gt, int Kdim, int npairs,
    int s1b, int s1e, int s2e, int s3e)
{
  int k = blockIdx.x*256 + threadIdx.x;
  if (k >= Kdim) return;
  int col = blockIdx.y;
  int pair = k >> 4, m = k & 15;
  int d = col & 15, kabs = col >> 4;
  float acc = 0.f;
  if (kabs > 0 && pair < npairs) {
    const float* Wv; int ss, se, kloc;
    if (kabs < 4)      { Wv = Wv1; ss = s1b; se = s1e; kloc = kabs - 1; }
    else if (kabs < 9) { Wv = Wv2; ss = s1e; se = s2e; kloc = kabs - 4; }
    else               { Wv = Wv3; ss = s2e; se = s3e; kloc = kabs - 9; }
    for (int slot = ss; slot < se; slot++)
      acc += TD[((pair*30) + (slot - 4))*8 + kloc] * Wv[(sl_origc[slot] + m)*16 + d];
    acc *= rsqrtf((float)(16*(se - ss)));
  }
  Gt[((size_t)((k >> 5)*256 + col))*32 + (k & 31)] = f2h(acc);
}

// ---- weight convert + transpose: Wt[n][k] = fp16(W[k][n]) ----
struct WDesc { const float* src; unsigned short* dst; int K; int lgN; };
struct WPack { WDesc d[9]; };
__global__ void wcvt_k(WPack p){
  WDesc d = p.d[blockIdx.y];
  int total = d.K << d.lgN;
  int gid = blockIdx.x*256 + threadIdx.x;
  if (gid >= total) return;
  int k = gid >> d.lgN, n = gid & ((1 << d.lgN) - 1);
  d.dst[(size_t)n*d.K + k] = f2h(d.src[gid]);
}

// Generic fp32 tiled GEMM (small two-body layers).
template<int FLAGS>
__global__ __launch_bounds__(256) void gemm_k(
    const float* __restrict__ A1, const float* __restrict__ A2,
    int K1, int K, const float* __restrict__ W, int N,
    float* Cout,
    const float* __restrict__ env, const float* __restrict__ alphap,
    const float* Xres)
{
  __shared__ float As[16][68];
  __shared__ float Ws[16][68];
  const int tid = threadIdx.x;
  const int bm = blockIdx.x * 64;
  const int bn = blockIdx.y * 64;
  const int tx = tid & 15, ty = tid >> 4;
  const int K2 = K - K1;
  float acc[4][4] = {};
  for (int k0 = 0; k0 < K; k0 += 16) {
#pragma unroll
    for (int i = 0; i < 4; i++) {
      int idx = tid + i*256;
      int m = idx >> 4, kk = idx & 15;
      int k = k0 + kk;
      float v = 0.f;
      if (k < K) {
        int row = bm + m;
        v = (k < K1) ? A1[(size_t)row*K1 + k] : A2[(size_t)row*K2 + (k-K1)];
      }
      As[kk][m] = v;
    }
#pragma unroll
    for (int i = 0; i < 4; i++) {
      int idx = tid + i*256;
      int n = idx & 63, kk = idx >> 6;
      int k = k0 + kk, col = bn + n;
      Ws[kk][n] = (k < K && col < N) ? W[(size_t)k*N + col] : 0.f;
    }
    __syncthreads();
#pragma unroll
    for (int kk = 0; kk < 16; kk++) {
      float a[4], b[4];
#pragma unroll
      for (int i=0;i<4;i++) a[i] = As[kk][ty*4+i];
#pragma unroll
      for (int j=0;j<4;j++) b[j] = Ws[kk][tx*4+j];
#pragma unroll
      for (int i=0;i<4;i++)
#pragma unroll
        for (int j=0;j<4;j++)
          acc[i][j] += a[i]*b[j];
    }
    __syncthreads();
  }
  const float rscale = 1.f/sqrtf((float)K);
  float a2 = 0.f, inv1a2 = 1.f;
  if (FLAGS & F_RESID) { float al = alphap[0]; a2 = al*al; inv1a2 = 1.f/(1.f+a2); }
#pragma unroll
  for (int i=0;i<4;i++) {
    int row = bm + ty*4 + i;
    float ev = (FLAGS & F_ENV) ? env[row] : 1.f;
#pragma unroll
    for (int j=0;j<4;j++) {
      int col = bn + tx*4 + j;
      if (col >= N) continue;
      float v = acc[i][j]*rscale;
      if (FLAGS & F_SILU) v = v/(1.f+__expf(-v));
      if (FLAGS & F_ENV)  v *= ev;
      if (FLAGS & F_RESID) v = (Xres[(size_t)row*N+col] + a2*v)*inv1a2;
      Cout[(size_t)row*N+col] = v;
    }
  }
}

// dense to 16 outputs, K=256 fixed, scale 1/16; A fp16
__global__ __launch_bounds__(256) void dense16_k(const unsigned short* __restrict__ A,
    const float* __restrict__ W, float* __restrict__ C)
{
  __shared__ float As[16*256];
  const int r0 = blockIdx.x << 4;
  const int tid = threadIdx.x;
  for (int i = tid; i < 16*256; i += 256)
    As[i] = h2f(A[((size_t)r0<<8) + i]);
  __syncthreads();
  const int r = tid >> 4, n = tid & 15;
  float acc = 0.f;
#pragma unroll 8
  for (int k = 0; k < 256; k++)
    acc += As[(r<<8)+k] * W[(k<<4)+n];
  C[((size_t)(r0+r)<<4)+n] = acc * 0.0625f;
}

__global__ void edge_init_k(const float* __restrict__ vectors, const int* __restrict__ senders,
    const int* __restrict__ receivers, const int* __restrict__ species,
    const float* __restrict__ emb, float* __restrict__ envb, float* __restrict__ Yb,
    float* __restrict__ x72)
{
  const int e = blockIdx.x*256 + threadIdx.x;
  float vx = vectors[e*3+0], vy = vectors[e*3+1], vz = vectors[e*3+2];
  float d = sqrtf(vx*vx+vy*vy+vz*vz);
  float dd = (d==0.f) ? 1.f : d;
  float invd = 1.f/dd;
  float x = vx*invd, y = vy*invd, z = vz*invd;
  float d2=d*d, d3=d2*d, d6=d3*d3, d7=d6*d, d8=d7*d;
  float envv = (d<1.f) ? (1.f - 28.f*d6 + 48.f*d7 - 21.f*d8) : 0.f;
  envb[e] = envv;
  float mask = (d==0.f)?0.f:1.f;
  const float SQ2 = 1.41421356237309515f;
  const float PIf = 3.14159265358979323846f;
  float* xr = x72 + (size_t)e*72;
#pragma unroll
  for (int n=1;n<=8;n++)
    xr[n-1] = SQ2 * sinf((float)n*PIf*dd)*invd*envv*mask;
  int sp_s = species[senders[e]], sp_r = species[receivers[e]];
  const float* es_ = emb + (size_t)sp_s*32;
  const float* er_ = emb + (size_t)sp_r*32;
#pragma unroll 8
  for (int k=0;k<32;k++){ xr[8+k] = es_[k]*mask; xr[40+k] = er_[k]*mask; }
  float x2=x*x, y2=y*y, z2=z*z;
  const float s3=1.7320508075688772f, s15=3.872983346207417f, s5=2.23606797749979f;
  const float s358=2.0916500663351889f, s105=10.246950765959598f;
  const float s218=1.6201851746019651f, s7=2.6457513110645907f;
  float* Yr = Yb + ((size_t)e<<4);
  Yr[0]=1.f;           Yr[1]=s3*y;          Yr[2]=s3*z;           Yr[3]=s3*x;
  Yr[4]=s15*x*y;       Yr[5]=s15*y*z;       Yr[6]=0.5f*s5*(3.f*z2-1.f);
  Yr[7]=s15*x*z;       Yr[8]=0.5f*s15*(x2-y2);
  Yr[9]=s358*y*(3.f*x2-y2);  Yr[10]=s105*x*y*z;  Yr[11]=s218*y*(5.f*z2-1.f);
  Yr[12]=0.5f*s7*(5.f*z2-3.f)*z;  Yr[13]=s218*x*(5.f*z2-1.f);
  Yr[14]=0.5f*s105*(x2-y2)*z;     Yr[15]=s358*x*(x2-y2);
}

// V16[e][a*16+m] = fp16(w0[e,m]*Y[e,a])
__global__ void vinit_k(const float* __restrict__ w0, const float* __restrict__ Y,
                        unsigned short* __restrict__ V)
{
  const int gid = blockIdx.x*256 + threadIdx.x;
  const int e = gid >> 8, idx = gid & 255;
  V[gid] = f2h(w0[(e<<4)+(idx&15)] * Y[(e<<4)+(idx>>4)]);
}

// node[senders[e]][a*16+m] += w[e,m]*Y[e,a]  (fp32 atomics)
__global__ void scatter_k(const float* __restrict__ w, const float* __restrict__ Y,
                          const int* __restrict__ senders, float* node)
{
  const int gid = blockIdx.x*256 + threadIdx.x;
  const int e = gid >> 8, idx = gid & 255;
  float v = w[(e<<4) + (idx&15)] * Y[(e<<4) + (idx>>4)];
  atomicAdd(&node[((size_t)senders[e]<<8) + idx], v);
}

// l3=0 TP (slots 0..3); B (V/Vn) fp16; tp0 out fp16
__global__ void tp2_k(const float* __restrict__ node, const unsigned short* __restrict__ Vn,
    const int* __restrict__ senders, const float* __restrict__ varepsp,
    const int* __restrict__ pmeta, const int* __restrict__ entIJ,
    const float* __restrict__ entVal, unsigned short* __restrict__ tp0)
{
  const int gid = blockIdx.x*256 + threadIdx.x;
  const int e = gid >> 6, c = gid & 63;
  const int p = c >> 4, m = c & 15;
  float ve = varepsp[0];
  float eps = rsqrtf(1.f + ve*ve);
  int s = senders[e];
  const float* Am = &node[((size_t)s<<8)];
  const unsigned short* Bm = &Vn[((size_t)e<<8)];
  int es = pmeta[p*4+1], ec = pmeta[p*4+2];
  float acc = 0.f;
  for (int t=0;t<ec;t++){
    int ij = entIJ[es+t];
    acc += entVal[es+t] * Am[((ij&255)<<4) + m] * h2f(Bm[(((ij>>8)&255)<<4) + m]);
  }
  tp0[((size_t)e<<6) + pmeta[p*4+0] + m] = f2h(acc * eps);
}

// out[e] = env[e] * dot(X16[e,:128], Wout) / sqrt(128)
__global__ void final_k(const unsigned short* __restrict__ X, const float* __restrict__ Wout,
                        const float* __restrict__ env, float* __restrict__ out)
{
  const int e = blockIdx.x*256 + threadIdx.x;
  float acc = 0.f;
#pragma unroll 16
  for (int k=0;k<128;k++) acc += h2f(X[((size_t)e<<7)+k])*Wout[k];
  out[e] = env[e]*acc*0.088388347648318447f;
}

// ============================ host launcher ============================

static void launch_gemm(int flags, const float* A1, const float* A2, int K1, int K,
    const float* W, int N, float* C, const float* env, const float* alphap,
    const float* Xres, hipStream_t stream)
{
  dim3 grid(E_EDGES/64, (N+63)/64);
  switch(flags){
    case F_NONE:        gemm_k<F_NONE>       <<<grid,256,0,stream>>>(A1,A2,K1,K,W,N,C,env,alphap,Xres); break;
    case F_SILU:        gemm_k<F_SILU>       <<<grid,256,0,stream>>>(A1,A2,K1,K,W,N,C,env,alphap,Xres); break;
    case F_ENV:         gemm_k<F_ENV>        <<<grid,256,0,stream>>>(A1,A2,K1,K,W,N,C,env,alphap,Xres); break;
    case F_ENV|F_RESID: gemm_k<F_ENV|F_RESID><<<grid,256,0,stream>>>(A1,A2,K1,K,W,N,C,env,alphap,Xres); break;
  }
}

static void launch_mgemm(int flags, int a16, const void* A1, const void* A2, int K1, int K,
    const unsigned short* Wt, int N, unsigned short* C, const float* env,
    const float* alphap, const unsigned short* Xres, hipStream_t stream)
{
  dim3 grid(E_EDGES/128, N/128);
  if (a16) {
    switch(flags){
      case F_NONE:        mgemm_k<F_NONE,1>       <<<grid,256,0,stream>>>(A1,A2,K1,K,Wt,N,C,env,alphap,Xres); break;
      case F_SILU:        mgemm_k<F_SILU,1>       <<<grid,256,0,stream>>>(A1,A2,K1,K,Wt,N,C,env,alphap,Xres); break;
      case F_ENV:         mgemm_k<F_ENV,1>        <<<grid,256,0,stream>>>(A1,A2,K1,K,Wt,N,C,env,alphap,Xres); break;
      case F_ENV|F_RESID: mgemm_k<F_ENV|F_RESID,1><<<grid,256,0,stream>>>(A1,A2,K1,K,Wt,N,C,env,alphap,Xres); break;
    }
  } else {
    switch(flags){
      case F_SILU:        mgemm_k<F_SILU,0>       <<<grid,256,0,stream>>>(A1,A2,K1,K,Wt,N,C,env,alphap,Xres); break;
      case F_ENV:         mgemm_k<F_ENV,0>        <<<grid,256,0,stream>>>(A1,A2,K1,K,Wt,N,C,env,alphap,Xres); break;
      default: break;
    }
  }
}

extern "C" void kernel_launch(void* const* d_in, const int* in_sizes, int n_in,
                              void* d_out, int out_size, void* d_ws, size_t ws_size,
                              hipStream_t stream)
{
  const float* vectors = (const float*)d_in[0];
  const float* vareps  = (const float*)d_in[1];
  const float* alpha   = (const float*)d_in[2];
  const float* emb     = (const float*)d_in[3];
  const float* W_tb1   = (const float*)d_in[4];
  const float* W_tb2   = (const float*)d_in[5];
  const float* W_tb3   = (const float*)d_in[6];
  const float* W_tb4   = (const float*)d_in[7];
  const float* W_w0    = (const float*)d_in[8];
  const float* W_w1    = (const float*)d_in[9];
  const float* W_l11   = (const float*)d_in[10];
  const float* W_l12   = (const float*)d_in[11];
  const float* W_l13   = (const float*)d_in[12];
  const float* W_v1    = (const float*)d_in[13];
  const float* W_v2    = (const float*)d_in[14];
  const float* W_v3    = (const float*)d_in[15];
  const float* W_w2    = (const float*)d_in[16];
  const float* W_l21   = (const float*)d_in[17];
  const float* W_l22   = (const float*)d_in[18];
  const float* W_l23   = (const float*)d_in[19];
  const float* W_h     = (const float*)d_in[20];
  const float* W_out   = (const float*)d_in[21];
  const int* senders   = (const int*)d_in[22];
  const int* receivers = (const int*)d_in[23];
  const int* species   = (const int*)d_in[24];

  static cgt::Tables tb;
  cgt::build(tb);
  const int Kdim = tb.npairs * 16;

  char* ws = (char*)d_ws;
  size_t off = 0;
  auto alloc = [&](size_t bytes)->void*{
    void* p = ws + off; off += (bytes + 255) & ~(size_t)255; return p;
  };
  float* t_val = (float*)alloc(sizeof(tb.val));
  int*   t_ij  = (int*)  alloc(sizeof(tb.ij));
  int*   t_pm  = (int*)  alloc(sizeof(tb.pmeta));
  float* t_td  = (float*)alloc(sizeof(tb.TD));
  int*   t_pr  = (int*)  alloc(sizeof(tb.pairs));
  int*   t_oc  = (int*)  alloc(sizeof(tb.sl_origc));
  float* envb  = (float*)alloc((size_t)E_EDGES*4);
  float* Yb    = (float*)alloc((size_t)E_EDGES*16*4);
  float* xb    = (float*)alloc((size_t)E_EDGES*256*4);
  float* Vb    = (float*)alloc((size_t)E_EDGES*256*4);
  float* bufA  = (float*)alloc((size_t)E_EDGES*256*4);
  float* bufB  = (float*)alloc((size_t)E_EDGES*256*4);
  float* wb    = (float*)alloc((size_t)E_EDGES*16*4);
  float* tp0b  = (float*)alloc((size_t)E_EDGES*64*4);
  float* nodeb = (float*)alloc((size_t)NNODES*256*4);
  unsigned short* Gt = (unsigned short*)alloc((size_t)256*Kdim*2);
  unsigned short* Wt_tb3 = (unsigned short*)alloc(64*128*2);
  unsigned short* Wt_tb4 = (unsigned short*)alloc(128*256*2);
  unsigned short* Wt_l11 = (unsigned short*)alloc(320*256*2);
  unsigned short* Wt_l12 = (unsigned short*)alloc(256*256*2);
  unsigned short* Wt_l13 = (unsigned short*)alloc(256*256*2);
  unsigned short* Wt_l21 = (unsigned short*)alloc(320*256*2);
  unsigned short* Wt_l22 = (unsigned short*)alloc(256*256*2);
  unsigned short* Wt_l23 = (unsigned short*)alloc(256*256*2);
  unsigned short* Wt_h   = (unsigned short*)alloc(256*128*2);
  if (off > ws_size) {
    fprintf(stderr, "[allegro] workspace too small: need %zu, have %zu\n", off, ws_size);
    return;
  }
  unsigned short* xb16 = (unsigned short*)xb;
  unsigned short* bA16 = (unsigned short*)bufA;
  unsigned short* bB16 = (unsigned short*)bufB;
  unsigned short* tp016 = (unsigned short*)tp0b;
  unsigned short* V16 = (unsigned short*)Vb;

  hipMemcpyAsync(t_val, tb.val,     sizeof(tb.val),     hipMemcpyHostToDevice, stream);
  hipMemcpyAsync(t_ij,  tb.ij,      sizeof(tb.ij),      hipMemcpyHostToDevice, stream);
  hipMemcpyAsync(t_pm,  tb.pmeta,   sizeof(tb.pmeta),   hipMemcpyHostToDevice, stream);
  hipMemcpyAsync(t_td,  tb.TD,      sizeof(tb.TD),      hipMemcpyHostToDevice, stream);
  hipMemcpyAsync(t_pr,  tb.pairs,   sizeof(tb.pairs),   hipMemcpyHostToDevice, stream);
  hipMemcpyAsync(t_oc,  tb.sl_origc,sizeof(tb.sl_origc),hipMemcpyHostToDevice, stream);

  const int s1b = tb.l3np[0];
  const int s1e = s1b + tb.l3np[1];
  const int s2e = s1e + tb.l3np[2];
  const int s3e = s2e + tb.l3np[3];

  {
    dim3 g((Kdim + 255)/256, 256);
    gbuild_k<<<g, 256, 0, stream>>>(t_td, W_v1, W_v2, W_v3, t_oc, Gt, Kdim,
                                    tb.npairs, s1b, s1e, s2e, s3e);
  }
  {
    WPack p;
    p.d[0] = { W_tb3, Wt_tb3,  64, 7 };
    p.d[1] = { W_tb4, Wt_tb4, 128, 8 };
    p.d[2] = { W_l11, Wt_l11, 320, 8 };
    p.d[3] = { W_l12, Wt_l12, 256, 8 };
    p.d[4] = { W_l13, Wt_l13, 256, 8 };
    p.d[5] = { W_l21, Wt_l21, 320, 8 };
    p.d[6] = { W_l22, Wt_l22, 256, 8 };
    p.d[7] = { W_h,   Wt_h,   256, 7 };
    p.d[8] = { W_l23, Wt_l23, 256, 8 };
    dim3 g(320, 9);
    wcvt_k<<<g, 256, 0, stream>>>(p);
  }

  // 1. edge features + Y + env  (x72 -> bufA fp32)
  edge_init_k<<<E_EDGES/256, 256, 0, stream>>>(vectors, senders, receivers, species,
                                               emb, envb, Yb, bufA);
  // 2. two-body MLP: 72->32->64 (fp32 gemm), 64->128->256 (fp16 mgemm)
  launch_gemm (F_SILU, bufA, nullptr, 72, 72,  W_tb1, 32,  bufB, envb, alpha, nullptr, stream);
  launch_gemm (F_SILU, bufB, nullptr, 32, 32,  W_tb2, 64,  bufA, envb, alpha, nullptr, stream);
  launch_mgemm(F_SILU, 0, bufA, nullptr, 64, 64,  Wt_tb3, 128, bB16, envb, alpha, nullptr, stream);
  launch_mgemm(F_ENV,  1, bB16, nullptr, 128,128, Wt_tb4, 256, xb16, envb, alpha, nullptr, stream);
  // 3. V = dense(x,W_w0) outer Y  ([a][m] layout, fp16)
  dense16_k<<<E_EDGES/16, 256, 0, stream>>>(xb16, W_w0, wb);
  vinit_k<<<E_EDGES, 256, 0, stream>>>(wb, Yb, V16);

  // ---- layer 1 ----
  dense16_k<<<E_EDGES/16, 256, 0, stream>>>(xb16, W_w1, wb);
  hipMemsetAsync(nodeb, 0, (size_t)NNODES*256*4, stream);
  scatter_k<<<E_EDGES, 256, 0, stream>>>(wb, Yb, senders, nodeb);
  tp2_k<<<E_EDGES*64/256, 256, 0, stream>>>(nodeb, V16, senders, vareps, t_pm, t_ij,
                                            t_val, tp016);
  vn_k<<<E_EDGES/VN_E, 512, 0, stream>>>(nodeb, V16, senders, vareps, t_pr, Gt, V16, Kdim);
  launch_mgemm(F_SILU,        1, xb16, tp016,  256, 320, Wt_l11, 256, bB16, envb, alpha, nullptr, stream);
  launch_mgemm(F_SILU,        1, bB16, nullptr,256, 256, Wt_l12, 256, bA16, envb, alpha, nullptr, stream);
  launch_mgemm(F_ENV|F_RESID, 1, bA16, nullptr,256, 256, Wt_l13, 256, xb16, envb, alpha, xb16,    stream);

  // ---- layer 2 (lmax_out = 0) ----
  dense16_k<<<E_EDGES/16, 256, 0, stream>>>(xb16, W_w2, wb);
  hipMemsetAsync(nodeb, 0, (size_t)NNODES*256*4, stream);
  scatter_k<<<E_EDGES, 256, 0, stream>>>(wb, Yb, senders, nodeb);
  tp2_k<<<E_EDGES*64/256, 256, 0, stream>>>(nodeb, V16, senders, vareps, t_pm, t_ij,
                                            t_val, tp016);
  launch_mgemm(F_SILU,        1, xb16, tp016,  256, 320, Wt_l21, 256, bB16, envb, alpha, nullptr, stream);
  launch_mgemm(F_SILU,        1, bB16, nullptr,256, 256, Wt_l22, 256, bA16, envb, alpha, nullptr, stream);
  launch_mgemm(F_ENV|F_RESID, 1, bA16, nullptr,256, 256, Wt_l23, 256, xb16, envb, alpha, xb16,    stream);

  // ---- head ----
  launch_mgemm(F_NONE, 1, xb16, nullptr, 256, 256, Wt_h, 128, bB16, envb, alpha, nullptr, stream);
  final_k<<<E_EDGES/256, 256, 0, stream>>>(bB16, W_out, envb, (float*)d_out);
}

// Round 13
// 496.488 us; speedup vs baseline: 1.1791x; 1.0223x over previous
//
#include <hip/hip_runtime.h>
#include <cmath>
#include <complex>
#include <cstdio>
#include <cstring>
#include <algorithm>

#define E_EDGES 32768
#define NNODES  2048
#define VN_E    128

// ============================ host-side CG tables ============================
namespace cgt {

static double fct(int n){
  static const double f[13] = {1.,1.,2.,6.,24.,120.,720.,5040.,40320.,362880.,
                               3628800.,39916800.,479001600.};
  return f[n];
}

static double cg(int j1,int m1,int j2,int m2,int j3,int m3){
  if (m1+m2 != m3) return 0.0;
  double pre = std::sqrt((2*j3+1)*fct(j1+j2-j3)*fct(j1-j2+j3)*fct(-j1+j2+j3)/fct(j1+j2+j3+1));
  pre *= std::sqrt(fct(j3+m3)*fct(j3-m3)*fct(j1-m1)*fct(j1+m1)*fct(j2-m2)*fct(j2+m2));
  int kmin = 0;
  if (j2-j3-m1 > kmin) kmin = j2-j3-m1;
  if (j1-j3+m2 > kmin) kmin = j1-j3+m2;
  int kmax = j1+j2-j3;
  if (j1-m1 < kmax) kmax = j1-m1;
  if (j2+m2 < kmax) kmax = j2+m2;
  double s = 0.0;
  for (int k=kmin;k<=kmax;k++){
    double d = fct(k)*fct(j1+j2-j3-k)*fct(j1-m1-k)*fct(j2+m2-k)*fct(j3-j2+m1+k)*fct(j3-j1-m2+k);
    s += ((k&1)? -1.0:1.0)/d;
  }
  return pre*s;
}

typedef std::complex<double> cd;

static void umat(int l, cd U[7][7]){
  for (int a=0;a<7;a++) for (int b=0;b<7;b++) U[a][b]=cd(0,0);
  U[l][l] = cd(1,0);
  double s2 = 1.0/std::sqrt(2.0);
  for (int m=1;m<=l;m++){
    double sg = (m&1)? -1.0 : 1.0;
    U[l+m][l-m] = cd(s2,0);
    U[l+m][l+m] = cd(sg*s2,0);
    U[l-m][l-m] = cd(0, s2);
    U[l-m][l+m] = cd(0, -sg*s2);
  }
}

static bool realCoupling(int l1,int l2,int l3, double T[7][7][7]){
  cd U1[7][7],U2[7][7],U3[7][7];
  umat(l1,U1); umat(l2,U2); umat(l3,U3);
  int n1=2*l1+1, n2=2*l2+1, n3=2*l3+1;
  double Cg[7][7][7];
  for (int m=0;m<n1;m++) for(int n=0;n<n2;n++) for(int k=0;k<n3;k++)
    Cg[m][n][k] = cg(l1,m-l1,l2,n-l2,l3,k-l3);
  double Tr[7][7][7], Ti[7][7][7];
  double nr=0, ni=0;
  for (int a=0;a<n1;a++) for(int b=0;b<n2;b++) for(int c=0;c<n3;c++){
    cd s(0,0);
    for (int m=0;m<n1;m++){
      if (U1[a][m]==cd(0,0)) continue;
      for (int n=0;n<n2;n++){
        if (U2[b][n]==cd(0,0)) continue;
        for (int k=0;k<n3;k++){
          double cgv = Cg[m][n][k];
          if (cgv==0.0) continue;
          s += U1[a][m]*U2[b][n]*std::conj(U3[c][k])*cgv;
        }
      }
    }
    Tr[a][b][c]=s.real(); Ti[a][b][c]=s.imag();
    nr += s.real()*s.real(); ni += s.imag()*s.imag();
  }
  bool useR = (nr >= ni);
  double nn = std::sqrt(useR? nr : ni);
  if (nn < 1e-8) return false;
  for (int a=0;a<n1;a++)for(int b=0;b<n2;b++)for(int c=0;c<n3;c++)
    T[a][b][c] = (useR? Tr[a][b][c] : Ti[a][b][c])/nn;
  return true;
}

struct Tables {
  float val[4096];
  int   ij[4096];
  int   pmeta[40*4];
  int   ccnt[40*8];
  int   l3base[4];
  int   l3np[4];
  int   npaths;
  int   nent;
  int   tptot;
  int   pairs[256];
  float TD[256*30*8];
  int   sl_origc[40];
  int   npairs;
};

struct PathTmp {
  int l1,l2,l3, tpoff, kd;
  int ec;
  double T[7][7][7];
};

static void build(Tables& tb){
  static PathTmp paths[40];
  int np = 0, tpoff = 0;
  int l3start[5];
  for (int l3=0;l3<=3;l3++){
    tb.l3base[l3] = tpoff;
    l3start[l3] = np;
    int kd = 2*l3+1;
    for (int l1=0;l1<=3;l1++) for (int l2=0;l2<=3;l2++){
      int lo = (l1>l2)? l1-l2 : l2-l1;
      int hi = std::min(l1+l2,3);
      if (l3 < lo || l3 > hi) continue;
      PathTmp& pt = paths[np];
      if (!realCoupling(l1,l2,l3,pt.T)) continue;
      pt.l1=l1; pt.l2=l2; pt.l3=l3; pt.kd=kd; pt.tpoff=tpoff;
      double scale = std::sqrt((double)kd);
      int cnt = 0;
      for (int a=0;a<2*l1+1;a++)for(int b=0;b<2*l2+1;b++)for(int c=0;c<kd;c++)
        if (std::fabs(pt.T[a][b][c]*scale) > 1e-7) cnt++;
      pt.ec = cnt;
      tpoff += 16*kd;
      np++;
    }
  }
  l3start[4] = np;
  for (int l3=0;l3<=3;l3++) tb.l3np[l3] = l3start[l3+1]-l3start[l3];
  static int order[40];
  for (int i=0;i<np;i++) order[i]=i;
  for (int l3=0;l3<=3;l3++)
    std::sort(order+l3start[l3], order+l3start[l3+1],
              [&](int a,int b){ return paths[a].ec > paths[b].ec; });
  std::memset(tb.TD, 0, sizeof(tb.TD));
  std::memset(tb.pairs, 0, sizeof(tb.pairs));
  static int pmap[16][16];
  for (int i=0;i<16;i++) for (int j=0;j<16;j++) pmap[i][j] = -1;
  int npr = 0;
  int ep = 0;
  for (int slot=0; slot<np; slot++){
    const PathTmp& pt = paths[order[slot]];
    double scale = std::sqrt((double)pt.kd);
    int s1 = pt.l1*pt.l1, s2 = pt.l2*pt.l2;
    tb.pmeta[slot*4+0] = pt.tpoff;
    tb.pmeta[slot*4+1] = ep;
    tb.sl_origc[slot] = ((pt.tpoff - tb.l3base[pt.l3]) / (16*pt.kd)) * 16;
    int tot = 0;
    for (int c=0;c<pt.kd;c++){
      int cnt = 0;
      for (int a=0;a<2*pt.l1+1;a++)for(int b=0;b<2*pt.l2+1;b++){
        double v = pt.T[a][b][c]*scale;
        if (std::fabs(v) > 1e-7){
          tb.val[ep] = (float)v;
          tb.ij[ep]  = (s1+a) | ((s2+b)<<8);
          ep++; cnt++;
          if (pt.l3 >= 1){
            int aa = s1+a, bb = s2+b;
            int pi = pmap[aa][bb];
            if (pi < 0){ pi = npr; pmap[aa][bb] = pi;
                         tb.pairs[npr] = aa | (bb<<8); npr++; }
            tb.TD[(pi*30 + (slot-4))*8 + c] = (float)v;
          }
        }
      }
      tb.ccnt[slot*8+c] = cnt;
      tot += cnt;
    }
    for (int c=pt.kd;c<8;c++) tb.ccnt[slot*8+c]=0;
    tb.pmeta[slot*4+2] = tot;
    tb.pmeta[slot*4+3] = pt.kd;
  }
  if (npr & 1){ tb.pairs[npr] = 0; npr++; }
  tb.npairs = npr;
  tb.npaths = np; tb.nent = ep; tb.tptot = tpoff;
}

} // namespace cgt

// ============================ device kernels ============================
// LAYOUT: node/V/Vn rows are [a][m]. MFMA-path activations fp16 in HBM.

enum GFlags { F_NONE=0, F_SILU=1, F_ENV=2, F_RESID=4 };

typedef _Float16 half8 __attribute__((ext_vector_type(8)));
typedef __attribute__((ext_vector_type(4))) float f32x4;

__device__ inline unsigned short f2h(float f){
  union { _Float16 h; unsigned short u; } x;
  x.h = (_Float16)f;
  return x.u;
}
__device__ inline float h2f(unsigned short u){
  union { _Float16 h; unsigned short u; } x; x.u = u;
  return (float)x.h;
}

__device__ inline int swz(int row, int kh){
  int b = row*64 + kh*2;
  return b ^ (((row >> 1) & 3) << 4);
}

// ---- fp16 MFMA GEMM: C16[M,N] = post( A[M,K] @ W[K,N] / sqrt(K) ) ----
template<int FLAGS, int A16>
__global__ __launch_bounds__(256) void mgemm_k(
    const void* __restrict__ A1v, const void* __restrict__ A2v,
    int K1, int K, const unsigned short* __restrict__ Wt, int N,
    unsigned short* Cout, const float* __restrict__ env,
    const float* __restrict__ alphap, const unsigned short* Xres)
{
  __shared__ unsigned short AsB[128*32];
  __shared__ unsigned short BsB[128*32];
  const int tid  = threadIdx.x;
  const int wave = tid >> 6, lane = tid & 63;
  const int bm = blockIdx.x*128, bn = blockIdx.y*128;
  const int wr = (wave >> 1)*64, wc = (wave & 1)*64;
  const int K2 = K - K1;
  f32x4 acc[4][4] = {};

  const int sr  = tid >> 3;
  const int skq = (tid & 7) * 4;
  const int sr2 = tid >> 1;
  const int skh = (tid & 1) * 16;
  const int bn_ = tid >> 1;
  const int bkh = (tid & 1) * 16;

  for (int k0 = 0; k0 < K; k0 += 32) {
    if (A16) {
      int kk = k0 + skh;
      const unsigned short* ap = (kk < K1)
        ? (const unsigned short*)A1v + (size_t)(bm + sr2)*K1 + kk
        : (const unsigned short*)A2v + (size_t)(bm + sr2)*K2 + (kk - K1);
      uint4 u0 = *(const uint4*)ap;
      uint4 u1 = *(const uint4*)(ap + 8);
      *(uint4*)((char*)AsB + swz(sr2, skh))     = u0;
      *(uint4*)((char*)AsB + swz(sr2, skh + 8)) = u1;
    } else {
#pragma unroll
      for (int q = 0; q < 4; q++) {
        int row = q*32 + sr;
        int grow = bm + row;
        int kk = k0 + skq;
        float4 f4 = (kk < K1)
          ? *(const float4*)((const float*)A1v + (size_t)grow*K1 + kk)
          : *(const float4*)((const float*)A2v + (size_t)grow*K2 + (kk - K1));
        ushort4 u;
        u.x = f2h(f4.x); u.y = f2h(f4.y); u.z = f2h(f4.z); u.w = f2h(f4.w);
        *(ushort4*)((char*)AsB + swz(row, skq)) = u;
      }
    }
    {
      const unsigned short* s = Wt + (size_t)(bn + bn_)*K + k0 + bkh;
#pragma unroll
      for (int q = 0; q < 4; q++) {
        ushort4 u = *(const ushort4*)(s + q*4);
        *(ushort4*)((char*)BsB + swz(bn_, bkh + q*4)) = u;
      }
    }
    __syncthreads();
    const int fr = lane & 15, fk = (lane >> 4) * 8;
    half8 af[4], bf[4];
#pragma unroll
    for (int i = 0; i < 4; i++)
      af[i] = *(half8*)((char*)AsB + swz(wr + i*16 + fr, fk));
#pragma unroll
    for (int j = 0; j < 4; j++)
      bf[j] = *(half8*)((char*)BsB + swz(wc + j*16 + fr, fk));
#pragma unroll
    for (int i = 0; i < 4; i++)
#pragma unroll
      for (int j = 0; j < 4; j++)
        acc[i][j] = __builtin_amdgcn_mfma_f32_16x16x32_f16(af[i], bf[j], acc[i][j], 0, 0, 0);
    __syncthreads();
  }

  const float rscale = 1.f/sqrtf((float)K);
  float a2 = 0.f, inv1a2 = 1.f;
  if (FLAGS & F_RESID) { float al = alphap[0]; a2 = al*al; inv1a2 = 1.f/(1.f+a2); }
#pragma unroll
  for (int i = 0; i < 4; i++) {
#pragma unroll
    for (int r = 0; r < 4; r++) {
      int row = bm + wr + i*16 + ((lane >> 4) << 2) + r;
      float ev = (FLAGS & F_ENV) ? env[row] : 1.f;
#pragma unroll
      for (int j = 0; j < 4; j++) {
        int col = bn + wc + j*16 + (lane & 15);
        float v = acc[i][j][r]*rscale;
        if (FLAGS & F_SILU) v = v/(1.f+__expf(-v));
        if (FLAGS & F_ENV)  v *= ev;
        if (FLAGS & F_RESID) v = (h2f(Xres[(size_t)row*N+col]) + a2*v)*inv1a2;
        Cout[(size_t)row*N+col] = f2h(v);
      }
    }
  }
}

// ---- fused 2-layer MLP (R13): out = resid(env * (silu(A@W1/16) @ W2 /16)) ----
// Block = 64 rows x full N=256; 4 waves, each 64 rows x 64 cols (acc[4][4]).
// Intermediate h (post-silu) lives in LDS only -> saves 33.6MB HBM round-trip
// + one kernel launch per layer. A, W1t, W2t, Out, Xres fp16.
__global__ __launch_bounds__(256) void mlp2_k(
    const unsigned short* __restrict__ A, const unsigned short* __restrict__ W1t,
    const unsigned short* __restrict__ W2t, unsigned short* __restrict__ Out,
    const unsigned short* __restrict__ Xres, const float* __restrict__ env,
    const float* __restrict__ alphap)
{
  __shared__ unsigned short AsB[64*32];     // 4 KB
  __shared__ unsigned short BsB[256*32];    // 16 KB
  __shared__ unsigned short Hs[64*264];     // 33.8 KB
  const int tid  = threadIdx.x;
  const int wave = tid >> 6, lane = tid & 63;
  const int bm = blockIdx.x*64;
  const int wc = wave*64;
  const int fr = lane & 15, fk = (lane >> 4) * 8;
  const int r4 = (lane >> 4) << 2;
  const int sra = tid >> 2;          // A staging row 0..63
  const int ska = (tid & 3) * 8;     // A staging k (8 halves)
  const int srb = tid >> 1;          // B staging row (per 128-half)
  const int skb = (tid & 1) * 16;    // B staging k half
  f32x4 acc[4][4] = {};

  // ---- stage 1: h = silu(A @ W1 / 16) -> Hs ----
  for (int k0 = 0; k0 < 256; k0 += 32) {
    {
      uint4 u = *(const uint4*)(A + (size_t)(bm + sra)*256 + k0 + ska);
      *(uint4*)((char*)AsB + swz(sra, ska)) = u;
    }
#pragma unroll
    for (int h = 0; h < 2; h++) {
      int n = h*128 + srb;
      const unsigned short* s = W1t + (size_t)n*256 + k0 + skb;
      uint4 u0 = *(const uint4*)s;
      uint4 u1 = *(const uint4*)(s + 8);
      *(uint4*)((char*)BsB + swz(n, skb))     = u0;
      *(uint4*)((char*)BsB + swz(n, skb + 8)) = u1;
    }
    __syncthreads();
    half8 af[4], bf[4];
#pragma unroll
    for (int i = 0; i < 4; i++)
      af[i] = *(half8*)((char*)AsB + swz(i*16 + fr, fk));
#pragma unroll
    for (int j = 0; j < 4; j++)
      bf[j] = *(half8*)((char*)BsB + swz(wc + j*16 + fr, fk));
#pragma unroll
    for (int i = 0; i < 4; i++)
#pragma unroll
      for (int j = 0; j < 4; j++)
        acc[i][j] = __builtin_amdgcn_mfma_f32_16x16x32_f16(af[i], bf[j], acc[i][j], 0, 0, 0);
    __syncthreads();
  }
#pragma unroll
  for (int i = 0; i < 4; i++)
#pragma unroll
    for (int r = 0; r < 4; r++) {
      int row = i*16 + r4 + r;
#pragma unroll
      for (int j = 0; j < 4; j++) {
        int col = wc + j*16 + fr;
        float v = acc[i][j][r]*0.0625f;
        v = v/(1.f+__expf(-v));
        Hs[row*264 + col] = f2h(v);
        acc[i][j][r] = 0.f;
      }
    }
  __syncthreads();

  // ---- stage 2: out = resid(env * (h @ W2 / 16)) ----
  for (int k0 = 0; k0 < 256; k0 += 32) {
#pragma unroll
    for (int h = 0; h < 2; h++) {
      int n = h*128 + srb;
      const unsigned short* s = W2t + (size_t)n*256 + k0 + skb;
      uint4 u0 = *(const uint4*)s;
      uint4 u1 = *(const uint4*)(s + 8);
      *(uint4*)((char*)BsB + swz(n, skb))     = u0;
      *(uint4*)((char*)BsB + swz(n, skb + 8)) = u1;
    }
    __syncthreads();
    half8 af[4], bf[4];
#pragma unroll
    for (int i = 0; i < 4; i++)
      af[i] = *(half8*)(Hs + (i*16 + fr)*264 + k0 + fk);
#pragma unroll
    for (int j = 0; j < 4; j++)
      bf[j] = *(half8*)((char*)BsB + swz(wc + j*16 + fr, fk));
#pragma unroll
    for (int i = 0; i < 4; i++)
#pragma unroll
      for (int j = 0; j < 4; j++)
        acc[i][j] = __builtin_amdgcn_mfma_f32_16x16x32_f16(af[i], bf[j], acc[i][j], 0, 0, 0);
    __syncthreads();
  }
  float al = alphap[0];
  float a2 = al*al, inv1a2 = 1.f/(1.f+a2);
#pragma unroll
  for (int i = 0; i < 4; i++)
#pragma unroll
    for (int r = 0; r < 4; r++) {
      int row = bm + i*16 + r4 + r;
      float ev = env[row];
#pragma unroll
      for (int j = 0; j < 4; j++) {
        int col = wc + j*16 + fr;
        float v = acc[i][j][r]*0.0625f*ev;
        v = (h2f(Xres[(size_t)row*256+col]) + a2*v)*inv1a2;
        Out[(size_t)row*256+col] = f2h(v);
      }
    }
}

// ---- fused Vn kernel (R12 structure) ----
__global__ __launch_bounds__(512) void vn_k(
    const float* __restrict__ node, const unsigned short* __restrict__ V,
    const int* __restrict__ senders, const float* __restrict__ varepsp,
    const int* __restrict__ pairsG, const unsigned short* __restrict__ Gtt,
    unsigned short* __restrict__ Vn, int Kdim)
{
  __shared__ unsigned short Ab[VN_E*264];
  __shared__ unsigned short Bb[VN_E*264];
  __shared__ int Ps[256];
  const int tid = threadIdx.x;
  const int e0 = blockIdx.x * VN_E;
  const int wave = tid >> 6, lane = tid & 63;
  float ve = varepsp[0];
  float eps = rsqrtf(1.f + ve*ve);
  if (tid < 256) Ps[tid] = pairsG[tid];
#pragma unroll
  for (int rr = 0; rr < 16; rr++) {
    int row = wave*16 + rr;
    int s = senders[e0 + row];
    float4 fa = *(const float4*)(node + ((size_t)s << 8) + 4*lane);
    uint2 ub = *(const uint2*)(V + (((size_t)(e0 + row)) << 8) + 4*lane);
    unsigned short* ad = Ab + row*264 + 4*lane;
    unsigned short* bd = Bb + row*264 + 4*lane;
    uint2 ua;
    ua.x = (unsigned)f2h(fa.x*eps) | ((unsigned)f2h(fa.y*eps) << 16);
    ua.y = (unsigned)f2h(fa.z*eps) | ((unsigned)f2h(fa.w*eps) << 16);
    *(uint2*)ad = ua;
    *(uint2*)bd = ub;
  }
  __syncthreads();
  const int rowb = (wave & 1) * 64;
  const int wc   = (wave >> 1) * 64;
  const int fr = lane & 15, fk = (lane >> 4) * 8;
  const int pairSel = fk >> 4;
  const int moff = fk & 15;
  const int nslab = Kdim >> 5;
  f32x4 acc[4][4] = {};

  const unsigned short* Ar0 = Ab + (rowb + fr)*264;
  const unsigned short* Br0 = Bb + (rowb + fr)*264;
  const unsigned short* Ar1 = Ab + (rowb + 16 + fr)*264;
  const unsigned short* Br1 = Bb + (rowb + 16 + fr)*264;
  const unsigned short* Ar2 = Ab + (rowb + 32 + fr)*264;
  const unsigned short* Br2 = Bb + (rowb + 32 + fr)*264;
  const unsigned short* Ar3 = Ab + (rowb + 48 + fr)*264;
  const unsigned short* Br3 = Bb + (rowb + 48 + fr)*264;

  const unsigned short* gp = Gtt + ((size_t)(wc + fr)) * 32 + fk;
  half8 b0 = *(const half8*)(gp);
  half8 b1 = *(const half8*)(gp + 512);
  half8 b2 = *(const half8*)(gp + 1024);
  half8 b3 = *(const half8*)(gp + 1536);
  half8 c0 = b0, c1 = b1, c2 = b2, c3 = b3;
  if (nslab > 1) {
    const unsigned short* g1 = gp + 8192;
    c0 = *(const half8*)(g1);
    c1 = *(const half8*)(g1 + 512);
    c2 = *(const half8*)(g1 + 1024);
    c3 = *(const half8*)(g1 + 1536);
  }
  int p0 = Ps[pairSel];
  int aoff = ((p0 & 255) << 4) + moff;
  int boff = (((p0 >> 8) & 255) << 4) + moff;
  half8 rA0 = *(const half8*)(Ar0 + aoff);
  half8 rB0 = *(const half8*)(Br0 + boff);
  half8 rA1 = *(const half8*)(Ar1 + aoff);
  half8 rB1 = *(const half8*)(Br1 + boff);
  half8 rA2 = *(const half8*)(Ar2 + aoff);
  half8 rB2 = *(const half8*)(Br2 + boff);
  half8 rA3 = *(const half8*)(Ar3 + aoff);
  half8 rB3 = *(const half8*)(Br3 + boff);

  for (int sl = 0; sl < nslab; sl++) {
    half8 a0 = rA0 * rB0;
    half8 a1 = rA1 * rB1;
    half8 a2 = rA2 * rB2;
    half8 a3 = rA3 * rB3;
    if (sl + 1 < nslab) {
      int pn = Ps[2*(sl + 1) + pairSel];
      int aoffn = ((pn & 255) << 4) + moff;
      int boffn = (((pn >> 8) & 255) << 4) + moff;
      rA0 = *(const half8*)(Ar0 + aoffn);
      rB0 = *(const half8*)(Br0 + boffn);
      rA1 = *(const half8*)(Ar1 + aoffn);
      rB1 = *(const half8*)(Br1 + boffn);
      rA2 = *(const half8*)(Ar2 + aoffn);
      rB2 = *(const half8*)(Br2 + boffn);
      rA3 = *(const half8*)(Ar3 + aoffn);
      rB3 = *(const half8*)(Br3 + boffn);
    }
    half8 d0, d1, d2, d3;
    if (sl + 2 < nslab) {
      const unsigned short* gn = gp + (size_t)(sl + 2) * 8192;
      d0 = *(const half8*)(gn);
      d1 = *(const half8*)(gn + 512);
      d2 = *(const half8*)(gn + 1024);
      d3 = *(const half8*)(gn + 1536);
    } else { d0 = c0; d1 = c1; d2 = c2; d3 = c3; }
    acc[0][0] = __builtin_amdgcn_mfma_f32_16x16x32_f16(a0, b0, acc[0][0], 0, 0, 0);
    acc[1][0] = __builtin_amdgcn_mfma_f32_16x16x32_f16(a1, b0, acc[1][0], 0, 0, 0);
    acc[2][0] = __builtin_amdgcn_mfma_f32_16x16x32_f16(a2, b0, acc[2][0], 0, 0, 0);
    acc[3][0] = __builtin_amdgcn_mfma_f32_16x16x32_f16(a3, b0, acc[3][0], 0, 0, 0);
    acc[0][1] = __builtin_amdgcn_mfma_f32_16x16x32_f16(a0, b1, acc[0][1], 0, 0, 0);
    acc[1][1] = __builtin_amdgcn_mfma_f32_16x16x32_f16(a1, b1, acc[1][1], 0, 0, 0);
    acc[2][1] = __builtin_amdgcn_mfma_f32_16x16x32_f16(a2, b1, acc[2][1], 0, 0, 0);
    acc[3][1] = __builtin_amdgcn_mfma_f32_16x16x32_f16(a3, b1, acc[3][1], 0, 0, 0);
    acc[0][2] = __builtin_amdgcn_mfma_f32_16x16x32_f16(a0, b2, acc[0][2], 0, 0, 0);
    acc[1][2] = __builtin_amdgcn_mfma_f32_16x16x32_f16(a1, b2, acc[1][2], 0, 0, 0);
    acc[2][2] = __builtin_amdgcn_mfma_f32_16x16x32_f16(a2, b2, acc[2][2], 0, 0, 0);
    acc[3][2] = __builtin_amdgcn_mfma_f32_16x16x32_f16(a3, b2, acc[3][2], 0, 0, 0);
    acc[0][3] = __builtin_amdgcn_mfma_f32_16x16x32_f16(a0, b3, acc[0][3], 0, 0, 0);
    acc[1][3] = __builtin_amdgcn_mfma_f32_16x16x32_f16(a1, b3, acc[1][3], 0, 0, 0);
    acc[2][3] = __builtin_amdgcn_mfma_f32_16x16x32_f16(a2, b3, acc[2][3], 0, 0, 0);
    acc[3][3] = __builtin_amdgcn_mfma_f32_16x16x32_f16(a3, b3, acc[3][3], 0, 0, 0);
    b0 = c0; b1 = c1; b2 = c2; b3 = c3;
    c0 = d0; c1 = d1; c2 = d2; c3 = d3;
  }
  const int r4 = (lane >> 4) << 2;
#pragma unroll
  for (int rg = 0; rg < 4; rg++) {
#pragma unroll
    for (int j = 0; j < 4; j++) {
#pragma unroll
      for (int r = 0; r < 4; r++) {
        int row = e0 + rowb + rg*16 + r4 + r;
        int col = wc + j*16 + fr;
        Vn[(size_t)row*256 + col] = f2h(acc[rg][j][r]);
      }
    }
  }
}

// ---- Gtt[slab][col][32] = coupling x Wv (fp16, tiled). col = kabs*16+d ----
__global__ void gbuild_k(const float* __restrict__ TD,
    const float* __restrict__ Wv1, const float* __restrict__ Wv2,
    const float* __restrict__ Wv3, const int* __restrict__ sl_origc,
    unsigned short* __restrict__ Gt, int Kdim, int npairs,
    int s1b, int s1e, int s2e, int s3e)
{
  int k = blockIdx.x*256 + threadIdx.x;
  if (k >= Kdim) return;
  int col = blockIdx.y;
  int pair = k >> 4, m = k & 15;
  int d = col & 15, kabs = col >> 4;
  float acc = 0.f;
  if (kabs > 0 && pair < npairs) {
    const float* Wv; int ss, se, kloc;
    if (kabs < 4)      { Wv = Wv1; ss = s1b; se = s1e; kloc = kabs - 1; }
    else if (kabs < 9) { Wv = Wv2; ss = s1e; se = s2e; kloc = kabs - 4; }
    else               { Wv = Wv3; ss = s2e; se = s3e; kloc = kabs - 9; }
    for (int slot = ss; slot < se; slot++)
      acc += TD[((pair*30) + (slot - 4))*8 + kloc] * Wv[(sl_origc[slot] + m)*16 + d];
    acc *= rsqrtf((float)(16*(se - ss)));
  }
  Gt[((size_t)((k >> 5)*256 + col))*32 + (k & 31)] = f2h(acc);
}

// ---- weight convert + transpose: Wt[n][k] = fp16(W[k][n]) ----
struct WDesc { const float* src; unsigned short* dst; int K; int lgN; };
struct WPack { WDesc d[8]; };
__global__ void wcvt_k(WPack p){
  WDesc d = p.d[blockIdx.y];
  int total = d.K << d.lgN;
  int gid = blockIdx.x*256 + threadIdx.x;
  if (gid >= total) return;
  int k = gid >> d.lgN, n = gid & ((1 << d.lgN) - 1);
  d.dst[(size_t)n*d.K + k] = f2h(d.src[gid]);
}

// ---- hc[k] = sum_j W_h[k][j] * W_out[j]  (head @ out collapsed) ----
__global__ void whc_k(const float* __restrict__ Wh, const float* __restrict__ Wout,
                      float* __restrict__ hc)
{
  int k = threadIdx.x;
  float s = 0.f;
#pragma unroll 16
  for (int j = 0; j < 128; j++) s += Wh[k*128 + j] * Wout[j];
  hc[k] = s;
}

// ---- out[e] = env[e] * dot(x16[e,:256], hc) / (16*sqrt(128)) ----
__global__ void final256_k(const unsigned short* __restrict__ X,
    const float* __restrict__ hc, const float* __restrict__ env,
    float* __restrict__ out)
{
  const int e = blockIdx.x*256 + threadIdx.x;
  float acc = 0.f;
#pragma unroll 16
  for (int k = 0; k < 256; k++) acc += h2f(X[((size_t)e<<8)+k])*hc[k];
  out[e] = env[e]*acc*0.0055242717280199023f;   // 1/(16*sqrt(128))
}

// Generic fp32 tiled GEMM (small two-body layers).
template<int FLAGS>
__global__ __launch_bounds__(256) void gemm_k(
    const float* __restrict__ A1, const float* __restrict__ A2,
    int K1, int K, const float* __restrict__ W, int N,
    float* Cout,
    const float* __restrict__ env, const float* __restrict__ alphap,
    const float* Xres)
{
  __shared__ float As[16][68];
  __shared__ float Ws[16][68];
  const int tid = threadIdx.x;
  const int bm = blockIdx.x * 64;
  const int bn = blockIdx.y * 64;
  const int tx = tid & 15, ty = tid >> 4;
  const int K2 = K - K1;
  float acc[4][4] = {};
  for (int k0 = 0; k0 < K; k0 += 16) {
#pragma unroll
    for (int i = 0; i < 4; i++) {
      int idx = tid + i*256;
      int m = idx >> 4, kk = idx & 15;
      int k = k0 + kk;
      float v = 0.f;
      if (k < K) {
        int row = bm + m;
        v = (k < K1) ? A1[(size_t)row*K1 + k] : A2[(size_t)row*K2 + (k-K1)];
      }
      As[kk][m] = v;
    }
#pragma unroll
    for (int i = 0; i < 4; i++) {
      int idx = tid + i*256;
      int n = idx & 63, kk = idx >> 6;
      int k = k0 + kk, col = bn + n;
      Ws[kk][n] = (k < K && col < N) ? W[(size_t)k*N + col] : 0.f;
    }
    __syncthreads();
#pragma unroll
    for (int kk = 0; kk < 16; kk++) {
      float a[4], b[4];
#pragma unroll
      for (int i=0;i<4;i++) a[i] = As[kk][ty*4+i];
#pragma unroll
      for (int j=0;j<4;j++) b[j] = Ws[kk][tx*4+j];
#pragma unroll
      for (int i=0;i<4;i++)
#pragma unroll
        for (int j=0;j<4;j++)
          acc[i][j] += a[i]*b[j];
    }
    __syncthreads();
  }
  const float rscale = 1.f/sqrtf((float)K);
  float a2 = 0.f, inv1a2 = 1.f;
  if (FLAGS & F_RESID) { float al = alphap[0]; a2 = al*al; inv1a2 = 1.f/(1.f+a2); }
#pragma unroll
  for (int i=0;i<4;i++) {
    int row = bm + ty*4 + i;
    float ev = (FLAGS & F_ENV) ? env[row] : 1.f;
#pragma unroll
    for (int j=0;j<4;j++) {
      int col = bn + tx*4 + j;
      if (col >= N) continue;
      float v = acc[i][j]*rscale;
      if (FLAGS & F_SILU) v = v/(1.f+__expf(-v));
      if (FLAGS & F_ENV)  v *= ev;
      if (FLAGS & F_RESID) v = (Xres[(size_t)row*N+col] + a2*v)*inv1a2;
      Cout[(size_t)row*N+col] = v;
    }
  }
}

// dense to 16 outputs, K=256, scale 1/16; A fp16 (layer-2 w2)
__global__ __launch_bounds__(256) void dense16_k(const unsigned short* __restrict__ A,
    const float* __restrict__ W, float* __restrict__ C)
{
  __shared__ float As[16*256];
  const int r0 = blockIdx.x << 4;
  const int tid = threadIdx.x;
  for (int i = tid; i < 16*256; i += 256)
    As[i] = h2f(A[((size_t)r0<<8) + i]);
  __syncthreads();
  const int r = tid >> 4, n = tid & 15;
  float acc = 0.f;
#pragma unroll 8
  for (int k = 0; k < 256; k++)
    acc += As[(r<<8)+k] * W[(k<<4)+n];
  C[((size_t)(r0+r)<<4)+n] = acc * 0.0625f;
}

// fused w0 + w1 + V-init: one xb read, V written in-block ([a][m] layout)
__global__ __launch_bounds__(256) void dense16v_k(const unsigned short* __restrict__ A,
    const float* __restrict__ W0, const float* __restrict__ W1,
    const float* __restrict__ Y, unsigned short* __restrict__ V,
    float* __restrict__ wb)
{
  __shared__ float As[16*256];
  __shared__ float w0s[256];
  const int r0 = blockIdx.x << 4;
  const int tid = threadIdx.x;
  for (int i = tid; i < 16*256; i += 256)
    As[i] = h2f(A[((size_t)r0<<8) + i]);
  __syncthreads();
  const int r = tid >> 4, n = tid & 15;
  float a0 = 0.f, a1 = 0.f;
#pragma unroll 8
  for (int k = 0; k < 256; k++) {
    float xv = As[(r<<8)+k];
    a0 += xv * W0[(k<<4)+n];
    a1 += xv * W1[(k<<4)+n];
  }
  w0s[tid] = a0 * 0.0625f;
  wb[((size_t)(r0+r)<<4)+n] = a1 * 0.0625f;
  __syncthreads();
  for (int i = tid; i < 4096; i += 256) {
    int e = i >> 8, idx = i & 255;
    V[(((size_t)(r0+e))<<8) + idx] = f2h(w0s[(e<<4)+(idx&15)] * Y[((r0+e)<<4)+(idx>>4)]);
  }
}

__global__ void edge_init_k(const float* __restrict__ vectors, const int* __restrict__ senders,
    const int* __restrict__ receivers, const int* __restrict__ species,
    const float* __restrict__ emb, float* __restrict__ envb, float* __restrict__ Yb,
    float* __restrict__ x72)
{
  const int e = blockIdx.x*256 + threadIdx.x;
  float vx = vectors[e*3+0], vy = vectors[e*3+1], vz = vectors[e*3+2];
  float d = sqrtf(vx*vx+vy*vy+vz*vz);
  float dd = (d==0.f) ? 1.f : d;
  float invd = 1.f/dd;
  float x = vx*invd, y = vy*invd, z = vz*invd;
  float d2=d*d, d3=d2*d, d6=d3*d3, d7=d6*d, d8=d7*d;
  float envv = (d<1.f) ? (1.f - 28.f*d6 + 48.f*d7 - 21.f*d8) : 0.f;
  envb[e] = envv;
  float mask = (d==0.f)?0.f:1.f;
  const float SQ2 = 1.41421356237309515f;
  const float PIf = 3.14159265358979323846f;
  float* xr = x72 + (size_t)e*72;
#pragma unroll
  for (int n=1;n<=8;n++)
    xr[n-1] = SQ2 * sinf((float)n*PIf*dd)*invd*envv*mask;
  int sp_s = species[senders[e]], sp_r = species[receivers[e]];
  const float* es_ = emb + (size_t)sp_s*32;
  const float* er_ = emb + (size_t)sp_r*32;
#pragma unroll 8
  for (int k=0;k<32;k++){ xr[8+k] = es_[k]*mask; xr[40+k] = er_[k]*mask; }
  float x2=x*x, y2=y*y, z2=z*z;
  const float s3=1.7320508075688772f, s15=3.872983346207417f, s5=2.23606797749979f;
  const float s358=2.0916500663351889f, s105=10.246950765959598f;
  const float s218=1.6201851746019651f, s7=2.6457513110645907f;
  float* Yr = Yb + ((size_t)e<<4);
  Yr[0]=1.f;           Yr[1]=s3*y;          Yr[2]=s3*z;           Yr[3]=s3*x;
  Yr[4]=s15*x*y;       Yr[5]=s15*y*z;       Yr[6]=0.5f*s5*(3.f*z2-1.f);
  Yr[7]=s15*x*z;       Yr[8]=0.5f*s15*(x2-y2);
  Yr[9]=s358*y*(3.f*x2-y2);  Yr[10]=s105*x*y*z;  Yr[11]=s218*y*(5.f*z2-1.f);
  Yr[12]=0.5f*s7*(5.f*z2-3.f)*z;  Yr[13]=s218*x*(5.f*z2-1.f);
  Yr[14]=0.5f*s105*(x2-y2)*z;     Yr[15]=s358*x*(x2-y2);
}

// node[senders[e]][a*16+m] += w[e,m]*Y[e,a]
__global__ void scatter_k(const float* __restrict__ w, const float* __restrict__ Y,
                          const int* __restrict__ senders, float* node)
{
  const int gid = blockIdx.x*256 + threadIdx.x;
  const int e = gid >> 8, idx = gid & 255;
  float v = w[(e<<4) + (idx&15)] * Y[(e<<4) + (idx>>4)];
  atomicAdd(&node[((size_t)senders[e]<<8) + idx], v);
}

// l3=0 TP (slots 0..3); B (V/Vn) fp16; tp0 out fp16
__global__ void tp2_k(const float* __restrict__ node, const unsigned short* __restrict__ Vn,
    const int* __restrict__ senders, const float* __restrict__ varepsp,
    const int* __restrict__ pmeta, const int* __restrict__ entIJ,
    const float* __restrict__ entVal, unsigned short* __restrict__ tp0)
{
  const int gid = blockIdx.x*256 + threadIdx.x;
  const int e = gid >> 6, c = gid & 63;
  const int p = c >> 4, m = c & 15;
  float ve = varepsp[0];
  float eps = rsqrtf(1.f + ve*ve);
  int s = senders[e];
  const float* Am = &node[((size_t)s<<8)];
  const unsigned short* Bm = &Vn[((size_t)e<<8)];
  int es = pmeta[p*4+1], ec = pmeta[p*4+2];
  float acc = 0.f;
  for (int t=0;t<ec;t++){
    int ij = entIJ[es+t];
    acc += entVal[es+t] * Am[((ij&255)<<4) + m] * h2f(Bm[(((ij>>8)&255)<<4) + m]);
  }
  tp0[((size_t)e<<6) + pmeta[p*4+0] + m] = f2h(acc * eps);
}

// ============================ host launcher ============================

static void launch_gemm(int flags, const float* A1, const float* A2, int K1, int K,
    const float* W, int N, float* C, const float* env, const float* alphap,
    const float* Xres, hipStream_t stream)
{
  dim3 grid(E_EDGES/64, (N+63)/64);
  switch(flags){
    case F_SILU:        gemm_k<F_SILU>       <<<grid,256,0,stream>>>(A1,A2,K1,K,W,N,C,env,alphap,Xres); break;
    case F_ENV:         gemm_k<F_ENV>        <<<grid,256,0,stream>>>(A1,A2,K1,K,W,N,C,env,alphap,Xres); break;
    default: break;
  }
}

static void launch_mgemm(int flags, int a16, const void* A1, const void* A2, int K1, int K,
    const unsigned short* Wt, int N, unsigned short* C, const float* env,
    const float* alphap, const unsigned short* Xres, hipStream_t stream)
{
  dim3 grid(E_EDGES/128, N/128);
  if (a16) {
    switch(flags){
      case F_SILU:        mgemm_k<F_SILU,1>       <<<grid,256,0,stream>>>(A1,A2,K1,K,Wt,N,C,env,alphap,Xres); break;
      case F_ENV:         mgemm_k<F_ENV,1>        <<<grid,256,0,stream>>>(A1,A2,K1,K,Wt,N,C,env,alphap,Xres); break;
      default: break;
    }
  } else {
    switch(flags){
      case F_SILU:        mgemm_k<F_SILU,0>       <<<grid,256,0,stream>>>(A1,A2,K1,K,Wt,N,C,env,alphap,Xres); break;
      case F_ENV:         mgemm_k<F_ENV,0>        <<<grid,256,0,stream>>>(A1,A2,K1,K,Wt,N,C,env,alphap,Xres); break;
      default: break;
    }
  }
}

extern "C" void kernel_launch(void* const* d_in, const int* in_sizes, int n_in,
                              void* d_out, int out_size, void* d_ws, size_t ws_size,
                              hipStream_t stream)
{
  const float* vectors = (const float*)d_in[0];
  const float* vareps  = (const float*)d_in[1];
  const float* alpha   = (const float*)d_in[2];
  const float* emb     = (const float*)d_in[3];
  const float* W_tb1   = (const float*)d_in[4];
  const float* W_tb2   = (const float*)d_in[5];
  const float* W_tb3   = (const float*)d_in[6];
  const float* W_tb4   = (const float*)d_in[7];
  const float* W_w0    = (const float*)d_in[8];
  const float* W_w1    = (const float*)d_in[9];
  const float* W_l11   = (const float*)d_in[10];
  const float* W_l12   = (const float*)d_in[11];
  const float* W_l13   = (const float*)d_in[12];
  const float* W_v1    = (const float*)d_in[13];
  const float* W_v2    = (const float*)d_in[14];
  const float* W_v3    = (const float*)d_in[15];
  const float* W_w2    = (const float*)d_in[16];
  const float* W_l21   = (const float*)d_in[17];
  const float* W_l22   = (const float*)d_in[18];
  const float* W_l23   = (const float*)d_in[19];
  const float* W_h     = (const float*)d_in[20];
  const float* W_out   = (const float*)d_in[21];
  const int* senders   = (const int*)d_in[22];
  const int* receivers = (const int*)d_in[23];
  const int* species   = (const int*)d_in[24];

  static cgt::Tables tb;
  cgt::build(tb);
  const int Kdim = tb.npairs * 16;

  char* ws = (char*)d_ws;
  size_t off = 0;
  auto alloc = [&](size_t bytes)->void*{
    void* p = ws + off; off += (bytes + 255) & ~(size_t)255; return p;
  };
  float* t_val = (float*)alloc(sizeof(tb.val));
  int*   t_ij  = (int*)  alloc(sizeof(tb.ij));
  int*   t_pm  = (int*)  alloc(sizeof(tb.pmeta));
  float* t_td  = (float*)alloc(sizeof(tb.TD));
  int*   t_pr  = (int*)  alloc(sizeof(tb.pairs));
  int*   t_oc  = (int*)  alloc(sizeof(tb.sl_origc));
  float* envb  = (float*)alloc((size_t)E_EDGES*4);
  float* Yb    = (float*)alloc((size_t)E_EDGES*16*4);
  float* xb    = (float*)alloc((size_t)E_EDGES*256*4);
  float* Vb    = (float*)alloc((size_t)E_EDGES*256*4);
  float* bufA  = (float*)alloc((size_t)E_EDGES*256*4);
  float* bufB  = (float*)alloc((size_t)E_EDGES*256*4);
  float* wb    = (float*)alloc((size_t)E_EDGES*16*4);
  float* tp0b  = (float*)alloc((size_t)E_EDGES*64*4);
  float* nodeb = (float*)alloc((size_t)NNODES*256*4);
  float* hcb   = (float*)alloc(256*4);
  unsigned short* Gt = (unsigned short*)alloc((size_t)256*Kdim*2);
  unsigned short* Wt_tb3 = (unsigned short*)alloc(64*128*2);
  unsigned short* Wt_tb4 = (unsigned short*)alloc(128*256*2);
  unsigned short* Wt_l11 = (unsigned short*)alloc(320*256*2);
  unsigned short* Wt_l12 = (unsigned short*)alloc(256*256*2);
  unsigned short* Wt_l13 = (unsigned short*)alloc(256*256*2);
  unsigned short* Wt_l21 = (unsigned short*)alloc(320*256*2);
  unsigned short* Wt_l22 = (unsigned short*)alloc(256*256*2);
  unsigned short* Wt_l23 = (unsigned short*)alloc(256*256*2);
  if (off > ws_size) {
    fprintf(stderr, "[allegro] workspace too small: need %zu, have %zu\n", off, ws_size);
    return;
  }
  unsigned short* xb16 = (unsigned short*)xb;
  unsigned short* bB16 = (unsigned short*)bufB;
  unsigned short* tp016 = (unsigned short*)tp0b;
  unsigned short* V16 = (unsigned short*)Vb;

  hipMemcpyAsync(t_val, tb.val,     sizeof(tb.val),     hipMemcpyHostToDevice, stream);
  hipMemcpyAsync(t_ij,  tb.ij,      sizeof(tb.ij),      hipMemcpyHostToDevice, stream);
  hipMemcpyAsync(t_pm,  tb.pmeta,   sizeof(tb.pmeta),   hipMemcpyHostToDevice, stream);
  hipMemcpyAsync(t_td,  tb.TD,      sizeof(tb.TD),      hipMemcpyHostToDevice, stream);
  hipMemcpyAsync(t_pr,  tb.pairs,   sizeof(tb.pairs),   hipMemcpyHostToDevice, stream);
  hipMemcpyAsync(t_oc,  tb.sl_origc,sizeof(tb.sl_origc),hipMemcpyHostToDevice, stream);

  const int s1b = tb.l3np[0];
  const int s1e = s1b + tb.l3np[1];
  const int s2e = s1e + tb.l3np[2];
  const int s3e = s2e + tb.l3np[3];

  {
    dim3 g((Kdim + 255)/256, 256);
    gbuild_k<<<g, 256, 0, stream>>>(t_td, W_v1, W_v2, W_v3, t_oc, Gt, Kdim,
                                    tb.npairs, s1b, s1e, s2e, s3e);
  }
  {
    WPack p;
    p.d[0] = { W_tb3, Wt_tb3,  64, 7 };
    p.d[1] = { W_tb4, Wt_tb4, 128, 8 };
    p.d[2] = { W_l11, Wt_l11, 320, 8 };
    p.d[3] = { W_l12, Wt_l12, 256, 8 };
    p.d[4] = { W_l13, Wt_l13, 256, 8 };
    p.d[5] = { W_l21, Wt_l21, 320, 8 };
    p.d[6] = { W_l22, Wt_l22, 256, 8 };
    p.d[7] = { W_l23, Wt_l23, 256, 8 };
    dim3 g(320, 8);
    wcvt_k<<<g, 256, 0, stream>>>(p);
  }
  whc_k<<<1, 256, 0, stream>>>(W_h, W_out, hcb);

  // 1. edge features + Y + env  (x72 -> bufA fp32)
  edge_init_k<<<E_EDGES/256, 256, 0, stream>>>(vectors, senders, receivers, species,
                                               emb, envb, Yb, bufA);
  // 2. two-body MLP
  launch_gemm (F_SILU, bufA, nullptr, 72, 72,  W_tb1, 32,  bufB, envb, alpha, nullptr, stream);
  launch_gemm (F_SILU, bufB, nullptr, 32, 32,  W_tb2, 64,  bufA, envb, alpha, nullptr, stream);
  launch_mgemm(F_SILU, 0, bufA, nullptr, 64, 64,  Wt_tb3, 128, bB16, envb, alpha, nullptr, stream);
  launch_mgemm(F_ENV,  1, bB16, nullptr, 128,128, Wt_tb4, 256, xb16, envb, alpha, nullptr, stream);
  // 3. fused w0+w1+V
  dense16v_k<<<E_EDGES/16, 256, 0, stream>>>(xb16, W_w0, W_w1, Yb, V16, wb);

  // ---- layer 1 ----
  hipMemsetAsync(nodeb, 0, (size_t)NNODES*256*4, stream);
  scatter_k<<<E_EDGES, 256, 0, stream>>>(wb, Yb, senders, nodeb);
  tp2_k<<<E_EDGES*64/256, 256, 0, stream>>>(nodeb, V16, senders, vareps, t_pm, t_ij,
                                            t_val, tp016);
  vn_k<<<E_EDGES/VN_E, 512, 0, stream>>>(nodeb, V16, senders, vareps, t_pr, Gt, V16, Kdim);
  launch_mgemm(F_SILU, 1, xb16, tp016, 256, 320, Wt_l11, 256, bB16, envb, alpha, nullptr, stream);
  mlp2_k<<<E_EDGES/64, 256, 0, stream>>>(bB16, Wt_l12, Wt_l13, xb16, xb16, envb, alpha);

  // ---- layer 2 (lmax_out = 0) ----
  dense16_k<<<E_EDGES/16, 256, 0, stream>>>(xb16, W_w2, wb);
  hipMemsetAsync(nodeb, 0, (size_t)NNODES*256*4, stream);
  scatter_k<<<E_EDGES, 256, 0, stream>>>(wb, Yb, senders, nodeb);
  tp2_k<<<E_EDGES*64/256, 256, 0, stream>>>(nodeb, V16, senders, vareps, t_pm, t_ij,
                                            t_val, tp016);
  launch_mgemm(F_SILU, 1, xb16, tp016, 256, 320, Wt_l21, 256, bB16, envb, alpha, nullptr, stream);
  mlp2_k<<<E_EDGES/64, 256, 0, stream>>>(bB16, Wt_l22, Wt_l23, xb16, xb16, envb, alpha);

  // ---- head (W_h @ W_out precombined) ----
  final256_k<<<E_EDGES/256, 256, 0, stream>>>(xb16, hcb, envb, (float*)d_out);
}

// Round 14
// 464.718 us; speedup vs baseline: 1.2597x; 1.0684x over previous
//
#include <hip/hip_runtime.h>
#include <cmath>
#include <complex>
#include <cstdio>
#include <cstring>
#include <algorithm>

#define E_EDGES 32768
#define NNODES  2048
#define VN_E    128

// ============================ host-side CG tables ============================
namespace cgt {

static double fct(int n){
  static const double f[13] = {1.,1.,2.,6.,24.,120.,720.,5040.,40320.,362880.,
                               3628800.,39916800.,479001600.};
  return f[n];
}

static double cg(int j1,int m1,int j2,int m2,int j3,int m3){
  if (m1+m2 != m3) return 0.0;
  double pre = std::sqrt((2*j3+1)*fct(j1+j2-j3)*fct(j1-j2+j3)*fct(-j1+j2+j3)/fct(j1+j2+j3+1));
  pre *= std::sqrt(fct(j3+m3)*fct(j3-m3)*fct(j1-m1)*fct(j1+m1)*fct(j2-m2)*fct(j2+m2));
  int kmin = 0;
  if (j2-j3-m1 > kmin) kmin = j2-j3-m1;
  if (j1-j3+m2 > kmin) kmin = j1-j3+m2;
  int kmax = j1+j2-j3;
  if (j1-m1 < kmax) kmax = j1-m1;
  if (j2+m2 < kmax) kmax = j2+m2;
  double s = 0.0;
  for (int k=kmin;k<=kmax;k++){
    double d = fct(k)*fct(j1+j2-j3-k)*fct(j1-m1-k)*fct(j2+m2-k)*fct(j3-j2+m1+k)*fct(j3-j1-m2+k);
    s += ((k&1)? -1.0:1.0)/d;
  }
  return pre*s;
}

typedef std::complex<double> cd;

static void umat(int l, cd U[7][7]){
  for (int a=0;a<7;a++) for (int b=0;b<7;b++) U[a][b]=cd(0,0);
  U[l][l] = cd(1,0);
  double s2 = 1.0/std::sqrt(2.0);
  for (int m=1;m<=l;m++){
    double sg = (m&1)? -1.0 : 1.0;
    U[l+m][l-m] = cd(s2,0);
    U[l+m][l+m] = cd(sg*s2,0);
    U[l-m][l-m] = cd(0, s2);
    U[l-m][l+m] = cd(0, -sg*s2);
  }
}

static bool realCoupling(int l1,int l2,int l3, double T[7][7][7]){
  cd U1[7][7],U2[7][7],U3[7][7];
  umat(l1,U1); umat(l2,U2); umat(l3,U3);
  int n1=2*l1+1, n2=2*l2+1, n3=2*l3+1;
  double Cg[7][7][7];
  for (int m=0;m<n1;m++) for(int n=0;n<n2;n++) for(int k=0;k<n3;k++)
    Cg[m][n][k] = cg(l1,m-l1,l2,n-l2,l3,k-l3);
  double Tr[7][7][7], Ti[7][7][7];
  double nr=0, ni=0;
  for (int a=0;a<n1;a++) for(int b=0;b<n2;b++) for(int c=0;c<n3;c++){
    cd s(0,0);
    for (int m=0;m<n1;m++){
      if (U1[a][m]==cd(0,0)) continue;
      for (int n=0;n<n2;n++){
        if (U2[b][n]==cd(0,0)) continue;
        for (int k=0;k<n3;k++){
          double cgv = Cg[m][n][k];
          if (cgv==0.0) continue;
          s += U1[a][m]*U2[b][n]*std::conj(U3[c][k])*cgv;
        }
      }
    }
    Tr[a][b][c]=s.real(); Ti[a][b][c]=s.imag();
    nr += s.real()*s.real(); ni += s.imag()*s.imag();
  }
  bool useR = (nr >= ni);
  double nn = std::sqrt(useR? nr : ni);
  if (nn < 1e-8) return false;
  for (int a=0;a<n1;a++)for(int b=0;b<n2;b++)for(int c=0;c<n3;c++)
    T[a][b][c] = (useR? Tr[a][b][c] : Ti[a][b][c])/nn;
  return true;
}

struct Tables {
  float val[4096];
  int   ij[4096];
  int   pmeta[40*4];
  int   ccnt[40*8];
  int   l3base[4];
  int   l3np[4];
  int   npaths;
  int   nent;
  int   tptot;
  int   pairs[256];
  float TD[256*30*8];
  int   sl_origc[40];
  int   npairs;
};

struct PathTmp {
  int l1,l2,l3, tpoff, kd;
  int ec;
  double T[7][7][7];
};

static void build(Tables& tb){
  static PathTmp paths[40];
  int np = 0, tpoff = 0;
  int l3start[5];
  for (int l3=0;l3<=3;l3++){
    tb.l3base[l3] = tpoff;
    l3start[l3] = np;
    int kd = 2*l3+1;
    for (int l1=0;l1<=3;l1++) for (int l2=0;l2<=3;l2++){
      int lo = (l1>l2)? l1-l2 : l2-l1;
      int hi = std::min(l1+l2,3);
      if (l3 < lo || l3 > hi) continue;
      PathTmp& pt = paths[np];
      if (!realCoupling(l1,l2,l3,pt.T)) continue;
      pt.l1=l1; pt.l2=l2; pt.l3=l3; pt.kd=kd; pt.tpoff=tpoff;
      double scale = std::sqrt((double)kd);
      int cnt = 0;
      for (int a=0;a<2*l1+1;a++)for(int b=0;b<2*l2+1;b++)for(int c=0;c<kd;c++)
        if (std::fabs(pt.T[a][b][c]*scale) > 1e-7) cnt++;
      pt.ec = cnt;
      tpoff += 16*kd;
      np++;
    }
  }
  l3start[4] = np;
  for (int l3=0;l3<=3;l3++) tb.l3np[l3] = l3start[l3+1]-l3start[l3];
  static int order[40];
  for (int i=0;i<np;i++) order[i]=i;
  for (int l3=0;l3<=3;l3++)
    std::sort(order+l3start[l3], order+l3start[l3+1],
              [&](int a,int b){ return paths[a].ec > paths[b].ec; });
  std::memset(tb.TD, 0, sizeof(tb.TD));
  std::memset(tb.pairs, 0, sizeof(tb.pairs));
  static int pmap[16][16];
  for (int i=0;i<16;i++) for (int j=0;j<16;j++) pmap[i][j] = -1;
  int npr = 0;
  int ep = 0;
  for (int slot=0; slot<np; slot++){
    const PathTmp& pt = paths[order[slot]];
    double scale = std::sqrt((double)pt.kd);
    int s1 = pt.l1*pt.l1, s2 = pt.l2*pt.l2;
    tb.pmeta[slot*4+0] = pt.tpoff;
    tb.pmeta[slot*4+1] = ep;
    tb.sl_origc[slot] = ((pt.tpoff - tb.l3base[pt.l3]) / (16*pt.kd)) * 16;
    int tot = 0;
    for (int c=0;c<pt.kd;c++){
      int cnt = 0;
      for (int a=0;a<2*pt.l1+1;a++)for(int b=0;b<2*pt.l2+1;b++){
        double v = pt.T[a][b][c]*scale;
        if (std::fabs(v) > 1e-7){
          tb.val[ep] = (float)v;
          tb.ij[ep]  = (s1+a) | ((s2+b)<<8);
          ep++; cnt++;
          if (pt.l3 >= 1){
            int aa = s1+a, bb = s2+b;
            int pi = pmap[aa][bb];
            if (pi < 0){ pi = npr; pmap[aa][bb] = pi;
                         tb.pairs[npr] = aa | (bb<<8); npr++; }
            tb.TD[(pi*30 + (slot-4))*8 + c] = (float)v;
          }
        }
      }
      tb.ccnt[slot*8+c] = cnt;
      tot += cnt;
    }
    for (int c=pt.kd;c<8;c++) tb.ccnt[slot*8+c]=0;
    tb.pmeta[slot*4+2] = tot;
    tb.pmeta[slot*4+3] = pt.kd;
  }
  if (npr & 1){ tb.pairs[npr] = 0; npr++; }
  tb.npairs = npr;
  tb.npaths = np; tb.nent = ep; tb.tptot = tpoff;
}

} // namespace cgt

// ============================ device kernels ============================
// LAYOUT: node/V/Vn rows are [a][m]. MFMA-path activations fp16 in HBM.

enum GFlags { F_NONE=0, F_SILU=1, F_ENV=2, F_RESID=4 };

typedef _Float16 half8 __attribute__((ext_vector_type(8)));
typedef __attribute__((ext_vector_type(4))) float f32x4;

__device__ inline unsigned short f2h(float f){
  union { _Float16 h; unsigned short u; } x;
  x.h = (_Float16)f;
  return x.u;
}
__device__ inline float h2f(unsigned short u){
  union { _Float16 h; unsigned short u; } x; x.u = u;
  return (float)x.h;
}

__device__ inline int swz(int row, int kh){
  int b = row*64 + kh*2;
  return b ^ (((row >> 1) & 3) << 4);
}

// ---- fp16 MFMA GEMM: C16[M,N] = post( A[M,K] @ W[K,N] / sqrt(K) ) ----
template<int FLAGS, int A16>
__global__ __launch_bounds__(256) void mgemm_k(
    const void* __restrict__ A1v, const void* __restrict__ A2v,
    int K1, int K, const unsigned short* __restrict__ Wt, int N,
    unsigned short* Cout, const float* __restrict__ env,
    const float* __restrict__ alphap, const unsigned short* Xres)
{
  __shared__ unsigned short AsB[128*32];
  __shared__ unsigned short BsB[128*32];
  const int tid  = threadIdx.x;
  const int wave = tid >> 6, lane = tid & 63;
  const int bm = blockIdx.x*128, bn = blockIdx.y*128;
  const int wr = (wave >> 1)*64, wc = (wave & 1)*64;
  const int K2 = K - K1;
  f32x4 acc[4][4] = {};

  const int sr  = tid >> 3;
  const int skq = (tid & 7) * 4;
  const int sr2 = tid >> 1;
  const int skh = (tid & 1) * 16;
  const int bn_ = tid >> 1;
  const int bkh = (tid & 1) * 16;

  for (int k0 = 0; k0 < K; k0 += 32) {
    if (A16) {
      int kk = k0 + skh;
      const unsigned short* ap = (kk < K1)
        ? (const unsigned short*)A1v + (size_t)(bm + sr2)*K1 + kk
        : (const unsigned short*)A2v + (size_t)(bm + sr2)*K2 + (kk - K1);
      uint4 u0 = *(const uint4*)ap;
      uint4 u1 = *(const uint4*)(ap + 8);
      *(uint4*)((char*)AsB + swz(sr2, skh))     = u0;
      *(uint4*)((char*)AsB + swz(sr2, skh + 8)) = u1;
    } else {
#pragma unroll
      for (int q = 0; q < 4; q++) {
        int row = q*32 + sr;
        int grow = bm + row;
        int kk = k0 + skq;
        float4 f4 = (kk < K1)
          ? *(const float4*)((const float*)A1v + (size_t)grow*K1 + kk)
          : *(const float4*)((const float*)A2v + (size_t)grow*K2 + (kk - K1));
        ushort4 u;
        u.x = f2h(f4.x); u.y = f2h(f4.y); u.z = f2h(f4.z); u.w = f2h(f4.w);
        *(ushort4*)((char*)AsB + swz(row, skq)) = u;
      }
    }
    {
      const unsigned short* s = Wt + (size_t)(bn + bn_)*K + k0 + bkh;
#pragma unroll
      for (int q = 0; q < 4; q++) {
        ushort4 u = *(const ushort4*)(s + q*4);
        *(ushort4*)((char*)BsB + swz(bn_, bkh + q*4)) = u;
      }
    }
    __syncthreads();
    const int fr = lane & 15, fk = (lane >> 4) * 8;
    half8 af[4], bf[4];
#pragma unroll
    for (int i = 0; i < 4; i++)
      af[i] = *(half8*)((char*)AsB + swz(wr + i*16 + fr, fk));
#pragma unroll
    for (int j = 0; j < 4; j++)
      bf[j] = *(half8*)((char*)BsB + swz(wc + j*16 + fr, fk));
#pragma unroll
    for (int i = 0; i < 4; i++)
#pragma unroll
      for (int j = 0; j < 4; j++)
        acc[i][j] = __builtin_amdgcn_mfma_f32_16x16x32_f16(af[i], bf[j], acc[i][j], 0, 0, 0);
    __syncthreads();
  }

  const float rscale = 1.f/sqrtf((float)K);
  float a2 = 0.f, inv1a2 = 1.f;
  if (FLAGS & F_RESID) { float al = alphap[0]; a2 = al*al; inv1a2 = 1.f/(1.f+a2); }
#pragma unroll
  for (int i = 0; i < 4; i++) {
#pragma unroll
    for (int r = 0; r < 4; r++) {
      int row = bm + wr + i*16 + ((lane >> 4) << 2) + r;
      float ev = (FLAGS & F_ENV) ? env[row] : 1.f;
#pragma unroll
      for (int j = 0; j < 4; j++) {
        int col = bn + wc + j*16 + (lane & 15);
        float v = acc[i][j][r]*rscale;
        if (FLAGS & F_SILU) v = v/(1.f+__expf(-v));
        if (FLAGS & F_ENV)  v *= ev;
        if (FLAGS & F_RESID) v = (h2f(Xres[(size_t)row*N+col]) + a2*v)*inv1a2;
        Cout[(size_t)row*N+col] = f2h(v);
      }
    }
  }
}

// ---- fused 2-layer MLP: out = resid(env * (silu(A@W1/16) @ W2 /16)) ----
__global__ __launch_bounds__(256) void mlp2_k(
    const unsigned short* __restrict__ A, const unsigned short* __restrict__ W1t,
    const unsigned short* __restrict__ W2t, unsigned short* __restrict__ Out,
    const unsigned short* __restrict__ Xres, const float* __restrict__ env,
    const float* __restrict__ alphap)
{
  __shared__ unsigned short AsB[64*32];
  __shared__ unsigned short BsB[256*32];
  __shared__ unsigned short Hs[64*264];
  const int tid  = threadIdx.x;
  const int wave = tid >> 6, lane = tid & 63;
  const int bm = blockIdx.x*64;
  const int wc = wave*64;
  const int fr = lane & 15, fk = (lane >> 4) * 8;
  const int r4 = (lane >> 4) << 2;
  const int sra = tid >> 2;
  const int ska = (tid & 3) * 8;
  const int srb = tid >> 1;
  const int skb = (tid & 1) * 16;
  f32x4 acc[4][4] = {};

  for (int k0 = 0; k0 < 256; k0 += 32) {
    {
      uint4 u = *(const uint4*)(A + (size_t)(bm + sra)*256 + k0 + ska);
      *(uint4*)((char*)AsB + swz(sra, ska)) = u;
    }
#pragma unroll
    for (int h = 0; h < 2; h++) {
      int n = h*128 + srb;
      const unsigned short* s = W1t + (size_t)n*256 + k0 + skb;
      uint4 u0 = *(const uint4*)s;
      uint4 u1 = *(const uint4*)(s + 8);
      *(uint4*)((char*)BsB + swz(n, skb))     = u0;
      *(uint4*)((char*)BsB + swz(n, skb + 8)) = u1;
    }
    __syncthreads();
    half8 af[4], bf[4];
#pragma unroll
    for (int i = 0; i < 4; i++)
      af[i] = *(half8*)((char*)AsB + swz(i*16 + fr, fk));
#pragma unroll
    for (int j = 0; j < 4; j++)
      bf[j] = *(half8*)((char*)BsB + swz(wc + j*16 + fr, fk));
#pragma unroll
    for (int i = 0; i < 4; i++)
#pragma unroll
      for (int j = 0; j < 4; j++)
        acc[i][j] = __builtin_amdgcn_mfma_f32_16x16x32_f16(af[i], bf[j], acc[i][j], 0, 0, 0);
    __syncthreads();
  }
#pragma unroll
  for (int i = 0; i < 4; i++)
#pragma unroll
    for (int r = 0; r < 4; r++) {
      int row = i*16 + r4 + r;
#pragma unroll
      for (int j = 0; j < 4; j++) {
        int col = wc + j*16 + fr;
        float v = acc[i][j][r]*0.0625f;
        v = v/(1.f+__expf(-v));
        Hs[row*264 + col] = f2h(v);
        acc[i][j][r] = 0.f;
      }
    }
  __syncthreads();

  for (int k0 = 0; k0 < 256; k0 += 32) {
#pragma unroll
    for (int h = 0; h < 2; h++) {
      int n = h*128 + srb;
      const unsigned short* s = W2t + (size_t)n*256 + k0 + skb;
      uint4 u0 = *(const uint4*)s;
      uint4 u1 = *(const uint4*)(s + 8);
      *(uint4*)((char*)BsB + swz(n, skb))     = u0;
      *(uint4*)((char*)BsB + swz(n, skb + 8)) = u1;
    }
    __syncthreads();
    half8 af[4], bf[4];
#pragma unroll
    for (int i = 0; i < 4; i++)
      af[i] = *(half8*)(Hs + (i*16 + fr)*264 + k0 + fk);
#pragma unroll
    for (int j = 0; j < 4; j++)
      bf[j] = *(half8*)((char*)BsB + swz(wc + j*16 + fr, fk));
#pragma unroll
    for (int i = 0; i < 4; i++)
#pragma unroll
      for (int j = 0; j < 4; j++)
        acc[i][j] = __builtin_amdgcn_mfma_f32_16x16x32_f16(af[i], bf[j], acc[i][j], 0, 0, 0);
    __syncthreads();
  }
  float al = alphap[0];
  float a2 = al*al, inv1a2 = 1.f/(1.f+a2);
#pragma unroll
  for (int i = 0; i < 4; i++)
#pragma unroll
    for (int r = 0; r < 4; r++) {
      int row = bm + i*16 + r4 + r;
      float ev = env[row];
#pragma unroll
      for (int j = 0; j < 4; j++) {
        int col = wc + j*16 + fr;
        float v = acc[i][j][r]*0.0625f*ev;
        v = (h2f(Xres[(size_t)row*256+col]) + a2*v)*inv1a2;
        Out[(size_t)row*256+col] = f2h(v);
      }
    }
}

// ---- fused Vn kernel + layer-1 tp0 (R14): node/V already staged in LDS ----
__global__ __launch_bounds__(512) void vn_k(
    const float* __restrict__ node, const unsigned short* __restrict__ V,
    const int* __restrict__ senders, const float* __restrict__ varepsp,
    const int* __restrict__ pairsG, const unsigned short* __restrict__ Gtt,
    unsigned short* __restrict__ Vn, int Kdim,
    const int* __restrict__ pmeta, const int* __restrict__ entIJ,
    const float* __restrict__ entVal, unsigned short* __restrict__ tp0)
{
  __shared__ unsigned short Ab[VN_E*264];
  __shared__ unsigned short Bb[VN_E*264];
  __shared__ int Ps[256];
  const int tid = threadIdx.x;
  const int e0 = blockIdx.x * VN_E;
  const int wave = tid >> 6, lane = tid & 63;
  float ve = varepsp[0];
  float eps = rsqrtf(1.f + ve*ve);
  if (tid < 256) Ps[tid] = pairsG[tid];
#pragma unroll
  for (int rr = 0; rr < 16; rr++) {
    int row = wave*16 + rr;
    int s = senders[e0 + row];
    float4 fa = *(const float4*)(node + ((size_t)s << 8) + 4*lane);
    uint2 ub = *(const uint2*)(V + (((size_t)(e0 + row)) << 8) + 4*lane);
    unsigned short* ad = Ab + row*264 + 4*lane;
    unsigned short* bd = Bb + row*264 + 4*lane;
    uint2 ua;
    ua.x = (unsigned)f2h(fa.x*eps) | ((unsigned)f2h(fa.y*eps) << 16);
    ua.y = (unsigned)f2h(fa.z*eps) | ((unsigned)f2h(fa.w*eps) << 16);
    *(uint2*)ad = ua;
    *(uint2*)bd = ub;
  }
  __syncthreads();
  // ---- fused l3=0 TP for these edges (Ab = eps*node, Bb = V) ----
  for (int o = tid; o < VN_E*64; o += 512) {
    int e = o >> 6, c = o & 63;
    int p = c >> 4, m = c & 15;
    const unsigned short* Ae = Ab + e*264;
    const unsigned short* Be = Bb + e*264;
    int es = pmeta[p*4+1], ec = pmeta[p*4+2];
    float acc = 0.f;
    for (int t = 0; t < ec; t++) {
      int ij = entIJ[es+t];
      acc += entVal[es+t] * h2f(Ae[((ij&255)<<4)+m]) * h2f(Be[(((ij>>8)&255)<<4)+m]);
    }
    tp0[((size_t)(e0+e)<<6) + pmeta[p*4+0] + m] = f2h(acc);
  }
  const int rowb = (wave & 1) * 64;
  const int wc   = (wave >> 1) * 64;
  const int fr = lane & 15, fk = (lane >> 4) * 8;
  const int pairSel = fk >> 4;
  const int moff = fk & 15;
  const int nslab = Kdim >> 5;
  f32x4 acc[4][4] = {};

  const unsigned short* Ar0 = Ab + (rowb + fr)*264;
  const unsigned short* Br0 = Bb + (rowb + fr)*264;
  const unsigned short* Ar1 = Ab + (rowb + 16 + fr)*264;
  const unsigned short* Br1 = Bb + (rowb + 16 + fr)*264;
  const unsigned short* Ar2 = Ab + (rowb + 32 + fr)*264;
  const unsigned short* Br2 = Bb + (rowb + 32 + fr)*264;
  const unsigned short* Ar3 = Ab + (rowb + 48 + fr)*264;
  const unsigned short* Br3 = Bb + (rowb + 48 + fr)*264;

  const unsigned short* gp = Gtt + ((size_t)(wc + fr)) * 32 + fk;
  half8 b0 = *(const half8*)(gp);
  half8 b1 = *(const half8*)(gp + 512);
  half8 b2 = *(const half8*)(gp + 1024);
  half8 b3 = *(const half8*)(gp + 1536);
  half8 c0 = b0, c1 = b1, c2 = b2, c3 = b3;
  if (nslab > 1) {
    const unsigned short* g1 = gp + 8192;
    c0 = *(const half8*)(g1);
    c1 = *(const half8*)(g1 + 512);
    c2 = *(const half8*)(g1 + 1024);
    c3 = *(const half8*)(g1 + 1536);
  }
  int p0 = Ps[pairSel];
  int aoff = ((p0 & 255) << 4) + moff;
  int boff = (((p0 >> 8) & 255) << 4) + moff;
  half8 rA0 = *(const half8*)(Ar0 + aoff);
  half8 rB0 = *(const half8*)(Br0 + boff);
  half8 rA1 = *(const half8*)(Ar1 + aoff);
  half8 rB1 = *(const half8*)(Br1 + boff);
  half8 rA2 = *(const half8*)(Ar2 + aoff);
  half8 rB2 = *(const half8*)(Br2 + boff);
  half8 rA3 = *(const half8*)(Ar3 + aoff);
  half8 rB3 = *(const half8*)(Br3 + boff);

  for (int sl = 0; sl < nslab; sl++) {
    half8 a0 = rA0 * rB0;
    half8 a1 = rA1 * rB1;
    half8 a2 = rA2 * rB2;
    half8 a3 = rA3 * rB3;
    if (sl + 1 < nslab) {
      int pn = Ps[2*(sl + 1) + pairSel];
      int aoffn = ((pn & 255) << 4) + moff;
      int boffn = (((pn >> 8) & 255) << 4) + moff;
      rA0 = *(const half8*)(Ar0 + aoffn);
      rB0 = *(const half8*)(Br0 + boffn);
      rA1 = *(const half8*)(Ar1 + aoffn);
      rB1 = *(const half8*)(Br1 + boffn);
      rA2 = *(const half8*)(Ar2 + aoffn);
      rB2 = *(const half8*)(Br2 + boffn);
      rA3 = *(const half8*)(Ar3 + aoffn);
      rB3 = *(const half8*)(Br3 + boffn);
    }
    half8 d0, d1, d2, d3;
    if (sl + 2 < nslab) {
      const unsigned short* gn = gp + (size_t)(sl + 2) * 8192;
      d0 = *(const half8*)(gn);
      d1 = *(const half8*)(gn + 512);
      d2 = *(const half8*)(gn + 1024);
      d3 = *(const half8*)(gn + 1536);
    } else { d0 = c0; d1 = c1; d2 = c2; d3 = c3; }
    acc[0][0] = __builtin_amdgcn_mfma_f32_16x16x32_f16(a0, b0, acc[0][0], 0, 0, 0);
    acc[1][0] = __builtin_amdgcn_mfma_f32_16x16x32_f16(a1, b0, acc[1][0], 0, 0, 0);
    acc[2][0] = __builtin_amdgcn_mfma_f32_16x16x32_f16(a2, b0, acc[2][0], 0, 0, 0);
    acc[3][0] = __builtin_amdgcn_mfma_f32_16x16x32_f16(a3, b0, acc[3][0], 0, 0, 0);
    acc[0][1] = __builtin_amdgcn_mfma_f32_16x16x32_f16(a0, b1, acc[0][1], 0, 0, 0);
    acc[1][1] = __builtin_amdgcn_mfma_f32_16x16x32_f16(a1, b1, acc[1][1], 0, 0, 0);
    acc[2][1] = __builtin_amdgcn_mfma_f32_16x16x32_f16(a2, b1, acc[2][1], 0, 0, 0);
    acc[3][1] = __builtin_amdgcn_mfma_f32_16x16x32_f16(a3, b1, acc[3][1], 0, 0, 0);
    acc[0][2] = __builtin_amdgcn_mfma_f32_16x16x32_f16(a0, b2, acc[0][2], 0, 0, 0);
    acc[1][2] = __builtin_amdgcn_mfma_f32_16x16x32_f16(a1, b2, acc[1][2], 0, 0, 0);
    acc[2][2] = __builtin_amdgcn_mfma_f32_16x16x32_f16(a2, b2, acc[2][2], 0, 0, 0);
    acc[3][2] = __builtin_amdgcn_mfma_f32_16x16x32_f16(a3, b2, acc[3][2], 0, 0, 0);
    acc[0][3] = __builtin_amdgcn_mfma_f32_16x16x32_f16(a0, b3, acc[0][3], 0, 0, 0);
    acc[1][3] = __builtin_amdgcn_mfma_f32_16x16x32_f16(a1, b3, acc[1][3], 0, 0, 0);
    acc[2][3] = __builtin_amdgcn_mfma_f32_16x16x32_f16(a2, b3, acc[2][3], 0, 0, 0);
    acc[3][3] = __builtin_amdgcn_mfma_f32_16x16x32_f16(a3, b3, acc[3][3], 0, 0, 0);
    b0 = c0; b1 = c1; b2 = c2; b3 = c3;
    c0 = d0; c1 = d1; c2 = d2; c3 = d3;
  }
  const int r4 = (lane >> 4) << 2;
#pragma unroll
  for (int rg = 0; rg < 4; rg++) {
#pragma unroll
    for (int j = 0; j < 4; j++) {
#pragma unroll
      for (int r = 0; r < 4; r++) {
        int row = e0 + rowb + rg*16 + r4 + r;
        int col = wc + j*16 + fr;
        Vn[(size_t)row*256 + col] = f2h(acc[rg][j][r]);
      }
    }
  }
}

// ---- Gtt[slab][col][32] = coupling x Wv (fp16, tiled). col = kabs*16+d ----
__global__ void gbuild_k(const float* __restrict__ TD,
    const float* __restrict__ Wv1, const float* __restrict__ Wv2,
    const float* __restrict__ Wv3, const int* __restrict__ sl_origc,
    unsigned short* __restrict__ Gt, int Kdim, int npairs,
    int s1b, int s1e, int s2e, int s3e)
{
  int k = blockIdx.x*256 + threadIdx.x;
  if (k >= Kdim) return;
  int col = blockIdx.y;
  int pair = k >> 4, m = k & 15;
  int d = col & 15, kabs = col >> 4;
  float acc = 0.f;
  if (kabs > 0 && pair < npairs) {
    const float* Wv; int ss, se, kloc;
    if (kabs < 4)      { Wv = Wv1; ss = s1b; se = s1e; kloc = kabs - 1; }
    else if (kabs < 9) { Wv = Wv2; ss = s1e; se = s2e; kloc = kabs - 4; }
    else               { Wv = Wv3; ss = s2e; se = s3e; kloc = kabs - 9; }
    for (int slot = ss; slot < se; slot++)
      acc += TD[((pair*30) + (slot - 4))*8 + kloc] * Wv[(sl_origc[slot] + m)*16 + d];
    acc *= rsqrtf((float)(16*(se - ss)));
  }
  Gt[((size_t)((k >> 5)*256 + col))*32 + (k & 31)] = f2h(acc);
}

// ---- weight convert + transpose: Wt[n][k] = fp16(W[k][n]) ----
struct WDesc { const float* src; unsigned short* dst; int K; int lgN; };
struct WPack { WDesc d[8]; };
__global__ void wcvt_k(WPack p){
  WDesc d = p.d[blockIdx.y];
  int total = d.K << d.lgN;
  int gid = blockIdx.x*256 + threadIdx.x;
  if (gid >= total) return;
  int k = gid >> d.lgN, n = gid & ((1 << d.lgN) - 1);
  d.dst[(size_t)n*d.K + k] = f2h(d.src[gid]);
}

// ---- hc[k] = sum_j W_h[k][j] * W_out[j] ----
__global__ void whc_k(const float* __restrict__ Wh, const float* __restrict__ Wout,
                      float* __restrict__ hc)
{
  int k = threadIdx.x;
  float s = 0.f;
#pragma unroll 16
  for (int j = 0; j < 128; j++) s += Wh[k*128 + j] * Wout[j];
  hc[k] = s;
}

// ---- out[e] = env[e] * dot(x16[e,:256], hc) / (16*sqrt(128)) ----
__global__ void final256_k(const unsigned short* __restrict__ X,
    const float* __restrict__ hc, const float* __restrict__ env,
    float* __restrict__ out)
{
  const int e = blockIdx.x*256 + threadIdx.x;
  float acc = 0.f;
#pragma unroll 16
  for (int k = 0; k < 256; k++) acc += h2f(X[((size_t)e<<8)+k])*hc[k];
  out[e] = env[e]*acc*0.0055242717280199023f;
}

// Generic fp32 tiled GEMM (small two-body layers).
template<int FLAGS>
__global__ __launch_bounds__(256) void gemm_k(
    const float* __restrict__ A1, const float* __restrict__ A2,
    int K1, int K, const float* __restrict__ W, int N,
    float* Cout,
    const float* __restrict__ env, const float* __restrict__ alphap,
    const float* Xres)
{
  __shared__ float As[16][68];
  __shared__ float Ws[16][68];
  const int tid = threadIdx.x;
  const int bm = blockIdx.x * 64;
  const int bn = blockIdx.y * 64;
  const int tx = tid & 15, ty = tid >> 4;
  const int K2 = K - K1;
  float acc[4][4] = {};
  for (int k0 = 0; k0 < K; k0 += 16) {
#pragma unroll
    for (int i = 0; i < 4; i++) {
      int idx = tid + i*256;
      int m = idx >> 4, kk = idx & 15;
      int k = k0 + kk;
      float v = 0.f;
      if (k < K) {
        int row = bm + m;
        v = (k < K1) ? A1[(size_t)row*K1 + k] : A2[(size_t)row*K2 + (k-K1)];
      }
      As[kk][m] = v;
    }
#pragma unroll
    for (int i = 0; i < 4; i++) {
      int idx = tid + i*256;
      int n = idx & 63, kk = idx >> 6;
      int k = k0 + kk, col = bn + n;
      Ws[kk][n] = (k < K && col < N) ? W[(size_t)k*N + col] : 0.f;
    }
    __syncthreads();
#pragma unroll
    for (int kk = 0; kk < 16; kk++) {
      float a[4], b[4];
#pragma unroll
      for (int i=0;i<4;i++) a[i] = As[kk][ty*4+i];
#pragma unroll
      for (int j=0;j<4;j++) b[j] = Ws[kk][tx*4+j];
#pragma unroll
      for (int i=0;i<4;i++)
#pragma unroll
        for (int j=0;j<4;j++)
          acc[i][j] += a[i]*b[j];
    }
    __syncthreads();
  }
  const float rscale = 1.f/sqrtf((float)K);
  float a2 = 0.f, inv1a2 = 1.f;
  if (FLAGS & F_RESID) { float al = alphap[0]; a2 = al*al; inv1a2 = 1.f/(1.f+a2); }
#pragma unroll
  for (int i=0;i<4;i++) {
    int row = bm + ty*4 + i;
    float ev = (FLAGS & F_ENV) ? env[row] : 1.f;
#pragma unroll
    for (int j=0;j<4;j++) {
      int col = bn + tx*4 + j;
      if (col >= N) continue;
      float v = acc[i][j]*rscale;
      if (FLAGS & F_SILU) v = v/(1.f+__expf(-v));
      if (FLAGS & F_ENV)  v *= ev;
      if (FLAGS & F_RESID) v = (Xres[(size_t)row*N+col] + a2*v)*inv1a2;
      Cout[(size_t)row*N+col] = v;
    }
  }
}

// dense to 16 outputs, K=256, scale 1/16; A fp16 (layer-2 w2)
__global__ __launch_bounds__(256) void dense16_k(const unsigned short* __restrict__ A,
    const float* __restrict__ W, float* __restrict__ C)
{
  __shared__ float As[16*256];
  const int r0 = blockIdx.x << 4;
  const int tid = threadIdx.x;
  for (int i = tid; i < 16*256; i += 256)
    As[i] = h2f(A[((size_t)r0<<8) + i]);
  __syncthreads();
  const int r = tid >> 4, n = tid & 15;
  float acc = 0.f;
#pragma unroll 8
  for (int k = 0; k < 256; k++)
    acc += As[(r<<8)+k] * W[(k<<4)+n];
  C[((size_t)(r0+r)<<4)+n] = acc * 0.0625f;
}

// fused w0 + w1 + V-init
__global__ __launch_bounds__(256) void dense16v_k(const unsigned short* __restrict__ A,
    const float* __restrict__ W0, const float* __restrict__ W1,
    const float* __restrict__ Y, unsigned short* __restrict__ V,
    float* __restrict__ wb)
{
  __shared__ float As[16*256];
  __shared__ float w0s[256];
  const int r0 = blockIdx.x << 4;
  const int tid = threadIdx.x;
  for (int i = tid; i < 16*256; i += 256)
    As[i] = h2f(A[((size_t)r0<<8) + i]);
  __syncthreads();
  const int r = tid >> 4, n = tid & 15;
  float a0 = 0.f, a1 = 0.f;
#pragma unroll 8
  for (int k = 0; k < 256; k++) {
    float xv = As[(r<<8)+k];
    a0 += xv * W0[(k<<4)+n];
    a1 += xv * W1[(k<<4)+n];
  }
  w0s[tid] = a0 * 0.0625f;
  wb[((size_t)(r0+r)<<4)+n] = a1 * 0.0625f;
  __syncthreads();
  for (int i = tid; i < 4096; i += 256) {
    int e = i >> 8, idx = i & 255;
    V[(((size_t)(r0+e))<<8) + idx] = f2h(w0s[(e<<4)+(idx&15)] * Y[((r0+e)<<4)+(idx>>4)]);
  }
}

__global__ void edge_init_k(const float* __restrict__ vectors, const int* __restrict__ senders,
    const int* __restrict__ receivers, const int* __restrict__ species,
    const float* __restrict__ emb, float* __restrict__ envb, float* __restrict__ Yb,
    float* __restrict__ x72)
{
  const int e = blockIdx.x*256 + threadIdx.x;
  float vx = vectors[e*3+0], vy = vectors[e*3+1], vz = vectors[e*3+2];
  float d = sqrtf(vx*vx+vy*vy+vz*vz);
  float dd = (d==0.f) ? 1.f : d;
  float invd = 1.f/dd;
  float x = vx*invd, y = vy*invd, z = vz*invd;
  float d2=d*d, d3=d2*d, d6=d3*d3, d7=d6*d, d8=d7*d;
  float envv = (d<1.f) ? (1.f - 28.f*d6 + 48.f*d7 - 21.f*d8) : 0.f;
  envb[e] = envv;
  float mask = (d==0.f)?0.f:1.f;
  const float SQ2 = 1.41421356237309515f;
  const float PIf = 3.14159265358979323846f;
  float* xr = x72 + (size_t)e*72;
#pragma unroll
  for (int n=1;n<=8;n++)
    xr[n-1] = SQ2 * sinf((float)n*PIf*dd)*invd*envv*mask;
  int sp_s = species[senders[e]], sp_r = species[receivers[e]];
  const float* es_ = emb + (size_t)sp_s*32;
  const float* er_ = emb + (size_t)sp_r*32;
#pragma unroll 8
  for (int k=0;k<32;k++){ xr[8+k] = es_[k]*mask; xr[40+k] = er_[k]*mask; }
  float x2=x*x, y2=y*y, z2=z*z;
  const float s3=1.7320508075688772f, s15=3.872983346207417f, s5=2.23606797749979f;
  const float s358=2.0916500663351889f, s105=10.246950765959598f;
  const float s218=1.6201851746019651f, s7=2.6457513110645907f;
  float* Yr = Yb + ((size_t)e<<4);
  Yr[0]=1.f;           Yr[1]=s3*y;          Yr[2]=s3*z;           Yr[3]=s3*x;
  Yr[4]=s15*x*y;       Yr[5]=s15*y*z;       Yr[6]=0.5f*s5*(3.f*z2-1.f);
  Yr[7]=s15*x*z;       Yr[8]=0.5f*s15*(x2-y2);
  Yr[9]=s358*y*(3.f*x2-y2);  Yr[10]=s105*x*y*z;  Yr[11]=s218*y*(5.f*z2-1.f);
  Yr[12]=0.5f*s7*(5.f*z2-3.f)*z;  Yr[13]=s218*x*(5.f*z2-1.f);
  Yr[14]=0.5f*s105*(x2-y2)*z;     Yr[15]=s358*x*(x2-y2);
}

// ---- sort-based node accumulation (replaces atomic scatter, R14) ----
__global__ void hist_k(const int* __restrict__ senders, int* cnt){
  int e = blockIdx.x*256 + threadIdx.x;
  atomicAdd(&cnt[senders[e]], 1);
}

__global__ void scan_k(const int* __restrict__ cnt, int* __restrict__ starts,
                       int* __restrict__ cursor){
  __shared__ int s[NNODES];
  const int tid = threadIdx.x;
  for (int i = tid; i < NNODES; i += 256) s[i] = cnt[i];
  __syncthreads();
  if (tid == 0) {
    int run = 0;
    for (int i = 0; i < NNODES; i++) { int c = s[i]; s[i] = run; run += c; }
  }
  __syncthreads();
  for (int i = tid; i < NNODES; i += 256) { starts[i] = s[i]; cursor[i] = s[i]; }
  if (tid == 0) starts[NNODES] = E_EDGES;
}

__global__ void perm_k(const int* __restrict__ senders, int* cursor,
                       int* __restrict__ perm){
  int e = blockIdx.x*256 + threadIdx.x;
  int pos = atomicAdd(&cursor[senders[e]], 1);
  perm[pos] = e;
}

// node[n][a*16+m] = sum_{e: senders[e]==n} w[e][m]*Y[e][a]; block per node.
__global__ __launch_bounds__(256) void nodesum_k(const float* __restrict__ w,
    const float* __restrict__ Y, const int* __restrict__ perm,
    const int* __restrict__ starts, float* __restrict__ node)
{
  __shared__ float buf[8*32];
  const int n = blockIdx.x;
  const int tid = threadIdx.x;
  const int s0 = starts[n], s1 = starts[n+1];
  const int a = tid >> 4, m = tid & 15;
  float acc = 0.f;
  for (int i = s0; i < s1; i += 8) {
    int nb = s1 - i; if (nb > 8) nb = 8;
    int slot = tid >> 5, comp = tid & 31;
    if (slot < nb) {
      int e = perm[i + slot];
      buf[slot*32 + comp] = (comp < 16) ? w[(e<<4)+comp] : Y[(e<<4)+comp-16];
    }
    __syncthreads();
    for (int q = 0; q < nb; q++)
      acc += buf[q*32 + m] * buf[q*32 + 16 + a];
    __syncthreads();
  }
  node[((size_t)n<<8) + tid] = acc;
}

// l3=0 TP standalone (layer 2); B = Vn fp16
__global__ void tp2_k(const float* __restrict__ node, const unsigned short* __restrict__ Vn,
    const int* __restrict__ senders, const float* __restrict__ varepsp,
    const int* __restrict__ pmeta, const int* __restrict__ entIJ,
    const float* __restrict__ entVal, unsigned short* __restrict__ tp0)
{
  const int gid = blockIdx.x*256 + threadIdx.x;
  const int e = gid >> 6, c = gid & 63;
  const int p = c >> 4, m = c & 15;
  float ve = varepsp[0];
  float eps = rsqrtf(1.f + ve*ve);
  int s = senders[e];
  const float* Am = &node[((size_t)s<<8)];
  const unsigned short* Bm = &Vn[((size_t)e<<8)];
  int es = pmeta[p*4+1], ec = pmeta[p*4+2];
  float acc = 0.f;
  for (int t=0;t<ec;t++){
    int ij = entIJ[es+t];
    acc += entVal[es+t] * Am[((ij&255)<<4) + m] * h2f(Bm[(((ij>>8)&255)<<4) + m]);
  }
  tp0[((size_t)e<<6) + pmeta[p*4+0] + m] = f2h(acc * eps);
}

// ============================ host launcher ============================

static void launch_gemm(int flags, const float* A1, const float* A2, int K1, int K,
    const float* W, int N, float* C, const float* env, const float* alphap,
    const float* Xres, hipStream_t stream)
{
  dim3 grid(E_EDGES/64, (N+63)/64);
  switch(flags){
    case F_SILU:        gemm_k<F_SILU>       <<<grid,256,0,stream>>>(A1,A2,K1,K,W,N,C,env,alphap,Xres); break;
    case F_ENV:         gemm_k<F_ENV>        <<<grid,256,0,stream>>>(A1,A2,K1,K,W,N,C,env,alphap,Xres); break;
    default: break;
  }
}

static void launch_mgemm(int flags, int a16, const void* A1, const void* A2, int K1, int K,
    const unsigned short* Wt, int N, unsigned short* C, const float* env,
    const float* alphap, const unsigned short* Xres, hipStream_t stream)
{
  dim3 grid(E_EDGES/128, N/128);
  if (a16) {
    switch(flags){
      case F_SILU:        mgemm_k<F_SILU,1>       <<<grid,256,0,stream>>>(A1,A2,K1,K,Wt,N,C,env,alphap,Xres); break;
      case F_ENV:         mgemm_k<F_ENV,1>        <<<grid,256,0,stream>>>(A1,A2,K1,K,Wt,N,C,env,alphap,Xres); break;
      default: break;
    }
  } else {
    switch(flags){
      case F_SILU:        mgemm_k<F_SILU,0>       <<<grid,256,0,stream>>>(A1,A2,K1,K,Wt,N,C,env,alphap,Xres); break;
      case F_ENV:         mgemm_k<F_ENV,0>        <<<grid,256,0,stream>>>(A1,A2,K1,K,Wt,N,C,env,alphap,Xres); break;
      default: break;
    }
  }
}

extern "C" void kernel_launch(void* const* d_in, const int* in_sizes, int n_in,
                              void* d_out, int out_size, void* d_ws, size_t ws_size,
                              hipStream_t stream)
{
  const float* vectors = (const float*)d_in[0];
  const float* vareps  = (const float*)d_in[1];
  const float* alpha   = (const float*)d_in[2];
  const float* emb     = (const float*)d_in[3];
  const float* W_tb1   = (const float*)d_in[4];
  const float* W_tb2   = (const float*)d_in[5];
  const float* W_tb3   = (const float*)d_in[6];
  const float* W_tb4   = (const float*)d_in[7];
  const float* W_w0    = (const float*)d_in[8];
  const float* W_w1    = (const float*)d_in[9];
  const float* W_l11   = (const float*)d_in[10];
  const float* W_l12   = (const float*)d_in[11];
  const float* W_l13   = (const float*)d_in[12];
  const float* W_v1    = (const float*)d_in[13];
  const float* W_v2    = (const float*)d_in[14];
  const float* W_v3    = (const float*)d_in[15];
  const float* W_w2    = (const float*)d_in[16];
  const float* W_l21   = (const float*)d_in[17];
  const float* W_l22   = (const float*)d_in[18];
  const float* W_l23   = (const float*)d_in[19];
  const float* W_h     = (const float*)d_in[20];
  const float* W_out   = (const float*)d_in[21];
  const int* senders   = (const int*)d_in[22];
  const int* receivers = (const int*)d_in[23];
  const int* species   = (const int*)d_in[24];

  static cgt::Tables tb;
  cgt::build(tb);
  const int Kdim = tb.npairs * 16;

  char* ws = (char*)d_ws;
  size_t off = 0;
  auto alloc = [&](size_t bytes)->void*{
    void* p = ws + off; off += (bytes + 255) & ~(size_t)255; return p;
  };
  float* t_val = (float*)alloc(sizeof(tb.val));
  int*   t_ij  = (int*)  alloc(sizeof(tb.ij));
  int*   t_pm  = (int*)  alloc(sizeof(tb.pmeta));
  float* t_td  = (float*)alloc(sizeof(tb.TD));
  int*   t_pr  = (int*)  alloc(sizeof(tb.pairs));
  int*   t_oc  = (int*)  alloc(sizeof(tb.sl_origc));
  float* envb  = (float*)alloc((size_t)E_EDGES*4);
  float* Yb    = (float*)alloc((size_t)E_EDGES*16*4);
  float* xb    = (float*)alloc((size_t)E_EDGES*256*4);
  float* Vb    = (float*)alloc((size_t)E_EDGES*256*4);
  float* bufA  = (float*)alloc((size_t)E_EDGES*256*4);
  float* bufB  = (float*)alloc((size_t)E_EDGES*256*4);
  float* wb    = (float*)alloc((size_t)E_EDGES*16*4);
  float* tp0b  = (float*)alloc((size_t)E_EDGES*64*4);
  float* nodeb = (float*)alloc((size_t)NNODES*256*4);
  float* hcb   = (float*)alloc(256*4);
  int* cntb    = (int*)alloc(NNODES*4);
  int* startsb = (int*)alloc((NNODES+1)*4);
  int* cursorb = (int*)alloc(NNODES*4);
  int* permb   = (int*)alloc(E_EDGES*4);
  unsigned short* Gt = (unsigned short*)alloc((size_t)256*Kdim*2);
  unsigned short* Wt_tb3 = (unsigned short*)alloc(64*128*2);
  unsigned short* Wt_tb4 = (unsigned short*)alloc(128*256*2);
  unsigned short* Wt_l11 = (unsigned short*)alloc(320*256*2);
  unsigned short* Wt_l12 = (unsigned short*)alloc(256*256*2);
  unsigned short* Wt_l13 = (unsigned short*)alloc(256*256*2);
  unsigned short* Wt_l21 = (unsigned short*)alloc(320*256*2);
  unsigned short* Wt_l22 = (unsigned short*)alloc(256*256*2);
  unsigned short* Wt_l23 = (unsigned short*)alloc(256*256*2);
  if (off > ws_size) {
    fprintf(stderr, "[allegro] workspace too small: need %zu, have %zu\n", off, ws_size);
    return;
  }
  unsigned short* xb16 = (unsigned short*)xb;
  unsigned short* bB16 = (unsigned short*)bufB;
  unsigned short* tp016 = (unsigned short*)tp0b;
  unsigned short* V16 = (unsigned short*)Vb;

  hipMemcpyAsync(t_val, tb.val,     sizeof(tb.val),     hipMemcpyHostToDevice, stream);
  hipMemcpyAsync(t_ij,  tb.ij,      sizeof(tb.ij),      hipMemcpyHostToDevice, stream);
  hipMemcpyAsync(t_pm,  tb.pmeta,   sizeof(tb.pmeta),   hipMemcpyHostToDevice, stream);
  hipMemcpyAsync(t_td,  tb.TD,      sizeof(tb.TD),      hipMemcpyHostToDevice, stream);
  hipMemcpyAsync(t_pr,  tb.pairs,   sizeof(tb.pairs),   hipMemcpyHostToDevice, stream);
  hipMemcpyAsync(t_oc,  tb.sl_origc,sizeof(tb.sl_origc),hipMemcpyHostToDevice, stream);

  const int s1b = tb.l3np[0];
  const int s1e = s1b + tb.l3np[1];
  const int s2e = s1e + tb.l3np[2];
  const int s3e = s2e + tb.l3np[3];

  {
    dim3 g((Kdim + 255)/256, 256);
    gbuild_k<<<g, 256, 0, stream>>>(t_td, W_v1, W_v2, W_v3, t_oc, Gt, Kdim,
                                    tb.npairs, s1b, s1e, s2e, s3e);
  }
  {
    WPack p;
    p.d[0] = { W_tb3, Wt_tb3,  64, 7 };
    p.d[1] = { W_tb4, Wt_tb4, 128, 8 };
    p.d[2] = { W_l11, Wt_l11, 320, 8 };
    p.d[3] = { W_l12, Wt_l12, 256, 8 };
    p.d[4] = { W_l13, Wt_l13, 256, 8 };
    p.d[5] = { W_l21, Wt_l21, 320, 8 };
    p.d[6] = { W_l22, Wt_l22, 256, 8 };
    p.d[7] = { W_l23, Wt_l23, 256, 8 };
    dim3 g(320, 8);
    wcvt_k<<<g, 256, 0, stream>>>(p);
  }
  whc_k<<<1, 256, 0, stream>>>(W_h, W_out, hcb);

  // edge->node sort (once; senders fixed for both layers)
  hipMemsetAsync(cntb, 0, NNODES*4, stream);
  hist_k<<<E_EDGES/256, 256, 0, stream>>>(senders, cntb);
  scan_k<<<1, 256, 0, stream>>>(cntb, startsb, cursorb);
  perm_k<<<E_EDGES/256, 256, 0, stream>>>(senders, cursorb, permb);

  // 1. edge features + Y + env  (x72 -> bufA fp32)
  edge_init_k<<<E_EDGES/256, 256, 0, stream>>>(vectors, senders, receivers, species,
                                               emb, envb, Yb, bufA);
  // 2. two-body MLP
  launch_gemm (F_SILU, bufA, nullptr, 72, 72,  W_tb1, 32,  bufB, envb, alpha, nullptr, stream);
  launch_gemm (F_SILU, bufB, nullptr, 32, 32,  W_tb2, 64,  bufA, envb, alpha, nullptr, stream);
  launch_mgemm(F_SILU, 0, bufA, nullptr, 64, 64,  Wt_tb3, 128, bB16, envb, alpha, nullptr, stream);
  launch_mgemm(F_ENV,  1, bB16, nullptr, 128,128, Wt_tb4, 256, xb16, envb, alpha, nullptr, stream);
  // 3. fused w0+w1+V
  dense16v_k<<<E_EDGES/16, 256, 0, stream>>>(xb16, W_w0, W_w1, Yb, V16, wb);

  // ---- layer 1 ----
  nodesum_k<<<NNODES, 256, 0, stream>>>(wb, Yb, permb, startsb, nodeb);
  // vn_k: fused tp0 (l3=0) + Vn GEMM (in-place V -> Vn)
  vn_k<<<E_EDGES/VN_E, 512, 0, stream>>>(nodeb, V16, senders, vareps, t_pr, Gt,
                                         V16, Kdim, t_pm, t_ij, t_val, tp016);
  launch_mgemm(F_SILU, 1, xb16, tp016, 256, 320, Wt_l11, 256, bB16, envb, alpha, nullptr, stream);
  mlp2_k<<<E_EDGES/64, 256, 0, stream>>>(bB16, Wt_l12, Wt_l13, xb16, xb16, envb, alpha);

  // ---- layer 2 (lmax_out = 0) ----
  dense16_k<<<E_EDGES/16, 256, 0, stream>>>(xb16, W_w2, wb);
  nodesum_k<<<NNODES, 256, 0, stream>>>(wb, Yb, permb, startsb, nodeb);
  tp2_k<<<E_EDGES*64/256, 256, 0, stream>>>(nodeb, V16, senders, vareps, t_pm, t_ij,
                                            t_val, tp016);
  launch_mgemm(F_SILU, 1, xb16, tp016, 256, 320, Wt_l21, 256, bB16, envb, alpha, nullptr, stream);
  mlp2_k<<<E_EDGES/64, 256, 0, stream>>>(bB16, Wt_l22, Wt_l23, xb16, xb16, envb, alpha);

  // ---- head (W_h @ W_out precombined) ----
  final256_k<<<E_EDGES/256, 256, 0, stream>>>(xb16, hcb, envb, (float*)d_out);
}

// Round 15
// 436.641 us; speedup vs baseline: 1.3407x; 1.0643x over previous
//
#include <hip/hip_runtime.h>
#include <cmath>
#include <complex>
#include <cstdio>
#include <cstring>
#include <algorithm>

#define E_EDGES 32768
#define NNODES  2048
#define VN_E    128

// ============================ host-side CG tables ============================
namespace cgt {

static double fct(int n){
  static const double f[13] = {1.,1.,2.,6.,24.,120.,720.,5040.,40320.,362880.,
                               3628800.,39916800.,479001600.};
  return f[n];
}

static double cg(int j1,int m1,int j2,int m2,int j3,int m3){
  if (m1+m2 != m3) return 0.0;
  double pre = std::sqrt((2*j3+1)*fct(j1+j2-j3)*fct(j1-j2+j3)*fct(-j1+j2+j3)/fct(j1+j2+j3+1));
  pre *= std::sqrt(fct(j3+m3)*fct(j3-m3)*fct(j1-m1)*fct(j1+m1)*fct(j2-m2)*fct(j2+m2));
  int kmin = 0;
  if (j2-j3-m1 > kmin) kmin = j2-j3-m1;
  if (j1-j3+m2 > kmin) kmin = j1-j3+m2;
  int kmax = j1+j2-j3;
  if (j1-m1 < kmax) kmax = j1-m1;
  if (j2+m2 < kmax) kmax = j2+m2;
  double s = 0.0;
  for (int k=kmin;k<=kmax;k++){
    double d = fct(k)*fct(j1+j2-j3-k)*fct(j1-m1-k)*fct(j2+m2-k)*fct(j3-j2+m1+k)*fct(j3-j1-m2+k);
    s += ((k&1)? -1.0:1.0)/d;
  }
  return pre*s;
}

typedef std::complex<double> cd;

static void umat(int l, cd U[7][7]){
  for (int a=0;a<7;a++) for (int b=0;b<7;b++) U[a][b]=cd(0,0);
  U[l][l] = cd(1,0);
  double s2 = 1.0/std::sqrt(2.0);
  for (int m=1;m<=l;m++){
    double sg = (m&1)? -1.0 : 1.0;
    U[l+m][l-m] = cd(s2,0);
    U[l+m][l+m] = cd(sg*s2,0);
    U[l-m][l-m] = cd(0, s2);
    U[l-m][l+m] = cd(0, -sg*s2);
  }
}

static bool realCoupling(int l1,int l2,int l3, double T[7][7][7]){
  cd U1[7][7],U2[7][7],U3[7][7];
  umat(l1,U1); umat(l2,U2); umat(l3,U3);
  int n1=2*l1+1, n2=2*l2+1, n3=2*l3+1;
  double Cg[7][7][7];
  for (int m=0;m<n1;m++) for(int n=0;n<n2;n++) for(int k=0;k<n3;k++)
    Cg[m][n][k] = cg(l1,m-l1,l2,n-l2,l3,k-l3);
  double Tr[7][7][7], Ti[7][7][7];
  double nr=0, ni=0;
  for (int a=0;a<n1;a++) for(int b=0;b<n2;b++) for(int c=0;c<n3;c++){
    cd s(0,0);
    for (int m=0;m<n1;m++){
      if (U1[a][m]==cd(0,0)) continue;
      for (int n=0;n<n2;n++){
        if (U2[b][n]==cd(0,0)) continue;
        for (int k=0;k<n3;k++){
          double cgv = Cg[m][n][k];
          if (cgv==0.0) continue;
          s += U1[a][m]*U2[b][n]*std::conj(U3[c][k])*cgv;
        }
      }
    }
    Tr[a][b][c]=s.real(); Ti[a][b][c]=s.imag();
    nr += s.real()*s.real(); ni += s.imag()*s.imag();
  }
  bool useR = (nr >= ni);
  double nn = std::sqrt(useR? nr : ni);
  if (nn < 1e-8) return false;
  for (int a=0;a<n1;a++)for(int b=0;b<n2;b++)for(int c=0;c<n3;c++)
    T[a][b][c] = (useR? Tr[a][b][c] : Ti[a][b][c])/nn;
  return true;
}

struct Tables {
  float val[4096];
  int   ij[4096];
  int   pmeta[40*4];
  int   ccnt[40*8];
  int   l3base[4];
  int   l3np[4];
  int   npaths;
  int   nent;
  int   tptot;
  int   pairs[256];
  float TD[256*30*8];
  int   sl_origc[40];
  int   npairs;
};

struct PathTmp {
  int l1,l2,l3, tpoff, kd;
  int ec;
  double T[7][7][7];
};

static void build(Tables& tb){
  static PathTmp paths[40];
  int np = 0, tpoff = 0;
  int l3start[5];
  for (int l3=0;l3<=3;l3++){
    tb.l3base[l3] = tpoff;
    l3start[l3] = np;
    int kd = 2*l3+1;
    for (int l1=0;l1<=3;l1++) for (int l2=0;l2<=3;l2++){
      int lo = (l1>l2)? l1-l2 : l2-l1;
      int hi = std::min(l1+l2,3);
      if (l3 < lo || l3 > hi) continue;
      PathTmp& pt = paths[np];
      if (!realCoupling(l1,l2,l3,pt.T)) continue;
      pt.l1=l1; pt.l2=l2; pt.l3=l3; pt.kd=kd; pt.tpoff=tpoff;
      double scale = std::sqrt((double)kd);
      int cnt = 0;
      for (int a=0;a<2*l1+1;a++)for(int b=0;b<2*l2+1;b++)for(int c=0;c<kd;c++)
        if (std::fabs(pt.T[a][b][c]*scale) > 1e-7) cnt++;
      pt.ec = cnt;
      tpoff += 16*kd;
      np++;
    }
  }
  l3start[4] = np;
  for (int l3=0;l3<=3;l3++) tb.l3np[l3] = l3start[l3+1]-l3start[l3];
  static int order[40];
  for (int i=0;i<np;i++) order[i]=i;
  for (int l3=0;l3<=3;l3++)
    std::sort(order+l3start[l3], order+l3start[l3+1],
              [&](int a,int b){ return paths[a].ec > paths[b].ec; });
  std::memset(tb.TD, 0, sizeof(tb.TD));
  std::memset(tb.pairs, 0, sizeof(tb.pairs));
  static int pmap[16][16];
  for (int i=0;i<16;i++) for (int j=0;j<16;j++) pmap[i][j] = -1;
  int npr = 0;
  int ep = 0;
  for (int slot=0; slot<np; slot++){
    const PathTmp& pt = paths[order[slot]];
    double scale = std::sqrt((double)pt.kd);
    int s1 = pt.l1*pt.l1, s2 = pt.l2*pt.l2;
    tb.pmeta[slot*4+0] = pt.tpoff;
    tb.pmeta[slot*4+1] = ep;
    tb.sl_origc[slot] = ((pt.tpoff - tb.l3base[pt.l3]) / (16*pt.kd)) * 16;
    int tot = 0;
    for (int c=0;c<pt.kd;c++){
      int cnt = 0;
      for (int a=0;a<2*pt.l1+1;a++)for(int b=0;b<2*pt.l2+1;b++){
        double v = pt.T[a][b][c]*scale;
        if (std::fabs(v) > 1e-7){
          tb.val[ep] = (float)v;
          tb.ij[ep]  = (s1+a) | ((s2+b)<<8);
          ep++; cnt++;
          if (pt.l3 >= 1){
            int aa = s1+a, bb = s2+b;
            int pi = pmap[aa][bb];
            if (pi < 0){ pi = npr; pmap[aa][bb] = pi;
                         tb.pairs[npr] = aa | (bb<<8); npr++; }
            tb.TD[(pi*30 + (slot-4))*8 + c] = (float)v;
          }
        }
      }
      tb.ccnt[slot*8+c] = cnt;
      tot += cnt;
    }
    for (int c=pt.kd;c<8;c++) tb.ccnt[slot*8+c]=0;
    tb.pmeta[slot*4+2] = tot;
    tb.pmeta[slot*4+3] = pt.kd;
  }
  if (npr & 1){ tb.pairs[npr] = 0; npr++; }
  tb.npairs = npr;
  tb.npaths = np; tb.nent = ep; tb.tptot = tpoff;
}

} // namespace cgt

// ============================ device kernels ============================
// LAYOUT: node/V/Vn rows are [a][m]. MFMA-path activations fp16 in HBM.

enum GFlags { F_NONE=0, F_SILU=1, F_ENV=2, F_RESID=4 };

typedef _Float16 half8 __attribute__((ext_vector_type(8)));
typedef __attribute__((ext_vector_type(4))) float f32x4;

__device__ inline unsigned short f2h(float f){
  union { _Float16 h; unsigned short u; } x;
  x.h = (_Float16)f;
  return x.u;
}
__device__ inline float h2f(unsigned short u){
  union { _Float16 h; unsigned short u; } x; x.u = u;
  return (float)x.h;
}

__device__ inline int swz(int row, int kh){
  int b = row*64 + kh*2;
  return b ^ (((row >> 1) & 3) << 4);
}

// ---- fp16 MFMA GEMM: C16[M,N] = post( A[M,K] @ W[K,N] / sqrt(K) ) ----
template<int FLAGS, int A16>
__global__ __launch_bounds__(256) void mgemm_k(
    const void* __restrict__ A1v, const void* __restrict__ A2v,
    int K1, int K, const unsigned short* __restrict__ Wt, int N,
    unsigned short* Cout, const float* __restrict__ env,
    const float* __restrict__ alphap, const unsigned short* Xres)
{
  __shared__ unsigned short AsB[128*32];
  __shared__ unsigned short BsB[128*32];
  const int tid  = threadIdx.x;
  const int wave = tid >> 6, lane = tid & 63;
  const int bm = blockIdx.x*128, bn = blockIdx.y*128;
  const int wr = (wave >> 1)*64, wc = (wave & 1)*64;
  const int K2 = K - K1;
  f32x4 acc[4][4] = {};

  const int sr  = tid >> 3;
  const int skq = (tid & 7) * 4;
  const int sr2 = tid >> 1;
  const int skh = (tid & 1) * 16;
  const int bn_ = tid >> 1;
  const int bkh = (tid & 1) * 16;

  for (int k0 = 0; k0 < K; k0 += 32) {
    if (A16) {
      int kk = k0 + skh;
      const unsigned short* ap = (kk < K1)
        ? (const unsigned short*)A1v + (size_t)(bm + sr2)*K1 + kk
        : (const unsigned short*)A2v + (size_t)(bm + sr2)*K2 + (kk - K1);
      uint4 u0 = *(const uint4*)ap;
      uint4 u1 = *(const uint4*)(ap + 8);
      *(uint4*)((char*)AsB + swz(sr2, skh))     = u0;
      *(uint4*)((char*)AsB + swz(sr2, skh + 8)) = u1;
    } else {
#pragma unroll
      for (int q = 0; q < 4; q++) {
        int row = q*32 + sr;
        int grow = bm + row;
        int kk = k0 + skq;
        float4 f4 = (kk < K1)
          ? *(const float4*)((const float*)A1v + (size_t)grow*K1 + kk)
          : *(const float4*)((const float*)A2v + (size_t)grow*K2 + (kk - K1));
        ushort4 u;
        u.x = f2h(f4.x); u.y = f2h(f4.y); u.z = f2h(f4.z); u.w = f2h(f4.w);
        *(ushort4*)((char*)AsB + swz(row, skq)) = u;
      }
    }
    {
      const unsigned short* s = Wt + (size_t)(bn + bn_)*K + k0 + bkh;
#pragma unroll
      for (int q = 0; q < 4; q++) {
        ushort4 u = *(const ushort4*)(s + q*4);
        *(ushort4*)((char*)BsB + swz(bn_, bkh + q*4)) = u;
      }
    }
    __syncthreads();
    const int fr = lane & 15, fk = (lane >> 4) * 8;
    half8 af[4], bf[4];
#pragma unroll
    for (int i = 0; i < 4; i++)
      af[i] = *(half8*)((char*)AsB + swz(wr + i*16 + fr, fk));
#pragma unroll
    for (int j = 0; j < 4; j++)
      bf[j] = *(half8*)((char*)BsB + swz(wc + j*16 + fr, fk));
#pragma unroll
    for (int i = 0; i < 4; i++)
#pragma unroll
      for (int j = 0; j < 4; j++)
        acc[i][j] = __builtin_amdgcn_mfma_f32_16x16x32_f16(af[i], bf[j], acc[i][j], 0, 0, 0);
    __syncthreads();
  }

  const float rscale = 1.f/sqrtf((float)K);
  float a2 = 0.f, inv1a2 = 1.f;
  if (FLAGS & F_RESID) { float al = alphap[0]; a2 = al*al; inv1a2 = 1.f/(1.f+a2); }
#pragma unroll
  for (int i = 0; i < 4; i++) {
#pragma unroll
    for (int r = 0; r < 4; r++) {
      int row = bm + wr + i*16 + ((lane >> 4) << 2) + r;
      float ev = (FLAGS & F_ENV) ? env[row] : 1.f;
#pragma unroll
      for (int j = 0; j < 4; j++) {
        int col = bn + wc + j*16 + (lane & 15);
        float v = acc[i][j][r]*rscale;
        if (FLAGS & F_SILU) v = v/(1.f+__expf(-v));
        if (FLAGS & F_ENV)  v *= ev;
        if (FLAGS & F_RESID) v = (h2f(Xres[(size_t)row*N+col]) + a2*v)*inv1a2;
        Cout[(size_t)row*N+col] = f2h(v);
      }
    }
  }
}

// ---- fused 3-layer latent MLP (R15) ----
// x_out = resid(env * (silu(silu([x|tp0]@W1/sqrt(320)) @ W2 /16) @ W3 /16))
// Block = 64 rows x N=256; h1,h2 live in LDS only. Replaces mgemm(l1)+mlp2:
// saves the 16.8MB x2 HBM round-trip of the l1 output + one launch per layer.
// In-place safe: block touches only its own 64 rows of X.
__global__ __launch_bounds__(256) void mlp3_k(
    const unsigned short* __restrict__ X, const unsigned short* __restrict__ T0,
    const unsigned short* __restrict__ W1t, const unsigned short* __restrict__ W2t,
    const unsigned short* __restrict__ W3t, unsigned short* __restrict__ Out,
    const float* __restrict__ env, const float* __restrict__ alphap)
{
  __shared__ unsigned short AsB[64*32];     // 4 KB
  __shared__ unsigned short BsB[256*32];    // 16 KB
  __shared__ unsigned short Hs[64*264];     // 33.8 KB (h1, then h2)
  const int tid  = threadIdx.x;
  const int wave = tid >> 6, lane = tid & 63;
  const int bm = blockIdx.x*64;
  const int wc = wave*64;
  const int fr = lane & 15, fk = (lane >> 4) * 8;
  const int r4 = (lane >> 4) << 2;
  const int sra = tid >> 2;          // A staging row 0..63
  const int ska = (tid & 3) * 8;     // A staging k (8 halves)
  const int srb = tid >> 1;          // B staging row (per 128-half)
  const int skb = (tid & 1) * 16;    // B staging k half
  f32x4 acc[4][4] = {};

  // ---- stage 1: h1 = silu([x|tp0] @ W1 / sqrt(320)) -> Hs ----
  for (int k0 = 0; k0 < 320; k0 += 32) {
    {
      int kk = k0 + ska;   // 16B chunk never straddles the 256 boundary
      const unsigned short* ap = (kk < 256)
        ? X  + (size_t)(bm + sra)*256 + kk
        : T0 + (size_t)(bm + sra)*64  + (kk - 256);
      uint4 u = *(const uint4*)ap;
      *(uint4*)((char*)AsB + swz(sra, ska)) = u;
    }
#pragma unroll
    for (int h = 0; h < 2; h++) {
      int n = h*128 + srb;
      const unsigned short* s = W1t + (size_t)n*320 + k0 + skb;
      uint4 u0 = *(const uint4*)s;
      uint4 u1 = *(const uint4*)(s + 8);
      *(uint4*)((char*)BsB + swz(n, skb))     = u0;
      *(uint4*)((char*)BsB + swz(n, skb + 8)) = u1;
    }
    __syncthreads();
    half8 af[4], bf[4];
#pragma unroll
    for (int i = 0; i < 4; i++)
      af[i] = *(half8*)((char*)AsB + swz(i*16 + fr, fk));
#pragma unroll
    for (int j = 0; j < 4; j++)
      bf[j] = *(half8*)((char*)BsB + swz(wc + j*16 + fr, fk));
#pragma unroll
    for (int i = 0; i < 4; i++)
#pragma unroll
      for (int j = 0; j < 4; j++)
        acc[i][j] = __builtin_amdgcn_mfma_f32_16x16x32_f16(af[i], bf[j], acc[i][j], 0, 0, 0);
    __syncthreads();
  }
  const float rs320 = 0.055901699437494740f;   // 1/sqrt(320)
#pragma unroll
  for (int i = 0; i < 4; i++)
#pragma unroll
    for (int r = 0; r < 4; r++) {
      int row = i*16 + r4 + r;
#pragma unroll
      for (int j = 0; j < 4; j++) {
        int col = wc + j*16 + fr;
        float v = acc[i][j][r]*rs320;
        v = v/(1.f+__expf(-v));
        Hs[row*264 + col] = f2h(v);
        acc[i][j][r] = 0.f;
      }
    }
  __syncthreads();

  // ---- stage 2: h2 = silu(h1 @ W2 / 16) -> Hs (overwrite after drain) ----
  for (int k0 = 0; k0 < 256; k0 += 32) {
#pragma unroll
    for (int h = 0; h < 2; h++) {
      int n = h*128 + srb;
      const unsigned short* s = W2t + (size_t)n*256 + k0 + skb;
      uint4 u0 = *(const uint4*)s;
      uint4 u1 = *(const uint4*)(s + 8);
      *(uint4*)((char*)BsB + swz(n, skb))     = u0;
      *(uint4*)((char*)BsB + swz(n, skb + 8)) = u1;
    }
    __syncthreads();
    half8 af[4], bf[4];
#pragma unroll
    for (int i = 0; i < 4; i++)
      af[i] = *(half8*)(Hs + (i*16 + fr)*264 + k0 + fk);
#pragma unroll
    for (int j = 0; j < 4; j++)
      bf[j] = *(half8*)((char*)BsB + swz(wc + j*16 + fr, fk));
#pragma unroll
    for (int i = 0; i < 4; i++)
#pragma unroll
      for (int j = 0; j < 4; j++)
        acc[i][j] = __builtin_amdgcn_mfma_f32_16x16x32_f16(af[i], bf[j], acc[i][j], 0, 0, 0);
    __syncthreads();
  }
#pragma unroll
  for (int i = 0; i < 4; i++)
#pragma unroll
    for (int r = 0; r < 4; r++) {
      int row = i*16 + r4 + r;
#pragma unroll
      for (int j = 0; j < 4; j++) {
        int col = wc + j*16 + fr;
        float v = acc[i][j][r]*0.0625f;
        v = v/(1.f+__expf(-v));
        Hs[row*264 + col] = f2h(v);
        acc[i][j][r] = 0.f;
      }
    }
  __syncthreads();

  // ---- stage 3: out = resid(env * (h2 @ W3 / 16)) ----
  for (int k0 = 0; k0 < 256; k0 += 32) {
#pragma unroll
    for (int h = 0; h < 2; h++) {
      int n = h*128 + srb;
      const unsigned short* s = W3t + (size_t)n*256 + k0 + skb;
      uint4 u0 = *(const uint4*)s;
      uint4 u1 = *(const uint4*)(s + 8);
      *(uint4*)((char*)BsB + swz(n, skb))     = u0;
      *(uint4*)((char*)BsB + swz(n, skb + 8)) = u1;
    }
    __syncthreads();
    half8 af[4], bf[4];
#pragma unroll
    for (int i = 0; i < 4; i++)
      af[i] = *(half8*)(Hs + (i*16 + fr)*264 + k0 + fk);
#pragma unroll
    for (int j = 0; j < 4; j++)
      bf[j] = *(half8*)((char*)BsB + swz(wc + j*16 + fr, fk));
#pragma unroll
    for (int i = 0; i < 4; i++)
#pragma unroll
      for (int j = 0; j < 4; j++)
        acc[i][j] = __builtin_amdgcn_mfma_f32_16x16x32_f16(af[i], bf[j], acc[i][j], 0, 0, 0);
    __syncthreads();
  }
  float al = alphap[0];
  float a2 = al*al, inv1a2 = 1.f/(1.f+a2);
#pragma unroll
  for (int i = 0; i < 4; i++)
#pragma unroll
    for (int r = 0; r < 4; r++) {
      int row = bm + i*16 + r4 + r;
      float ev = env[row];
#pragma unroll
      for (int j = 0; j < 4; j++) {
        int col = wc + j*16 + fr;
        float v = acc[i][j][r]*0.0625f*ev;
        v = (h2f(X[(size_t)row*256+col]) + a2*v)*inv1a2;
        Out[(size_t)row*256+col] = f2h(v);
      }
    }
}

// ---- fused Vn kernel + layer-1 tp0 ----
__global__ __launch_bounds__(512) void vn_k(
    const float* __restrict__ node, const unsigned short* __restrict__ V,
    const int* __restrict__ senders, const float* __restrict__ varepsp,
    const int* __restrict__ pairsG, const unsigned short* __restrict__ Gtt,
    unsigned short* __restrict__ Vn, int Kdim,
    const int* __restrict__ pmeta, const int* __restrict__ entIJ,
    const float* __restrict__ entVal, unsigned short* __restrict__ tp0)
{
  __shared__ unsigned short Ab[VN_E*264];
  __shared__ unsigned short Bb[VN_E*264];
  __shared__ int Ps[256];
  const int tid = threadIdx.x;
  const int e0 = blockIdx.x * VN_E;
  const int wave = tid >> 6, lane = tid & 63;
  float ve = varepsp[0];
  float eps = rsqrtf(1.f + ve*ve);
  if (tid < 256) Ps[tid] = pairsG[tid];
#pragma unroll
  for (int rr = 0; rr < 16; rr++) {
    int row = wave*16 + rr;
    int s = senders[e0 + row];
    float4 fa = *(const float4*)(node + ((size_t)s << 8) + 4*lane);
    uint2 ub = *(const uint2*)(V + (((size_t)(e0 + row)) << 8) + 4*lane);
    unsigned short* ad = Ab + row*264 + 4*lane;
    unsigned short* bd = Bb + row*264 + 4*lane;
    uint2 ua;
    ua.x = (unsigned)f2h(fa.x*eps) | ((unsigned)f2h(fa.y*eps) << 16);
    ua.y = (unsigned)f2h(fa.z*eps) | ((unsigned)f2h(fa.w*eps) << 16);
    *(uint2*)ad = ua;
    *(uint2*)bd = ub;
  }
  __syncthreads();
  for (int o = tid; o < VN_E*64; o += 512) {
    int e = o >> 6, c = o & 63;
    int p = c >> 4, m = c & 15;
    const unsigned short* Ae = Ab + e*264;
    const unsigned short* Be = Bb + e*264;
    int es = pmeta[p*4+1], ec = pmeta[p*4+2];
    float acc = 0.f;
    for (int t = 0; t < ec; t++) {
      int ij = entIJ[es+t];
      acc += entVal[es+t] * h2f(Ae[((ij&255)<<4)+m]) * h2f(Be[(((ij>>8)&255)<<4)+m]);
    }
    tp0[((size_t)(e0+e)<<6) + pmeta[p*4+0] + m] = f2h(acc);
  }
  const int rowb = (wave & 1) * 64;
  const int wc   = (wave >> 1) * 64;
  const int fr = lane & 15, fk = (lane >> 4) * 8;
  const int pairSel = fk >> 4;
  const int moff = fk & 15;
  const int nslab = Kdim >> 5;
  f32x4 acc[4][4] = {};

  const unsigned short* Ar0 = Ab + (rowb + fr)*264;
  const unsigned short* Br0 = Bb + (rowb + fr)*264;
  const unsigned short* Ar1 = Ab + (rowb + 16 + fr)*264;
  const unsigned short* Br1 = Bb + (rowb + 16 + fr)*264;
  const unsigned short* Ar2 = Ab + (rowb + 32 + fr)*264;
  const unsigned short* Br2 = Bb + (rowb + 32 + fr)*264;
  const unsigned short* Ar3 = Ab + (rowb + 48 + fr)*264;
  const unsigned short* Br3 = Bb + (rowb + 48 + fr)*264;

  const unsigned short* gp = Gtt + ((size_t)(wc + fr)) * 32 + fk;
  half8 b0 = *(const half8*)(gp);
  half8 b1 = *(const half8*)(gp + 512);
  half8 b2 = *(const half8*)(gp + 1024);
  half8 b3 = *(const half8*)(gp + 1536);
  half8 c0 = b0, c1 = b1, c2 = b2, c3 = b3;
  if (nslab > 1) {
    const unsigned short* g1 = gp + 8192;
    c0 = *(const half8*)(g1);
    c1 = *(const half8*)(g1 + 512);
    c2 = *(const half8*)(g1 + 1024);
    c3 = *(const half8*)(g1 + 1536);
  }
  int p0 = Ps[pairSel];
  int aoff = ((p0 & 255) << 4) + moff;
  int boff = (((p0 >> 8) & 255) << 4) + moff;
  half8 rA0 = *(const half8*)(Ar0 + aoff);
  half8 rB0 = *(const half8*)(Br0 + boff);
  half8 rA1 = *(const half8*)(Ar1 + aoff);
  half8 rB1 = *(const half8*)(Br1 + boff);
  half8 rA2 = *(const half8*)(Ar2 + aoff);
  half8 rB2 = *(const half8*)(Br2 + boff);
  half8 rA3 = *(const half8*)(Ar3 + aoff);
  half8 rB3 = *(const half8*)(Br3 + boff);

  for (int sl = 0; sl < nslab; sl++) {
    half8 a0 = rA0 * rB0;
    half8 a1 = rA1 * rB1;
    half8 a2 = rA2 * rB2;
    half8 a3 = rA3 * rB3;
    if (sl + 1 < nslab) {
      int pn = Ps[2*(sl + 1) + pairSel];
      int aoffn = ((pn & 255) << 4) + moff;
      int boffn = (((pn >> 8) & 255) << 4) + moff;
      rA0 = *(const half8*)(Ar0 + aoffn);
      rB0 = *(const half8*)(Br0 + boffn);
      rA1 = *(const half8*)(Ar1 + aoffn);
      rB1 = *(const half8*)(Br1 + boffn);
      rA2 = *(const half8*)(Ar2 + aoffn);
      rB2 = *(const half8*)(Br2 + boffn);
      rA3 = *(const half8*)(Ar3 + aoffn);
      rB3 = *(const half8*)(Br3 + boffn);
    }
    half8 d0, d1, d2, d3;
    if (sl + 2 < nslab) {
      const unsigned short* gn = gp + (size_t)(sl + 2) * 8192;
      d0 = *(const half8*)(gn);
      d1 = *(const half8*)(gn + 512);
      d2 = *(const half8*)(gn + 1024);
      d3 = *(const half8*)(gn + 1536);
    } else { d0 = c0; d1 = c1; d2 = c2; d3 = c3; }
    acc[0][0] = __builtin_amdgcn_mfma_f32_16x16x32_f16(a0, b0, acc[0][0], 0, 0, 0);
    acc[1][0] = __builtin_amdgcn_mfma_f32_16x16x32_f16(a1, b0, acc[1][0], 0, 0, 0);
    acc[2][0] = __builtin_amdgcn_mfma_f32_16x16x32_f16(a2, b0, acc[2][0], 0, 0, 0);
    acc[3][0] = __builtin_amdgcn_mfma_f32_16x16x32_f16(a3, b0, acc[3][0], 0, 0, 0);
    acc[0][1] = __builtin_amdgcn_mfma_f32_16x16x32_f16(a0, b1, acc[0][1], 0, 0, 0);
    acc[1][1] = __builtin_amdgcn_mfma_f32_16x16x32_f16(a1, b1, acc[1][1], 0, 0, 0);
    acc[2][1] = __builtin_amdgcn_mfma_f32_16x16x32_f16(a2, b1, acc[2][1], 0, 0, 0);
    acc[3][1] = __builtin_amdgcn_mfma_f32_16x16x32_f16(a3, b1, acc[3][1], 0, 0, 0);
    acc[0][2] = __builtin_amdgcn_mfma_f32_16x16x32_f16(a0, b2, acc[0][2], 0, 0, 0);
    acc[1][2] = __builtin_amdgcn_mfma_f32_16x16x32_f16(a1, b2, acc[1][2], 0, 0, 0);
    acc[2][2] = __builtin_amdgcn_mfma_f32_16x16x32_f16(a2, b2, acc[2][2], 0, 0, 0);
    acc[3][2] = __builtin_amdgcn_mfma_f32_16x16x32_f16(a3, b2, acc[3][2], 0, 0, 0);
    acc[0][3] = __builtin_amdgcn_mfma_f32_16x16x32_f16(a0, b3, acc[0][3], 0, 0, 0);
    acc[1][3] = __builtin_amdgcn_mfma_f32_16x16x32_f16(a1, b3, acc[1][3], 0, 0, 0);
    acc[2][3] = __builtin_amdgcn_mfma_f32_16x16x32_f16(a2, b3, acc[2][3], 0, 0, 0);
    acc[3][3] = __builtin_amdgcn_mfma_f32_16x16x32_f16(a3, b3, acc[3][3], 0, 0, 0);
    b0 = c0; b1 = c1; b2 = c2; b3 = c3;
    c0 = d0; c1 = d1; c2 = d2; c3 = d3;
  }
  const int r4 = (lane >> 4) << 2;
#pragma unroll
  for (int rg = 0; rg < 4; rg++) {
#pragma unroll
    for (int j = 0; j < 4; j++) {
#pragma unroll
      for (int r = 0; r < 4; r++) {
        int row = e0 + rowb + rg*16 + r4 + r;
        int col = wc + j*16 + fr;
        Vn[(size_t)row*256 + col] = f2h(acc[rg][j][r]);
      }
    }
  }
}

// ---- Gtt[slab][col][32] = coupling x Wv (fp16, tiled). col = kabs*16+d ----
__global__ void gbuild_k(const float* __restrict__ TD,
    const float* __restrict__ Wv1, const float* __restrict__ Wv2,
    const float* __restrict__ Wv3, const int* __restrict__ sl_origc,
    unsigned short* __restrict__ Gt, int Kdim, int npairs,
    int s1b, int s1e, int s2e, int s3e)
{
  int k = blockIdx.x*256 + threadIdx.x;
  if (k >= Kdim) return;
  int col = blockIdx.y;
  int pair = k >> 4, m = k & 15;
  int d = col & 15, kabs = col >> 4;
  float acc = 0.f;
  if (kabs > 0 && pair < npairs) {
    const float* Wv; int ss, se, kloc;
    if (kabs < 4)      { Wv = Wv1; ss = s1b; se = s1e; kloc = kabs - 1; }
    else if (kabs < 9) { Wv = Wv2; ss = s1e; se = s2e; kloc = kabs - 4; }
    else               { Wv = Wv3; ss = s2e; se = s3e; kloc = kabs - 9; }
    for (int slot = ss; slot < se; slot++)
      acc += TD[((pair*30) + (slot - 4))*8 + kloc] * Wv[(sl_origc[slot] + m)*16 + d];
    acc *= rsqrtf((float)(16*(se - ss)));
  }
  Gt[((size_t)((k >> 5)*256 + col))*32 + (k & 31)] = f2h(acc);
}

// ---- weight convert + transpose: Wt[n][k] = fp16(W[k][n]) ----
struct WDesc { const float* src; unsigned short* dst; int K; int lgN; };
struct WPack { WDesc d[8]; };
__global__ void wcvt_k(WPack p){
  WDesc d = p.d[blockIdx.y];
  int total = d.K << d.lgN;
  int gid = blockIdx.x*256 + threadIdx.x;
  if (gid >= total) return;
  int k = gid >> d.lgN, n = gid & ((1 << d.lgN) - 1);
  d.dst[(size_t)n*d.K + k] = f2h(d.src[gid]);
}

// ---- hc[k] = sum_j W_h[k][j] * W_out[j] ----
__global__ void whc_k(const float* __restrict__ Wh, const float* __restrict__ Wout,
                      float* __restrict__ hc)
{
  int k = threadIdx.x;
  float s = 0.f;
#pragma unroll 16
  for (int j = 0; j < 128; j++) s += Wh[k*128 + j] * Wout[j];
  hc[k] = s;
}

// ---- out[e] = env[e] * dot(x16[e,:256], hc) / (16*sqrt(128)) ----
__global__ void final256_k(const unsigned short* __restrict__ X,
    const float* __restrict__ hc, const float* __restrict__ env,
    float* __restrict__ out)
{
  const int e = blockIdx.x*256 + threadIdx.x;
  float acc = 0.f;
#pragma unroll 16
  for (int k = 0; k < 256; k++) acc += h2f(X[((size_t)e<<8)+k])*hc[k];
  out[e] = env[e]*acc*0.0055242717280199023f;
}

// Generic fp32 tiled GEMM (small two-body layers).
template<int FLAGS>
__global__ __launch_bounds__(256) void gemm_k(
    const float* __restrict__ A1, const float* __restrict__ A2,
    int K1, int K, const float* __restrict__ W, int N,
    float* Cout,
    const float* __restrict__ env, const float* __restrict__ alphap,
    const float* Xres)
{
  __shared__ float As[16][68];
  __shared__ float Ws[16][68];
  const int tid = threadIdx.x;
  const int bm = blockIdx.x * 64;
  const int bn = blockIdx.y * 64;
  const int tx = tid & 15, ty = tid >> 4;
  const int K2 = K - K1;
  float acc[4][4] = {};
  for (int k0 = 0; k0 < K; k0 += 16) {
#pragma unroll
    for (int i = 0; i < 4; i++) {
      int idx = tid + i*256;
      int m = idx >> 4, kk = idx & 15;
      int k = k0 + kk;
      float v = 0.f;
      if (k < K) {
        int row = bm + m;
        v = (k < K1) ? A1[(size_t)row*K1 + k] : A2[(size_t)row*K2 + (k-K1)];
      }
      As[kk][m] = v;
    }
#pragma unroll
    for (int i = 0; i < 4; i++) {
      int idx = tid + i*256;
      int n = idx & 63, kk = idx >> 6;
      int k = k0 + kk, col = bn + n;
      Ws[kk][n] = (k < K && col < N) ? W[(size_t)k*N + col] : 0.f;
    }
    __syncthreads();
#pragma unroll
    for (int kk = 0; kk < 16; kk++) {
      float a[4], b[4];
#pragma unroll
      for (int i=0;i<4;i++) a[i] = As[kk][ty*4+i];
#pragma unroll
      for (int j=0;j<4;j++) b[j] = Ws[kk][tx*4+j];
#pragma unroll
      for (int i=0;i<4;i++)
#pragma unroll
        for (int j=0;j<4;j++)
          acc[i][j] += a[i]*b[j];
    }
    __syncthreads();
  }
  const float rscale = 1.f/sqrtf((float)K);
  float a2 = 0.f, inv1a2 = 1.f;
  if (FLAGS & F_RESID) { float al = alphap[0]; a2 = al*al; inv1a2 = 1.f/(1.f+a2); }
#pragma unroll
  for (int i=0;i<4;i++) {
    int row = bm + ty*4 + i;
    float ev = (FLAGS & F_ENV) ? env[row] : 1.f;
#pragma unroll
    for (int j=0;j<4;j++) {
      int col = bn + tx*4 + j;
      if (col >= N) continue;
      float v = acc[i][j]*rscale;
      if (FLAGS & F_SILU) v = v/(1.f+__expf(-v));
      if (FLAGS & F_ENV)  v *= ev;
      if (FLAGS & F_RESID) v = (Xres[(size_t)row*N+col] + a2*v)*inv1a2;
      Cout[(size_t)row*N+col] = v;
    }
  }
}

// dense to 16 outputs, K=256, scale 1/16; A fp16 (layer-2 w2)
__global__ __launch_bounds__(256) void dense16_k(const unsigned short* __restrict__ A,
    const float* __restrict__ W, float* __restrict__ C)
{
  __shared__ float As[16*256];
  const int r0 = blockIdx.x << 4;
  const int tid = threadIdx.x;
  for (int i = tid; i < 16*256; i += 256)
    As[i] = h2f(A[((size_t)r0<<8) + i]);
  __syncthreads();
  const int r = tid >> 4, n = tid & 15;
  float acc = 0.f;
#pragma unroll 8
  for (int k = 0; k < 256; k++)
    acc += As[(r<<8)+k] * W[(k<<4)+n];
  C[((size_t)(r0+r)<<4)+n] = acc * 0.0625f;
}

// fused w0 + w1 + V-init
__global__ __launch_bounds__(256) void dense16v_k(const unsigned short* __restrict__ A,
    const float* __restrict__ W0, const float* __restrict__ W1,
    const float* __restrict__ Y, unsigned short* __restrict__ V,
    float* __restrict__ wb)
{
  __shared__ float As[16*256];
  __shared__ float w0s[256];
  const int r0 = blockIdx.x << 4;
  const int tid = threadIdx.x;
  for (int i = tid; i < 16*256; i += 256)
    As[i] = h2f(A[((size_t)r0<<8) + i]);
  __syncthreads();
  const int r = tid >> 4, n = tid & 15;
  float a0 = 0.f, a1 = 0.f;
#pragma unroll 8
  for (int k = 0; k < 256; k++) {
    float xv = As[(r<<8)+k];
    a0 += xv * W0[(k<<4)+n];
    a1 += xv * W1[(k<<4)+n];
  }
  w0s[tid] = a0 * 0.0625f;
  wb[((size_t)(r0+r)<<4)+n] = a1 * 0.0625f;
  __syncthreads();
  for (int i = tid; i < 4096; i += 256) {
    int e = i >> 8, idx = i & 255;
    V[(((size_t)(r0+e))<<8) + idx] = f2h(w0s[(e<<4)+(idx&15)] * Y[((r0+e)<<4)+(idx>>4)]);
  }
}

__global__ void edge_init_k(const float* __restrict__ vectors, const int* __restrict__ senders,
    const int* __restrict__ receivers, const int* __restrict__ species,
    const float* __restrict__ emb, float* __restrict__ envb, float* __restrict__ Yb,
    float* __restrict__ x72)
{
  const int e = blockIdx.x*256 + threadIdx.x;
  float vx = vectors[e*3+0], vy = vectors[e*3+1], vz = vectors[e*3+2];
  float d = sqrtf(vx*vx+vy*vy+vz*vz);
  float dd = (d==0.f) ? 1.f : d;
  float invd = 1.f/dd;
  float x = vx*invd, y = vy*invd, z = vz*invd;
  float d2=d*d, d3=d2*d, d6=d3*d3, d7=d6*d, d8=d7*d;
  float envv = (d<1.f) ? (1.f - 28.f*d6 + 48.f*d7 - 21.f*d8) : 0.f;
  envb[e] = envv;
  float mask = (d==0.f)?0.f:1.f;
  const float SQ2 = 1.41421356237309515f;
  const float PIf = 3.14159265358979323846f;
  float* xr = x72 + (size_t)e*72;
#pragma unroll
  for (int n=1;n<=8;n++)
    xr[n-1] = SQ2 * sinf((float)n*PIf*dd)*invd*envv*mask;
  int sp_s = species[senders[e]], sp_r = species[receivers[e]];
  const float* es_ = emb + (size_t)sp_s*32;
  const float* er_ = emb + (size_t)sp_r*32;
#pragma unroll 8
  for (int k=0;k<32;k++){ xr[8+k] = es_[k]*mask; xr[40+k] = er_[k]*mask; }
  float x2=x*x, y2=y*y, z2=z*z;
  const float s3=1.7320508075688772f, s15=3.872983346207417f, s5=2.23606797749979f;
  const float s358=2.0916500663351889f, s105=10.246950765959598f;
  const float s218=1.6201851746019651f, s7=2.6457513110645907f;
  float* Yr = Yb + ((size_t)e<<4);
  Yr[0]=1.f;           Yr[1]=s3*y;          Yr[2]=s3*z;           Yr[3]=s3*x;
  Yr[4]=s15*x*y;       Yr[5]=s15*y*z;       Yr[6]=0.5f*s5*(3.f*z2-1.f);
  Yr[7]=s15*x*z;       Yr[8]=0.5f*s15*(x2-y2);
  Yr[9]=s358*y*(3.f*x2-y2);  Yr[10]=s105*x*y*z;  Yr[11]=s218*y*(5.f*z2-1.f);
  Yr[12]=0.5f*s7*(5.f*z2-3.f)*z;  Yr[13]=s218*x*(5.f*z2-1.f);
  Yr[14]=0.5f*s105*(x2-y2)*z;     Yr[15]=s358*x*(x2-y2);
}

// ---- sort-based node accumulation ----
__global__ void hist_k(const int* __restrict__ senders, int* cnt){
  int e = blockIdx.x*256 + threadIdx.x;
  atomicAdd(&cnt[senders[e]], 1);
}

__global__ void scan_k(const int* __restrict__ cnt, int* __restrict__ starts,
                       int* __restrict__ cursor){
  __shared__ int s[NNODES];
  const int tid = threadIdx.x;
  for (int i = tid; i < NNODES; i += 256) s[i] = cnt[i];
  __syncthreads();
  if (tid == 0) {
    int run = 0;
    for (int i = 0; i < NNODES; i++) { int c = s[i]; s[i] = run; run += c; }
  }
  __syncthreads();
  for (int i = tid; i < NNODES; i += 256) { starts[i] = s[i]; cursor[i] = s[i]; }
  if (tid == 0) starts[NNODES] = E_EDGES;
}

__global__ void perm_k(const int* __restrict__ senders, int* cursor,
                       int* __restrict__ perm){
  int e = blockIdx.x*256 + threadIdx.x;
  int pos = atomicAdd(&cursor[senders[e]], 1);
  perm[pos] = e;
}

// node[n][a*16+m] = sum_{e: senders[e]==n} w[e][m]*Y[e][a]; block per node.
__global__ __launch_bounds__(256) void nodesum_k(const float* __restrict__ w,
    const float* __restrict__ Y, const int* __restrict__ perm,
    const int* __restrict__ starts, float* __restrict__ node)
{
  __shared__ float buf[8*32];
  const int n = blockIdx.x;
  const int tid = threadIdx.x;
  const int s0 = starts[n], s1 = starts[n+1];
  const int a = tid >> 4, m = tid & 15;
  float acc = 0.f;
  for (int i = s0; i < s1; i += 8) {
    int nb = s1 - i; if (nb > 8) nb = 8;
    int slot = tid >> 5, comp = tid & 31;
    if (slot < nb) {
      int e = perm[i + slot];
      buf[slot*32 + comp] = (comp < 16) ? w[(e<<4)+comp] : Y[(e<<4)+comp-16];
    }
    __syncthreads();
    for (int q = 0; q < nb; q++)
      acc += buf[q*32 + m] * buf[q*32 + 16 + a];
    __syncthreads();
  }
  node[((size_t)n<<8) + tid] = acc;
}

// l3=0 TP standalone (layer 2); B = Vn fp16
__global__ void tp2_k(const float* __restrict__ node, const unsigned short* __restrict__ Vn,
    const int* __restrict__ senders, const float* __restrict__ varepsp,
    const int* __restrict__ pmeta, const int* __restrict__ entIJ,
    const float* __restrict__ entVal, unsigned short* __restrict__ tp0)
{
  const int gid = blockIdx.x*256 + threadIdx.x;
  const int e = gid >> 6, c = gid & 63;
  const int p = c >> 4, m = c & 15;
  float ve = varepsp[0];
  float eps = rsqrtf(1.f + ve*ve);
  int s = senders[e];
  const float* Am = &node[((size_t)s<<8)];
  const unsigned short* Bm = &Vn[((size_t)e<<8)];
  int es = pmeta[p*4+1], ec = pmeta[p*4+2];
  float acc = 0.f;
  for (int t=0;t<ec;t++){
    int ij = entIJ[es+t];
    acc += entVal[es+t] * Am[((ij&255)<<4) + m] * h2f(Bm[(((ij>>8)&255)<<4) + m]);
  }
  tp0[((size_t)e<<6) + pmeta[p*4+0] + m] = f2h(acc * eps);
}

// ============================ host launcher ============================

static void launch_gemm(int flags, const float* A1, const float* A2, int K1, int K,
    const float* W, int N, float* C, const float* env, const float* alphap,
    const float* Xres, hipStream_t stream)
{
  dim3 grid(E_EDGES/64, (N+63)/64);
  switch(flags){
    case F_SILU:        gemm_k<F_SILU>       <<<grid,256,0,stream>>>(A1,A2,K1,K,W,N,C,env,alphap,Xres); break;
    case F_ENV:         gemm_k<F_ENV>        <<<grid,256,0,stream>>>(A1,A2,K1,K,W,N,C,env,alphap,Xres); break;
    default: break;
  }
}

static void launch_mgemm(int flags, int a16, const void* A1, const void* A2, int K1, int K,
    const unsigned short* Wt, int N, unsigned short* C, const float* env,
    const float* alphap, const unsigned short* Xres, hipStream_t stream)
{
  dim3 grid(E_EDGES/128, N/128);
  if (a16) {
    switch(flags){
      case F_ENV:         mgemm_k<F_ENV,1>        <<<grid,256,0,stream>>>(A1,A2,K1,K,Wt,N,C,env,alphap,Xres); break;
      default: break;
    }
  } else {
    switch(flags){
      case F_SILU:        mgemm_k<F_SILU,0>       <<<grid,256,0,stream>>>(A1,A2,K1,K,Wt,N,C,env,alphap,Xres); break;
      default: break;
    }
  }
}

extern "C" void kernel_launch(void* const* d_in, const int* in_sizes, int n_in,
                              void* d_out, int out_size, void* d_ws, size_t ws_size,
                              hipStream_t stream)
{
  const float* vectors = (const float*)d_in[0];
  const float* vareps  = (const float*)d_in[1];
  const float* alpha   = (const float*)d_in[2];
  const float* emb     = (const float*)d_in[3];
  const float* W_tb1   = (const float*)d_in[4];
  const float* W_tb2   = (const float*)d_in[5];
  const float* W_tb3   = (const float*)d_in[6];
  const float* W_tb4   = (const float*)d_in[7];
  const float* W_w0    = (const float*)d_in[8];
  const float* W_w1    = (const float*)d_in[9];
  const float* W_l11   = (const float*)d_in[10];
  const float* W_l12   = (const float*)d_in[11];
  const float* W_l13   = (const float*)d_in[12];
  const float* W_v1    = (const float*)d_in[13];
  const float* W_v2    = (const float*)d_in[14];
  const float* W_v3    = (const float*)d_in[15];
  const float* W_w2    = (const float*)d_in[16];
  const float* W_l21   = (const float*)d_in[17];
  const float* W_l22   = (const float*)d_in[18];
  const float* W_l23   = (const float*)d_in[19];
  const float* W_h     = (const float*)d_in[20];
  const float* W_out   = (const float*)d_in[21];
  const int* senders   = (const int*)d_in[22];
  const int* receivers = (const int*)d_in[23];
  const int* species   = (const int*)d_in[24];

  static cgt::Tables tb;
  cgt::build(tb);
  const int Kdim = tb.npairs * 16;

  char* ws = (char*)d_ws;
  size_t off = 0;
  auto alloc = [&](size_t bytes)->void*{
    void* p = ws + off; off += (bytes + 255) & ~(size_t)255; return p;
  };
  float* t_val = (float*)alloc(sizeof(tb.val));
  int*   t_ij  = (int*)  alloc(sizeof(tb.ij));
  int*   t_pm  = (int*)  alloc(sizeof(tb.pmeta));
  float* t_td  = (float*)alloc(sizeof(tb.TD));
  int*   t_pr  = (int*)  alloc(sizeof(tb.pairs));
  int*   t_oc  = (int*)  alloc(sizeof(tb.sl_origc));
  float* envb  = (float*)alloc((size_t)E_EDGES*4);
  float* Yb    = (float*)alloc((size_t)E_EDGES*16*4);
  float* xb    = (float*)alloc((size_t)E_EDGES*256*4);
  float* Vb    = (float*)alloc((size_t)E_EDGES*256*4);
  float* bufA  = (float*)alloc((size_t)E_EDGES*256*4);
  float* bufB  = (float*)alloc((size_t)E_EDGES*256*4);
  float* wb    = (float*)alloc((size_t)E_EDGES*16*4);
  float* tp0b  = (float*)alloc((size_t)E_EDGES*64*4);
  float* nodeb = (float*)alloc((size_t)NNODES*256*4);
  float* hcb   = (float*)alloc(256*4);
  int* cntb    = (int*)alloc(NNODES*4);
  int* startsb = (int*)alloc((NNODES+1)*4);
  int* cursorb = (int*)alloc(NNODES*4);
  int* permb   = (int*)alloc(E_EDGES*4);
  unsigned short* Gt = (unsigned short*)alloc((size_t)256*Kdim*2);
  unsigned short* Wt_tb3 = (unsigned short*)alloc(64*128*2);
  unsigned short* Wt_tb4 = (unsigned short*)alloc(128*256*2);
  unsigned short* Wt_l11 = (unsigned short*)alloc(320*256*2);
  unsigned short* Wt_l12 = (unsigned short*)alloc(256*256*2);
  unsigned short* Wt_l13 = (unsigned short*)alloc(256*256*2);
  unsigned short* Wt_l21 = (unsigned short*)alloc(320*256*2);
  unsigned short* Wt_l22 = (unsigned short*)alloc(256*256*2);
  unsigned short* Wt_l23 = (unsigned short*)alloc(256*256*2);
  if (off > ws_size) {
    fprintf(stderr, "[allegro] workspace too small: need %zu, have %zu\n", off, ws_size);
    return;
  }
  unsigned short* xb16 = (unsigned short*)xb;
  unsigned short* bB16 = (unsigned short*)bufB;
  unsigned short* tp016 = (unsigned short*)tp0b;
  unsigned short* V16 = (unsigned short*)Vb;

  hipMemcpyAsync(t_val, tb.val,     sizeof(tb.val),     hipMemcpyHostToDevice, stream);
  hipMemcpyAsync(t_ij,  tb.ij,      sizeof(tb.ij),      hipMemcpyHostToDevice, stream);
  hipMemcpyAsync(t_pm,  tb.pmeta,   sizeof(tb.pmeta),   hipMemcpyHostToDevice, stream);
  hipMemcpyAsync(t_td,  tb.TD,      sizeof(tb.TD),      hipMemcpyHostToDevice, stream);
  hipMemcpyAsync(t_pr,  tb.pairs,   sizeof(tb.pairs),   hipMemcpyHostToDevice, stream);
  hipMemcpyAsync(t_oc,  tb.sl_origc,sizeof(tb.sl_origc),hipMemcpyHostToDevice, stream);

  const int s1b = tb.l3np[0];
  const int s1e = s1b + tb.l3np[1];
  const int s2e = s1e + tb.l3np[2];
  const int s3e = s2e + tb.l3np[3];

  {
    dim3 g((Kdim + 255)/256, 256);
    gbuild_k<<<g, 256, 0, stream>>>(t_td, W_v1, W_v2, W_v3, t_oc, Gt, Kdim,
                                    tb.npairs, s1b, s1e, s2e, s3e);
  }
  {
    WPack p;
    p.d[0] = { W_tb3, Wt_tb3,  64, 7 };
    p.d[1] = { W_tb4, Wt_tb4, 128, 8 };
    p.d[2] = { W_l11, Wt_l11, 320, 8 };
    p.d[3] = { W_l12, Wt_l12, 256, 8 };
    p.d[4] = { W_l13, Wt_l13, 256, 8 };
    p.d[5] = { W_l21, Wt_l21, 320, 8 };
    p.d[6] = { W_l22, Wt_l22, 256, 8 };
    p.d[7] = { W_l23, Wt_l23, 256, 8 };
    dim3 g(320, 8);
    wcvt_k<<<g, 256, 0, stream>>>(p);
  }
  whc_k<<<1, 256, 0, stream>>>(W_h, W_out, hcb);

  // edge->node sort (once; senders fixed for both layers)
  hipMemsetAsync(cntb, 0, NNODES*4, stream);
  hist_k<<<E_EDGES/256, 256, 0, stream>>>(senders, cntb);
  scan_k<<<1, 256, 0, stream>>>(cntb, startsb, cursorb);
  perm_k<<<E_EDGES/256, 256, 0, stream>>>(senders, cursorb, permb);

  // 1. edge features + Y + env  (x72 -> bufA fp32)
  edge_init_k<<<E_EDGES/256, 256, 0, stream>>>(vectors, senders, receivers, species,
                                               emb, envb, Yb, bufA);
  // 2. two-body MLP
  launch_gemm (F_SILU, bufA, nullptr, 72, 72,  W_tb1, 32,  bufB, envb, alpha, nullptr, stream);
  launch_gemm (F_SILU, bufB, nullptr, 32, 32,  W_tb2, 64,  bufA, envb, alpha, nullptr, stream);
  launch_mgemm(F_SILU, 0, bufA, nullptr, 64, 64,  Wt_tb3, 128, bB16, envb, alpha, nullptr, stream);
  launch_mgemm(F_ENV,  1, bB16, nullptr, 128,128, Wt_tb4, 256, xb16, envb, alpha, nullptr, stream);
  // 3. fused w0+w1+V
  dense16v_k<<<E_EDGES/16, 256, 0, stream>>>(xb16, W_w0, W_w1, Yb, V16, wb);

  // ---- layer 1 ----
  nodesum_k<<<NNODES, 256, 0, stream>>>(wb, Yb, permb, startsb, nodeb);
  vn_k<<<E_EDGES/VN_E, 512, 0, stream>>>(nodeb, V16, senders, vareps, t_pr, Gt,
                                         V16, Kdim, t_pm, t_ij, t_val, tp016);
  mlp3_k<<<E_EDGES/64, 256, 0, stream>>>(xb16, tp016, Wt_l11, Wt_l12, Wt_l13,
                                         xb16, envb, alpha);

  // ---- layer 2 (lmax_out = 0) ----
  dense16_k<<<E_EDGES/16, 256, 0, stream>>>(xb16, W_w2, wb);
  nodesum_k<<<NNODES, 256, 0, stream>>>(wb, Yb, permb, startsb, nodeb);
  tp2_k<<<E_EDGES*64/256, 256, 0, stream>>>(nodeb, V16, senders, vareps, t_pm, t_ij,
                                            t_val, tp016);
  mlp3_k<<<E_EDGES/64, 256, 0, stream>>>(xb16, tp016, Wt_l21, Wt_l22, Wt_l23,
                                         xb16, envb, alpha);

  // ---- head (W_h @ W_out precombined) ----
  final256_k<<<E_EDGES/256, 256, 0, stream>>>(xb16, hcb, envb, (float*)d_out);
}

// Round 16
// 408.038 us; speedup vs baseline: 1.4347x; 1.0701x over previous
//
#include <hip/hip_runtime.h>
#include <cmath>
#include <complex>
#include <cstdio>
#include <cstring>
#include <algorithm>

#define E_EDGES 32768
#define NNODES  2048
#define VN_E    128

// ============================ host-side CG tables ============================
namespace cgt {

static double fct(int n){
  static const double f[13] = {1.,1.,2.,6.,24.,120.,720.,5040.,40320.,362880.,
                               3628800.,39916800.,479001600.};
  return f[n];
}

static double cg(int j1,int m1,int j2,int m2,int j3,int m3){
  if (m1+m2 != m3) return 0.0;
  double pre = std::sqrt((2*j3+1)*fct(j1+j2-j3)*fct(j1-j2+j3)*fct(-j1+j2+j3)/fct(j1+j2+j3+1));
  pre *= std::sqrt(fct(j3+m3)*fct(j3-m3)*fct(j1-m1)*fct(j1+m1)*fct(j2-m2)*fct(j2+m2));
  int kmin = 0;
  if (j2-j3-m1 > kmin) kmin = j2-j3-m1;
  if (j1-j3+m2 > kmin) kmin = j1-j3+m2;
  int kmax = j1+j2-j3;
  if (j1-m1 < kmax) kmax = j1-m1;
  if (j2+m2 < kmax) kmax = j2+m2;
  double s = 0.0;
  for (int k=kmin;k<=kmax;k++){
    double d = fct(k)*fct(j1+j2-j3-k)*fct(j1-m1-k)*fct(j2+m2-k)*fct(j3-j2+m1+k)*fct(j3-j1-m2+k);
    s += ((k&1)? -1.0:1.0)/d;
  }
  return pre*s;
}

typedef std::complex<double> cd;

static void umat(int l, cd U[7][7]){
  for (int a=0;a<7;a++) for (int b=0;b<7;b++) U[a][b]=cd(0,0);
  U[l][l] = cd(1,0);
  double s2 = 1.0/std::sqrt(2.0);
  for (int m=1;m<=l;m++){
    double sg = (m&1)? -1.0 : 1.0;
    U[l+m][l-m] = cd(s2,0);
    U[l+m][l+m] = cd(sg*s2,0);
    U[l-m][l-m] = cd(0, s2);
    U[l-m][l+m] = cd(0, -sg*s2);
  }
}

static bool realCoupling(int l1,int l2,int l3, double T[7][7][7]){
  cd U1[7][7],U2[7][7],U3[7][7];
  umat(l1,U1); umat(l2,U2); umat(l3,U3);
  int n1=2*l1+1, n2=2*l2+1, n3=2*l3+1;
  double Cg[7][7][7];
  for (int m=0;m<n1;m++) for(int n=0;n<n2;n++) for(int k=0;k<n3;k++)
    Cg[m][n][k] = cg(l1,m-l1,l2,n-l2,l3,k-l3);
  double Tr[7][7][7], Ti[7][7][7];
  double nr=0, ni=0;
  for (int a=0;a<n1;a++) for(int b=0;b<n2;b++) for(int c=0;c<n3;c++){
    cd s(0,0);
    for (int m=0;m<n1;m++){
      if (U1[a][m]==cd(0,0)) continue;
      for (int n=0;n<n2;n++){
        if (U2[b][n]==cd(0,0)) continue;
        for (int k=0;k<n3;k++){
          double cgv = Cg[m][n][k];
          if (cgv==0.0) continue;
          s += U1[a][m]*U2[b][n]*std::conj(U3[c][k])*cgv;
        }
      }
    }
    Tr[a][b][c]=s.real(); Ti[a][b][c]=s.imag();
    nr += s.real()*s.real(); ni += s.imag()*s.imag();
  }
  bool useR = (nr >= ni);
  double nn = std::sqrt(useR? nr : ni);
  if (nn < 1e-8) return false;
  for (int a=0;a<n1;a++)for(int b=0;b<n2;b++)for(int c=0;c<n3;c++)
    T[a][b][c] = (useR? Tr[a][b][c] : Ti[a][b][c])/nn;
  return true;
}

struct Tables {
  float val[4096];
  int   ij[4096];
  int   pmeta[40*4];
  int   ccnt[40*8];
  int   l3base[4];
  int   l3np[4];
  int   npaths;
  int   nent;
  int   tptot;
  int   pairs[256];
  float TD[256*30*8];
  int   sl_origc[40];
  int   npairs;
};

struct PathTmp {
  int l1,l2,l3, tpoff, kd;
  int ec;
  double T[7][7][7];
};

static void build(Tables& tb){
  static PathTmp paths[40];
  int np = 0, tpoff = 0;
  int l3start[5];
  for (int l3=0;l3<=3;l3++){
    tb.l3base[l3] = tpoff;
    l3start[l3] = np;
    int kd = 2*l3+1;
    for (int l1=0;l1<=3;l1++) for (int l2=0;l2<=3;l2++){
      int lo = (l1>l2)? l1-l2 : l2-l1;
      int hi = std::min(l1+l2,3);
      if (l3 < lo || l3 > hi) continue;
      PathTmp& pt = paths[np];
      if (!realCoupling(l1,l2,l3,pt.T)) continue;
      pt.l1=l1; pt.l2=l2; pt.l3=l3; pt.kd=kd; pt.tpoff=tpoff;
      double scale = std::sqrt((double)kd);
      int cnt = 0;
      for (int a=0;a<2*l1+1;a++)for(int b=0;b<2*l2+1;b++)for(int c=0;c<kd;c++)
        if (std::fabs(pt.T[a][b][c]*scale) > 1e-7) cnt++;
      pt.ec = cnt;
      tpoff += 16*kd;
      np++;
    }
  }
  l3start[4] = np;
  for (int l3=0;l3<=3;l3++) tb.l3np[l3] = l3start[l3+1]-l3start[l3];
  static int order[40];
  for (int i=0;i<np;i++) order[i]=i;
  for (int l3=0;l3<=3;l3++)
    std::sort(order+l3start[l3], order+l3start[l3+1],
              [&](int a,int b){ return paths[a].ec > paths[b].ec; });
  std::memset(tb.TD, 0, sizeof(tb.TD));
  std::memset(tb.pairs, 0, sizeof(tb.pairs));
  static int pmap[16][16];
  for (int i=0;i<16;i++) for (int j=0;j<16;j++) pmap[i][j] = -1;
  int npr = 0;
  int ep = 0;
  for (int slot=0; slot<np; slot++){
    const PathTmp& pt = paths[order[slot]];
    double scale = std::sqrt((double)pt.kd);
    int s1 = pt.l1*pt.l1, s2 = pt.l2*pt.l2;
    tb.pmeta[slot*4+0] = pt.tpoff;
    tb.pmeta[slot*4+1] = ep;
    tb.sl_origc[slot] = ((pt.tpoff - tb.l3base[pt.l3]) / (16*pt.kd)) * 16;
    int tot = 0;
    for (int c=0;c<pt.kd;c++){
      int cnt = 0;
      for (int a=0;a<2*pt.l1+1;a++)for(int b=0;b<2*pt.l2+1;b++){
        double v = pt.T[a][b][c]*scale;
        if (std::fabs(v) > 1e-7){
          tb.val[ep] = (float)v;
          tb.ij[ep]  = (s1+a) | ((s2+b)<<8);
          ep++; cnt++;
          if (pt.l3 >= 1){
            int aa = s1+a, bb = s2+b;
            int pi = pmap[aa][bb];
            if (pi < 0){ pi = npr; pmap[aa][bb] = pi;
                         tb.pairs[npr] = aa | (bb<<8); npr++; }
            tb.TD[(pi*30 + (slot-4))*8 + c] = (float)v;
          }
        }
      }
      tb.ccnt[slot*8+c] = cnt;
      tot += cnt;
    }
    for (int c=pt.kd;c<8;c++) tb.ccnt[slot*8+c]=0;
    tb.pmeta[slot*4+2] = tot;
    tb.pmeta[slot*4+3] = pt.kd;
  }
  if (npr & 1){ tb.pairs[npr] = 0; npr++; }
  tb.npairs = npr;
  tb.npaths = np; tb.nent = ep; tb.tptot = tpoff;
}

} // namespace cgt

// ============================ device kernels ============================
// LAYOUT: node/V/Vn rows are [a][m]. MFMA-path activations fp16 in HBM.

typedef _Float16 half8 __attribute__((ext_vector_type(8)));
typedef __attribute__((ext_vector_type(4))) float f32x4;

__device__ inline unsigned short f2h(float f){
  union { _Float16 h; unsigned short u; } x;
  x.h = (_Float16)f;
  return x.u;
}
__device__ inline float h2f(unsigned short u){
  union { _Float16 h; unsigned short u; } x; x.u = u;
  return (float)x.h;
}

__device__ inline int swz(int row, int kh){
  int b = row*64 + kh*2;
  return b ^ (((row >> 1) & 3) << 4);
}

__device__ inline float silu(float v){ return v/(1.f+__expf(-v)); }

#define MFMA16 __builtin_amdgcn_mfma_f32_16x16x32_f16

// ---- fused two-body chain (R16): x72 ->32->64->128->256, + [w0|w1], + V ----
// Per 64-edge block: all intermediates in LDS ping-pong (HsA/HsB); writes
// Xout (fp16), wb (w1, fp32), V (fp16, [a][m]). Replaces 2x fp32 gemm +
// 2x mgemm + dense16v (5 launches, ~59MB HBM round-trips).
__global__ __launch_bounds__(256) void tb_fused_k(
    const float* __restrict__ X72, const unsigned short* __restrict__ Wt1,
    const unsigned short* __restrict__ Wt2, const unsigned short* __restrict__ Wt3,
    const unsigned short* __restrict__ Wt4, const unsigned short* __restrict__ Wt01,
    const float* __restrict__ Yb, const float* __restrict__ envb,
    unsigned short* __restrict__ Xout, unsigned short* __restrict__ V,
    float* __restrict__ wb)
{
  __shared__ unsigned short AsB[64*32];     // 4 KB
  __shared__ unsigned short BsB[256*32];    // 16 KB
  __shared__ unsigned short HsA[64*264];    // 33.8 KB
  __shared__ unsigned short HsB[64*264];    // 33.8 KB
  __shared__ float w0s[64*16];              // 4 KB
  const int tid  = threadIdx.x;
  const int wave = tid >> 6, lane = tid & 63;
  const int bm = blockIdx.x*64;
  const int mrow = wave*16;                 // wave's 16-row stripe
  const int fr = lane & 15, fk = (lane >> 4) * 8;
  const int r4 = (lane >> 4) << 2;
  const int sra = tid >> 2, ska = (tid & 3) * 8;
  const int srb = tid >> 1, skb = (tid & 1) * 16;

  // ---- stage 1: h = silu(x72 @ W1 / sqrt(72)), N=32, K=72 (pad 96) ----
  {
    f32x4 acc[2] = {};
    for (int k0 = 0; k0 < 96; k0 += 32) {
      {
        unsigned short u[8];
        int rowg = bm + sra;
#pragma unroll
        for (int q = 0; q < 8; q++) {
          int k = k0 + ska + q;
          u[q] = (k < 72) ? f2h(X72[(size_t)rowg*72 + k]) : (unsigned short)0;
        }
        *(ushort4*)((char*)AsB + swz(sra, ska))     = *(ushort4*)&u[0];
        *(ushort4*)((char*)AsB + swz(sra, ska + 4)) = *(ushort4*)&u[4];
      }
      if (tid < 64) {
        int n = tid >> 1, kb = (tid & 1) * 16;
        unsigned short u[16];
#pragma unroll
        for (int q = 0; q < 16; q++) {
          int k = k0 + kb + q;
          u[q] = (k < 72) ? Wt1[n*72 + k] : (unsigned short)0;
        }
        *(uint4*)((char*)BsB + swz(n, kb))     = *(uint4*)&u[0];
        *(uint4*)((char*)BsB + swz(n, kb + 8)) = *(uint4*)&u[8];
      }
      __syncthreads();
      half8 af = *(half8*)((char*)AsB + swz(mrow + fr, fk));
      half8 b0 = *(half8*)((char*)BsB + swz(fr, fk));
      half8 b1 = *(half8*)((char*)BsB + swz(16 + fr, fk));
      acc[0] = MFMA16(af, b0, acc[0], 0, 0, 0);
      acc[1] = MFMA16(af, b1, acc[1], 0, 0, 0);
      __syncthreads();
    }
    const float rs = 0.11785113019775793f;   // 1/sqrt(72)
#pragma unroll
    for (int j = 0; j < 2; j++)
#pragma unroll
      for (int r = 0; r < 4; r++) {
        int row = mrow + r4 + r;
        HsA[row*264 + j*16 + fr] = f2h(silu(acc[j][r]*rs));
      }
    __syncthreads();
  }

  // ---- stage 2: h = silu(h @ W2 / sqrt(32)), N=64, K=32 ----
  {
    f32x4 acc[4] = {};
    if (tid < 128) {
      int n = tid >> 1, kb = (tid & 1) * 16;
      const unsigned short* s = Wt2 + n*32 + kb;
      uint4 u0 = *(const uint4*)s;
      uint4 u1 = *(const uint4*)(s + 8);
      *(uint4*)((char*)BsB + swz(n, kb))     = u0;
      *(uint4*)((char*)BsB + swz(n, kb + 8)) = u1;
    }
    __syncthreads();
    half8 af = *(half8*)(HsA + (mrow + fr)*264 + fk);
#pragma unroll
    for (int j = 0; j < 4; j++) {
      half8 bf = *(half8*)((char*)BsB + swz(j*16 + fr, fk));
      acc[j] = MFMA16(af, bf, acc[j], 0, 0, 0);
    }
    __syncthreads();
    const float rs = 0.17677669529663687f;   // 1/sqrt(32)
#pragma unroll
    for (int j = 0; j < 4; j++)
#pragma unroll
      for (int r = 0; r < 4; r++) {
        int row = mrow + r4 + r;
        HsB[row*264 + j*16 + fr] = f2h(silu(acc[j][r]*rs));
      }
    __syncthreads();
  }

  // ---- stage 3: h = silu(h @ W3 / 8), N=128, K=64 ----
  {
    f32x4 acc[8] = {};
    for (int k0 = 0; k0 < 64; k0 += 32) {
      {
        int n = srb, kb = skb;    // 128 rows x 32 k
        const unsigned short* s = Wt3 + n*64 + k0 + kb;
        uint4 u0 = *(const uint4*)s;
        uint4 u1 = *(const uint4*)(s + 8);
        *(uint4*)((char*)BsB + swz(n, kb))     = u0;
        *(uint4*)((char*)BsB + swz(n, kb + 8)) = u1;
      }
      __syncthreads();
      half8 af = *(half8*)(HsB + (mrow + fr)*264 + k0 + fk);
#pragma unroll
      for (int j = 0; j < 8; j++) {
        half8 bf = *(half8*)((char*)BsB + swz(j*16 + fr, fk));
        acc[j] = MFMA16(af, bf, acc[j], 0, 0, 0);
      }
      __syncthreads();
    }
    const float rs = 0.125f;   // 1/sqrt(64)
#pragma unroll
    for (int j = 0; j < 8; j++)
#pragma unroll
      for (int r = 0; r < 4; r++) {
        int row = mrow + r4 + r;
        HsA[row*264 + j*16 + fr] = f2h(silu(acc[j][r]*rs));
      }
    __syncthreads();
  }

  // ---- stage 4: x = env * (h @ W4 / sqrt(128)), N=256, K=128 ----
  {
    f32x4 acc[16] = {};
    for (int k0 = 0; k0 < 128; k0 += 32) {
#pragma unroll
      for (int h = 0; h < 2; h++) {
        int n = h*128 + srb;
        const unsigned short* s = Wt4 + (size_t)n*128 + k0 + skb;
        uint4 u0 = *(const uint4*)s;
        uint4 u1 = *(const uint4*)(s + 8);
        *(uint4*)((char*)BsB + swz(n, skb))     = u0;
        *(uint4*)((char*)BsB + swz(n, skb + 8)) = u1;
      }
      __syncthreads();
      half8 af = *(half8*)(HsA + (mrow + fr)*264 + k0 + fk);
#pragma unroll
      for (int j = 0; j < 16; j++) {
        half8 bf = *(half8*)((char*)BsB + swz(j*16 + fr, fk));
        acc[j] = MFMA16(af, bf, acc[j], 0, 0, 0);
      }
      __syncthreads();
    }
    const float rs = 0.08838834764831845f;   // 1/sqrt(128)
#pragma unroll
    for (int j = 0; j < 16; j++)
#pragma unroll
      for (int r = 0; r < 4; r++) {
        int row = mrow + r4 + r;
        float v = acc[j][r]*rs*envb[bm + row];
        unsigned short hv = f2h(v);
        HsB[row*264 + j*16 + fr] = hv;
        Xout[((size_t)(bm + row))*256 + j*16 + fr] = hv;
      }
    __syncthreads();
  }

  // ---- stage 5: [w0|w1] = x @ [W0|W1] / 16, N=32, K=256 ----
  {
    f32x4 acc[2] = {};
    for (int k0 = 0; k0 < 256; k0 += 32) {
      if (tid < 64) {
        int n = tid >> 1, kb = (tid & 1) * 16;
        const unsigned short* s = Wt01 + (size_t)n*256 + k0 + kb;
        uint4 u0 = *(const uint4*)s;
        uint4 u1 = *(const uint4*)(s + 8);
        *(uint4*)((char*)BsB + swz(n, kb))     = u0;
        *(uint4*)((char*)BsB + swz(n, kb + 8)) = u1;
      }
      __syncthreads();
      half8 af = *(half8*)(HsB + (mrow + fr)*264 + k0 + fk);
      half8 b0 = *(half8*)((char*)BsB + swz(fr, fk));
      half8 b1 = *(half8*)((char*)BsB + swz(16 + fr, fk));
      acc[0] = MFMA16(af, b0, acc[0], 0, 0, 0);
      acc[1] = MFMA16(af, b1, acc[1], 0, 0, 0);
      __syncthreads();
    }
#pragma unroll
    for (int r = 0; r < 4; r++) {
      int row = mrow + r4 + r;
      w0s[row*16 + fr] = acc[0][r]*0.0625f;
      wb[((size_t)(bm + row))*16 + fr] = acc[1][r]*0.0625f;
    }
    __syncthreads();
  }

  // ---- V init: V[e][a*16+m] = w0[e][m] * Y[e][a] ----
  for (int i = tid; i < 64*256; i += 256) {
    int e = i >> 8, idx = i & 255;
    V[(((size_t)(bm + e)) << 8) + idx] =
        f2h(w0s[e*16 + (idx & 15)] * Yb[(bm + e)*16 + (idx >> 4)]);
  }
}

// ---- fused 3-layer latent MLP ----
__global__ __launch_bounds__(256) void mlp3_k(
    const unsigned short* __restrict__ X, const unsigned short* __restrict__ T0,
    const unsigned short* __restrict__ W1t, const unsigned short* __restrict__ W2t,
    const unsigned short* __restrict__ W3t, unsigned short* __restrict__ Out,
    const float* __restrict__ env, const float* __restrict__ alphap)
{
  __shared__ unsigned short AsB[64*32];
  __shared__ unsigned short BsB[256*32];
  __shared__ unsigned short Hs[64*264];
  const int tid  = threadIdx.x;
  const int wave = tid >> 6, lane = tid & 63;
  const int bm = blockIdx.x*64;
  const int wc = wave*64;
  const int fr = lane & 15, fk = (lane >> 4) * 8;
  const int r4 = (lane >> 4) << 2;
  const int sra = tid >> 2;
  const int ska = (tid & 3) * 8;
  const int srb = tid >> 1;
  const int skb = (tid & 1) * 16;
  f32x4 acc[4][4] = {};

  for (int k0 = 0; k0 < 320; k0 += 32) {
    {
      int kk = k0 + ska;
      const unsigned short* ap = (kk < 256)
        ? X  + (size_t)(bm + sra)*256 + kk
        : T0 + (size_t)(bm + sra)*64  + (kk - 256);
      uint4 u = *(const uint4*)ap;
      *(uint4*)((char*)AsB + swz(sra, ska)) = u;
    }
#pragma unroll
    for (int h = 0; h < 2; h++) {
      int n = h*128 + srb;
      const unsigned short* s = W1t + (size_t)n*320 + k0 + skb;
      uint4 u0 = *(const uint4*)s;
      uint4 u1 = *(const uint4*)(s + 8);
      *(uint4*)((char*)BsB + swz(n, skb))     = u0;
      *(uint4*)((char*)BsB + swz(n, skb + 8)) = u1;
    }
    __syncthreads();
    half8 af[4], bf[4];
#pragma unroll
    for (int i = 0; i < 4; i++)
      af[i] = *(half8*)((char*)AsB + swz(i*16 + fr, fk));
#pragma unroll
    for (int j = 0; j < 4; j++)
      bf[j] = *(half8*)((char*)BsB + swz(wc + j*16 + fr, fk));
#pragma unroll
    for (int i = 0; i < 4; i++)
#pragma unroll
      for (int j = 0; j < 4; j++)
        acc[i][j] = MFMA16(af[i], bf[j], acc[i][j], 0, 0, 0);
    __syncthreads();
  }
  const float rs320 = 0.055901699437494740f;
#pragma unroll
  for (int i = 0; i < 4; i++)
#pragma unroll
    for (int r = 0; r < 4; r++) {
      int row = i*16 + r4 + r;
#pragma unroll
      for (int j = 0; j < 4; j++) {
        int col = wc + j*16 + fr;
        Hs[row*264 + col] = f2h(silu(acc[i][j][r]*rs320));
        acc[i][j][r] = 0.f;
      }
    }
  __syncthreads();

  for (int k0 = 0; k0 < 256; k0 += 32) {
#pragma unroll
    for (int h = 0; h < 2; h++) {
      int n = h*128 + srb;
      const unsigned short* s = W2t + (size_t)n*256 + k0 + skb;
      uint4 u0 = *(const uint4*)s;
      uint4 u1 = *(const uint4*)(s + 8);
      *(uint4*)((char*)BsB + swz(n, skb))     = u0;
      *(uint4*)((char*)BsB + swz(n, skb + 8)) = u1;
    }
    __syncthreads();
    half8 af[4], bf[4];
#pragma unroll
    for (int i = 0; i < 4; i++)
      af[i] = *(half8*)(Hs + (i*16 + fr)*264 + k0 + fk);
#pragma unroll
    for (int j = 0; j < 4; j++)
      bf[j] = *(half8*)((char*)BsB + swz(wc + j*16 + fr, fk));
#pragma unroll
    for (int i = 0; i < 4; i++)
#pragma unroll
      for (int j = 0; j < 4; j++)
        acc[i][j] = MFMA16(af[i], bf[j], acc[i][j], 0, 0, 0);
    __syncthreads();
  }
#pragma unroll
  for (int i = 0; i < 4; i++)
#pragma unroll
    for (int r = 0; r < 4; r++) {
      int row = i*16 + r4 + r;
#pragma unroll
      for (int j = 0; j < 4; j++) {
        int col = wc + j*16 + fr;
        Hs[row*264 + col] = f2h(silu(acc[i][j][r]*0.0625f));
        acc[i][j][r] = 0.f;
      }
    }
  __syncthreads();

  for (int k0 = 0; k0 < 256; k0 += 32) {
#pragma unroll
    for (int h = 0; h < 2; h++) {
      int n = h*128 + srb;
      const unsigned short* s = W3t + (size_t)n*256 + k0 + skb;
      uint4 u0 = *(const uint4*)s;
      uint4 u1 = *(const uint4*)(s + 8);
      *(uint4*)((char*)BsB + swz(n, skb))     = u0;
      *(uint4*)((char*)BsB + swz(n, skb + 8)) = u1;
    }
    __syncthreads();
    half8 af[4], bf[4];
#pragma unroll
    for (int i = 0; i < 4; i++)
      af[i] = *(half8*)(Hs + (i*16 + fr)*264 + k0 + fk);
#pragma unroll
    for (int j = 0; j < 4; j++)
      bf[j] = *(half8*)((char*)BsB + swz(wc + j*16 + fr, fk));
#pragma unroll
    for (int i = 0; i < 4; i++)
#pragma unroll
      for (int j = 0; j < 4; j++)
        acc[i][j] = MFMA16(af[i], bf[j], acc[i][j], 0, 0, 0);
    __syncthreads();
  }
  float al = alphap[0];
  float a2 = al*al, inv1a2 = 1.f/(1.f+a2);
#pragma unroll
  for (int i = 0; i < 4; i++)
#pragma unroll
    for (int r = 0; r < 4; r++) {
      int row = bm + i*16 + r4 + r;
      float ev = env[row];
#pragma unroll
      for (int j = 0; j < 4; j++) {
        int col = wc + j*16 + fr;
        float v = acc[i][j][r]*0.0625f*ev;
        v = (h2f(X[(size_t)row*256+col]) + a2*v)*inv1a2;
        Out[(size_t)row*256+col] = f2h(v);
      }
    }
}

// ---- fused Vn kernel + layer-1 tp0 ----
__global__ __launch_bounds__(512) void vn_k(
    const float* __restrict__ node, const unsigned short* __restrict__ V,
    const int* __restrict__ senders, const float* __restrict__ varepsp,
    const int* __restrict__ pairsG, const unsigned short* __restrict__ Gtt,
    unsigned short* __restrict__ Vn, int Kdim,
    const int* __restrict__ pmeta, const int* __restrict__ entIJ,
    const float* __restrict__ entVal, unsigned short* __restrict__ tp0)
{
  __shared__ unsigned short Ab[VN_E*264];
  __shared__ unsigned short Bb[VN_E*264];
  __shared__ int Ps[256];
  const int tid = threadIdx.x;
  const int e0 = blockIdx.x * VN_E;
  const int wave = tid >> 6, lane = tid & 63;
  float ve = varepsp[0];
  float eps = rsqrtf(1.f + ve*ve);
  if (tid < 256) Ps[tid] = pairsG[tid];
#pragma unroll
  for (int rr = 0; rr < 16; rr++) {
    int row = wave*16 + rr;
    int s = senders[e0 + row];
    float4 fa = *(const float4*)(node + ((size_t)s << 8) + 4*lane);
    uint2 ub = *(const uint2*)(V + (((size_t)(e0 + row)) << 8) + 4*lane);
    unsigned short* ad = Ab + row*264 + 4*lane;
    unsigned short* bd = Bb + row*264 + 4*lane;
    uint2 ua;
    ua.x = (unsigned)f2h(fa.x*eps) | ((unsigned)f2h(fa.y*eps) << 16);
    ua.y = (unsigned)f2h(fa.z*eps) | ((unsigned)f2h(fa.w*eps) << 16);
    *(uint2*)ad = ua;
    *(uint2*)bd = ub;
  }
  __syncthreads();
  for (int o = tid; o < VN_E*64; o += 512) {
    int e = o >> 6, c = o & 63;
    int p = c >> 4, m = c & 15;
    const unsigned short* Ae = Ab + e*264;
    const unsigned short* Be = Bb + e*264;
    int es = pmeta[p*4+1], ec = pmeta[p*4+2];
    float acc = 0.f;
    for (int t = 0; t < ec; t++) {
      int ij = entIJ[es+t];
      acc += entVal[es+t] * h2f(Ae[((ij&255)<<4)+m]) * h2f(Be[(((ij>>8)&255)<<4)+m]);
    }
    tp0[((size_t)(e0+e)<<6) + pmeta[p*4+0] + m] = f2h(acc);
  }
  const int rowb = (wave & 1) * 64;
  const int wc   = (wave >> 1) * 64;
  const int fr = lane & 15, fk = (lane >> 4) * 8;
  const int pairSel = fk >> 4;
  const int moff = fk & 15;
  const int nslab = Kdim >> 5;
  f32x4 acc[4][4] = {};

  const unsigned short* Ar0 = Ab + (rowb + fr)*264;
  const unsigned short* Br0 = Bb + (rowb + fr)*264;
  const unsigned short* Ar1 = Ab + (rowb + 16 + fr)*264;
  const unsigned short* Br1 = Bb + (rowb + 16 + fr)*264;
  const unsigned short* Ar2 = Ab + (rowb + 32 + fr)*264;
  const unsigned short* Br2 = Bb + (rowb + 32 + fr)*264;
  const unsigned short* Ar3 = Ab + (rowb + 48 + fr)*264;
  const unsigned short* Br3 = Bb + (rowb + 48 + fr)*264;

  const unsigned short* gp = Gtt + ((size_t)(wc + fr)) * 32 + fk;
  half8 b0 = *(const half8*)(gp);
  half8 b1 = *(const half8*)(gp + 512);
  half8 b2 = *(const half8*)(gp + 1024);
  half8 b3 = *(const half8*)(gp + 1536);
  half8 c0 = b0, c1 = b1, c2 = b2, c3 = b3;
  if (nslab > 1) {
    const unsigned short* g1 = gp + 8192;
    c0 = *(const half8*)(g1);
    c1 = *(const half8*)(g1 + 512);
    c2 = *(const half8*)(g1 + 1024);
    c3 = *(const half8*)(g1 + 1536);
  }
  int p0 = Ps[pairSel];
  int aoff = ((p0 & 255) << 4) + moff;
  int boff = (((p0 >> 8) & 255) << 4) + moff;
  half8 rA0 = *(const half8*)(Ar0 + aoff);
  half8 rB0 = *(const half8*)(Br0 + boff);
  half8 rA1 = *(const half8*)(Ar1 + aoff);
  half8 rB1 = *(const half8*)(Br1 + boff);
  half8 rA2 = *(const half8*)(Ar2 + aoff);
  half8 rB2 = *(const half8*)(Br2 + boff);
  half8 rA3 = *(const half8*)(Ar3 + aoff);
  half8 rB3 = *(const half8*)(Br3 + boff);

  for (int sl = 0; sl < nslab; sl++) {
    half8 a0 = rA0 * rB0;
    half8 a1 = rA1 * rB1;
    half8 a2 = rA2 * rB2;
    half8 a3 = rA3 * rB3;
    if (sl + 1 < nslab) {
      int pn = Ps[2*(sl + 1) + pairSel];
      int aoffn = ((pn & 255) << 4) + moff;
      int boffn = (((pn >> 8) & 255) << 4) + moff;
      rA0 = *(const half8*)(Ar0 + aoffn);
      rB0 = *(const half8*)(Br0 + boffn);
      rA1 = *(const half8*)(Ar1 + aoffn);
      rB1 = *(const half8*)(Br1 + boffn);
      rA2 = *(const half8*)(Ar2 + aoffn);
      rB2 = *(const half8*)(Br2 + boffn);
      rA3 = *(const half8*)(Ar3 + aoffn);
      rB3 = *(const half8*)(Br3 + boffn);
    }
    half8 d0, d1, d2, d3;
    if (sl + 2 < nslab) {
      const unsigned short* gn = gp + (size_t)(sl + 2) * 8192;
      d0 = *(const half8*)(gn);
      d1 = *(const half8*)(gn + 512);
      d2 = *(const half8*)(gn + 1024);
      d3 = *(const half8*)(gn + 1536);
    } else { d0 = c0; d1 = c1; d2 = c2; d3 = c3; }
    acc[0][0] = MFMA16(a0, b0, acc[0][0], 0, 0, 0);
    acc[1][0] = MFMA16(a1, b0, acc[1][0], 0, 0, 0);
    acc[2][0] = MFMA16(a2, b0, acc[2][0], 0, 0, 0);
    acc[3][0] = MFMA16(a3, b0, acc[3][0], 0, 0, 0);
    acc[0][1] = MFMA16(a0, b1, acc[0][1], 0, 0, 0);
    acc[1][1] = MFMA16(a1, b1, acc[1][1], 0, 0, 0);
    acc[2][1] = MFMA16(a2, b1, acc[2][1], 0, 0, 0);
    acc[3][1] = MFMA16(a3, b1, acc[3][1], 0, 0, 0);
    acc[0][2] = MFMA16(a0, b2, acc[0][2], 0, 0, 0);
    acc[1][2] = MFMA16(a1, b2, acc[1][2], 0, 0, 0);
    acc[2][2] = MFMA16(a2, b2, acc[2][2], 0, 0, 0);
    acc[3][2] = MFMA16(a3, b2, acc[3][2], 0, 0, 0);
    acc[0][3] = MFMA16(a0, b3, acc[0][3], 0, 0, 0);
    acc[1][3] = MFMA16(a1, b3, acc[1][3], 0, 0, 0);
    acc[2][3] = MFMA16(a2, b3, acc[2][3], 0, 0, 0);
    acc[3][3] = MFMA16(a3, b3, acc[3][3], 0, 0, 0);
    b0 = c0; b1 = c1; b2 = c2; b3 = c3;
    c0 = d0; c1 = d1; c2 = d2; c3 = d3;
  }
  const int r4 = (lane >> 4) << 2;
#pragma unroll
  for (int rg = 0; rg < 4; rg++) {
#pragma unroll
    for (int j = 0; j < 4; j++) {
#pragma unroll
      for (int r = 0; r < 4; r++) {
        int row = e0 + rowb + rg*16 + r4 + r;
        int col = wc + j*16 + fr;
        Vn[(size_t)row*256 + col] = f2h(acc[rg][j][r]);
      }
    }
  }
}

// ---- Gtt[slab][col][32] = coupling x Wv (fp16, tiled). col = kabs*16+d ----
__global__ void gbuild_k(const float* __restrict__ TD,
    const float* __restrict__ Wv1, const float* __restrict__ Wv2,
    const float* __restrict__ Wv3, const int* __restrict__ sl_origc,
    unsigned short* __restrict__ Gt, int Kdim, int npairs,
    int s1b, int s1e, int s2e, int s3e)
{
  int k = blockIdx.x*256 + threadIdx.x;
  if (k >= Kdim) return;
  int col = blockIdx.y;
  int pair = k >> 4, m = k & 15;
  int d = col & 15, kabs = col >> 4;
  float acc = 0.f;
  if (kabs > 0 && pair < npairs) {
    const float* Wv; int ss, se, kloc;
    if (kabs < 4)      { Wv = Wv1; ss = s1b; se = s1e; kloc = kabs - 1; }
    else if (kabs < 9) { Wv = Wv2; ss = s1e; se = s2e; kloc = kabs - 4; }
    else               { Wv = Wv3; ss = s2e; se = s3e; kloc = kabs - 9; }
    for (int slot = ss; slot < se; slot++)
      acc += TD[((pair*30) + (slot - 4))*8 + kloc] * Wv[(sl_origc[slot] + m)*16 + d];
    acc *= rsqrtf((float)(16*(se - ss)));
  }
  Gt[((size_t)((k >> 5)*256 + col))*32 + (k & 31)] = f2h(acc);
}

// ---- weight convert + transpose: Wt[n][k] = fp16(W[k][n]) ----
struct WDesc { const float* src; unsigned short* dst; int K; int lgN; };
struct WPack { WDesc d[10]; };
__global__ void wcvt_k(WPack p){
  WDesc d = p.d[blockIdx.y];
  int total = d.K << d.lgN;
  int gid = blockIdx.x*256 + threadIdx.x;
  if (gid >= total) return;
  int k = gid >> d.lgN, n = gid & ((1 << d.lgN) - 1);
  d.dst[(size_t)n*d.K + k] = f2h(d.src[gid]);
}

// ---- Wt01[n][k]: n<16 -> W0[k][n]; n>=16 -> W1[k][n-16] ----
__global__ void wcvt01_k(const float* __restrict__ W0, const float* __restrict__ W1,
                         unsigned short* __restrict__ dst){
  int gid = blockIdx.x*256 + threadIdx.x;    // 256*32 total
  int k = gid >> 5, n = gid & 31;
  float v = (n < 16) ? W0[k*16 + n] : W1[k*16 + (n - 16)];
  dst[(size_t)n*256 + k] = f2h(v);
}

// ---- hc[k] = sum_j W_h[k][j] * W_out[j] ----
__global__ void whc_k(const float* __restrict__ Wh, const float* __restrict__ Wout,
                      float* __restrict__ hc)
{
  int k = threadIdx.x;
  float s = 0.f;
#pragma unroll 16
  for (int j = 0; j < 128; j++) s += Wh[k*128 + j] * Wout[j];
  hc[k] = s;
}

// ---- out[e] = env[e] * dot(x16[e,:256], hc) / (16*sqrt(128)) ----
__global__ void final256_k(const unsigned short* __restrict__ X,
    const float* __restrict__ hc, const float* __restrict__ env,
    float* __restrict__ out)
{
  const int e = blockIdx.x*256 + threadIdx.x;
  float acc = 0.f;
#pragma unroll 16
  for (int k = 0; k < 256; k++) acc += h2f(X[((size_t)e<<8)+k])*hc[k];
  out[e] = env[e]*acc*0.0055242717280199023f;
}

// dense to 16 outputs, K=256, scale 1/16; A fp16 (layer-2 w2)
__global__ __launch_bounds__(256) void dense16_k(const unsigned short* __restrict__ A,
    const float* __restrict__ W, float* __restrict__ C)
{
  __shared__ float As[16*256];
  const int r0 = blockIdx.x << 4;
  const int tid = threadIdx.x;
  for (int i = tid; i < 16*256; i += 256)
    As[i] = h2f(A[((size_t)r0<<8) + i]);
  __syncthreads();
  const int r = tid >> 4, n = tid & 15;
  float acc = 0.f;
#pragma unroll 8
  for (int k = 0; k < 256; k++)
    acc += As[(r<<8)+k] * W[(k<<4)+n];
  C[((size_t)(r0+r)<<4)+n] = acc * 0.0625f;
}

__global__ void edge_init_k(const float* __restrict__ vectors, const int* __restrict__ senders,
    const int* __restrict__ receivers, const int* __restrict__ species,
    const float* __restrict__ emb, float* __restrict__ envb, float* __restrict__ Yb,
    float* __restrict__ x72)
{
  const int e = blockIdx.x*256 + threadIdx.x;
  float vx = vectors[e*3+0], vy = vectors[e*3+1], vz = vectors[e*3+2];
  float d = sqrtf(vx*vx+vy*vy+vz*vz);
  float dd = (d==0.f) ? 1.f : d;
  float invd = 1.f/dd;
  float x = vx*invd, y = vy*invd, z = vz*invd;
  float d2=d*d, d3=d2*d, d6=d3*d3, d7=d6*d, d8=d7*d;
  float envv = (d<1.f) ? (1.f - 28.f*d6 + 48.f*d7 - 21.f*d8) : 0.f;
  envb[e] = envv;
  float mask = (d==0.f)?0.f:1.f;
  const float SQ2 = 1.41421356237309515f;
  const float PIf = 3.14159265358979323846f;
  float* xr = x72 + (size_t)e*72;
#pragma unroll
  for (int n=1;n<=8;n++)
    xr[n-1] = SQ2 * sinf((float)n*PIf*dd)*invd*envv*mask;
  int sp_s = species[senders[e]], sp_r = species[receivers[e]];
  const float* es_ = emb + (size_t)sp_s*32;
  const float* er_ = emb + (size_t)sp_r*32;
#pragma unroll 8
  for (int k=0;k<32;k++){ xr[8+k] = es_[k]*mask; xr[40+k] = er_[k]*mask; }
  float x2=x*x, y2=y*y, z2=z*z;
  const float s3=1.7320508075688772f, s15=3.872983346207417f, s5=2.23606797749979f;
  const float s358=2.0916500663351889f, s105=10.246950765959598f;
  const float s218=1.6201851746019651f, s7=2.6457513110645907f;
  float* Yr = Yb + ((size_t)e<<4);
  Yr[0]=1.f;           Yr[1]=s3*y;          Yr[2]=s3*z;           Yr[3]=s3*x;
  Yr[4]=s15*x*y;       Yr[5]=s15*y*z;       Yr[6]=0.5f*s5*(3.f*z2-1.f);
  Yr[7]=s15*x*z;       Yr[8]=0.5f*s15*(x2-y2);
  Yr[9]=s358*y*(3.f*x2-y2);  Yr[10]=s105*x*y*z;  Yr[11]=s218*y*(5.f*z2-1.f);
  Yr[12]=0.5f*s7*(5.f*z2-3.f)*z;  Yr[13]=s218*x*(5.f*z2-1.f);
  Yr[14]=0.5f*s105*(x2-y2)*z;     Yr[15]=s358*x*(x2-y2);
}

// ---- sort-based node accumulation ----
__global__ void hist_k(const int* __restrict__ senders, int* cnt){
  int e = blockIdx.x*256 + threadIdx.x;
  atomicAdd(&cnt[senders[e]], 1);
}

__global__ void scan_k(const int* __restrict__ cnt, int* __restrict__ starts,
                       int* __restrict__ cursor){
  __shared__ int s[NNODES];
  const int tid = threadIdx.x;
  for (int i = tid; i < NNODES; i += 256) s[i] = cnt[i];
  __syncthreads();
  if (tid == 0) {
    int run = 0;
    for (int i = 0; i < NNODES; i++) { int c = s[i]; s[i] = run; run += c; }
  }
  __syncthreads();
  for (int i = tid; i < NNODES; i += 256) { starts[i] = s[i]; cursor[i] = s[i]; }
  if (tid == 0) starts[NNODES] = E_EDGES;
}

__global__ void perm_k(const int* __restrict__ senders, int* cursor,
                       int* __restrict__ perm){
  int e = blockIdx.x*256 + threadIdx.x;
  int pos = atomicAdd(&cursor[senders[e]], 1);
  perm[pos] = e;
}

// node[n][a*16+m] = sum_{e: senders[e]==n} w[e][m]*Y[e][a]; block per node.
__global__ __launch_bounds__(256) void nodesum_k(const float* __restrict__ w,
    const float* __restrict__ Y, const int* __restrict__ perm,
    const int* __restrict__ starts, float* __restrict__ node)
{
  __shared__ float buf[8*32];
  const int n = blockIdx.x;
  const int tid = threadIdx.x;
  const int s0 = starts[n], s1 = starts[n+1];
  const int a = tid >> 4, m = tid & 15;
  float acc = 0.f;
  for (int i = s0; i < s1; i += 8) {
    int nb = s1 - i; if (nb > 8) nb = 8;
    int slot = tid >> 5, comp = tid & 31;
    if (slot < nb) {
      int e = perm[i + slot];
      buf[slot*32 + comp] = (comp < 16) ? w[(e<<4)+comp] : Y[(e<<4)+comp-16];
    }
    __syncthreads();
    for (int q = 0; q < nb; q++)
      acc += buf[q*32 + m] * buf[q*32 + 16 + a];
    __syncthreads();
  }
  node[((size_t)n<<8) + tid] = acc;
}

// l3=0 TP standalone (layer 2); B = Vn fp16
__global__ void tp2_k(const float* __restrict__ node, const unsigned short* __restrict__ Vn,
    const int* __restrict__ senders, const float* __restrict__ varepsp,
    const int* __restrict__ pmeta, const int* __restrict__ entIJ,
    const float* __restrict__ entVal, unsigned short* __restrict__ tp0)
{
  const int gid = blockIdx.x*256 + threadIdx.x;
  const int e = gid >> 6, c = gid & 63;
  const int p = c >> 4, m = c & 15;
  float ve = varepsp[0];
  float eps = rsqrtf(1.f + ve*ve);
  int s = senders[e];
  const float* Am = &node[((size_t)s<<8)];
  const unsigned short* Bm = &Vn[((size_t)e<<8)];
  int es = pmeta[p*4+1], ec = pmeta[p*4+2];
  float acc = 0.f;
  for (int t=0;t<ec;t++){
    int ij = entIJ[es+t];
    acc += entVal[es+t] * Am[((ij&255)<<4) + m] * h2f(Bm[(((ij>>8)&255)<<4) + m]);
  }
  tp0[((size_t)e<<6) + pmeta[p*4+0] + m] = f2h(acc * eps);
}

// ============================ host launcher ============================

extern "C" void kernel_launch(void* const* d_in, const int* in_sizes, int n_in,
                              void* d_out, int out_size, void* d_ws, size_t ws_size,
                              hipStream_t stream)
{
  const float* vectors = (const float*)d_in[0];
  const float* vareps  = (const float*)d_in[1];
  const float* alpha   = (const float*)d_in[2];
  const float* emb     = (const float*)d_in[3];
  const float* W_tb1   = (const float*)d_in[4];
  const float* W_tb2   = (const float*)d_in[5];
  const float* W_tb3   = (const float*)d_in[6];
  const float* W_tb4   = (const float*)d_in[7];
  const float* W_w0    = (const float*)d_in[8];
  const float* W_w1    = (const float*)d_in[9];
  const float* W_l11   = (const float*)d_in[10];
  const float* W_l12   = (const float*)d_in[11];
  const float* W_l13   = (const float*)d_in[12];
  const float* W_v1    = (const float*)d_in[13];
  const float* W_v2    = (const float*)d_in[14];
  const float* W_v3    = (const float*)d_in[15];
  const float* W_w2    = (const float*)d_in[16];
  const float* W_l21   = (const float*)d_in[17];
  const float* W_l22   = (const float*)d_in[18];
  const float* W_l23   = (const float*)d_in[19];
  const float* W_h     = (const float*)d_in[20];
  const float* W_out   = (const float*)d_in[21];
  const int* senders   = (const int*)d_in[22];
  const int* receivers = (const int*)d_in[23];
  const int* species   = (const int*)d_in[24];

  static cgt::Tables tb;
  cgt::build(tb);
  const int Kdim = tb.npairs * 16;

  char* ws = (char*)d_ws;
  size_t off = 0;
  auto alloc = [&](size_t bytes)->void*{
    void* p = ws + off; off += (bytes + 255) & ~(size_t)255; return p;
  };
  float* t_val = (float*)alloc(sizeof(tb.val));
  int*   t_ij  = (int*)  alloc(sizeof(tb.ij));
  int*   t_pm  = (int*)  alloc(sizeof(tb.pmeta));
  float* t_td  = (float*)alloc(sizeof(tb.TD));
  int*   t_pr  = (int*)  alloc(sizeof(tb.pairs));
  int*   t_oc  = (int*)  alloc(sizeof(tb.sl_origc));
  float* envb  = (float*)alloc((size_t)E_EDGES*4);
  float* Yb    = (float*)alloc((size_t)E_EDGES*16*4);
  float* xb    = (float*)alloc((size_t)E_EDGES*256*4);
  float* Vb    = (float*)alloc((size_t)E_EDGES*256*4);
  float* bufA  = (float*)alloc((size_t)E_EDGES*72*4);
  float* wb    = (float*)alloc((size_t)E_EDGES*16*4);
  float* tp0b  = (float*)alloc((size_t)E_EDGES*64*4);
  float* nodeb = (float*)alloc((size_t)NNODES*256*4);
  float* hcb   = (float*)alloc(256*4);
  int* cntb    = (int*)alloc(NNODES*4);
  int* startsb = (int*)alloc((NNODES+1)*4);
  int* cursorb = (int*)alloc(NNODES*4);
  int* permb   = (int*)alloc(E_EDGES*4);
  unsigned short* Gt = (unsigned short*)alloc((size_t)256*Kdim*2);
  unsigned short* Wt_tb1 = (unsigned short*)alloc(32*72*2);
  unsigned short* Wt_tb2 = (unsigned short*)alloc(64*32*2);
  unsigned short* Wt_tb3 = (unsigned short*)alloc(128*64*2);
  unsigned short* Wt_tb4 = (unsigned short*)alloc(256*128*2);
  unsigned short* Wt_w01 = (unsigned short*)alloc(32*256*2);
  unsigned short* Wt_l11 = (unsigned short*)alloc(320*256*2);
  unsigned short* Wt_l12 = (unsigned short*)alloc(256*256*2);
  unsigned short* Wt_l13 = (unsigned short*)alloc(256*256*2);
  unsigned short* Wt_l21 = (unsigned short*)alloc(320*256*2);
  unsigned short* Wt_l22 = (unsigned short*)alloc(256*256*2);
  unsigned short* Wt_l23 = (unsigned short*)alloc(256*256*2);
  if (off > ws_size) {
    fprintf(stderr, "[allegro] workspace too small: need %zu, have %zu\n", off, ws_size);
    return;
  }
  unsigned short* xb16 = (unsigned short*)xb;
  unsigned short* tp016 = (unsigned short*)tp0b;
  unsigned short* V16 = (unsigned short*)Vb;

  hipMemcpyAsync(t_val, tb.val,     sizeof(tb.val),     hipMemcpyHostToDevice, stream);
  hipMemcpyAsync(t_ij,  tb.ij,      sizeof(tb.ij),      hipMemcpyHostToDevice, stream);
  hipMemcpyAsync(t_pm,  tb.pmeta,   sizeof(tb.pmeta),   hipMemcpyHostToDevice, stream);
  hipMemcpyAsync(t_td,  tb.TD,      sizeof(tb.TD),      hipMemcpyHostToDevice, stream);
  hipMemcpyAsync(t_pr,  tb.pairs,   sizeof(tb.pairs),   hipMemcpyHostToDevice, stream);
  hipMemcpyAsync(t_oc,  tb.sl_origc,sizeof(tb.sl_origc),hipMemcpyHostToDevice, stream);

  const int s1b = tb.l3np[0];
  const int s1e = s1b + tb.l3np[1];
  const int s2e = s1e + tb.l3np[2];
  const int s3e = s2e + tb.l3np[3];

  {
    dim3 g((Kdim + 255)/256, 256);
    gbuild_k<<<g, 256, 0, stream>>>(t_td, W_v1, W_v2, W_v3, t_oc, Gt, Kdim,
                                    tb.npairs, s1b, s1e, s2e, s3e);
  }
  {
    WPack p;
    p.d[0] = { W_tb1, Wt_tb1,  72, 5 };
    p.d[1] = { W_tb2, Wt_tb2,  32, 6 };
    p.d[2] = { W_tb3, Wt_tb3,  64, 7 };
    p.d[3] = { W_tb4, Wt_tb4, 128, 8 };
    p.d[4] = { W_l11, Wt_l11, 320, 8 };
    p.d[5] = { W_l12, Wt_l12, 256, 8 };
    p.d[6] = { W_l13, Wt_l13, 256, 8 };
    p.d[7] = { W_l21, Wt_l21, 320, 8 };
    p.d[8] = { W_l22, Wt_l22, 256, 8 };
    p.d[9] = { W_l23, Wt_l23, 256, 8 };
    dim3 g(320, 10);
    wcvt_k<<<g, 256, 0, stream>>>(p);
  }
  wcvt01_k<<<32, 256, 0, stream>>>(W_w0, W_w1, Wt_w01);
  whc_k<<<1, 256, 0, stream>>>(W_h, W_out, hcb);

  // edge->node sort (once; senders fixed for both layers)
  hipMemsetAsync(cntb, 0, NNODES*4, stream);
  hist_k<<<E_EDGES/256, 256, 0, stream>>>(senders, cntb);
  scan_k<<<1, 256, 0, stream>>>(cntb, startsb, cursorb);
  perm_k<<<E_EDGES/256, 256, 0, stream>>>(senders, cursorb, permb);

  // 1. edge features + Y + env  (x72 -> bufA fp32)
  edge_init_k<<<E_EDGES/256, 256, 0, stream>>>(vectors, senders, receivers, species,
                                               emb, envb, Yb, bufA);
  // 2+3. fused two-body MLP + w0/w1 + V init
  tb_fused_k<<<E_EDGES/64, 256, 0, stream>>>(bufA, Wt_tb1, Wt_tb2, Wt_tb3, Wt_tb4,
                                             Wt_w01, Yb, envb, xb16, V16, wb);

  // ---- layer 1 ----
  nodesum_k<<<NNODES, 256, 0, stream>>>(wb, Yb, permb, startsb, nodeb);
  vn_k<<<E_EDGES/VN_E, 512, 0, stream>>>(nodeb, V16, senders, vareps, t_pr, Gt,
                                         V16, Kdim, t_pm, t_ij, t_val, tp016);
  mlp3_k<<<E_EDGES/64, 256, 0, stream>>>(xb16, tp016, Wt_l11, Wt_l12, Wt_l13,
                                         xb16, envb, alpha);

  // ---- layer 2 (lmax_out = 0) ----
  dense16_k<<<E_EDGES/16, 256, 0, stream>>>(xb16, W_w2, wb);
  nodesum_k<<<NNODES, 256, 0, stream>>>(wb, Yb, permb, startsb, nodeb);
  tp2_k<<<E_EDGES*64/256, 256, 0, stream>>>(nodeb, V16, senders, vareps, t_pm, t_ij,
                                            t_val, tp016);
  mlp3_k<<<E_EDGES/64, 256, 0, stream>>>(xb16, tp016, Wt_l21, Wt_l22, Wt_l23,
                                         xb16, envb, alpha);

  // ---- head (W_h @ W_out precombined) ----
  final256_k<<<E_EDGES/256, 256, 0, stream>>>(xb16, hcb, envb, (float*)d_out);
}

// Round 17
// 401.940 us; speedup vs baseline: 1.4565x; 1.0152x over previous
//
#include <hip/hip_runtime.h>
#include <cmath>
#include <complex>
#include <cstdio>
#include <cstring>
#include <algorithm>

#define E_EDGES 32768
#define NNODES  2048
#define VN_E    128

// ============================ host-side CG tables ============================
namespace cgt {

static double fct(int n){
  static const double f[13] = {1.,1.,2.,6.,24.,120.,720.,5040.,40320.,362880.,
                               3628800.,39916800.,479001600.};
  return f[n];
}

static double cg(int j1,int m1,int j2,int m2,int j3,int m3){
  if (m1+m2 != m3) return 0.0;
  double pre = std::sqrt((2*j3+1)*fct(j1+j2-j3)*fct(j1-j2+j3)*fct(-j1+j2+j3)/fct(j1+j2+j3+1));
  pre *= std::sqrt(fct(j3+m3)*fct(j3-m3)*fct(j1-m1)*fct(j1+m1)*fct(j2-m2)*fct(j2+m2));
  int kmin = 0;
  if (j2-j3-m1 > kmin) kmin = j2-j3-m1;
  if (j1-j3+m2 > kmin) kmin = j1-j3+m2;
  int kmax = j1+j2-j3;
  if (j1-m1 < kmax) kmax = j1-m1;
  if (j2+m2 < kmax) kmax = j2+m2;
  double s = 0.0;
  for (int k=kmin;k<=kmax;k++){
    double d = fct(k)*fct(j1+j2-j3-k)*fct(j1-m1-k)*fct(j2+m2-k)*fct(j3-j2+m1+k)*fct(j3-j1-m2+k);
    s += ((k&1)? -1.0:1.0)/d;
  }
  return pre*s;
}

typedef std::complex<double> cd;

static void umat(int l, cd U[7][7]){
  for (int a=0;a<7;a++) for (int b=0;b<7;b++) U[a][b]=cd(0,0);
  U[l][l] = cd(1,0);
  double s2 = 1.0/std::sqrt(2.0);
  for (int m=1;m<=l;m++){
    double sg = (m&1)? -1.0 : 1.0;
    U[l+m][l-m] = cd(s2,0);
    U[l+m][l+m] = cd(sg*s2,0);
    U[l-m][l-m] = cd(0, s2);
    U[l-m][l+m] = cd(0, -sg*s2);
  }
}

static bool realCoupling(int l1,int l2,int l3, double T[7][7][7]){
  cd U1[7][7],U2[7][7],U3[7][7];
  umat(l1,U1); umat(l2,U2); umat(l3,U3);
  int n1=2*l1+1, n2=2*l2+1, n3=2*l3+1;
  double Cg[7][7][7];
  for (int m=0;m<n1;m++) for(int n=0;n<n2;n++) for(int k=0;k<n3;k++)
    Cg[m][n][k] = cg(l1,m-l1,l2,n-l2,l3,k-l3);
  double Tr[7][7][7], Ti[7][7][7];
  double nr=0, ni=0;
  for (int a=0;a<n1;a++) for(int b=0;b<n2;b++) for(int c=0;c<n3;c++){
    cd s(0,0);
    for (int m=0;m<n1;m++){
      if (U1[a][m]==cd(0,0)) continue;
      for (int n=0;n<n2;n++){
        if (U2[b][n]==cd(0,0)) continue;
        for (int k=0;k<n3;k++){
          double cgv = Cg[m][n][k];
          if (cgv==0.0) continue;
          s += U1[a][m]*U2[b][n]*std::conj(U3[c][k])*cgv;
        }
      }
    }
    Tr[a][b][c]=s.real(); Ti[a][b][c]=s.imag();
    nr += s.real()*s.real(); ni += s.imag()*s.imag();
  }
  bool useR = (nr >= ni);
  double nn = std::sqrt(useR? nr : ni);
  if (nn < 1e-8) return false;
  for (int a=0;a<n1;a++)for(int b=0;b<n2;b++)for(int c=0;c<n3;c++)
    T[a][b][c] = (useR? Tr[a][b][c] : Ti[a][b][c])/nn;
  return true;
}

struct Tables {
  float val[4096];
  int   ij[4096];
  int   pmeta[40*4];
  int   ccnt[40*8];
  int   l3base[4];
  int   l3np[4];
  int   npaths;
  int   nent;
  int   tptot;
  int   pairs[256];
  float TD[256*30*8];
  int   sl_origc[40];
  int   npairs;
};

struct PathTmp {
  int l1,l2,l3, tpoff, kd;
  int ec;
  double T[7][7][7];
};

static void build(Tables& tb){
  static PathTmp paths[40];
  int np = 0, tpoff = 0;
  int l3start[5];
  for (int l3=0;l3<=3;l3++){
    tb.l3base[l3] = tpoff;
    l3start[l3] = np;
    int kd = 2*l3+1;
    for (int l1=0;l1<=3;l1++) for (int l2=0;l2<=3;l2++){
      int lo = (l1>l2)? l1-l2 : l2-l1;
      int hi = std::min(l1+l2,3);
      if (l3 < lo || l3 > hi) continue;
      PathTmp& pt = paths[np];
      if (!realCoupling(l1,l2,l3,pt.T)) continue;
      pt.l1=l1; pt.l2=l2; pt.l3=l3; pt.kd=kd; pt.tpoff=tpoff;
      double scale = std::sqrt((double)kd);
      int cnt = 0;
      for (int a=0;a<2*l1+1;a++)for(int b=0;b<2*l2+1;b++)for(int c=0;c<kd;c++)
        if (std::fabs(pt.T[a][b][c]*scale) > 1e-7) cnt++;
      pt.ec = cnt;
      tpoff += 16*kd;
      np++;
    }
  }
  l3start[4] = np;
  for (int l3=0;l3<=3;l3++) tb.l3np[l3] = l3start[l3+1]-l3start[l3];
  static int order[40];
  for (int i=0;i<np;i++) order[i]=i;
  for (int l3=0;l3<=3;l3++)
    std::sort(order+l3start[l3], order+l3start[l3+1],
              [&](int a,int b){ return paths[a].ec > paths[b].ec; });
  std::memset(tb.TD, 0, sizeof(tb.TD));
  std::memset(tb.pairs, 0, sizeof(tb.pairs));
  static int pmap[16][16];
  for (int i=0;i<16;i++) for (int j=0;j<16;j++) pmap[i][j] = -1;
  int npr = 0;
  int ep = 0;
  for (int slot=0; slot<np; slot++){
    const PathTmp& pt = paths[order[slot]];
    double scale = std::sqrt((double)pt.kd);
    int s1 = pt.l1*pt.l1, s2 = pt.l2*pt.l2;
    tb.pmeta[slot*4+0] = pt.tpoff;
    tb.pmeta[slot*4+1] = ep;
    tb.sl_origc[slot] = ((pt.tpoff - tb.l3base[pt.l3]) / (16*pt.kd)) * 16;
    int tot = 0;
    for (int c=0;c<pt.kd;c++){
      int cnt = 0;
      for (int a=0;a<2*pt.l1+1;a++)for(int b=0;b<2*pt.l2+1;b++){
        double v = pt.T[a][b][c]*scale;
        if (std::fabs(v) > 1e-7){
          tb.val[ep] = (float)v;
          tb.ij[ep]  = (s1+a) | ((s2+b)<<8);
          ep++; cnt++;
          if (pt.l3 >= 1){
            int aa = s1+a, bb = s2+b;
            int pi = pmap[aa][bb];
            if (pi < 0){ pi = npr; pmap[aa][bb] = pi;
                         tb.pairs[npr] = aa | (bb<<8); npr++; }
            tb.TD[(pi*30 + (slot-4))*8 + c] = (float)v;
          }
        }
      }
      tb.ccnt[slot*8+c] = cnt;
      tot += cnt;
    }
    for (int c=pt.kd;c<8;c++) tb.ccnt[slot*8+c]=0;
    tb.pmeta[slot*4+2] = tot;
    tb.pmeta[slot*4+3] = pt.kd;
  }
  if (npr & 1){ tb.pairs[npr] = 0; npr++; }
  tb.npairs = npr;
  tb.npaths = np; tb.nent = ep; tb.tptot = tpoff;
}

} // namespace cgt

// ============================ device kernels ============================
// LAYOUT: node/V/Vn rows are [a][m]. MFMA-path activations fp16 in HBM.

typedef _Float16 half8 __attribute__((ext_vector_type(8)));
typedef __attribute__((ext_vector_type(4))) float f32x4;

__device__ inline unsigned short f2h(float f){
  union { _Float16 h; unsigned short u; } x;
  x.h = (_Float16)f;
  return x.u;
}
__device__ inline float h2f(unsigned short u){
  union { _Float16 h; unsigned short u; } x; x.u = u;
  return (float)x.h;
}

__device__ inline int swz(int row, int kh){
  int b = row*64 + kh*2;
  return b ^ (((row >> 1) & 3) << 4);
}

__device__ inline float silu(float v){ return v/(1.f+__expf(-v)); }

#define MFMA16 __builtin_amdgcn_mfma_f32_16x16x32_f16

// ---- fused two-body chain (R16): x72 ->32->64->128->256, + [w0|w1], + V ----
// Per 64-edge block: all intermediates in LDS ping-pong (HsA/HsB); writes
// Xout (fp16), wb (w1, fp32), V (fp16, [a][m]). Replaces 2x fp32 gemm +
// 2x mgemm + dense16v (5 launches, ~59MB HBM round-trips).
__global__ __launch_bounds__(256) void tb_fused_k(
    const float* __restrict__ X72, const unsigned short* __restrict__ Wt1,
    const unsigned short* __restrict__ Wt2, const unsigned short* __restrict__ Wt3,
    const unsigned short* __restrict__ Wt4, const unsigned short* __restrict__ Wt01,
    const float* __restrict__ Yb, const float* __restrict__ envb,
    unsigned short* __restrict__ Xout, unsigned short* __restrict__ V,
    float* __restrict__ wb)
{
  __shared__ unsigned short AsB[64*32];     // 4 KB
  __shared__ unsigned short BsB[256*32];    // 16 KB
  __shared__ unsigned short HsA[64*264];    // 33.8 KB
  __shared__ unsigned short HsB[64*264];    // 33.8 KB
  __shared__ float w0s[64*16];              // 4 KB
  const int tid  = threadIdx.x;
  const int wave = tid >> 6, lane = tid & 63;
  const int bm = blockIdx.x*64;
  const int mrow = wave*16;                 // wave's 16-row stripe
  const int fr = lane & 15, fk = (lane >> 4) * 8;
  const int r4 = (lane >> 4) << 2;
  const int sra = tid >> 2, ska = (tid & 3) * 8;
  const int srb = tid >> 1, skb = (tid & 1) * 16;

  // ---- stage 1: h = silu(x72 @ W1 / sqrt(72)), N=32, K=72 (pad 96) ----
  {
    f32x4 acc[2] = {};
    for (int k0 = 0; k0 < 96; k0 += 32) {
      {
        unsigned short u[8];
        int rowg = bm + sra;
#pragma unroll
        for (int q = 0; q < 8; q++) {
          int k = k0 + ska + q;
          u[q] = (k < 72) ? f2h(X72[(size_t)rowg*72 + k]) : (unsigned short)0;
        }
        *(ushort4*)((char*)AsB + swz(sra, ska))     = *(ushort4*)&u[0];
        *(ushort4*)((char*)AsB + swz(sra, ska + 4)) = *(ushort4*)&u[4];
      }
      if (tid < 64) {
        int n = tid >> 1, kb = (tid & 1) * 16;
        unsigned short u[16];
#pragma unroll
        for (int q = 0; q < 16; q++) {
          int k = k0 + kb + q;
          u[q] = (k < 72) ? Wt1[n*72 + k] : (unsigned short)0;
        }
        *(uint4*)((char*)BsB + swz(n, kb))     = *(uint4*)&u[0];
        *(uint4*)((char*)BsB + swz(n, kb + 8)) = *(uint4*)&u[8];
      }
      __syncthreads();
      half8 af = *(half8*)((char*)AsB + swz(mrow + fr, fk));
      half8 b0 = *(half8*)((char*)BsB + swz(fr, fk));
      half8 b1 = *(half8*)((char*)BsB + swz(16 + fr, fk));
      acc[0] = MFMA16(af, b0, acc[0], 0, 0, 0);
      acc[1] = MFMA16(af, b1, acc[1], 0, 0, 0);
      __syncthreads();
    }
    const float rs = 0.11785113019775793f;   // 1/sqrt(72)
#pragma unroll
    for (int j = 0; j < 2; j++)
#pragma unroll
      for (int r = 0; r < 4; r++) {
        int row = mrow + r4 + r;
        HsA[row*264 + j*16 + fr] = f2h(silu(acc[j][r]*rs));
      }
    __syncthreads();
  }

  // ---- stage 2: h = silu(h @ W2 / sqrt(32)), N=64, K=32 ----
  {
    f32x4 acc[4] = {};
    if (tid < 128) {
      int n = tid >> 1, kb = (tid & 1) * 16;
      const unsigned short* s = Wt2 + n*32 + kb;
      uint4 u0 = *(const uint4*)s;
      uint4 u1 = *(const uint4*)(s + 8);
      *(uint4*)((char*)BsB + swz(n, kb))     = u0;
      *(uint4*)((char*)BsB + swz(n, kb + 8)) = u1;
    }
    __syncthreads();
    half8 af = *(half8*)(HsA + (mrow + fr)*264 + fk);
#pragma unroll
    for (int j = 0; j < 4; j++) {
      half8 bf = *(half8*)((char*)BsB + swz(j*16 + fr, fk));
      acc[j] = MFMA16(af, bf, acc[j], 0, 0, 0);
    }
    __syncthreads();
    const float rs = 0.17677669529663687f;   // 1/sqrt(32)
#pragma unroll
    for (int j = 0; j < 4; j++)
#pragma unroll
      for (int r = 0; r < 4; r++) {
        int row = mrow + r4 + r;
        HsB[row*264 + j*16 + fr] = f2h(silu(acc[j][r]*rs));
      }
    __syncthreads();
  }

  // ---- stage 3: h = silu(h @ W3 / 8), N=128, K=64 ----
  {
    f32x4 acc[8] = {};
    for (int k0 = 0; k0 < 64; k0 += 32) {
      {
        int n = srb, kb = skb;    // 128 rows x 32 k
        const unsigned short* s = Wt3 + n*64 + k0 + kb;
        uint4 u0 = *(const uint4*)s;
        uint4 u1 = *(const uint4*)(s + 8);
        *(uint4*)((char*)BsB + swz(n, kb))     = u0;
        *(uint4*)((char*)BsB + swz(n, kb + 8)) = u1;
      }
      __syncthreads();
      half8 af = *(half8*)(HsB + (mrow + fr)*264 + k0 + fk);
#pragma unroll
      for (int j = 0; j < 8; j++) {
        half8 bf = *(half8*)((char*)BsB + swz(j*16 + fr, fk));
        acc[j] = MFMA16(af, bf, acc[j], 0, 0, 0);
      }
      __syncthreads();
    }
    const float rs = 0.125f;   // 1/sqrt(64)
#pragma unroll
    for (int j = 0; j < 8; j++)
#pragma unroll
      for (int r = 0; r < 4; r++) {
        int row = mrow + r4 + r;
        HsA[row*264 + j*16 + fr] = f2h(silu(acc[j][r]*rs));
      }
    __syncthreads();
  }

  // ---- stage 4: x = env * (h @ W4 / sqrt(128)), N=256, K=128 ----
  {
    f32x4 acc[16] = {};
    for (int k0 = 0; k0 < 128; k0 += 32) {
#pragma unroll
      for (int h = 0; h < 2; h++) {
        int n = h*128 + srb;
        const unsigned short* s = Wt4 + (size_t)n*128 + k0 + skb;
        uint4 u0 = *(const uint4*)s;
        uint4 u1 = *(const uint4*)(s + 8);
        *(uint4*)((char*)BsB + swz(n, skb))     = u0;
        *(uint4*)((char*)BsB + swz(n, skb + 8)) = u1;
      }
      __syncthreads();
      half8 af = *(half8*)(HsA + (mrow + fr)*264 + k0 + fk);
#pragma unroll
      for (int j = 0; j < 16; j++) {
        half8 bf = *(half8*)((char*)BsB + swz(j*16 + fr, fk));
        acc[j] = MFMA16(af, bf, acc[j], 0, 0, 0);
      }
      __syncthreads();
    }
    const float rs = 0.08838834764831845f;   // 1/sqrt(128)
#pragma unroll
    for (int j = 0; j < 16; j++)
#pragma unroll
      for (int r = 0; r < 4; r++) {
        int row = mrow + r4 + r;
        float v = acc[j][r]*rs*envb[bm + row];
        unsigned short hv = f2h(v);
        HsB[row*264 + j*16 + fr] = hv;
        Xout[((size_t)(bm + row))*256 + j*16 + fr] = hv;
      }
    __syncthreads();
  }

  // ---- stage 5: [w0|w1] = x @ [W0|W1] / 16, N=32, K=256 ----
  {
    f32x4 acc[2] = {};
    for (int k0 = 0; k0 < 256; k0 += 32) {
      if (tid < 64) {
        int n = tid >> 1, kb = (tid & 1) * 16;
        const unsigned short* s = Wt01 + (size_t)n*256 + k0 + kb;
        uint4 u0 = *(const uint4*)s;
        uint4 u1 = *(const uint4*)(s + 8);
        *(uint4*)((char*)BsB + swz(n, kb))     = u0;
        *(uint4*)((char*)BsB + swz(n, kb + 8)) = u1;
      }
      __syncthreads();
      half8 af = *(half8*)(HsB + (mrow + fr)*264 + k0 + fk);
      half8 b0 = *(half8*)((char*)BsB + swz(fr, fk));
      half8 b1 = *(half8*)((char*)BsB + swz(16 + fr, fk));
      acc[0] = MFMA16(af, b0, acc[0], 0, 0, 0);
      acc[1] = MFMA16(af, b1, acc[1], 0, 0, 0);
      __syncthreads();
    }
#pragma unroll
    for (int r = 0; r < 4; r++) {
      int row = mrow + r4 + r;
      w0s[row*16 + fr] = acc[0][r]*0.0625f;
      wb[((size_t)(bm + row))*16 + fr] = acc[1][r]*0.0625f;
    }
    __syncthreads();
  }

  // ---- V init: V[e][a*16+m] = w0[e][m] * Y[e][a] ----
  for (int i = tid; i < 64*256; i += 256) {
    int e = i >> 8, idx = i & 255;
    V[(((size_t)(bm + e)) << 8) + idx] =
        f2h(w0s[e*16 + (idx & 15)] * Yb[(bm + e)*16 + (idx >> 4)]);
  }
}

// ---- fused 3-layer latent MLP ----
__global__ __launch_bounds__(256) void mlp3_k(
    const unsigned short* __restrict__ X, const unsigned short* __restrict__ T0,
    const unsigned short* __restrict__ W1t, const unsigned short* __restrict__ W2t,
    const unsigned short* __restrict__ W3t, unsigned short* __restrict__ Out,
    const float* __restrict__ env, const float* __restrict__ alphap)
{
  __shared__ unsigned short AsB[64*32];
  __shared__ unsigned short BsB[256*32];
  __shared__ unsigned short Hs[64*264];
  const int tid  = threadIdx.x;
  const int wave = tid >> 6, lane = tid & 63;
  const int bm = blockIdx.x*64;
  const int wc = wave*64;
  const int fr = lane & 15, fk = (lane >> 4) * 8;
  const int r4 = (lane >> 4) << 2;
  const int sra = tid >> 2;
  const int ska = (tid & 3) * 8;
  const int srb = tid >> 1;
  const int skb = (tid & 1) * 16;
  f32x4 acc[4][4] = {};

  for (int k0 = 0; k0 < 320; k0 += 32) {
    {
      int kk = k0 + ska;
      const unsigned short* ap = (kk < 256)
        ? X  + (size_t)(bm + sra)*256 + kk
        : T0 + (size_t)(bm + sra)*64  + (kk - 256);
      uint4 u = *(const uint4*)ap;
      *(uint4*)((char*)AsB + swz(sra, ska)) = u;
    }
#pragma unroll
    for (int h = 0; h < 2; h++) {
      int n = h*128 + srb;
      const unsigned short* s = W1t + (size_t)n*320 + k0 + skb;
      uint4 u0 = *(const uint4*)s;
      uint4 u1 = *(const uint4*)(s + 8);
      *(uint4*)((char*)BsB + swz(n, skb))     = u0;
      *(uint4*)((char*)BsB + swz(n, skb + 8)) = u1;
    }
    __syncthreads();
    half8 af[4], bf[4];
#pragma unroll
    for (int i = 0; i < 4; i++)
      af[i] = *(half8*)((char*)AsB + swz(i*16 + fr, fk));
#pragma unroll
    for (int j = 0; j < 4; j++)
      bf[j] = *(half8*)((char*)BsB + swz(wc + j*16 + fr, fk));
#pragma unroll
    for (int i = 0; i < 4; i++)
#pragma unroll
      for (int j = 0; j < 4; j++)
        acc[i][j] = MFMA16(af[i], bf[j], acc[i][j], 0, 0, 0);
    __syncthreads();
  }
  const float rs320 = 0.055901699437494740f;
#pragma unroll
  for (int i = 0; i < 4; i++)
#pragma unroll
    for (int r = 0; r < 4; r++) {
      int row = i*16 + r4 + r;
#pragma unroll
      for (int j = 0; j < 4; j++) {
        int col = wc + j*16 + fr;
        Hs[row*264 + col] = f2h(silu(acc[i][j][r]*rs320));
        acc[i][j][r] = 0.f;
      }
    }
  __syncthreads();

  for (int k0 = 0; k0 < 256; k0 += 32) {
#pragma unroll
    for (int h = 0; h < 2; h++) {
      int n = h*128 + srb;
      const unsigned short* s = W2t + (size_t)n*256 + k0 + skb;
      uint4 u0 = *(const uint4*)s;
      uint4 u1 = *(const uint4*)(s + 8);
      *(uint4*)((char*)BsB + swz(n, skb))     = u0;
      *(uint4*)((char*)BsB + swz(n, skb + 8)) = u1;
    }
    __syncthreads();
    half8 af[4], bf[4];
#pragma unroll
    for (int i = 0; i < 4; i++)
      af[i] = *(half8*)(Hs + (i*16 + fr)*264 + k0 + fk);
#pragma unroll
    for (int j = 0; j < 4; j++)
      bf[j] = *(half8*)((char*)BsB + swz(wc + j*16 + fr, fk));
#pragma unroll
    for (int i = 0; i < 4; i++)
#pragma unroll
      for (int j = 0; j < 4; j++)
        acc[i][j] = MFMA16(af[i], bf[j], acc[i][j], 0, 0, 0);
    __syncthreads();
  }
#pragma unroll
  for (int i = 0; i < 4; i++)
#pragma unroll
    for (int r = 0; r < 4; r++) {
      int row = i*16 + r4 + r;
#pragma unroll
      for (int j = 0; j < 4; j++) {
        int col = wc + j*16 + fr;
        Hs[row*264 + col] = f2h(silu(acc[i][j][r]*0.0625f));
        acc[i][j][r] = 0.f;
      }
    }
  __syncthreads();

  for (int k0 = 0; k0 < 256; k0 += 32) {
#pragma unroll
    for (int h = 0; h < 2; h++) {
      int n = h*128 + srb;
      const unsigned short* s = W3t + (size_t)n*256 + k0 + skb;
      uint4 u0 = *(const uint4*)s;
      uint4 u1 = *(const uint4*)(s + 8);
      *(uint4*)((char*)BsB + swz(n, skb))     = u0;
      *(uint4*)((char*)BsB + swz(n, skb + 8)) = u1;
    }
    __syncthreads();
    half8 af[4], bf[4];
#pragma unroll
    for (int i = 0; i < 4; i++)
      af[i] = *(half8*)(Hs + (i*16 + fr)*264 + k0 + fk);
#pragma unroll
    for (int j = 0; j < 4; j++)
      bf[j] = *(half8*)((char*)BsB + swz(wc + j*16 + fr, fk));
#pragma unroll
    for (int i = 0; i < 4; i++)
#pragma unroll
      for (int j = 0; j < 4; j++)
        acc[i][j] = MFMA16(af[i], bf[j], acc[i][j], 0, 0, 0);
    __syncthreads();
  }
  float al = alphap[0];
  float a2 = al*al, inv1a2 = 1.f/(1.f+a2);
#pragma unroll
  for (int i = 0; i < 4; i++)
#pragma unroll
    for (int r = 0; r < 4; r++) {
      int row = bm + i*16 + r4 + r;
      float ev = env[row];
#pragma unroll
      for (int j = 0; j < 4; j++) {
        int col = wc + j*16 + fr;
        float v = acc[i][j][r]*0.0625f*ev;
        v = (h2f(X[(size_t)row*256+col]) + a2*v)*inv1a2;
        Out[(size_t)row*256+col] = f2h(v);
      }
    }
}

// ---- fused Vn kernel + layer-1 tp0 ----
__global__ __launch_bounds__(512) void vn_k(
    const float* __restrict__ node, const unsigned short* __restrict__ V,
    const int* __restrict__ senders, const float* __restrict__ varepsp,
    const int* __restrict__ pairsG, const unsigned short* __restrict__ Gtt,
    unsigned short* __restrict__ Vn, int Kdim,
    const int* __restrict__ pmeta, const int* __restrict__ entIJ,
    const float* __restrict__ entVal, unsigned short* __restrict__ tp0)
{
  __shared__ unsigned short Ab[VN_E*264];
  __shared__ unsigned short Bb[VN_E*264];
  __shared__ int Ps[256];
  const int tid = threadIdx.x;
  const int e0 = blockIdx.x * VN_E;
  const int wave = tid >> 6, lane = tid & 63;
  float ve = varepsp[0];
  float eps = rsqrtf(1.f + ve*ve);
  if (tid < 256) Ps[tid] = pairsG[tid];
#pragma unroll
  for (int rr = 0; rr < 16; rr++) {
    int row = wave*16 + rr;
    int s = senders[e0 + row];
    float4 fa = *(const float4*)(node + ((size_t)s << 8) + 4*lane);
    uint2 ub = *(const uint2*)(V + (((size_t)(e0 + row)) << 8) + 4*lane);
    unsigned short* ad = Ab + row*264 + 4*lane;
    unsigned short* bd = Bb + row*264 + 4*lane;
    uint2 ua;
    ua.x = (unsigned)f2h(fa.x*eps) | ((unsigned)f2h(fa.y*eps) << 16);
    ua.y = (unsigned)f2h(fa.z*eps) | ((unsigned)f2h(fa.w*eps) << 16);
    *(uint2*)ad = ua;
    *(uint2*)bd = ub;
  }
  __syncthreads();
  for (int o = tid; o < VN_E*64; o += 512) {
    int e = o >> 6, c = o & 63;
    int p = c >> 4, m = c & 15;
    const unsigned short* Ae = Ab + e*264;
    const unsigned short* Be = Bb + e*264;
    int es = pmeta[p*4+1], ec = pmeta[p*4+2];
    float acc = 0.f;
    for (int t = 0; t < ec; t++) {
      int ij = entIJ[es+t];
      acc += entVal[es+t] * h2f(Ae[((ij&255)<<4)+m]) * h2f(Be[(((ij>>8)&255)<<4)+m]);
    }
    tp0[((size_t)(e0+e)<<6) + pmeta[p*4+0] + m] = f2h(acc);
  }
  const int rowb = (wave & 1) * 64;
  const int wc   = (wave >> 1) * 64;
  const int fr = lane & 15, fk = (lane >> 4) * 8;
  const int pairSel = fk >> 4;
  const int moff = fk & 15;
  const int nslab = Kdim >> 5;
  f32x4 acc[4][4] = {};

  const unsigned short* Ar0 = Ab + (rowb + fr)*264;
  const unsigned short* Br0 = Bb + (rowb + fr)*264;
  const unsigned short* Ar1 = Ab + (rowb + 16 + fr)*264;
  const unsigned short* Br1 = Bb + (rowb + 16 + fr)*264;
  const unsigned short* Ar2 = Ab + (rowb + 32 + fr)*264;
  const unsigned short* Br2 = Bb + (rowb + 32 + fr)*264;
  const unsigned short* Ar3 = Ab + (rowb + 48 + fr)*264;
  const unsigned short* Br3 = Bb + (rowb + 48 + fr)*264;

  const unsigned short* gp = Gtt + ((size_t)(wc + fr)) * 32 + fk;
  half8 b0 = *(const half8*)(gp);
  half8 b1 = *(const half8*)(gp + 512);
  half8 b2 = *(const half8*)(gp + 1024);
  half8 b3 = *(const half8*)(gp + 1536);
  half8 c0 = b0, c1 = b1, c2 = b2, c3 = b3;
  if (nslab > 1) {
    const unsigned short* g1 = gp + 8192;
    c0 = *(const half8*)(g1);
    c1 = *(const half8*)(g1 + 512);
    c2 = *(const half8*)(g1 + 1024);
    c3 = *(const half8*)(g1 + 1536);
  }
  int p0 = Ps[pairSel];
  int aoff = ((p0 & 255) << 4) + moff;
  int boff = (((p0 >> 8) & 255) << 4) + moff;
  half8 rA0 = *(const half8*)(Ar0 + aoff);
  half8 rB0 = *(const half8*)(Br0 + boff);
  half8 rA1 = *(const half8*)(Ar1 + aoff);
  half8 rB1 = *(const half8*)(Br1 + boff);
  half8 rA2 = *(const half8*)(Ar2 + aoff);
  half8 rB2 = *(const half8*)(Br2 + boff);
  half8 rA3 = *(const half8*)(Ar3 + aoff);
  half8 rB3 = *(const half8*)(Br3 + boff);

  for (int sl = 0; sl < nslab; sl++) {
    half8 a0 = rA0 * rB0;
    half8 a1 = rA1 * rB1;
    half8 a2 = rA2 * rB2;
    half8 a3 = rA3 * rB3;
    if (sl + 1 < nslab) {
      int pn = Ps[2*(sl + 1) + pairSel];
      int aoffn = ((pn & 255) << 4) + moff;
      int boffn = (((pn >> 8) & 255) << 4) + moff;
      rA0 = *(const half8*)(Ar0 + aoffn);
      rB0 = *(const half8*)(Br0 + boffn);
      rA1 = *(const half8*)(Ar1 + aoffn);
      rB1 = *(const half8*)(Br1 + boffn);
      rA2 = *(const half8*)(Ar2 + aoffn);
      rB2 = *(const half8*)(Br2 + boffn);
      rA3 = *(const half8*)(Ar3 + aoffn);
      rB3 = *(const half8*)(Br3 + boffn);
    }
    half8 d0, d1, d2, d3;
    if (sl + 2 < nslab) {
      const unsigned short* gn = gp + (size_t)(sl + 2) * 8192;
      d0 = *(const half8*)(gn);
      d1 = *(const half8*)(gn + 512);
      d2 = *(const half8*)(gn + 1024);
      d3 = *(const half8*)(gn + 1536);
    } else { d0 = c0; d1 = c1; d2 = c2; d3 = c3; }
    acc[0][0] = MFMA16(a0, b0, acc[0][0], 0, 0, 0);
    acc[1][0] = MFMA16(a1, b0, acc[1][0], 0, 0, 0);
    acc[2][0] = MFMA16(a2, b0, acc[2][0], 0, 0, 0);
    acc[3][0] = MFMA16(a3, b0, acc[3][0], 0, 0, 0);
    acc[0][1] = MFMA16(a0, b1, acc[0][1], 0, 0, 0);
    acc[1][1] = MFMA16(a1, b1, acc[1][1], 0, 0, 0);
    acc[2][1] = MFMA16(a2, b1, acc[2][1], 0, 0, 0);
    acc[3][1] = MFMA16(a3, b1, acc[3][1], 0, 0, 0);
    acc[0][2] = MFMA16(a0, b2, acc[0][2], 0, 0, 0);
    acc[1][2] = MFMA16(a1, b2, acc[1][2], 0, 0, 0);
    acc[2][2] = MFMA16(a2, b2, acc[2][2], 0, 0, 0);
    acc[3][2] = MFMA16(a3, b2, acc[3][2], 0, 0, 0);
    acc[0][3] = MFMA16(a0, b3, acc[0][3], 0, 0, 0);
    acc[1][3] = MFMA16(a1, b3, acc[1][3], 0, 0, 0);
    acc[2][3] = MFMA16(a2, b3, acc[2][3], 0, 0, 0);
    acc[3][3] = MFMA16(a3, b3, acc[3][3], 0, 0, 0);
    b0 = c0; b1 = c1; b2 = c2; b3 = c3;
    c0 = d0; c1 = d1; c2 = d2; c3 = d3;
  }
  const int r4 = (lane >> 4) << 2;
#pragma unroll
  for (int rg = 0; rg < 4; rg++) {
#pragma unroll
    for (int j = 0; j < 4; j++) {
#pragma unroll
      for (int r = 0; r < 4; r++) {
        int row = e0 + rowb + rg*16 + r4 + r;
        int col = wc + j*16 + fr;
        Vn[(size_t)row*256 + col] = f2h(acc[rg][j][r]);
      }
    }
  }
}

// ---- Gtt[slab][col][32] = coupling x Wv (fp16, tiled). col = kabs*16+d ----
__global__ void gbuild_k(const float* __restrict__ TD,
    const float* __restrict__ Wv1, const float* __restrict__ Wv2,
    const float* __restrict__ Wv3, const int* __restrict__ sl_origc,
    unsigned short* __restrict__ Gt, int Kdim, int npairs,
    int s1b, int s1e, int s2e, int s3e)
{
  int k = blockIdx.x*256 + threadIdx.x;
  if (k >= Kdim) return;
  int col = blockIdx.y;
  int pair = k >> 4, m = k & 15;
  int d = col & 15, kabs = col >> 4;
  float acc = 0.f;
  if (kabs > 0 && pair < npairs) {
    const float* Wv; int ss, se, kloc;
    if (kabs < 4)      { Wv = Wv1; ss = s1b; se = s1e; kloc = kabs - 1; }
    else if (kabs < 9) { Wv = Wv2; ss = s1e; se = s2e; kloc = kabs - 4; }
    else               { Wv = Wv3; ss = s2e; se = s3e; kloc = kabs - 9; }
    for (int slot = ss; slot < se; slot++)
      acc += TD[((pair*30) + (slot - 4))*8 + kloc] * Wv[(sl_origc[slot] + m)*16 + d];
    acc *= rsqrtf((float)(16*(se - ss)));
  }
  Gt[((size_t)((k >> 5)*256 + col))*32 + (k & 31)] = f2h(acc);
}

// ---- weight convert + transpose: Wt[n][k] = fp16(W[k][n]) ----
struct WDesc { const float* src; unsigned short* dst; int K; int lgN; };
struct WPack { WDesc d[10]; };
__global__ void wcvt_k(WPack p){
  WDesc d = p.d[blockIdx.y];
  int total = d.K << d.lgN;
  int gid = blockIdx.x*256 + threadIdx.x;
  if (gid >= total) return;
  int k = gid >> d.lgN, n = gid & ((1 << d.lgN) - 1);
  d.dst[(size_t)n*d.K + k] = f2h(d.src[gid]);
}

// ---- Wt01[n][k]: n<16 -> W0[k][n]; n>=16 -> W1[k][n-16] ----
__global__ void wcvt01_k(const float* __restrict__ W0, const float* __restrict__ W1,
                         unsigned short* __restrict__ dst){
  int gid = blockIdx.x*256 + threadIdx.x;    // 256*32 total
  int k = gid >> 5, n = gid & 31;
  float v = (n < 16) ? W0[k*16 + n] : W1[k*16 + (n - 16)];
  dst[(size_t)n*256 + k] = f2h(v);
}

// ---- hc[k] = sum_j W_h[k][j] * W_out[j] ----
__global__ void whc_k(const float* __restrict__ Wh, const float* __restrict__ Wout,
                      float* __restrict__ hc)
{
  int k = threadIdx.x;
  float s = 0.f;
#pragma unroll 16
  for (int j = 0; j < 128; j++) s += Wh[k*128 + j] * Wout[j];
  hc[k] = s;
}

// ---- out[e] = env[e] * dot(x16[e,:256], hc) / (16*sqrt(128)) ----
__global__ void final256_k(const unsigned short* __restrict__ X,
    const float* __restrict__ hc, const float* __restrict__ env,
    float* __restrict__ out)
{
  const int e = blockIdx.x*256 + threadIdx.x;
  float acc = 0.f;
#pragma unroll 16
  for (int k = 0; k < 256; k++) acc += h2f(X[((size_t)e<<8)+k])*hc[k];
  out[e] = env[e]*acc*0.0055242717280199023f;
}

// dense to 16 outputs, K=256, scale 1/16; A fp16 (layer-2 w2)
__global__ __launch_bounds__(256) void dense16_k(const unsigned short* __restrict__ A,
    const float* __restrict__ W, float* __restrict__ C)
{
  __shared__ float As[16*256];
  const int r0 = blockIdx.x << 4;
  const int tid = threadIdx.x;
  for (int i = tid; i < 16*256; i += 256)
    As[i] = h2f(A[((size_t)r0<<8) + i]);
  __syncthreads();
  const int r = tid >> 4, n = tid & 15;
  float acc = 0.f;
#pragma unroll 8
  for (int k = 0; k < 256; k++)
    acc += As[(r<<8)+k] * W[(k<<4)+n];
  C[((size_t)(r0+r)<<4)+n] = acc * 0.0625f;
}

__global__ void edge_init_k(const float* __restrict__ vectors, const int* __restrict__ senders,
    const int* __restrict__ receivers, const int* __restrict__ species,
    const float* __restrict__ emb, float* __restrict__ envb, float* __restrict__ Yb,
    float* __restrict__ x72)
{
  const int e = blockIdx.x*256 + threadIdx.x;
  float vx = vectors[e*3+0], vy = vectors[e*3+1], vz = vectors[e*3+2];
  float d = sqrtf(vx*vx+vy*vy+vz*vz);
  float dd = (d==0.f) ? 1.f : d;
  float invd = 1.f/dd;
  float x = vx*invd, y = vy*invd, z = vz*invd;
  float d2=d*d, d3=d2*d, d6=d3*d3, d7=d6*d, d8=d7*d;
  float envv = (d<1.f) ? (1.f - 28.f*d6 + 48.f*d7 - 21.f*d8) : 0.f;
  envb[e] = envv;
  float mask = (d==0.f)?0.f:1.f;
  const float SQ2 = 1.41421356237309515f;
  const float PIf = 3.14159265358979323846f;
  float* xr = x72 + (size_t)e*72;
#pragma unroll
  for (int n=1;n<=8;n++)
    xr[n-1] = SQ2 * sinf((float)n*PIf*dd)*invd*envv*mask;
  int sp_s = species[senders[e]], sp_r = species[receivers[e]];
  const float* es_ = emb + (size_t)sp_s*32;
  const float* er_ = emb + (size_t)sp_r*32;
#pragma unroll 8
  for (int k=0;k<32;k++){ xr[8+k] = es_[k]*mask; xr[40+k] = er_[k]*mask; }
  float x2=x*x, y2=y*y, z2=z*z;
  const float s3=1.7320508075688772f, s15=3.872983346207417f, s5=2.23606797749979f;
  const float s358=2.0916500663351889f, s105=10.246950765959598f;
  const float s218=1.6201851746019651f, s7=2.6457513110645907f;
  float* Yr = Yb + ((size_t)e<<4);
  Yr[0]=1.f;           Yr[1]=s3*y;          Yr[2]=s3*z;           Yr[3]=s3*x;
  Yr[4]=s15*x*y;       Yr[5]=s15*y*z;       Yr[6]=0.5f*s5*(3.f*z2-1.f);
  Yr[7]=s15*x*z;       Yr[8]=0.5f*s15*(x2-y2);
  Yr[9]=s358*y*(3.f*x2-y2);  Yr[10]=s105*x*y*z;  Yr[11]=s218*y*(5.f*z2-1.f);
  Yr[12]=0.5f*s7*(5.f*z2-3.f)*z;  Yr[13]=s218*x*(5.f*z2-1.f);
  Yr[14]=0.5f*s105*(x2-y2)*z;     Yr[15]=s358*x*(x2-y2);
}

// ---- sort-based node accumulation ----
__global__ void hist_k(const int* __restrict__ senders, int* cnt){
  int e = blockIdx.x*256 + threadIdx.x;
  atomicAdd(&cnt[senders[e]], 1);
}

__global__ void scan_k(const int* __restrict__ cnt, int* __restrict__ starts,
                       int* __restrict__ cursor){
  __shared__ int s[NNODES];
  const int tid = threadIdx.x;
  for (int i = tid; i < NNODES; i += 256) s[i] = cnt[i];
  __syncthreads();
  if (tid == 0) {
    int run = 0;
    for (int i = 0; i < NNODES; i++) { int c = s[i]; s[i] = run; run += c; }
  }
  __syncthreads();
  for (int i = tid; i < NNODES; i += 256) { starts[i] = s[i]; cursor[i] = s[i]; }
  if (tid == 0) starts[NNODES] = E_EDGES;
}

__global__ void perm_k(const int* __restrict__ senders, int* cursor,
                       int* __restrict__ perm){
  int e = blockIdx.x*256 + threadIdx.x;
  int pos = atomicAdd(&cursor[senders[e]], 1);
  perm[pos] = e;
}

// node[n][a*16+m] = sum_{e: senders[e]==n} w[e][m]*Y[e][a]; block per node.
__global__ __launch_bounds__(256) void nodesum_k(const float* __restrict__ w,
    const float* __restrict__ Y, const int* __restrict__ perm,
    const int* __restrict__ starts, float* __restrict__ node)
{
  __shared__ float buf[8*32];
  const int n = blockIdx.x;
  const int tid = threadIdx.x;
  const int s0 = starts[n], s1 = starts[n+1];
  const int a = tid >> 4, m = tid & 15;
  float acc = 0.f;
  for (int i = s0; i < s1; i += 8) {
    int nb = s1 - i; if (nb > 8) nb = 8;
    int slot = tid >> 5, comp = tid & 31;
    if (slot < nb) {
      int e = perm[i + slot];
      buf[slot*32 + comp] = (comp < 16) ? w[(e<<4)+comp] : Y[(e<<4)+comp-16];
    }
    __syncthreads();
    for (int q = 0; q < nb; q++)
      acc += buf[q*32 + m] * buf[q*32 + 16 + a];
    __syncthreads();
  }
  node[((size_t)n<<8) + tid] = acc;
}

// l3=0 TP standalone (layer 2); B = Vn fp16
__global__ void tp2_k(const float* __restrict__ node, const unsigned short* __restrict__ Vn,
    const int* __restrict__ senders, const float* __restrict__ varepsp,
    const int* __restrict__ pmeta, const int* __restrict__ entIJ,
    const float* __restrict__ entVal, unsigned short* __restrict__ tp0)
{
  const int gid = blockIdx.x*256 + threadIdx.x;
  const int e = gid >> 6, c = gid & 63;
  const int p = c >> 4, m = c & 15;
  float ve = varepsp[0];
  float eps = rsqrtf(1.f + ve*ve);
  int s = senders[e];
  const float* Am = &node[((size_t)s<<8)];
  const unsigned short* Bm = &Vn[((size_t)e<<8)];
  int es = pmeta[p*4+1], ec = pmeta[p*4+2];
  float acc = 0.f;
  for (int t=0;t<ec;t++){
    int ij = entIJ[es+t];
    acc += entVal[es+t] * Am[((ij&255)<<4) + m] * h2f(Bm[(((ij>>8)&255)<<4) + m]);
  }
  tp0[((size_t)e<<6) + pmeta[p*4+0] + m] = f2h(acc * eps);
}

// ============================ host launcher ============================

extern "C" void kernel_launch(void* const* d_in, const int* in_sizes, int n_in,
                              void* d_out, int out_size, void* d_ws, size_t ws_size,
                              hipStream_t stream)
{
  const float* vectors = (const float*)d_in[0];
  const float* vareps  = (const float*)d_in[1];
  const float* alpha   = (const float*)d_in[2];
  const float* emb     = (const float*)d_in[3];
  const float* W_tb1   = (const float*)d_in[4];
  const float* W_tb2   = (const float*)d_in[5];
  const float* W_tb3   = (const float*)d_in[6];
  const float* W_tb4   = (const float*)d_in[7];
  const float* W_w0    = (const float*)d_in[8];
  const float* W_w1    = (const float*)d_in[9];
  const float* W_l11   = (const float*)d_in[10];
  const float* W_l12   = (const float*)d_in[11];
  const float* W_l13   = (const float*)d_in[12];
  const float* W_v1    = (const float*)d_in[13];
  const float* W_v2    = (const float*)d_in[14];
  const float* W_v3    = (const float*)d_in[15];
  const float* W_w2    = (const float*)d_in[16];
  const float* W_l21   = (const float*)d_in[17];
  const float* W_l22   = (const float*)d_in[18];
  const float* W_l23   = (const float*)d_in[19];
  const float* W_h     = (const float*)d_in[20];
  const float* W_out   = (const float*)d_in[21];
  const int* senders   = (const int*)d_in[22];
  const int* receivers = (const int*)d_in[23];
  const int* species   = (const int*)d_in[24];

  static cgt::Tables tb;
  cgt::build(tb);
  const int Kdim = tb.npairs * 16;

  char* ws = (char*)d_ws;
  size_t off = 0;
  auto alloc = [&](size_t bytes)->void*{
    void* p = ws + off; off += (bytes + 255) & ~(size_t)255; return p;
  };
  float* t_val = (float*)alloc(sizeof(tb.val));
  int*   t_ij  = (int*)  alloc(sizeof(tb.ij));
  int*   t_pm  = (int*)  alloc(sizeof(tb.pmeta));
  float* t_td  = (float*)alloc(sizeof(tb.TD));
  int*   t_pr  = (int*)  alloc(sizeof(tb.pairs));
  int*   t_oc  = (int*)  alloc(sizeof(tb.sl_origc));
  float* envb  = (float*)alloc((size_t)E_EDGES*4);
  float* Yb    = (float*)alloc((size_t)E_EDGES*16*4);
  float* xb    = (float*)alloc((size_t)E_EDGES*256*4);
  float* Vb    = (float*)alloc((size_t)E_EDGES*256*4);
  float* bufA  = (float*)alloc((size_t)E_EDGES*72*4);
  float* wb    = (float*)alloc((size_t)E_EDGES*16*4);
  float* tp0b  = (float*)alloc((size_t)E_EDGES*64*4);
  float* nodeb = (float*)alloc((size_t)NNODES*256*4);
  float* hcb   = (float*)alloc(256*4);
  int* cntb    = (int*)alloc(NNODES*4);
  int* startsb = (int*)alloc((NNODES+1)*4);
  int* cursorb = (int*)alloc(NNODES*4);
  int* permb   = (int*)alloc(E_EDGES*4);
  unsigned short* Gt = (unsigned short*)alloc((size_t)256*Kdim*2);
  unsigned short* Wt_tb1 = (unsigned short*)alloc(32*72*2);
  unsigned short* Wt_tb2 = (unsigned short*)alloc(64*32*2);
  unsigned short* Wt_tb3 = (unsigned short*)alloc(128*64*2);
  unsigned short* Wt_tb4 = (unsigned short*)alloc(256*128*2);
  unsigned short* Wt_w01 = (unsigned short*)alloc(32*256*2);
  unsigned short* Wt_l11 = (unsigned short*)alloc(320*256*2);
  unsigned short* Wt_l12 = (unsigned short*)alloc(256*256*2);
  unsigned short* Wt_l13 = (unsigned short*)alloc(256*256*2);
  unsigned short* Wt_l21 = (unsigned short*)alloc(320*256*2);
  unsigned short* Wt_l22 = (unsigned short*)alloc(256*256*2);
  unsigned short* Wt_l23 = (unsigned short*)alloc(256*256*2);
  if (off > ws_size) {
    fprintf(stderr, "[allegro] workspace too small: need %zu, have %zu\n", off, ws_size);
    return;
  }
  unsigned short* xb16 = (unsigned short*)xb;
  unsigned short* tp016 = (unsigned short*)tp0b;
  unsigned short* V16 = (unsigned short*)Vb;

  hipMemcpyAsync(t_val, tb.val,     sizeof(tb.val),     hipMemcpyHostToDevice, stream);
  hipMemcpyAsync(t_ij,  tb.ij,      sizeof(tb.ij),      hipMemcpyHostToDevice, stream);
  hipMemcpyAsync(t_pm,  tb.pmeta,   sizeof(tb.pmeta),   hipMemcpyHostToDevice, stream);
  hipMemcpyAsync(t_td,  tb.TD,      sizeof(tb.TD),      hipMemcpyHostToDevice, stream);
  hipMemcpyAsync(t_pr,  tb.pairs,   sizeof(tb.pairs),   hipMemcpyHostToDevice, stream);
  hipMemcpyAsync(t_oc,  tb.sl_origc,sizeof(tb.sl_origc),hipMemcpyHostToDevice, stream);

  const int s1b = tb.l3np[0];
  const int s1e = s1b + tb.l3np[1];
  const int s2e = s1e + tb.l3np[2];
  const int s3e = s2e + tb.l3np[3];

  {
    dim3 g((Kdim + 255)/256, 256);
    gbuild_k<<<g, 256, 0, stream>>>(t_td, W_v1, W_v2, W_v3, t_oc, Gt, Kdim,
                                    tb.npairs, s1b, s1e, s2e, s3e);
  }
  {
    WPack p;
    p.d[0] = { W_tb1, Wt_tb1,  72, 5 };
    p.d[1] = { W_tb2, Wt_tb2,  32, 6 };
    p.d[2] = { W_tb3, Wt_tb3,  64, 7 };
    p.d[3] = { W_tb4, Wt_tb4, 128, 8 };
    p.d[4] = { W_l11, Wt_l11, 320, 8 };
    p.d[5] = { W_l12, Wt_l12, 256, 8 };
    p.d[6] = { W_l13, Wt_l13, 256, 8 };
    p.d[7] = { W_l21, Wt_l21, 320, 8 };
    p.d[8] = { W_l22, Wt_l22, 256, 8 };
    p.d[9] = { W_l23, Wt_l23, 256, 8 };
    dim3 g(320, 10);
    wcvt_k<<<g, 256, 0, stream>>>(p);
  }
  wcvt01_k<<<32, 256, 0, stream>>>(W_w0, W_w1, Wt_w01);
  whc_k<<<1, 256, 0, stream>>>(W_h, W_out, hcb);

  // edge->node sort (once; senders fixed for both layers)
  hipMemsetAsync(cntb, 0, NNODES*4, stream);
  hist_k<<<E_EDGES/256, 256, 0, stream>>>(senders, cntb);
  scan_k<<<1, 256, 0, stream>>>(cntb, startsb, cursorb);
  perm_k<<<E_EDGES/256, 256, 0, stream>>>(senders, cursorb, permb);

  // 1. edge features + Y + env  (x72 -> bufA fp32)
  edge_init_k<<<E_EDGES/256, 256, 0, stream>>>(vectors, senders, receivers, species,
                                               emb, envb, Yb, bufA);
  // 2+3. fused two-body MLP + w0/w1 + V init
  tb_fused_k<<<E_EDGES/64, 256, 0, stream>>>(bufA, Wt_tb1, Wt_tb2, Wt_tb3, Wt_tb4,
                                             Wt_w01, Yb, envb, xb16, V16, wb);

  // ---- layer 1 ----
  nodesum_k<<<NNODES, 256, 0, stream>>>(wb, Yb, permb, startsb, nodeb);
  vn_k<<<E_EDGES/VN_E, 512, 0, stream>>>(nodeb, V16, senders, vareps, t_pr, Gt,
                                         V16, Kdim, t_pm, t_ij, t_val, tp016);
  mlp3_k<<<E_EDGES/64, 256, 0, stream>>>(xb16, tp016, Wt_l11, Wt_l12, Wt_l13,
                                         xb16, envb, alpha);

  // ---- layer 2 (lmax_out = 0) ----
  dense16_k<<<E_EDGES/16, 256, 0, stream>>>(xb16, W_w2, wb);
  nodesum_k<<<NNODES, 256, 0, stream>>>(wb, Yb, permb, startsb, nodeb);
  tp2_k<<<E_EDGES*64/256, 256, 0, stream>>>(nodeb, V16, senders, vareps, t_pm, t_ij,
                                            t_val, tp016);
  mlp3_k<<<E_EDGES/64, 256, 0, stream>>>(xb16, tp016, Wt_l21, Wt_l22, Wt_l23,
                                         xb16, envb, alpha);

  // ---- head (W_h @ W_out precombined) ----
  final256_k<<<E_EDGES/256, 256, 0, stream>>>(xb16, hcb, envb, (float*)d_out);
}

// Round 18
// 387.985 us; speedup vs baseline: 1.5089x; 1.0360x over previous
//
#include <hip/hip_runtime.h>
#include <cmath>
#include <complex>
#include <cstdio>
#include <cstring>
#include <algorithm>

#define E_EDGES 32768
#define NNODES  2048
#define VN_E    128

// ============================ host-side CG tables ============================
namespace cgt {

static double fct(int n){
  static const double f[13] = {1.,1.,2.,6.,24.,120.,720.,5040.,40320.,362880.,
                               3628800.,39916800.,479001600.};
  return f[n];
}

static double cg(int j1,int m1,int j2,int m2,int j3,int m3){
  if (m1+m2 != m3) return 0.0;
  double pre = std::sqrt((2*j3+1)*fct(j1+j2-j3)*fct(j1-j2+j3)*fct(-j1+j2+j3)/fct(j1+j2+j3+1));
  pre *= std::sqrt(fct(j3+m3)*fct(j3-m3)*fct(j1-m1)*fct(j1+m1)*fct(j2-m2)*fct(j2+m2));
  int kmin = 0;
  if (j2-j3-m1 > kmin) kmin = j2-j3-m1;
  if (j1-j3+m2 > kmin) kmin = j1-j3+m2;
  int kmax = j1+j2-j3;
  if (j1-m1 < kmax) kmax = j1-m1;
  if (j2+m2 < kmax) kmax = j2+m2;
  double s = 0.0;
  for (int k=kmin;k<=kmax;k++){
    double d = fct(k)*fct(j1+j2-j3-k)*fct(j1-m1-k)*fct(j2+m2-k)*fct(j3-j2+m1+k)*fct(j3-j1-m2+k);
    s += ((k&1)? -1.0:1.0)/d;
  }
  return pre*s;
}

typedef std::complex<double> cd;

static void umat(int l, cd U[7][7]){
  for (int a=0;a<7;a++) for (int b=0;b<7;b++) U[a][b]=cd(0,0);
  U[l][l] = cd(1,0);
  double s2 = 1.0/std::sqrt(2.0);
  for (int m=1;m<=l;m++){
    double sg = (m&1)? -1.0 : 1.0;
    U[l+m][l-m] = cd(s2,0);
    U[l+m][l+m] = cd(sg*s2,0);
    U[l-m][l-m] = cd(0, s2);
    U[l-m][l+m] = cd(0, -sg*s2);
  }
}

static bool realCoupling(int l1,int l2,int l3, double T[7][7][7]){
  cd U1[7][7],U2[7][7],U3[7][7];
  umat(l1,U1); umat(l2,U2); umat(l3,U3);
  int n1=2*l1+1, n2=2*l2+1, n3=2*l3+1;
  double Cg[7][7][7];
  for (int m=0;m<n1;m++) for(int n=0;n<n2;n++) for(int k=0;k<n3;k++)
    Cg[m][n][k] = cg(l1,m-l1,l2,n-l2,l3,k-l3);
  double Tr[7][7][7], Ti[7][7][7];
  double nr=0, ni=0;
  for (int a=0;a<n1;a++) for(int b=0;b<n2;b++) for(int c=0;c<n3;c++){
    cd s(0,0);
    for (int m=0;m<n1;m++){
      if (U1[a][m]==cd(0,0)) continue;
      for (int n=0;n<n2;n++){
        if (U2[b][n]==cd(0,0)) continue;
        for (int k=0;k<n3;k++){
          double cgv = Cg[m][n][k];
          if (cgv==0.0) continue;
          s += U1[a][m]*U2[b][n]*std::conj(U3[c][k])*cgv;
        }
      }
    }
    Tr[a][b][c]=s.real(); Ti[a][b][c]=s.imag();
    nr += s.real()*s.real(); ni += s.imag()*s.imag();
  }
  bool useR = (nr >= ni);
  double nn = std::sqrt(useR? nr : ni);
  if (nn < 1e-8) return false;
  for (int a=0;a<n1;a++)for(int b=0;b<n2;b++)for(int c=0;c<n3;c++)
    T[a][b][c] = (useR? Tr[a][b][c] : Ti[a][b][c])/nn;
  return true;
}

struct Tables {
  float val[4096];
  int   ij[4096];
  int   pmeta[40*4];
  int   ccnt[40*8];
  int   l3base[4];
  int   l3np[4];
  int   npaths;
  int   nent;
  int   tptot;
  int   pairs[256];
  float TD[256*30*8];
  int   sl_origc[40];
  int   npairs;
};

struct PathTmp {
  int l1,l2,l3, tpoff, kd;
  int ec;
  double T[7][7][7];
};

static void build(Tables& tb){
  static PathTmp paths[40];
  int np = 0, tpoff = 0;
  int l3start[5];
  for (int l3=0;l3<=3;l3++){
    tb.l3base[l3] = tpoff;
    l3start[l3] = np;
    int kd = 2*l3+1;
    for (int l1=0;l1<=3;l1++) for (int l2=0;l2<=3;l2++){
      int lo = (l1>l2)? l1-l2 : l2-l1;
      int hi = std::min(l1+l2,3);
      if (l3 < lo || l3 > hi) continue;
      PathTmp& pt = paths[np];
      if (!realCoupling(l1,l2,l3,pt.T)) continue;
      pt.l1=l1; pt.l2=l2; pt.l3=l3; pt.kd=kd; pt.tpoff=tpoff;
      double scale = std::sqrt((double)kd);
      int cnt = 0;
      for (int a=0;a<2*l1+1;a++)for(int b=0;b<2*l2+1;b++)for(int c=0;c<kd;c++)
        if (std::fabs(pt.T[a][b][c]*scale) > 1e-7) cnt++;
      pt.ec = cnt;
      tpoff += 16*kd;
      np++;
    }
  }
  l3start[4] = np;
  for (int l3=0;l3<=3;l3++) tb.l3np[l3] = l3start[l3+1]-l3start[l3];
  static int order[40];
  for (int i=0;i<np;i++) order[i]=i;
  for (int l3=0;l3<=3;l3++)
    std::sort(order+l3start[l3], order+l3start[l3+1],
              [&](int a,int b){ return paths[a].ec > paths[b].ec; });
  std::memset(tb.TD, 0, sizeof(tb.TD));
  std::memset(tb.pairs, 0, sizeof(tb.pairs));
  static int pmap[16][16];
  for (int i=0;i<16;i++) for (int j=0;j<16;j++) pmap[i][j] = -1;
  int npr = 0;
  int ep = 0;
  for (int slot=0; slot<np; slot++){
    const PathTmp& pt = paths[order[slot]];
    double scale = std::sqrt((double)pt.kd);
    int s1 = pt.l1*pt.l1, s2 = pt.l2*pt.l2;
    tb.pmeta[slot*4+0] = pt.tpoff;
    tb.pmeta[slot*4+1] = ep;
    tb.sl_origc[slot] = ((pt.tpoff - tb.l3base[pt.l3]) / (16*pt.kd)) * 16;
    int tot = 0;
    for (int c=0;c<pt.kd;c++){
      int cnt = 0;
      for (int a=0;a<2*pt.l1+1;a++)for(int b=0;b<2*pt.l2+1;b++){
        double v = pt.T[a][b][c]*scale;
        if (std::fabs(v) > 1e-7){
          tb.val[ep] = (float)v;
          tb.ij[ep]  = (s1+a) | ((s2+b)<<8);
          ep++; cnt++;
          if (pt.l3 >= 1){
            int aa = s1+a, bb = s2+b;
            int pi = pmap[aa][bb];
            if (pi < 0){ pi = npr; pmap[aa][bb] = pi;
                         tb.pairs[npr] = aa | (bb<<8); npr++; }
            tb.TD[(pi*30 + (slot-4))*8 + c] = (float)v;
          }
        }
      }
      tb.ccnt[slot*8+c] = cnt;
      tot += cnt;
    }
    for (int c=pt.kd;c<8;c++) tb.ccnt[slot*8+c]=0;
    tb.pmeta[slot*4+2] = tot;
    tb.pmeta[slot*4+3] = pt.kd;
  }
  if (npr & 1){ tb.pairs[npr] = 0; npr++; }
  tb.npairs = npr;
  tb.npaths = np; tb.nent = ep; tb.tptot = tpoff;
}

} // namespace cgt

// ============================ device kernels ============================
// LAYOUT: node/V/Vn rows are [a][m]. MFMA-path activations fp16 in HBM.

typedef _Float16 half8 __attribute__((ext_vector_type(8)));
typedef __attribute__((ext_vector_type(4))) float f32x4;

__device__ inline unsigned short f2h(float f){
  union { _Float16 h; unsigned short u; } x;
  x.h = (_Float16)f;
  return x.u;
}
__device__ inline float h2f(unsigned short u){
  union { _Float16 h; unsigned short u; } x; x.u = u;
  return (float)x.h;
}

__device__ inline int swz(int row, int kh){
  int b = row*64 + kh*2;
  return b ^ (((row >> 1) & 3) << 4);
}

__device__ inline float silu(float v){ return v/(1.f+__expf(-v)); }

#define MFMA16 __builtin_amdgcn_mfma_f32_16x16x32_f16

// ---- fused two-body chain: x72 ->32->64->128->256, + [w0|w1], + V ----
__global__ __launch_bounds__(256) void tb_fused_k(
    const float* __restrict__ X72, const unsigned short* __restrict__ Wt1,
    const unsigned short* __restrict__ Wt2, const unsigned short* __restrict__ Wt3,
    const unsigned short* __restrict__ Wt4, const unsigned short* __restrict__ Wt01,
    const float* __restrict__ Yb, const float* __restrict__ envb,
    unsigned short* __restrict__ Xout, unsigned short* __restrict__ V,
    float* __restrict__ wb)
{
  __shared__ unsigned short AsB[64*32];
  __shared__ unsigned short BsB[256*32];
  __shared__ unsigned short HsA[64*264];
  __shared__ unsigned short HsB[64*264];
  __shared__ float w0s[64*16];
  const int tid  = threadIdx.x;
  const int wave = tid >> 6, lane = tid & 63;
  const int bm = blockIdx.x*64;
  const int mrow = wave*16;
  const int fr = lane & 15, fk = (lane >> 4) * 8;
  const int r4 = (lane >> 4) << 2;
  const int sra = tid >> 2, ska = (tid & 3) * 8;
  const int srb = tid >> 1, skb = (tid & 1) * 16;

  // ---- stage 1: h = silu(x72 @ W1 / sqrt(72)), N=32, K=72 (pad 96) ----
  {
    f32x4 acc[2] = {};
    for (int k0 = 0; k0 < 96; k0 += 32) {
      {
        unsigned short u[8];
        int rowg = bm + sra;
#pragma unroll
        for (int q = 0; q < 8; q++) {
          int k = k0 + ska + q;
          u[q] = (k < 72) ? f2h(X72[(size_t)rowg*72 + k]) : (unsigned short)0;
        }
        *(ushort4*)((char*)AsB + swz(sra, ska))     = *(ushort4*)&u[0];
        *(ushort4*)((char*)AsB + swz(sra, ska + 4)) = *(ushort4*)&u[4];
      }
      if (tid < 64) {
        int n = tid >> 1, kb = (tid & 1) * 16;
        unsigned short u[16];
#pragma unroll
        for (int q = 0; q < 16; q++) {
          int k = k0 + kb + q;
          u[q] = (k < 72) ? Wt1[n*72 + k] : (unsigned short)0;
        }
        *(uint4*)((char*)BsB + swz(n, kb))     = *(uint4*)&u[0];
        *(uint4*)((char*)BsB + swz(n, kb + 8)) = *(uint4*)&u[8];
      }
      __syncthreads();
      half8 af = *(half8*)((char*)AsB + swz(mrow + fr, fk));
      half8 b0 = *(half8*)((char*)BsB + swz(fr, fk));
      half8 b1 = *(half8*)((char*)BsB + swz(16 + fr, fk));
      acc[0] = MFMA16(af, b0, acc[0], 0, 0, 0);
      acc[1] = MFMA16(af, b1, acc[1], 0, 0, 0);
      __syncthreads();
    }
    const float rs = 0.11785113019775793f;
#pragma unroll
    for (int j = 0; j < 2; j++)
#pragma unroll
      for (int r = 0; r < 4; r++) {
        int row = mrow + r4 + r;
        HsA[row*264 + j*16 + fr] = f2h(silu(acc[j][r]*rs));
      }
    __syncthreads();
  }

  // ---- stage 2: h = silu(h @ W2 / sqrt(32)), N=64, K=32 ----
  {
    f32x4 acc[4] = {};
    if (tid < 128) {
      int n = tid >> 1, kb = (tid & 1) * 16;
      const unsigned short* s = Wt2 + n*32 + kb;
      uint4 u0 = *(const uint4*)s;
      uint4 u1 = *(const uint4*)(s + 8);
      *(uint4*)((char*)BsB + swz(n, kb))     = u0;
      *(uint4*)((char*)BsB + swz(n, kb + 8)) = u1;
    }
    __syncthreads();
    half8 af = *(half8*)(HsA + (mrow + fr)*264 + fk);
#pragma unroll
    for (int j = 0; j < 4; j++) {
      half8 bf = *(half8*)((char*)BsB + swz(j*16 + fr, fk));
      acc[j] = MFMA16(af, bf, acc[j], 0, 0, 0);
    }
    __syncthreads();
    const float rs = 0.17677669529663687f;
#pragma unroll
    for (int j = 0; j < 4; j++)
#pragma unroll
      for (int r = 0; r < 4; r++) {
        int row = mrow + r4 + r;
        HsB[row*264 + j*16 + fr] = f2h(silu(acc[j][r]*rs));
      }
    __syncthreads();
  }

  // ---- stage 3: h = silu(h @ W3 / 8), N=128, K=64 ----
  {
    f32x4 acc[8] = {};
    for (int k0 = 0; k0 < 64; k0 += 32) {
      {
        int n = srb, kb = skb;
        const unsigned short* s = Wt3 + n*64 + k0 + kb;
        uint4 u0 = *(const uint4*)s;
        uint4 u1 = *(const uint4*)(s + 8);
        *(uint4*)((char*)BsB + swz(n, kb))     = u0;
        *(uint4*)((char*)BsB + swz(n, kb + 8)) = u1;
      }
      __syncthreads();
      half8 af = *(half8*)(HsB + (mrow + fr)*264 + k0 + fk);
#pragma unroll
      for (int j = 0; j < 8; j++) {
        half8 bf = *(half8*)((char*)BsB + swz(j*16 + fr, fk));
        acc[j] = MFMA16(af, bf, acc[j], 0, 0, 0);
      }
      __syncthreads();
    }
    const float rs = 0.125f;
#pragma unroll
    for (int j = 0; j < 8; j++)
#pragma unroll
      for (int r = 0; r < 4; r++) {
        int row = mrow + r4 + r;
        HsA[row*264 + j*16 + fr] = f2h(silu(acc[j][r]*rs));
      }
    __syncthreads();
  }

  // ---- stage 4: x = env * (h @ W4 / sqrt(128)), N=256, K=128 ----
  {
    f32x4 acc[16] = {};
    for (int k0 = 0; k0 < 128; k0 += 32) {
#pragma unroll
      for (int h = 0; h < 2; h++) {
        int n = h*128 + srb;
        const unsigned short* s = Wt4 + (size_t)n*128 + k0 + skb;
        uint4 u0 = *(const uint4*)s;
        uint4 u1 = *(const uint4*)(s + 8);
        *(uint4*)((char*)BsB + swz(n, skb))     = u0;
        *(uint4*)((char*)BsB + swz(n, skb + 8)) = u1;
      }
      __syncthreads();
      half8 af = *(half8*)(HsA + (mrow + fr)*264 + k0 + fk);
#pragma unroll
      for (int j = 0; j < 16; j++) {
        half8 bf = *(half8*)((char*)BsB + swz(j*16 + fr, fk));
        acc[j] = MFMA16(af, bf, acc[j], 0, 0, 0);
      }
      __syncthreads();
    }
    const float rs = 0.08838834764831845f;
#pragma unroll
    for (int j = 0; j < 16; j++)
#pragma unroll
      for (int r = 0; r < 4; r++) {
        int row = mrow + r4 + r;
        float v = acc[j][r]*rs*envb[bm + row];
        unsigned short hv = f2h(v);
        HsB[row*264 + j*16 + fr] = hv;
        Xout[((size_t)(bm + row))*256 + j*16 + fr] = hv;
      }
    __syncthreads();
  }

  // ---- stage 5: [w0|w1] = x @ [W0|W1] / 16, N=32, K=256 ----
  {
    f32x4 acc[2] = {};
    for (int k0 = 0; k0 < 256; k0 += 32) {
      if (tid < 64) {
        int n = tid >> 1, kb = (tid & 1) * 16;
        const unsigned short* s = Wt01 + (size_t)n*256 + k0 + kb;
        uint4 u0 = *(const uint4*)s;
        uint4 u1 = *(const uint4*)(s + 8);
        *(uint4*)((char*)BsB + swz(n, kb))     = u0;
        *(uint4*)((char*)BsB + swz(n, kb + 8)) = u1;
      }
      __syncthreads();
      half8 af = *(half8*)(HsB + (mrow + fr)*264 + k0 + fk);
      half8 b0 = *(half8*)((char*)BsB + swz(fr, fk));
      half8 b1 = *(half8*)((char*)BsB + swz(16 + fr, fk));
      acc[0] = MFMA16(af, b0, acc[0], 0, 0, 0);
      acc[1] = MFMA16(af, b1, acc[1], 0, 0, 0);
      __syncthreads();
    }
#pragma unroll
    for (int r = 0; r < 4; r++) {
      int row = mrow + r4 + r;
      w0s[row*16 + fr] = acc[0][r]*0.0625f;
      wb[((size_t)(bm + row))*16 + fr] = acc[1][r]*0.0625f;
    }
    __syncthreads();
  }

  // ---- V init ----
  for (int i = tid; i < 64*256; i += 256) {
    int e = i >> 8, idx = i & 255;
    V[(((size_t)(bm + e)) << 8) + idx] =
        f2h(w0s[e*16 + (idx & 15)] * Yb[(bm + e)*16 + (idx >> 4)]);
  }
}

// ---- fused 3-layer latent MLP v2 (R18): 128 rows/block, 512 threads ----
// MODE 0 (layer 1): writes x_new (global) + w2 = x_new @ W_w2/16 -> wb.
// MODE 1 (layer 2): x_new stays in LDS; writes out[e] = env*dot(x_new,hc)*s.
// 8 waves = 2 row-halves x 4 col-quarters; B-tile staged once per k-step
// serves 128 rows (2x MFMA per staged byte vs R17's 64-row blocks).
template<int MODE>
__global__ __launch_bounds__(512) void mlp3_k(
    const unsigned short* __restrict__ X, const unsigned short* __restrict__ T0,
    const unsigned short* __restrict__ W1t, const unsigned short* __restrict__ W2t,
    const unsigned short* __restrict__ W3t, unsigned short* __restrict__ Out,
    const float* __restrict__ env, const float* __restrict__ alphap,
    const unsigned short* __restrict__ Wtw2, float* __restrict__ wb,
    const float* __restrict__ hc, float* __restrict__ outE)
{
  __shared__ unsigned short AsB[128*32];    // 8 KB
  __shared__ unsigned short BsB[256*32];    // 16 KB
  __shared__ unsigned short Hs[128*264];    // 67.6 KB
  __shared__ float hcs[256];
  __shared__ float red[512];
  const int tid  = threadIdx.x;
  const int wave = tid >> 6, lane = tid & 63;
  const int bm = blockIdx.x*128;
  const int rowh = (wave >> 2)*64;
  const int wc = (wave & 3)*64;
  const int fr = lane & 15, fk = (lane >> 4) * 8;
  const int r4 = (lane >> 4) << 2;
  const int sra = tid >> 2, ska = (tid & 3) * 8;
  const int srb = tid >> 1, skb = (tid & 1) * 16;
  if (MODE == 1 && tid < 256) hcs[tid] = hc[tid];
  f32x4 acc[4][4] = {};

  // ---- stage 1: h1 = silu([x|tp0] @ W1 / sqrt(320)) -> Hs ----
  for (int k0 = 0; k0 < 320; k0 += 32) {
    {
      int kk = k0 + ska;
      const unsigned short* ap = (kk < 256)
        ? X  + (size_t)(bm + sra)*256 + kk
        : T0 + (size_t)(bm + sra)*64  + (kk - 256);
      *(uint4*)((char*)AsB + swz(sra, ska)) = *(const uint4*)ap;
    }
    {
      const unsigned short* s = W1t + (size_t)srb*320 + k0 + skb;
      *(uint4*)((char*)BsB + swz(srb, skb))     = *(const uint4*)s;
      *(uint4*)((char*)BsB + swz(srb, skb + 8)) = *(const uint4*)(s + 8);
    }
    __syncthreads();
    half8 af[4], bf[4];
#pragma unroll
    for (int i = 0; i < 4; i++)
      af[i] = *(half8*)((char*)AsB + swz(rowh + i*16 + fr, fk));
#pragma unroll
    for (int j = 0; j < 4; j++)
      bf[j] = *(half8*)((char*)BsB + swz(wc + j*16 + fr, fk));
#pragma unroll
    for (int i = 0; i < 4; i++)
#pragma unroll
      for (int j = 0; j < 4; j++)
        acc[i][j] = MFMA16(af[i], bf[j], acc[i][j], 0, 0, 0);
    __syncthreads();
  }
  const float rs320 = 0.055901699437494740f;
#pragma unroll
  for (int i = 0; i < 4; i++)
#pragma unroll
    for (int r = 0; r < 4; r++) {
      int row = rowh + i*16 + r4 + r;
#pragma unroll
      for (int j = 0; j < 4; j++) {
        Hs[row*264 + wc + j*16 + fr] = f2h(silu(acc[i][j][r]*rs320));
        acc[i][j][r] = 0.f;
      }
    }
  __syncthreads();

  // ---- stage 2: h2 = silu(h1 @ W2 / 16) ----
  for (int k0 = 0; k0 < 256; k0 += 32) {
    {
      const unsigned short* s = W2t + (size_t)srb*256 + k0 + skb;
      *(uint4*)((char*)BsB + swz(srb, skb))     = *(const uint4*)s;
      *(uint4*)((char*)BsB + swz(srb, skb + 8)) = *(const uint4*)(s + 8);
    }
    __syncthreads();
    half8 af[4], bf[4];
#pragma unroll
    for (int i = 0; i < 4; i++)
      af[i] = *(half8*)(Hs + (rowh + i*16 + fr)*264 + k0 + fk);
#pragma unroll
    for (int j = 0; j < 4; j++)
      bf[j] = *(half8*)((char*)BsB + swz(wc + j*16 + fr, fk));
#pragma unroll
    for (int i = 0; i < 4; i++)
#pragma unroll
      for (int j = 0; j < 4; j++)
        acc[i][j] = MFMA16(af[i], bf[j], acc[i][j], 0, 0, 0);
    __syncthreads();
  }
#pragma unroll
  for (int i = 0; i < 4; i++)
#pragma unroll
    for (int r = 0; r < 4; r++) {
      int row = rowh + i*16 + r4 + r;
#pragma unroll
      for (int j = 0; j < 4; j++) {
        Hs[row*264 + wc + j*16 + fr] = f2h(silu(acc[i][j][r]*0.0625f));
        acc[i][j][r] = 0.f;
      }
    }
  __syncthreads();

  // ---- stage 3: x_new = resid(env * (h2 @ W3 / 16)) ----
  for (int k0 = 0; k0 < 256; k0 += 32) {
    {
      const unsigned short* s = W3t + (size_t)srb*256 + k0 + skb;
      *(uint4*)((char*)BsB + swz(srb, skb))     = *(const uint4*)s;
      *(uint4*)((char*)BsB + swz(srb, skb + 8)) = *(const uint4*)(s + 8);
    }
    __syncthreads();
    half8 af[4], bf[4];
#pragma unroll
    for (int i = 0; i < 4; i++)
      af[i] = *(half8*)(Hs + (rowh + i*16 + fr)*264 + k0 + fk);
#pragma unroll
    for (int j = 0; j < 4; j++)
      bf[j] = *(half8*)((char*)BsB + swz(wc + j*16 + fr, fk));
#pragma unroll
    for (int i = 0; i < 4; i++)
#pragma unroll
      for (int j = 0; j < 4; j++)
        acc[i][j] = MFMA16(af[i], bf[j], acc[i][j], 0, 0, 0);
    __syncthreads();
  }
  {
    float al = alphap[0];
    float a2 = al*al, inv1a2 = 1.f/(1.f+a2);
#pragma unroll
    for (int i = 0; i < 4; i++)
#pragma unroll
      for (int r = 0; r < 4; r++) {
        int row = rowh + i*16 + r4 + r;
        int grow = bm + row;
        float ev = env[grow];
#pragma unroll
        for (int j = 0; j < 4; j++) {
          int col = wc + j*16 + fr;
          float v = acc[i][j][r]*0.0625f*ev;
          v = (h2f(X[(size_t)grow*256 + col]) + a2*v)*inv1a2;
          unsigned short hv = f2h(v);
          Hs[row*264 + col] = hv;
          if (MODE == 0) Out[(size_t)grow*256 + col] = hv;
        }
      }
  }
  __syncthreads();

  if (MODE == 0) {
    // ---- stage 4: w2 = x_new @ W_w2 / 16, N=16, K=256 ----
    f32x4 acc2[4] = {};
    for (int k0 = 0; k0 < 256; k0 += 32) {
      if (tid < 32) {
        int n = tid >> 1, kb = (tid & 1) * 16;
        const unsigned short* s = Wtw2 + (size_t)n*256 + k0 + kb;
        *(uint4*)((char*)BsB + swz(n, kb))     = *(const uint4*)s;
        *(uint4*)((char*)BsB + swz(n, kb + 8)) = *(const uint4*)(s + 8);
      }
      __syncthreads();
      if ((wave & 3) == 0) {
        half8 bf = *(half8*)((char*)BsB + swz(fr, fk));
#pragma unroll
        for (int i = 0; i < 4; i++) {
          half8 af = *(half8*)(Hs + (rowh + i*16 + fr)*264 + k0 + fk);
          acc2[i] = MFMA16(af, bf, acc2[i], 0, 0, 0);
        }
      }
      __syncthreads();
    }
    if ((wave & 3) == 0) {
#pragma unroll
      for (int i = 0; i < 4; i++)
#pragma unroll
        for (int r = 0; r < 4; r++)
          wb[((size_t)(bm + rowh + i*16 + r4 + r))*16 + fr] = acc2[i][r]*0.0625f;
    }
  } else {
    // ---- final head: out[e] = env * dot(x_new, hc) / (16*sqrt(128)) ----
    int row = tid >> 2, q = tid & 3;
    float p = 0.f;
#pragma unroll 16
    for (int c = q*64; c < q*64 + 64; c++)
      p += h2f(Hs[row*264 + c]) * hcs[c];
    red[tid] = p;
    __syncthreads();
    if (q == 0) {
      float t = red[tid] + red[tid+1] + red[tid+2] + red[tid+3];
      outE[bm + row] = env[bm + row]*t*0.0055242717280199023f;
    }
  }
}

// ---- fused Vn kernel + layer-1 tp0 ----
__global__ __launch_bounds__(512) void vn_k(
    const float* __restrict__ node, const unsigned short* __restrict__ V,
    const int* __restrict__ senders, const float* __restrict__ varepsp,
    const int* __restrict__ pairsG, const unsigned short* __restrict__ Gtt,
    unsigned short* __restrict__ Vn, int Kdim,
    const int* __restrict__ pmeta, const int* __restrict__ entIJ,
    const float* __restrict__ entVal, unsigned short* __restrict__ tp0)
{
  __shared__ unsigned short Ab[VN_E*264];
  __shared__ unsigned short Bb[VN_E*264];
  __shared__ int Ps[256];
  const int tid = threadIdx.x;
  const int e0 = blockIdx.x * VN_E;
  const int wave = tid >> 6, lane = tid & 63;
  float ve = varepsp[0];
  float eps = rsqrtf(1.f + ve*ve);
  if (tid < 256) Ps[tid] = pairsG[tid];
#pragma unroll
  for (int rr = 0; rr < 16; rr++) {
    int row = wave*16 + rr;
    int s = senders[e0 + row];
    float4 fa = *(const float4*)(node + ((size_t)s << 8) + 4*lane);
    uint2 ub = *(const uint2*)(V + (((size_t)(e0 + row)) << 8) + 4*lane);
    unsigned short* ad = Ab + row*264 + 4*lane;
    unsigned short* bd = Bb + row*264 + 4*lane;
    uint2 ua;
    ua.x = (unsigned)f2h(fa.x*eps) | ((unsigned)f2h(fa.y*eps) << 16);
    ua.y = (unsigned)f2h(fa.z*eps) | ((unsigned)f2h(fa.w*eps) << 16);
    *(uint2*)ad = ua;
    *(uint2*)bd = ub;
  }
  __syncthreads();
  for (int o = tid; o < VN_E*64; o += 512) {
    int e = o >> 6, c = o & 63;
    int p = c >> 4, m = c & 15;
    const unsigned short* Ae = Ab + e*264;
    const unsigned short* Be = Bb + e*264;
    int es = pmeta[p*4+1], ec = pmeta[p*4+2];
    float acc = 0.f;
    for (int t = 0; t < ec; t++) {
      int ij = entIJ[es+t];
      acc += entVal[es+t] * h2f(Ae[((ij&255)<<4)+m]) * h2f(Be[(((ij>>8)&255)<<4)+m]);
    }
    tp0[((size_t)(e0+e)<<6) + pmeta[p*4+0] + m] = f2h(acc);
  }
  const int rowb = (wave & 1) * 64;
  const int wc   = (wave >> 1) * 64;
  const int fr = lane & 15, fk = (lane >> 4) * 8;
  const int pairSel = fk >> 4;
  const int moff = fk & 15;
  const int nslab = Kdim >> 5;
  f32x4 acc[4][4] = {};

  const unsigned short* Ar0 = Ab + (rowb + fr)*264;
  const unsigned short* Br0 = Bb + (rowb + fr)*264;
  const unsigned short* Ar1 = Ab + (rowb + 16 + fr)*264;
  const unsigned short* Br1 = Bb + (rowb + 16 + fr)*264;
  const unsigned short* Ar2 = Ab + (rowb + 32 + fr)*264;
  const unsigned short* Br2 = Bb + (rowb + 32 + fr)*264;
  const unsigned short* Ar3 = Ab + (rowb + 48 + fr)*264;
  const unsigned short* Br3 = Bb + (rowb + 48 + fr)*264;

  const unsigned short* gp = Gtt + ((size_t)(wc + fr)) * 32 + fk;
  half8 b0 = *(const half8*)(gp);
  half8 b1 = *(const half8*)(gp + 512);
  half8 b2 = *(const half8*)(gp + 1024);
  half8 b3 = *(const half8*)(gp + 1536);
  half8 c0 = b0, c1 = b1, c2 = b2, c3 = b3;
  if (nslab > 1) {
    const unsigned short* g1 = gp + 8192;
    c0 = *(const half8*)(g1);
    c1 = *(const half8*)(g1 + 512);
    c2 = *(const half8*)(g1 + 1024);
    c3 = *(const half8*)(g1 + 1536);
  }
  int p0 = Ps[pairSel];
  int aoff = ((p0 & 255) << 4) + moff;
  int boff = (((p0 >> 8) & 255) << 4) + moff;
  half8 rA0 = *(const half8*)(Ar0 + aoff);
  half8 rB0 = *(const half8*)(Br0 + boff);
  half8 rA1 = *(const half8*)(Ar1 + aoff);
  half8 rB1 = *(const half8*)(Br1 + boff);
  half8 rA2 = *(const half8*)(Ar2 + aoff);
  half8 rB2 = *(const half8*)(Br2 + boff);
  half8 rA3 = *(const half8*)(Ar3 + aoff);
  half8 rB3 = *(const half8*)(Br3 + boff);

  for (int sl = 0; sl < nslab; sl++) {
    half8 a0 = rA0 * rB0;
    half8 a1 = rA1 * rB1;
    half8 a2 = rA2 * rB2;
    half8 a3 = rA3 * rB3;
    if (sl + 1 < nslab) {
      int pn = Ps[2*(sl + 1) + pairSel];
      int aoffn = ((pn & 255) << 4) + moff;
      int boffn = (((pn >> 8) & 255) << 4) + moff;
      rA0 = *(const half8*)(Ar0 + aoffn);
      rB0 = *(const half8*)(Br0 + boffn);
      rA1 = *(const half8*)(Ar1 + aoffn);
      rB1 = *(const half8*)(Br1 + boffn);
      rA2 = *(const half8*)(Ar2 + aoffn);
      rB2 = *(const half8*)(Br2 + boffn);
      rA3 = *(const half8*)(Ar3 + aoffn);
      rB3 = *(const half8*)(Br3 + boffn);
    }
    half8 d0, d1, d2, d3;
    if (sl + 2 < nslab) {
      const unsigned short* gn = gp + (size_t)(sl + 2) * 8192;
      d0 = *(const half8*)(gn);
      d1 = *(const half8*)(gn + 512);
      d2 = *(const half8*)(gn + 1024);
      d3 = *(const half8*)(gn + 1536);
    } else { d0 = c0; d1 = c1; d2 = c2; d3 = c3; }
    acc[0][0] = MFMA16(a0, b0, acc[0][0], 0, 0, 0);
    acc[1][0] = MFMA16(a1, b0, acc[1][0], 0, 0, 0);
    acc[2][0] = MFMA16(a2, b0, acc[2][0], 0, 0, 0);
    acc[3][0] = MFMA16(a3, b0, acc[3][0], 0, 0, 0);
    acc[0][1] = MFMA16(a0, b1, acc[0][1], 0, 0, 0);
    acc[1][1] = MFMA16(a1, b1, acc[1][1], 0, 0, 0);
    acc[2][1] = MFMA16(a2, b1, acc[2][1], 0, 0, 0);
    acc[3][1] = MFMA16(a3, b1, acc[3][1], 0, 0, 0);
    acc[0][2] = MFMA16(a0, b2, acc[0][2], 0, 0, 0);
    acc[1][2] = MFMA16(a1, b2, acc[1][2], 0, 0, 0);
    acc[2][2] = MFMA16(a2, b2, acc[2][2], 0, 0, 0);
    acc[3][2] = MFMA16(a3, b2, acc[3][2], 0, 0, 0);
    acc[0][3] = MFMA16(a0, b3, acc[0][3], 0, 0, 0);
    acc[1][3] = MFMA16(a1, b3, acc[1][3], 0, 0, 0);
    acc[2][3] = MFMA16(a2, b3, acc[2][3], 0, 0, 0);
    acc[3][3] = MFMA16(a3, b3, acc[3][3], 0, 0, 0);
    b0 = c0; b1 = c1; b2 = c2; b3 = c3;
    c0 = d0; c1 = d1; c2 = d2; c3 = d3;
  }
  const int r4 = (lane >> 4) << 2;
#pragma unroll
  for (int rg = 0; rg < 4; rg++) {
#pragma unroll
    for (int j = 0; j < 4; j++) {
#pragma unroll
      for (int r = 0; r < 4; r++) {
        int row = e0 + rowb + rg*16 + r4 + r;
        int col = wc + j*16 + fr;
        Vn[(size_t)row*256 + col] = f2h(acc[rg][j][r]);
      }
    }
  }
}

// ---- Gtt[slab][col][32] = coupling x Wv (fp16, tiled). col = kabs*16+d ----
__global__ void gbuild_k(const float* __restrict__ TD,
    const float* __restrict__ Wv1, const float* __restrict__ Wv2,
    const float* __restrict__ Wv3, const int* __restrict__ sl_origc,
    unsigned short* __restrict__ Gt, int Kdim, int npairs,
    int s1b, int s1e, int s2e, int s3e)
{
  int k = blockIdx.x*256 + threadIdx.x;
  if (k >= Kdim) return;
  int col = blockIdx.y;
  int pair = k >> 4, m = k & 15;
  int d = col & 15, kabs = col >> 4;
  float acc = 0.f;
  if (kabs > 0 && pair < npairs) {
    const float* Wv; int ss, se, kloc;
    if (kabs < 4)      { Wv = Wv1; ss = s1b; se = s1e; kloc = kabs - 1; }
    else if (kabs < 9) { Wv = Wv2; ss = s1e; se = s2e; kloc = kabs - 4; }
    else               { Wv = Wv3; ss = s2e; se = s3e; kloc = kabs - 9; }
    for (int slot = ss; slot < se; slot++)
      acc += TD[((pair*30) + (slot - 4))*8 + kloc] * Wv[(sl_origc[slot] + m)*16 + d];
    acc *= rsqrtf((float)(16*(se - ss)));
  }
  Gt[((size_t)((k >> 5)*256 + col))*32 + (k & 31)] = f2h(acc);
}

// ---- weight convert + transpose: Wt[n][k] = fp16(W[k][n]) ----
struct WDesc { const float* src; unsigned short* dst; int K; int lgN; };
struct WPack { WDesc d[11]; };
__global__ void wcvt_k(WPack p){
  WDesc d = p.d[blockIdx.y];
  int total = d.K << d.lgN;
  int gid = blockIdx.x*256 + threadIdx.x;
  if (gid >= total) return;
  int k = gid >> d.lgN, n = gid & ((1 << d.lgN) - 1);
  d.dst[(size_t)n*d.K + k] = f2h(d.src[gid]);
}

// ---- Wt01[n][k]: n<16 -> W0[k][n]; n>=16 -> W1[k][n-16] ----
__global__ void wcvt01_k(const float* __restrict__ W0, const float* __restrict__ W1,
                         unsigned short* __restrict__ dst){
  int gid = blockIdx.x*256 + threadIdx.x;
  int k = gid >> 5, n = gid & 31;
  float v = (n < 16) ? W0[k*16 + n] : W1[k*16 + (n - 16)];
  dst[(size_t)n*256 + k] = f2h(v);
}

// ---- hc[k] = sum_j W_h[k][j] * W_out[j] ----
__global__ void whc_k(const float* __restrict__ Wh, const float* __restrict__ Wout,
                      float* __restrict__ hc)
{
  int k = threadIdx.x;
  float s = 0.f;
#pragma unroll 16
  for (int j = 0; j < 128; j++) s += Wh[k*128 + j] * Wout[j];
  hc[k] = s;
}

__global__ void edge_init_k(const float* __restrict__ vectors, const int* __restrict__ senders,
    const int* __restrict__ receivers, const int* __restrict__ species,
    const float* __restrict__ emb, float* __restrict__ envb, float* __restrict__ Yb,
    float* __restrict__ x72)
{
  const int e = blockIdx.x*256 + threadIdx.x;
  float vx = vectors[e*3+0], vy = vectors[e*3+1], vz = vectors[e*3+2];
  float d = sqrtf(vx*vx+vy*vy+vz*vz);
  float dd = (d==0.f) ? 1.f : d;
  float invd = 1.f/dd;
  float x = vx*invd, y = vy*invd, z = vz*invd;
  float d2=d*d, d3=d2*d, d6=d3*d3, d7=d6*d, d8=d7*d;
  float envv = (d<1.f) ? (1.f - 28.f*d6 + 48.f*d7 - 21.f*d8) : 0.f;
  envb[e] = envv;
  float mask = (d==0.f)?0.f:1.f;
  const float SQ2 = 1.41421356237309515f;
  const float PIf = 3.14159265358979323846f;
  float* xr = x72 + (size_t)e*72;
#pragma unroll
  for (int n=1;n<=8;n++)
    xr[n-1] = SQ2 * sinf((float)n*PIf*dd)*invd*envv*mask;
  int sp_s = species[senders[e]], sp_r = species[receivers[e]];
  const float* es_ = emb + (size_t)sp_s*32;
  const float* er_ = emb + (size_t)sp_r*32;
#pragma unroll 8
  for (int k=0;k<32;k++){ xr[8+k] = es_[k]*mask; xr[40+k] = er_[k]*mask; }
  float x2=x*x, y2=y*y, z2=z*z;
  const float s3=1.7320508075688772f, s15=3.872983346207417f, s5=2.23606797749979f;
  const float s358=2.0916500663351889f, s105=10.246950765959598f;
  const float s218=1.6201851746019651f, s7=2.6457513110645907f;
  float* Yr = Yb + ((size_t)e<<4);
  Yr[0]=1.f;           Yr[1]=s3*y;          Yr[2]=s3*z;           Yr[3]=s3*x;
  Yr[4]=s15*x*y;       Yr[5]=s15*y*z;       Yr[6]=0.5f*s5*(3.f*z2-1.f);
  Yr[7]=s15*x*z;       Yr[8]=0.5f*s15*(x2-y2);
  Yr[9]=s358*y*(3.f*x2-y2);  Yr[10]=s105*x*y*z;  Yr[11]=s218*y*(5.f*z2-1.f);
  Yr[12]=0.5f*s7*(5.f*z2-3.f)*z;  Yr[13]=s218*x*(5.f*z2-1.f);
  Yr[14]=0.5f*s105*(x2-y2)*z;     Yr[15]=s358*x*(x2-y2);
}

// ---- sort-based node accumulation ----
__global__ void hist_k(const int* __restrict__ senders, int* cnt){
  int e = blockIdx.x*256 + threadIdx.x;
  atomicAdd(&cnt[senders[e]], 1);
}

__global__ void scan_k(const int* __restrict__ cnt, int* __restrict__ starts,
                       int* __restrict__ cursor){
  __shared__ int s[NNODES];
  const int tid = threadIdx.x;
  for (int i = tid; i < NNODES; i += 256) s[i] = cnt[i];
  __syncthreads();
  if (tid == 0) {
    int run = 0;
    for (int i = 0; i < NNODES; i++) { int c = s[i]; s[i] = run; run += c; }
  }
  __syncthreads();
  for (int i = tid; i < NNODES; i += 256) { starts[i] = s[i]; cursor[i] = s[i]; }
  if (tid == 0) starts[NNODES] = E_EDGES;
}

__global__ void perm_k(const int* __restrict__ senders, int* cursor,
                       int* __restrict__ perm){
  int e = blockIdx.x*256 + threadIdx.x;
  int pos = atomicAdd(&cursor[senders[e]], 1);
  perm[pos] = e;
}

// node[n][a*16+m] = sum_{e: senders[e]==n} w[e][m]*Y[e][a]; block per node.
__global__ __launch_bounds__(256) void nodesum_k(const float* __restrict__ w,
    const float* __restrict__ Y, const int* __restrict__ perm,
    const int* __restrict__ starts, float* __restrict__ node)
{
  __shared__ float buf[8*32];
  const int n = blockIdx.x;
  const int tid = threadIdx.x;
  const int s0 = starts[n], s1 = starts[n+1];
  const int a = tid >> 4, m = tid & 15;
  float acc = 0.f;
  for (int i = s0; i < s1; i += 8) {
    int nb = s1 - i; if (nb > 8) nb = 8;
    int slot = tid >> 5, comp = tid & 31;
    if (slot < nb) {
      int e = perm[i + slot];
      buf[slot*32 + comp] = (comp < 16) ? w[(e<<4)+comp] : Y[(e<<4)+comp-16];
    }
    __syncthreads();
    for (int q = 0; q < nb; q++)
      acc += buf[q*32 + m] * buf[q*32 + 16 + a];
    __syncthreads();
  }
  node[((size_t)n<<8) + tid] = acc;
}

// l3=0 TP standalone (layer 2); B = Vn fp16
__global__ void tp2_k(const float* __restrict__ node, const unsigned short* __restrict__ Vn,
    const int* __restrict__ senders, const float* __restrict__ varepsp,
    const int* __restrict__ pmeta, const int* __restrict__ entIJ,
    const float* __restrict__ entVal, unsigned short* __restrict__ tp0)
{
  const int gid = blockIdx.x*256 + threadIdx.x;
  const int e = gid >> 6, c = gid & 63;
  const int p = c >> 4, m = c & 15;
  float ve = varepsp[0];
  float eps = rsqrtf(1.f + ve*ve);
  int s = senders[e];
  const float* Am = &node[((size_t)s<<8)];
  const unsigned short* Bm = &Vn[((size_t)e<<8)];
  int es = pmeta[p*4+1], ec = pmeta[p*4+2];
  float acc = 0.f;
  for (int t=0;t<ec;t++){
    int ij = entIJ[es+t];
    acc += entVal[es+t] * Am[((ij&255)<<4) + m] * h2f(Bm[(((ij>>8)&255)<<4) + m]);
  }
  tp0[((size_t)e<<6) + pmeta[p*4+0] + m] = f2h(acc * eps);
}

// ============================ host launcher ============================

extern "C" void kernel_launch(void* const* d_in, const int* in_sizes, int n_in,
                              void* d_out, int out_size, void* d_ws, size_t ws_size,
                              hipStream_t stream)
{
  const float* vectors = (const float*)d_in[0];
  const float* vareps  = (const float*)d_in[1];
  const float* alpha   = (const float*)d_in[2];
  const float* emb     = (const float*)d_in[3];
  const float* W_tb1   = (const float*)d_in[4];
  const float* W_tb2   = (const float*)d_in[5];
  const float* W_tb3   = (const float*)d_in[6];
  const float* W_tb4   = (const float*)d_in[7];
  const float* W_w0    = (const float*)d_in[8];
  const float* W_w1    = (const float*)d_in[9];
  const float* W_l11   = (const float*)d_in[10];
  const float* W_l12   = (const float*)d_in[11];
  const float* W_l13   = (const float*)d_in[12];
  const float* W_v1    = (const float*)d_in[13];
  const float* W_v2    = (const float*)d_in[14];
  const float* W_v3    = (const float*)d_in[15];
  const float* W_w2    = (const float*)d_in[16];
  const float* W_l21   = (const float*)d_in[17];
  const float* W_l22   = (const float*)d_in[18];
  const float* W_l23   = (const float*)d_in[19];
  const float* W_h     = (const float*)d_in[20];
  const float* W_out   = (const float*)d_in[21];
  const int* senders   = (const int*)d_in[22];
  const int* receivers = (const int*)d_in[23];
  const int* species   = (const int*)d_in[24];

  static cgt::Tables tb;
  cgt::build(tb);
  const int Kdim = tb.npairs * 16;

  char* ws = (char*)d_ws;
  size_t off = 0;
  auto alloc = [&](size_t bytes)->void*{
    void* p = ws + off; off += (bytes + 255) & ~(size_t)255; return p;
  };
  float* t_val = (float*)alloc(sizeof(tb.val));
  int*   t_ij  = (int*)  alloc(sizeof(tb.ij));
  int*   t_pm  = (int*)  alloc(sizeof(tb.pmeta));
  float* t_td  = (float*)alloc(sizeof(tb.TD));
  int*   t_pr  = (int*)  alloc(sizeof(tb.pairs));
  int*   t_oc  = (int*)  alloc(sizeof(tb.sl_origc));
  float* envb  = (float*)alloc((size_t)E_EDGES*4);
  float* Yb    = (float*)alloc((size_t)E_EDGES*16*4);
  float* xb    = (float*)alloc((size_t)E_EDGES*256*4);
  float* Vb    = (float*)alloc((size_t)E_EDGES*256*4);
  float* bufA  = (float*)alloc((size_t)E_EDGES*72*4);
  float* wb    = (float*)alloc((size_t)E_EDGES*16*4);
  float* tp0b  = (float*)alloc((size_t)E_EDGES*64*4);
  float* nodeb = (float*)alloc((size_t)NNODES*256*4);
  float* hcb   = (float*)alloc(256*4);
  int* cntb    = (int*)alloc(NNODES*4);
  int* startsb = (int*)alloc((NNODES+1)*4);
  int* cursorb = (int*)alloc(NNODES*4);
  int* permb   = (int*)alloc(E_EDGES*4);
  unsigned short* Gt = (unsigned short*)alloc((size_t)256*Kdim*2);
  unsigned short* Wt_tb1 = (unsigned short*)alloc(32*72*2);
  unsigned short* Wt_tb2 = (unsigned short*)alloc(64*32*2);
  unsigned short* Wt_tb3 = (unsigned short*)alloc(128*64*2);
  unsigned short* Wt_tb4 = (unsigned short*)alloc(256*128*2);
  unsigned short* Wt_w01 = (unsigned short*)alloc(32*256*2);
  unsigned short* Wt_w2  = (unsigned short*)alloc(16*256*2);
  unsigned short* Wt_l11 = (unsigned short*)alloc(320*256*2);
  unsigned short* Wt_l12 = (unsigned short*)alloc(256*256*2);
  unsigned short* Wt_l13 = (unsigned short*)alloc(256*256*2);
  unsigned short* Wt_l21 = (unsigned short*)alloc(320*256*2);
  unsigned short* Wt_l22 = (unsigned short*)alloc(256*256*2);
  unsigned short* Wt_l23 = (unsigned short*)alloc(256*256*2);
  if (off > ws_size) {
    fprintf(stderr, "[allegro] workspace too small: need %zu, have %zu\n", off, ws_size);
    return;
  }
  unsigned short* xb16 = (unsigned short*)xb;
  unsigned short* tp016 = (unsigned short*)tp0b;
  unsigned short* V16 = (unsigned short*)Vb;

  hipMemcpyAsync(t_val, tb.val,     sizeof(tb.val),     hipMemcpyHostToDevice, stream);
  hipMemcpyAsync(t_ij,  tb.ij,      sizeof(tb.ij),      hipMemcpyHostToDevice, stream);
  hipMemcpyAsync(t_pm,  tb.pmeta,   sizeof(tb.pmeta),   hipMemcpyHostToDevice, stream);
  hipMemcpyAsync(t_td,  tb.TD,      sizeof(tb.TD),      hipMemcpyHostToDevice, stream);
  hipMemcpyAsync(t_pr,  tb.pairs,   sizeof(tb.pairs),   hipMemcpyHostToDevice, stream);
  hipMemcpyAsync(t_oc,  tb.sl_origc,sizeof(tb.sl_origc),hipMemcpyHostToDevice, stream);

  const int s1b = tb.l3np[0];
  const int s1e = s1b + tb.l3np[1];
  const int s2e = s1e + tb.l3np[2];
  const int s3e = s2e + tb.l3np[3];

  {
    dim3 g((Kdim + 255)/256, 256);
    gbuild_k<<<g, 256, 0, stream>>>(t_td, W_v1, W_v2, W_v3, t_oc, Gt, Kdim,
                                    tb.npairs, s1b, s1e, s2e, s3e);
  }
  {
    WPack p;
    p.d[0]  = { W_tb1, Wt_tb1,  72, 5 };
    p.d[1]  = { W_tb2, Wt_tb2,  32, 6 };
    p.d[2]  = { W_tb3, Wt_tb3,  64, 7 };
    p.d[3]  = { W_tb4, Wt_tb4, 128, 8 };
    p.d[4]  = { W_l11, Wt_l11, 320, 8 };
    p.d[5]  = { W_l12, Wt_l12, 256, 8 };
    p.d[6]  = { W_l13, Wt_l13, 256, 8 };
    p.d[7]  = { W_l21, Wt_l21, 320, 8 };
    p.d[8]  = { W_l22, Wt_l22, 256, 8 };
    p.d[9]  = { W_l23, Wt_l23, 256, 8 };
    p.d[10] = { W_w2,  Wt_w2,  256, 4 };
    dim3 g(320, 11);
    wcvt_k<<<g, 256, 0, stream>>>(p);
  }
  wcvt01_k<<<32, 256, 0, stream>>>(W_w0, W_w1, Wt_w01);
  whc_k<<<1, 256, 0, stream>>>(W_h, W_out, hcb);

  // edge->node sort (once; senders fixed for both layers)
  hipMemsetAsync(cntb, 0, NNODES*4, stream);
  hist_k<<<E_EDGES/256, 256, 0, stream>>>(senders, cntb);
  scan_k<<<1, 256, 0, stream>>>(cntb, startsb, cursorb);
  perm_k<<<E_EDGES/256, 256, 0, stream>>>(senders, cursorb, permb);

  // 1. edge features + Y + env  (x72 -> bufA fp32)
  edge_init_k<<<E_EDGES/256, 256, 0, stream>>>(vectors, senders, receivers, species,
                                               emb, envb, Yb, bufA);
  // 2+3. fused two-body MLP + w0/w1 + V init
  tb_fused_k<<<E_EDGES/64, 256, 0, stream>>>(bufA, Wt_tb1, Wt_tb2, Wt_tb3, Wt_tb4,
                                             Wt_w01, Yb, envb, xb16, V16, wb);

  // ---- layer 1 ----
  nodesum_k<<<NNODES, 256, 0, stream>>>(wb, Yb, permb, startsb, nodeb);
  vn_k<<<E_EDGES/VN_E, 512, 0, stream>>>(nodeb, V16, senders, vareps, t_pr, Gt,
                                         V16, Kdim, t_pm, t_ij, t_val, tp016);
  mlp3_k<0><<<E_EDGES/128, 512, 0, stream>>>(xb16, tp016, Wt_l11, Wt_l12, Wt_l13,
                                             xb16, envb, alpha, Wt_w2, wb,
                                             nullptr, nullptr);

  // ---- layer 2 (lmax_out = 0): w2 already in wb from mlp3<0> ----
  nodesum_k<<<NNODES, 256, 0, stream>>>(wb, Yb, permb, startsb, nodeb);
  tp2_k<<<E_EDGES*64/256, 256, 0, stream>>>(nodeb, V16, senders, vareps, t_pm, t_ij,
                                            t_val, tp016);
  mlp3_k<1><<<E_EDGES/128, 512, 0, stream>>>(xb16, tp016, Wt_l21, Wt_l22, Wt_l23,
                                             nullptr, envb, alpha, nullptr, nullptr,
                                             hcb, (float*)d_out);
}